// Round 1
// baseline (2425.878 us; speedup 1.0000x reference)
//
#include <hip/hip_runtime.h>
#include <hip/hip_bf16.h>
#include <float.h>

// Problem constants
static constexpr int BB  = 4;
static constexpr int NN  = 4096;
static constexpr int KSN = 16;
static constexpr int RN  = BB * NN;     // 16384 rows (b,n)
#define EPSBN 1e-5f

// ---------------------------------------------------------------------------
// KNN: per batch, top-16 smallest d2 = sq_i + sq_j - 2*dot. 64 thr/block,
// 256 blocks (B=4 x 64 tiles). pts + sq staged in LDS (64 KB).
// ---------------------------------------------------------------------------
__global__ __launch_bounds__(64) void knn_kernel(const float* __restrict__ data,
                                                 int* __restrict__ idx) {
  __shared__ float px[NN], py[NN], pz[NN], sq[NN];
  const int b    = blockIdx.x >> 6;
  const int tile = blockIdx.x & 63;
  const int t    = threadIdx.x;
  const float* db = data + (size_t)b * NN * 9;
  for (int j = t; j < NN; j += 64) {
    float x = db[j * 9 + 0], y = db[j * 9 + 1], z = db[j * 9 + 2];
    px[j] = x; py[j] = y; pz[j] = z;
    sq[j] = x * x + y * y + z * z;
  }
  __syncthreads();
  const int i = tile * 64 + t;
  const float xi = px[i], yi = py[i], zi = pz[i], si = sq[i];
  float dist[KSN];
  int   ind[KSN];
#pragma unroll
  for (int s = 0; s < KSN; ++s) { dist[s] = FLT_MAX; ind[s] = 0; }
  for (int j = 0; j < NN; ++j) {
    float d = si + sq[j] - 2.0f * (xi * px[j] + yi * py[j] + zi * pz[j]);
    if (d < dist[KSN - 1]) {
      float dj = d; int jj = j;
#pragma unroll
      for (int s = 0; s < KSN; ++s) {     // bubble insert, static indices only
        bool lt = dj < dist[s];
        float td = dist[s]; int ti = ind[s];
        dist[s] = lt ? dj : td; ind[s] = lt ? jj : ti;
        dj = lt ? td : dj;      jj = lt ? ti : jj;
      }
    }
  }
  int* op = idx + (size_t)(b * NN + i) * KSN;
#pragma unroll
  for (int s = 0; s < KSN; ++s) op[s] = ind[s];
}

// ---------------------------------------------------------------------------
// fc: y = data @ W_fc + b_fc   (K=9, C=64), accumulate column stats.
// ---------------------------------------------------------------------------
__global__ __launch_bounds__(256) void fc_kernel(const float* __restrict__ data,
                                                 const float* __restrict__ W,
                                                 const float* __restrict__ bias,
                                                 float* __restrict__ y,
                                                 float* __restrict__ stats) {
  const int t = blockIdx.x * 256 + threadIdx.x;  // t < RN*64
  const int r = t >> 6, c = t & 63;
  const float* dr = data + (size_t)r * 9;
  float acc = bias[c];
#pragma unroll
  for (int k = 0; k < 9; ++k) acc = fmaf(dr[k], W[k * 64 + c], acc);
  y[t] = acc;
  __shared__ float red[256];
  red[threadIdx.x] = acc;
  __syncthreads();
  if (threadIdx.x < 64) {
    float s = red[threadIdx.x] + red[threadIdx.x + 64] + red[threadIdx.x + 128] + red[threadIdx.x + 192];
    atomicAdd(&stats[threadIdx.x], s);
  }
  __syncthreads();
  red[threadIdx.x] = acc * acc;
  __syncthreads();
  if (threadIdx.x < 64) {
    float s = red[threadIdx.x] + red[threadIdx.x + 64] + red[threadIdx.x + 128] + red[threadIdx.x + 192];
    atomicAdd(&stats[64 + threadIdx.x], s);
  }
}

// ---------------------------------------------------------------------------
// BN(+ReLU) normalize in place. stats = [sum[C], sumsq[C]].
// ---------------------------------------------------------------------------
__global__ void bn_norm_kernel(float* __restrict__ buf, const float* __restrict__ stats,
                               int cmask, int C, float inv_cnt, int total) {
  int t = blockIdx.x * 256 + threadIdx.x;
  if (t >= total) return;
  int c = t & cmask;
  float m = stats[c] * inv_cnt;
  float v = fmaxf(stats[C + c] * inv_cnt - m * m, 0.0f);
  float rs = rsqrtf(v + EPSBN);
  float x = (buf[t] - m) * rs;
  buf[t] = fmaxf(x, 0.0f);
}

// ---------------------------------------------------------------------------
// Edge conv: per point build e = [c | nb-c | (ptsdiff)] and h = e @ W (C=256),
// max over 16 neighbors, column stats over all (b,n,k). Block = 256 thr
// (1 col each), 16 points per block. bn_relu+max commute (monotone per-chan).
// ---------------------------------------------------------------------------
template <bool HAS_PTS>
__global__ __launch_bounds__(256) void edge_conv_kernel(const float* __restrict__ X,
                                                        const int* __restrict__ idx,
                                                        const float* __restrict__ data,
                                                        const float* __restrict__ W,
                                                        float* __restrict__ out,
                                                        float* __restrict__ stats) {
  __shared__ float c_lds[64];
  __shared__ float nb_lds[16][64];
  __shared__ float dp_lds[16][3];
  __shared__ int   j_lds[16];
  const int t  = threadIdx.x;
  const int p0 = blockIdx.x * 16;
  float s1 = 0.0f, s2 = 0.0f;
  for (int p = 0; p < 16; ++p) {
    const int pt = p0 + p;
    const int b  = pt >> 12;
    if (t < 16) j_lds[t] = idx[(size_t)pt * KSN + t];
    if (t < 64) c_lds[t] = X[(size_t)pt * 64 + t];
    __syncthreads();
#pragma unroll
    for (int i = 0; i < 4; ++i) {
      int e = t + i * 256;
      int kk = e >> 6, k = e & 63;
      nb_lds[kk][k] = X[(size_t)((b << 12) + j_lds[kk]) * 64 + k] - c_lds[k];
    }
    if (HAS_PTS && t < 48) {
      int kk = t / 3, k = t - kk * 3;
      dp_lds[kk][k] = data[(size_t)((b << 12) + j_lds[kk]) * 9 + k] - data[(size_t)pt * 9 + k];
    }
    __syncthreads();
    // center contribution shared across all 16 neighbor rows
    float base = 0.0f;
    for (int k = 0; k < 64; ++k) base = fmaf(c_lds[k], W[k * 256 + t], base);
    float h[16];
#pragma unroll
    for (int kk = 0; kk < 16; ++kk) h[kk] = base;
    for (int k = 0; k < 64; ++k) {
      float w = W[(64 + k) * 256 + t];
#pragma unroll
      for (int kk = 0; kk < 16; ++kk) h[kk] = fmaf(nb_lds[kk][k], w, h[kk]);
    }
    if (HAS_PTS) {
#pragma unroll
      for (int k = 0; k < 3; ++k) {
        float w = W[(128 + k) * 256 + t];
#pragma unroll
        for (int kk = 0; kk < 16; ++kk) h[kk] = fmaf(dp_lds[kk][k], w, h[kk]);
      }
    }
    float mx = -FLT_MAX;
#pragma unroll
    for (int kk = 0; kk < 16; ++kk) {
      s1 += h[kk];
      s2 = fmaf(h[kk], h[kk], s2);
      mx = fmaxf(mx, h[kk]);
    }
    out[(size_t)pt * 256 + t] = mx;
    __syncthreads();
  }
  atomicAdd(&stats[t], s1);
  atomicAdd(&stats[256 + t], s2);
}

// ---------------------------------------------------------------------------
// agg[r,c] = max over 16 neighbors of X[(b,j),c], float4 per thread.
// lg = log2(C/4).
// ---------------------------------------------------------------------------
__global__ void agg_kernel(const float* __restrict__ X, const int* __restrict__ idx,
                           float* __restrict__ out, int lg) {
  const int c4 = 1 << lg;
  int t = blockIdx.x * 256 + threadIdx.x;
  int total = RN * c4;
  if (t >= total) return;
  int r = t >> lg, cq = t & (c4 - 1);
  int base = (r >> 12) << 12;
  const int* ip = idx + (size_t)r * KSN;
  float4 mx = make_float4(-FLT_MAX, -FLT_MAX, -FLT_MAX, -FLT_MAX);
  const int C = c4 * 4;
#pragma unroll
  for (int k = 0; k < KSN; ++k) {
    int j = ip[k];
    const float4 v = *reinterpret_cast<const float4*>(X + (size_t)(base + j) * C + cq * 4);
    mx.x = fmaxf(mx.x, v.x); mx.y = fmaxf(mx.y, v.y);
    mx.z = fmaxf(mx.z, v.z); mx.w = fmaxf(mx.w, v.w);
  }
  *reinterpret_cast<float4*>(out + (size_t)r * C + cq * 4) = mx;
}

// ---------------------------------------------------------------------------
// Tiled fp32 GEMM Y = A @ W (A: RN x K row-major, W: K x C row-major)
// BM=BN=64, BK=16, 256 thr, 4x4 per thread. Column stats always accumulated.
// MODE 0: A from buffer.  MODE 2: A = [x1|x2] (K=128).  MODE 3: A = [g|x1|x2].
// DOMAX: skip Y write; write per-row-tile column max to pmax (for g = max_n).
// ---------------------------------------------------------------------------
template <int MODE, bool DOMAX>
__global__ __launch_bounds__(256) void gemm_kernel(const float* __restrict__ A,
                                                   const float* __restrict__ px1,
                                                   const float* __restrict__ px2,
                                                   const float* __restrict__ pg,
                                                   const float* __restrict__ W,
                                                   float* __restrict__ Y,
                                                   float* __restrict__ pmax,
                                                   float* __restrict__ stats,
                                                   int K, int C) {
  __shared__ float a_lds[16][65];
  __shared__ float b_lds[16][64];
  __shared__ float red[64 * 17];
  const int t  = threadIdx.x;
  const int r0 = blockIdx.x * 64, c0 = blockIdx.y * 64;
  const int tr = t >> 4, tc = t & 15;
  float acc[4][4] = {{0.f}};
  for (int k0 = 0; k0 < K; k0 += 16) {
#pragma unroll
    for (int i = 0; i < 4; ++i) {
      int e = t + i * 256;
      int ar = e >> 4, ak = e & 15;
      int rr = r0 + ar, kk = k0 + ak;
      float v;
      if (MODE == 0) {
        v = A[(size_t)rr * K + kk];
      } else if (MODE == 2) {
        v = (kk < 64) ? px1[(size_t)rr * 64 + kk] : px2[(size_t)rr * 64 + kk - 64];
      } else {
        int b = rr >> 12;
        v = (kk < 1024) ? pg[b * 1024 + kk]
            : (kk < 1088 ? px1[(size_t)rr * 64 + kk - 1024]
                         : px2[(size_t)rr * 64 + kk - 1088]);
      }
      a_lds[ak][ar] = v;
    }
#pragma unroll
    for (int i = 0; i < 4; ++i) {
      int e = t + i * 256;
      int bk = e >> 6, bc = e & 63;
      b_lds[bk][bc] = W[(size_t)(k0 + bk) * C + c0 + bc];
    }
    __syncthreads();
#pragma unroll
    for (int k = 0; k < 16; ++k) {
      float av[4], bv[4];
#pragma unroll
      for (int i = 0; i < 4; ++i) av[i] = a_lds[k][tr * 4 + i];
#pragma unroll
      for (int j = 0; j < 4; ++j) bv[j] = b_lds[k][tc * 4 + j];
#pragma unroll
      for (int i = 0; i < 4; ++i)
#pragma unroll
        for (int j = 0; j < 4; ++j) acc[i][j] = fmaf(av[i], bv[j], acc[i][j]);
    }
    __syncthreads();
  }
  if (!DOMAX) {
#pragma unroll
    for (int i = 0; i < 4; ++i) {
      int rr = r0 + tr * 4 + i;
#pragma unroll
      for (int j = 0; j < 4; ++j) Y[(size_t)rr * C + c0 + tc * 4 + j] = acc[i][j];
    }
  }
  float s1[4] = {0.f, 0.f, 0.f, 0.f}, s2[4] = {0.f, 0.f, 0.f, 0.f};
#pragma unroll
  for (int i = 0; i < 4; ++i)
#pragma unroll
    for (int j = 0; j < 4; ++j) {
      s1[j] += acc[i][j];
      s2[j] = fmaf(acc[i][j], acc[i][j], s2[j]);
    }
#pragma unroll
  for (int j = 0; j < 4; ++j) red[(tc * 4 + j) * 17 + tr] = s1[j];
  __syncthreads();
  if (t < 64) {
    float s = 0.f;
    for (int q = 0; q < 16; ++q) s += red[t * 17 + q];
    atomicAdd(&stats[c0 + t], s);
  }
  __syncthreads();
#pragma unroll
  for (int j = 0; j < 4; ++j) red[(tc * 4 + j) * 17 + tr] = s2[j];
  __syncthreads();
  if (t < 64) {
    float s = 0.f;
    for (int q = 0; q < 16; ++q) s += red[t * 17 + q];
    atomicAdd(&stats[C + c0 + t], s);
  }
  if (DOMAX) {
    __syncthreads();
    float m[4];
#pragma unroll
    for (int j = 0; j < 4; ++j) {
      m[j] = fmaxf(fmaxf(acc[0][j], acc[1][j]), fmaxf(acc[2][j], acc[3][j]));
      red[(tc * 4 + j) * 17 + tr] = m[j];
    }
    __syncthreads();
    if (t < 64) {
      float mm = -FLT_MAX;
      for (int q = 0; q < 16; ++q) mm = fmaxf(mm, red[t * 17 + q]);
      pmax[(size_t)blockIdx.x * C + c0 + t] = mm;
    }
  }
}

// g[b,c] = relu((max over 64 row-tiles of pmax - m) * rsqrt(v+eps))
__global__ void fin_g_kernel(const float* __restrict__ pmax, const float* __restrict__ stats,
                             float* __restrict__ g) {
  int t = blockIdx.x * 256 + threadIdx.x;  // 4096 threads
  int b = t >> 10, c = t & 1023;
  const float inv = 1.0f / 16384.0f;
  float m = stats[c] * inv;
  float v = fmaxf(stats[1024 + c] * inv - m * m, 0.0f);
  float rs = rsqrtf(v + EPSBN);
  float mx = -FLT_MAX;
  for (int s = 0; s < 64; ++s) mx = fmaxf(mx, pmax[(size_t)(b * 64 + s) * 1024 + c]);
  g[t] = fmaxf((mx - m) * rs, 0.0f);
}

// out[b,c,n] = sum_k h[b,n,k] * W13[k,c]
__global__ void final13_kernel(const float* __restrict__ h, const float* __restrict__ W,
                               float* __restrict__ out) {
  int t = blockIdx.x * 256 + threadIdx.x;
  if (t >= RN * 13) return;
  int r = t / 13, c = t - r * 13;
  float acc = 0.0f;
  for (int k = 0; k < 256; ++k) acc = fmaf(h[(size_t)r * 256 + k], W[k * 13 + c], acc);
  int b = r >> 12, n = r & 4095;
  out[(size_t)b * 13 * NN + (size_t)c * NN + n] = acc;
}

// ---------------------------------------------------------------------------
extern "C" void kernel_launch(void* const* d_in, const int* in_sizes, int n_in,
                              void* d_out, int out_size, void* d_ws, size_t ws_size,
                              hipStream_t stream) {
  (void)in_sizes; (void)n_in; (void)out_size; (void)ws_size;
  const float* data = (const float*)d_in[0];
  const float* W_fc = (const float*)d_in[1];
  const float* b_fc = (const float*)d_in[2];
  const float* W1   = (const float*)d_in[3];
  const float* W2   = (const float*)d_in[4];
  const float* W3   = (const float*)d_in[5];
  const float* W4   = (const float*)d_in[6];
  const float* W5   = (const float*)d_in[7];
  const float* W6   = (const float*)d_in[8];
  const float* W10  = (const float*)d_in[9];
  const float* W11  = (const float*)d_in[10];
  const float* W12  = (const float*)d_in[11];
  const float* W13  = (const float*)d_in[12];
  float* out = (float*)d_out;

  float* ws  = (float*)d_ws;
  int*   idx = (int*)d_ws;                   // 262144 ints
  size_t o = 262144;
  float* x0   = ws + o; o += (size_t)RN * 64;
  float* x1v  = ws + o; o += (size_t)RN * 64;
  float* x2v  = ws + o; o += (size_t)RN * 64;
  float* bufA = ws + o; o += (size_t)RN * 256;
  float* bufB = ws + o; o += (size_t)RN * 256;
  float* bufC = ws + o; o += (size_t)RN * 64;
  float* gbuf = ws + o; o += 4096;
  float* pmax = ws + o; o += (size_t)256 * 1024;
  float* h11  = ws + o; o += (size_t)RN * 512;
  float* h12  = ws + o; o += (size_t)RN * 256;
  float* stats = ws + o; o += 8192;

  float* S0 = stats;          // 64 cols  (fc)
  float* S1 = stats + 128;    // 256 (edge1)
  float* S2 = stats + 640;    // 64  (W2)
  float* S3 = stats + 768;    // 64  (W3)
  float* S4 = stats + 896;    // 256 (edge2)
  float* S5 = stats + 1408;   // 64  (W5)
  float* S6 = stats + 1536;   // 64  (W6)
  float* S7 = stats + 1664;   // 1024 (W10)
  float* S8 = stats + 3712;   // 512 (W11)
  float* S9 = stats + 4736;   // 256 (W12)

  hipMemsetAsync(stats, 0, 5248 * sizeof(float), stream);

  knn_kernel<<<256, 64, 0, stream>>>(data, idx);

  fc_kernel<<<RN * 64 / 256, 256, 0, stream>>>(data, W_fc, b_fc, x0, S0);
  bn_norm_kernel<<<RN * 64 / 256, 256, 0, stream>>>(x0, S0, 63, 64, 1.0f / RN, RN * 64);

  edge_conv_kernel<true><<<RN / 16, 256, 0, stream>>>(x0, idx, data, W1, bufA, S1);
  bn_norm_kernel<<<RN * 256 / 256, 256, 0, stream>>>(bufA, S1, 255, 256, 1.0f / (RN * 16), RN * 256);

  agg_kernel<<<RN * 64 / 256, 256, 0, stream>>>(bufA, idx, bufB, 6);
  gemm_kernel<0, false><<<dim3(256, 1), 256, 0, stream>>>(bufB, nullptr, nullptr, nullptr, W2, bufC, nullptr, S2, 256, 64);
  bn_norm_kernel<<<RN * 64 / 256, 256, 0, stream>>>(bufC, S2, 63, 64, 1.0f / RN, RN * 64);

  agg_kernel<<<RN * 16 / 256, 256, 0, stream>>>(bufC, idx, bufB, 4);
  gemm_kernel<0, false><<<dim3(256, 1), 256, 0, stream>>>(bufB, nullptr, nullptr, nullptr, W3, x1v, nullptr, S3, 64, 64);
  bn_norm_kernel<<<RN * 64 / 256, 256, 0, stream>>>(x1v, S3, 63, 64, 1.0f / RN, RN * 64);

  edge_conv_kernel<false><<<RN / 16, 256, 0, stream>>>(x1v, idx, data, W4, bufA, S4);
  bn_norm_kernel<<<RN * 256 / 256, 256, 0, stream>>>(bufA, S4, 255, 256, 1.0f / (RN * 16), RN * 256);

  agg_kernel<<<RN * 64 / 256, 256, 0, stream>>>(bufA, idx, bufB, 6);
  gemm_kernel<0, false><<<dim3(256, 1), 256, 0, stream>>>(bufB, nullptr, nullptr, nullptr, W5, bufC, nullptr, S5, 256, 64);
  bn_norm_kernel<<<RN * 64 / 256, 256, 0, stream>>>(bufC, S5, 63, 64, 1.0f / RN, RN * 64);

  agg_kernel<<<RN * 16 / 256, 256, 0, stream>>>(bufC, idx, bufB, 4);
  gemm_kernel<0, false><<<dim3(256, 1), 256, 0, stream>>>(bufB, nullptr, nullptr, nullptr, W6, x2v, nullptr, S6, 64, 64);
  bn_norm_kernel<<<RN * 64 / 256, 256, 0, stream>>>(x2v, S6, 63, 64, 1.0f / RN, RN * 64);

  // W10 path: stats + per-row-tile max only (y never materialized)
  gemm_kernel<2, true><<<dim3(256, 16), 256, 0, stream>>>(nullptr, x1v, x2v, nullptr, W10, nullptr, pmax, S7, 128, 1024);
  fin_g_kernel<<<16, 256, 0, stream>>>(pmax, S7, gbuf);

  gemm_kernel<3, false><<<dim3(256, 8), 256, 0, stream>>>(nullptr, x1v, x2v, gbuf, W11, h11, nullptr, S8, 1152, 512);
  bn_norm_kernel<<<RN * 512 / 256, 256, 0, stream>>>(h11, S8, 511, 512, 1.0f / RN, RN * 512);

  gemm_kernel<0, false><<<dim3(256, 4), 256, 0, stream>>>(h11, nullptr, nullptr, nullptr, W12, h12, nullptr, S9, 512, 256);
  bn_norm_kernel<<<RN * 256 / 256, 256, 0, stream>>>(h12, S9, 255, 256, 1.0f / RN, RN * 256);

  final13_kernel<<<(RN * 13 + 255) / 256, 256, 0, stream>>>(h12, W13, out);
}

// Round 2
// 2061.664 us; speedup vs baseline: 1.1767x; 1.1767x over previous
//
#include <hip/hip_runtime.h>
#include <hip/hip_bf16.h>
#include <float.h>

// Problem constants
static constexpr int BB  = 4;
static constexpr int NN  = 4096;
static constexpr int KSN = 16;
static constexpr int RN  = BB * NN;     // 16384 rows (b,n)
#define EPSBN 1e-5f

// ---------------------------------------------------------------------------
// Prep: pack (x,y,z,|p|^2) as float4 per point. 64 KB per batch -> L2.
// ---------------------------------------------------------------------------
__global__ void prep_kernel(const float* __restrict__ data, float4* __restrict__ pack) {
  int t = blockIdx.x * 256 + threadIdx.x;
  if (t >= RN) return;
  const float* dr = data + (size_t)t * 9;
  float x = dr[0], y = dr[1], z = dr[2];
  pack[t] = make_float4(x, y, z, fmaf(z, z, fmaf(y, y, x * x)));
}

// ---------------------------------------------------------------------------
// KNN: 16 threads per point, each scans 256 contiguous j's keeping a sorted
// register top-16 (static indices only), then log2(16) pairwise merges in
// LDS (two-pointer; runtime indices hit LDS only). Order of idx is
// irrelevant downstream (gather->max), only membership matters.
// ---------------------------------------------------------------------------
__global__ __launch_bounds__(256) void knn_kernel(const float4* __restrict__ pack,
                                                  int* __restrict__ idx) {
  __shared__ float dcand[256 * 16];
  __shared__ int   icand[256 * 16];
  const int tid = threadIdx.x;
  const int pl  = tid >> 4;                 // point-local 0..15
  const int seg = tid & 15;                 // j-segment 0..15
  const int p   = blockIdx.x * 16 + pl;     // global row
  const int b   = p >> 12;
  const float4 me = pack[p];
  const float4* __restrict__ pb = pack + ((size_t)b << 12);
  float dist[16]; int ind[16];
#pragma unroll
  for (int s = 0; s < 16; ++s) { dist[s] = FLT_MAX; ind[s] = 0; }
  const int j0 = seg * 256;
#pragma unroll 4
  for (int jj = 0; jj < 256; ++jj) {
    const int j = j0 + jj;
    const float4 q = pb[j];
    float d = me.w + q.w - 2.0f * fmaf(me.x, q.x, fmaf(me.y, q.y, me.z * q.z));
    if (d < dist[15]) {
      float dj = d; int ji = j;
#pragma unroll
      for (int s = 0; s < 16; ++s) {        // bubble insert, static indices
        bool lt = dj < dist[s];
        float td = dist[s]; int ti = ind[s];
        dist[s] = lt ? dj : td; ind[s] = lt ? ji : ti;
        dj = lt ? td : dj;      ji = lt ? ti : ji;
      }
    }
  }
#pragma unroll
  for (int s = 0; s < 16; ++s) {
    dcand[tid * 16 + s] = dist[s];
    icand[tid * 16 + s] = ind[s];
  }
  __syncthreads();
  // tree merge: stride 1,2,4,8 — two-pointer merge of two sorted 16-lists
  for (int stride = 1; stride < 16; stride <<= 1) {
    if ((seg & (2 * stride - 1)) == 0) {
      const int la = tid * 16, lb = (tid + stride) * 16;
      float od[16]; int oi[16];
      int ia = 0, ib = 0;
#pragma unroll
      for (int s = 0; s < 16; ++s) {
        float da = dcand[la + ia], db = dcand[lb + ib];
        bool ta = (da <= db);
        od[s] = ta ? da : db;
        oi[s] = ta ? icand[la + ia] : icand[lb + ib];
        ia += ta; ib += !ta;
      }
#pragma unroll
      for (int s = 0; s < 16; ++s) { dcand[la + s] = od[s]; icand[la + s] = oi[s]; }
    }
    __syncthreads();
  }
  if (seg == 0) {
    int* op = idx + (size_t)p * KSN;
#pragma unroll
    for (int s = 0; s < 16; ++s) op[s] = icand[tid * 16 + s];
  }
}

// ---------------------------------------------------------------------------
// fc: y = data @ W_fc + b_fc   (K=9, C=64), accumulate column stats.
// ---------------------------------------------------------------------------
__global__ __launch_bounds__(256) void fc_kernel(const float* __restrict__ data,
                                                 const float* __restrict__ W,
                                                 const float* __restrict__ bias,
                                                 float* __restrict__ y,
                                                 float* __restrict__ stats) {
  const int t = blockIdx.x * 256 + threadIdx.x;  // t < RN*64
  const int r = t >> 6, c = t & 63;
  const float* dr = data + (size_t)r * 9;
  float acc = bias[c];
#pragma unroll
  for (int k = 0; k < 9; ++k) acc = fmaf(dr[k], W[k * 64 + c], acc);
  y[t] = acc;
  __shared__ float red[256];
  red[threadIdx.x] = acc;
  __syncthreads();
  if (threadIdx.x < 64) {
    float s = red[threadIdx.x] + red[threadIdx.x + 64] + red[threadIdx.x + 128] + red[threadIdx.x + 192];
    atomicAdd(&stats[threadIdx.x], s);
  }
  __syncthreads();
  red[threadIdx.x] = acc * acc;
  __syncthreads();
  if (threadIdx.x < 64) {
    float s = red[threadIdx.x] + red[threadIdx.x + 64] + red[threadIdx.x + 128] + red[threadIdx.x + 192];
    atomicAdd(&stats[64 + threadIdx.x], s);
  }
}

// ---------------------------------------------------------------------------
// BN(+ReLU) normalize in place. stats = [sum[C], sumsq[C]].
// ---------------------------------------------------------------------------
__global__ void bn_norm_kernel(float* __restrict__ buf, const float* __restrict__ stats,
                               int cmask, int C, float inv_cnt, int total) {
  int t = blockIdx.x * 256 + threadIdx.x;
  if (t >= total) return;
  int c = t & cmask;
  float m = stats[c] * inv_cnt;
  float v = fmaxf(stats[C + c] * inv_cnt - m * m, 0.0f);
  float rs = rsqrtf(v + EPSBN);
  float x = (buf[t] - m) * rs;
  buf[t] = fmaxf(x, 0.0f);
}

// ---------------------------------------------------------------------------
// Edge conv: per point build e = [c | nb-c | (ptsdiff)] and h = e @ W (C=256),
// max over 16 neighbors, column stats over all (b,n,k). Block = 256 thr
// (1 col each), 16 points per block. bn_relu+max commute (monotone per-chan).
// ---------------------------------------------------------------------------
template <bool HAS_PTS>
__global__ __launch_bounds__(256) void edge_conv_kernel(const float* __restrict__ X,
                                                        const int* __restrict__ idx,
                                                        const float* __restrict__ data,
                                                        const float* __restrict__ W,
                                                        float* __restrict__ out,
                                                        float* __restrict__ stats) {
  __shared__ float c_lds[64];
  __shared__ float nb_lds[16][64];
  __shared__ float dp_lds[16][3];
  __shared__ int   j_lds[16];
  const int t  = threadIdx.x;
  const int p0 = blockIdx.x * 16;
  float s1 = 0.0f, s2 = 0.0f;
  for (int p = 0; p < 16; ++p) {
    const int pt = p0 + p;
    const int b  = pt >> 12;
    if (t < 16) j_lds[t] = idx[(size_t)pt * KSN + t];
    if (t < 64) c_lds[t] = X[(size_t)pt * 64 + t];
    __syncthreads();
#pragma unroll
    for (int i = 0; i < 4; ++i) {
      int e = t + i * 256;
      int kk = e >> 6, k = e & 63;
      nb_lds[kk][k] = X[(size_t)((b << 12) + j_lds[kk]) * 64 + k] - c_lds[k];
    }
    if (HAS_PTS && t < 48) {
      int kk = t / 3, k = t - kk * 3;
      dp_lds[kk][k] = data[(size_t)((b << 12) + j_lds[kk]) * 9 + k] - data[(size_t)pt * 9 + k];
    }
    __syncthreads();
    // center contribution shared across all 16 neighbor rows
    float base = 0.0f;
    for (int k = 0; k < 64; ++k) base = fmaf(c_lds[k], W[k * 256 + t], base);
    float h[16];
#pragma unroll
    for (int kk = 0; kk < 16; ++kk) h[kk] = base;
    for (int k = 0; k < 64; ++k) {
      float w = W[(64 + k) * 256 + t];
#pragma unroll
      for (int kk = 0; kk < 16; ++kk) h[kk] = fmaf(nb_lds[kk][k], w, h[kk]);
    }
    if (HAS_PTS) {
#pragma unroll
      for (int k = 0; k < 3; ++k) {
        float w = W[(128 + k) * 256 + t];
#pragma unroll
        for (int kk = 0; kk < 16; ++kk) h[kk] = fmaf(dp_lds[kk][k], w, h[kk]);
      }
    }
    float mx = -FLT_MAX;
#pragma unroll
    for (int kk = 0; kk < 16; ++kk) {
      s1 += h[kk];
      s2 = fmaf(h[kk], h[kk], s2);
      mx = fmaxf(mx, h[kk]);
    }
    out[(size_t)pt * 256 + t] = mx;
    __syncthreads();
  }
  atomicAdd(&stats[t], s1);
  atomicAdd(&stats[256 + t], s2);
}

// ---------------------------------------------------------------------------
// agg[r,c] = max over 16 neighbors of X[(b,j),c], float4 per thread.
// lg = log2(C/4).
// ---------------------------------------------------------------------------
__global__ void agg_kernel(const float* __restrict__ X, const int* __restrict__ idx,
                           float* __restrict__ out, int lg) {
  const int c4 = 1 << lg;
  int t = blockIdx.x * 256 + threadIdx.x;
  int total = RN * c4;
  if (t >= total) return;
  int r = t >> lg, cq = t & (c4 - 1);
  int base = (r >> 12) << 12;
  const int* ip = idx + (size_t)r * KSN;
  float4 mx = make_float4(-FLT_MAX, -FLT_MAX, -FLT_MAX, -FLT_MAX);
  const int C = c4 * 4;
#pragma unroll
  for (int k = 0; k < KSN; ++k) {
    int j = ip[k];
    const float4 v = *reinterpret_cast<const float4*>(X + (size_t)(base + j) * C + cq * 4);
    mx.x = fmaxf(mx.x, v.x); mx.y = fmaxf(mx.y, v.y);
    mx.z = fmaxf(mx.z, v.z); mx.w = fmaxf(mx.w, v.w);
  }
  *reinterpret_cast<float4*>(out + (size_t)r * C + cq * 4) = mx;
}

// ---------------------------------------------------------------------------
// Tiled fp32 GEMM Y = A @ W (A: RN x K row-major, W: K x C row-major)
// BM=BN=64, BK=16, 256 thr, 4x4 per thread. Column stats always accumulated.
// MODE 0: A from buffer.  MODE 2: A = [x1|x2] (K=128).  MODE 3: A = [g|x1|x2].
// DOMAX: skip Y write; write per-row-tile column max to pmax (for g = max_n).
// ---------------------------------------------------------------------------
template <int MODE, bool DOMAX>
__global__ __launch_bounds__(256) void gemm_kernel(const float* __restrict__ A,
                                                   const float* __restrict__ px1,
                                                   const float* __restrict__ px2,
                                                   const float* __restrict__ pg,
                                                   const float* __restrict__ W,
                                                   float* __restrict__ Y,
                                                   float* __restrict__ pmax,
                                                   float* __restrict__ stats,
                                                   int K, int C) {
  __shared__ float a_lds[16][65];
  __shared__ float b_lds[16][64];
  __shared__ float red[64 * 17];
  const int t  = threadIdx.x;
  const int r0 = blockIdx.x * 64, c0 = blockIdx.y * 64;
  const int tr = t >> 4, tc = t & 15;
  float acc[4][4] = {{0.f}};
  for (int k0 = 0; k0 < K; k0 += 16) {
#pragma unroll
    for (int i = 0; i < 4; ++i) {
      int e = t + i * 256;
      int ar = e >> 4, ak = e & 15;
      int rr = r0 + ar, kk = k0 + ak;
      float v;
      if (MODE == 0) {
        v = A[(size_t)rr * K + kk];
      } else if (MODE == 2) {
        v = (kk < 64) ? px1[(size_t)rr * 64 + kk] : px2[(size_t)rr * 64 + kk - 64];
      } else {
        int b = rr >> 12;
        v = (kk < 1024) ? pg[b * 1024 + kk]
            : (kk < 1088 ? px1[(size_t)rr * 64 + kk - 1024]
                         : px2[(size_t)rr * 64 + kk - 1088]);
      }
      a_lds[ak][ar] = v;
    }
#pragma unroll
    for (int i = 0; i < 4; ++i) {
      int e = t + i * 256;
      int bk = e >> 6, bc = e & 63;
      b_lds[bk][bc] = W[(size_t)(k0 + bk) * C + c0 + bc];
    }
    __syncthreads();
#pragma unroll
    for (int k = 0; k < 16; ++k) {
      float av[4], bv[4];
#pragma unroll
      for (int i = 0; i < 4; ++i) av[i] = a_lds[k][tr * 4 + i];
#pragma unroll
      for (int j = 0; j < 4; ++j) bv[j] = b_lds[k][tc * 4 + j];
#pragma unroll
      for (int i = 0; i < 4; ++i)
#pragma unroll
        for (int j = 0; j < 4; ++j) acc[i][j] = fmaf(av[i], bv[j], acc[i][j]);
    }
    __syncthreads();
  }
  if (!DOMAX) {
#pragma unroll
    for (int i = 0; i < 4; ++i) {
      int rr = r0 + tr * 4 + i;
#pragma unroll
      for (int j = 0; j < 4; ++j) Y[(size_t)rr * C + c0 + tc * 4 + j] = acc[i][j];
    }
  }
  float s1[4] = {0.f, 0.f, 0.f, 0.f}, s2[4] = {0.f, 0.f, 0.f, 0.f};
#pragma unroll
  for (int i = 0; i < 4; ++i)
#pragma unroll
    for (int j = 0; j < 4; ++j) {
      s1[j] += acc[i][j];
      s2[j] = fmaf(acc[i][j], acc[i][j], s2[j]);
    }
#pragma unroll
  for (int j = 0; j < 4; ++j) red[(tc * 4 + j) * 17 + tr] = s1[j];
  __syncthreads();
  if (t < 64) {
    float s = 0.f;
    for (int q = 0; q < 16; ++q) s += red[t * 17 + q];
    atomicAdd(&stats[c0 + t], s);
  }
  __syncthreads();
#pragma unroll
  for (int j = 0; j < 4; ++j) red[(tc * 4 + j) * 17 + tr] = s2[j];
  __syncthreads();
  if (t < 64) {
    float s = 0.f;
    for (int q = 0; q < 16; ++q) s += red[t * 17 + q];
    atomicAdd(&stats[C + c0 + t], s);
  }
  if (DOMAX) {
    __syncthreads();
    float m[4];
#pragma unroll
    for (int j = 0; j < 4; ++j) {
      m[j] = fmaxf(fmaxf(acc[0][j], acc[1][j]), fmaxf(acc[2][j], acc[3][j]));
      red[(tc * 4 + j) * 17 + tr] = m[j];
    }
    __syncthreads();
    if (t < 64) {
      float mm = -FLT_MAX;
      for (int q = 0; q < 16; ++q) mm = fmaxf(mm, red[t * 17 + q]);
      pmax[(size_t)blockIdx.x * C + c0 + t] = mm;
    }
  }
}

// g[b,c] = relu((max over 64 row-tiles of pmax - m) * rsqrt(v+eps))
__global__ void fin_g_kernel(const float* __restrict__ pmax, const float* __restrict__ stats,
                             float* __restrict__ g) {
  int t = blockIdx.x * 256 + threadIdx.x;  // 4096 threads
  int b = t >> 10, c = t & 1023;
  const float inv = 1.0f / 16384.0f;
  float m = stats[c] * inv;
  float v = fmaxf(stats[1024 + c] * inv - m * m, 0.0f);
  float rs = rsqrtf(v + EPSBN);
  float mx = -FLT_MAX;
  for (int s = 0; s < 64; ++s) mx = fmaxf(mx, pmax[(size_t)(b * 64 + s) * 1024 + c]);
  g[t] = fmaxf((mx - m) * rs, 0.0f);
}

// out[b,c,n] = sum_k h[b,n,k] * W13[k,c]
__global__ void final13_kernel(const float* __restrict__ h, const float* __restrict__ W,
                               float* __restrict__ out) {
  int t = blockIdx.x * 256 + threadIdx.x;
  if (t >= RN * 13) return;
  int r = t / 13, c = t - r * 13;
  float acc = 0.0f;
  for (int k = 0; k < 256; ++k) acc = fmaf(h[(size_t)r * 256 + k], W[k * 13 + c], acc);
  int b = r >> 12, n = r & 4095;
  out[(size_t)b * 13 * NN + (size_t)c * NN + n] = acc;
}

// ---------------------------------------------------------------------------
extern "C" void kernel_launch(void* const* d_in, const int* in_sizes, int n_in,
                              void* d_out, int out_size, void* d_ws, size_t ws_size,
                              hipStream_t stream) {
  (void)in_sizes; (void)n_in; (void)out_size; (void)ws_size;
  const float* data = (const float*)d_in[0];
  const float* W_fc = (const float*)d_in[1];
  const float* b_fc = (const float*)d_in[2];
  const float* W1   = (const float*)d_in[3];
  const float* W2   = (const float*)d_in[4];
  const float* W3   = (const float*)d_in[5];
  const float* W4   = (const float*)d_in[6];
  const float* W5   = (const float*)d_in[7];
  const float* W6   = (const float*)d_in[8];
  const float* W10  = (const float*)d_in[9];
  const float* W11  = (const float*)d_in[10];
  const float* W12  = (const float*)d_in[11];
  const float* W13  = (const float*)d_in[12];
  float* out = (float*)d_out;

  float* ws  = (float*)d_ws;
  int*   idx = (int*)d_ws;                   // 262144 ints
  size_t o = 262144;
  float* x0   = ws + o; o += (size_t)RN * 64;
  float* x1v  = ws + o; o += (size_t)RN * 64;
  float* x2v  = ws + o; o += (size_t)RN * 64;
  float* bufA = ws + o; o += (size_t)RN * 256;
  float* bufB = ws + o; o += (size_t)RN * 256;
  float* bufC = ws + o; o += (size_t)RN * 64;
  float* gbuf = ws + o; o += 4096;
  float* pmax = ws + o; o += (size_t)256 * 1024;
  float* h11  = ws + o; o += (size_t)RN * 512;
  float* h12  = ws + o; o += (size_t)RN * 256;
  float* stats = ws + o; o += 8192;
  float4* pack = (float4*)(ws + o); o += (size_t)RN * 4;

  float* S0 = stats;          // 64 cols  (fc)
  float* S1 = stats + 128;    // 256 (edge1)
  float* S2 = stats + 640;    // 64  (W2)
  float* S3 = stats + 768;    // 64  (W3)
  float* S4 = stats + 896;    // 256 (edge2)
  float* S5 = stats + 1408;   // 64  (W5)
  float* S6 = stats + 1536;   // 64  (W6)
  float* S7 = stats + 1664;   // 1024 (W10)
  float* S8 = stats + 3712;   // 512 (W11)
  float* S9 = stats + 4736;   // 256 (W12)

  hipMemsetAsync(stats, 0, 5248 * sizeof(float), stream);

  prep_kernel<<<RN / 256, 256, 0, stream>>>(data, pack);
  knn_kernel<<<RN / 16, 256, 0, stream>>>(pack, idx);

  fc_kernel<<<RN * 64 / 256, 256, 0, stream>>>(data, W_fc, b_fc, x0, S0);
  bn_norm_kernel<<<RN * 64 / 256, 256, 0, stream>>>(x0, S0, 63, 64, 1.0f / RN, RN * 64);

  edge_conv_kernel<true><<<RN / 16, 256, 0, stream>>>(x0, idx, data, W1, bufA, S1);
  bn_norm_kernel<<<RN * 256 / 256, 256, 0, stream>>>(bufA, S1, 255, 256, 1.0f / (RN * 16), RN * 256);

  agg_kernel<<<RN * 64 / 256, 256, 0, stream>>>(bufA, idx, bufB, 6);
  gemm_kernel<0, false><<<dim3(256, 1), 256, 0, stream>>>(bufB, nullptr, nullptr, nullptr, W2, bufC, nullptr, S2, 256, 64);
  bn_norm_kernel<<<RN * 64 / 256, 256, 0, stream>>>(bufC, S2, 63, 64, 1.0f / RN, RN * 64);

  agg_kernel<<<RN * 16 / 256, 256, 0, stream>>>(bufC, idx, bufB, 4);
  gemm_kernel<0, false><<<dim3(256, 1), 256, 0, stream>>>(bufB, nullptr, nullptr, nullptr, W3, x1v, nullptr, S3, 64, 64);
  bn_norm_kernel<<<RN * 64 / 256, 256, 0, stream>>>(x1v, S3, 63, 64, 1.0f / RN, RN * 64);

  edge_conv_kernel<false><<<RN / 16, 256, 0, stream>>>(x1v, idx, data, W4, bufA, S4);
  bn_norm_kernel<<<RN * 256 / 256, 256, 0, stream>>>(bufA, S4, 255, 256, 1.0f / (RN * 16), RN * 256);

  agg_kernel<<<RN * 64 / 256, 256, 0, stream>>>(bufA, idx, bufB, 6);
  gemm_kernel<0, false><<<dim3(256, 1), 256, 0, stream>>>(bufB, nullptr, nullptr, nullptr, W5, bufC, nullptr, S5, 256, 64);
  bn_norm_kernel<<<RN * 64 / 256, 256, 0, stream>>>(bufC, S5, 63, 64, 1.0f / RN, RN * 64);

  agg_kernel<<<RN * 16 / 256, 256, 0, stream>>>(bufC, idx, bufB, 4);
  gemm_kernel<0, false><<<dim3(256, 1), 256, 0, stream>>>(bufB, nullptr, nullptr, nullptr, W6, x2v, nullptr, S6, 64, 64);
  bn_norm_kernel<<<RN * 64 / 256, 256, 0, stream>>>(x2v, S6, 63, 64, 1.0f / RN, RN * 64);

  // W10 path: stats + per-row-tile max only (y never materialized)
  gemm_kernel<2, true><<<dim3(256, 16), 256, 0, stream>>>(nullptr, x1v, x2v, nullptr, W10, nullptr, pmax, S7, 128, 1024);
  fin_g_kernel<<<16, 256, 0, stream>>>(pmax, S7, gbuf);

  gemm_kernel<3, false><<<dim3(256, 8), 256, 0, stream>>>(nullptr, x1v, x2v, gbuf, W11, h11, nullptr, S8, 1152, 512);
  bn_norm_kernel<<<RN * 512 / 256, 256, 0, stream>>>(h11, S8, 511, 512, 1.0f / RN, RN * 512);

  gemm_kernel<0, false><<<dim3(256, 4), 256, 0, stream>>>(h11, nullptr, nullptr, nullptr, W12, h12, nullptr, S9, 512, 256);
  bn_norm_kernel<<<RN * 256 / 256, 256, 0, stream>>>(h12, S9, 255, 256, 1.0f / RN, RN * 256);

  final13_kernel<<<(RN * 13 + 255) / 256, 256, 0, stream>>>(h12, W13, out);
}

// Round 4
// 1443.315 us; speedup vs baseline: 1.6808x; 1.4284x over previous
//
#include <hip/hip_runtime.h>
#include <hip/hip_bf16.h>
#include <float.h>

static constexpr int BB  = 4;
static constexpr int NN  = 4096;
static constexpr int KSN = 16;
static constexpr int RN  = BB * NN;     // 16384 rows (b,n)
#define EPSBN 1e-5f

typedef __attribute__((ext_vector_type(8))) short short8;
typedef __attribute__((ext_vector_type(4))) float f32x4;

__device__ inline unsigned short f2bf(float f) {
  union { float f; unsigned u; } v; v.f = f;
  unsigned r = v.u + 0x7FFF + ((v.u >> 16) & 1);
  return (unsigned short)(r >> 16);
}
__device__ inline float bf2f(unsigned short h) {
  union { unsigned u; float f; } v; v.u = ((unsigned)h) << 16; return v.f;
}

// ---------------------------------------------------------------------------
// Prep: pack (x,y,z,|p|^2) as float4 per point.
// ---------------------------------------------------------------------------
__global__ void prep_kernel(const float* __restrict__ data, float4* __restrict__ pack) {
  int t = blockIdx.x * 256 + threadIdx.x;
  if (t >= RN) return;
  const float* dr = data + (size_t)t * 9;
  float x = dr[0], y = dr[1], z = dr[2];
  pack[t] = make_float4(x, y, z, fmaf(z, z, fmaf(y, y, x * x)));
}

// ---------------------------------------------------------------------------
// Weight prep: W1p = W1top - W1mid (fp32); W1mid transposed [256][64] as
// bf16 hi/lo pair; W1bt = pts-rows as float4[256]; same for W4.
// ---------------------------------------------------------------------------
__global__ void prep_w_kernel(const float* __restrict__ W1, const float* __restrict__ W4,
                              float* __restrict__ W1p,
                              unsigned short* __restrict__ W1mh, unsigned short* __restrict__ W1ml,
                              float4* __restrict__ W1bt,
                              float* __restrict__ W4p,
                              unsigned short* __restrict__ W4mh, unsigned short* __restrict__ W4ml) {
  int t = blockIdx.x * 256 + threadIdx.x;   // 16384
  int k = t >> 8, cc = t & 255;
  float w1top = W1[k * 256 + cc], w1mid = W1[(64 + k) * 256 + cc];
  W1p[t] = w1top - w1mid;
  unsigned short h1 = f2bf(w1mid);
  W1mh[cc * 64 + k] = h1;
  W1ml[cc * 64 + k] = f2bf(w1mid - bf2f(h1));
  float w4top = W4[k * 256 + cc], w4mid = W4[(64 + k) * 256 + cc];
  W4p[t] = w4top - w4mid;
  unsigned short h4 = f2bf(w4mid);
  W4mh[cc * 64 + k] = h4;
  W4ml[cc * 64 + k] = f2bf(w4mid - bf2f(h4));
  if (t < 256) W1bt[t] = make_float4(W1[128 * 256 + t], W1[129 * 256 + t], W1[130 * 256 + t], 0.f);
}

// x -> bf16 hi/lo pair
__global__ void tobf2_kernel(const float* __restrict__ x, unsigned short* __restrict__ hi,
                             unsigned short* __restrict__ lo, int n) {
  int t = blockIdx.x * 256 + threadIdx.x;
  if (t < n) {
    float v = x[t];
    unsigned short h = f2bf(v);
    hi[t] = h;
    lo[t] = f2bf(v - bf2f(h));
  }
}

// ---------------------------------------------------------------------------
// KNN: one wave per point, no LDS. Lane keeps 64 ordered-uint keys in regs
// (static unrolled) + top-2 buffer; 16 passes of 64-bit shfl min-reduce.
// Key = (ordered_dist << 12) | j  -> unique, index tie-break like top_k.
// ---------------------------------------------------------------------------
__global__ __launch_bounds__(256) void knn_kernel(const float4* __restrict__ pack,
                                                  int* __restrict__ idx) {
  const int lane = threadIdx.x & 63;
  const int p = blockIdx.x * 4 + (threadIdx.x >> 6);
  const int b = p >> 12;
  const float4* __restrict__ pb = pack + ((size_t)b << 12);
  const float4 me = pack[p];
  unsigned u[64];
  unsigned long long m1 = ~0ull, m2 = ~0ull;
#pragma unroll
  for (int s = 0; s < 64; ++s) {
    const float4 q = pb[s * 64 + lane];
    float d = me.w + q.w - 2.0f * fmaf(me.x, q.x, fmaf(me.y, q.y, me.z * q.z));
    unsigned ub = __float_as_uint(d);
    ub = (ub & 0x80000000u) ? ~ub : (ub | 0x80000000u);
    u[s] = ub;
    unsigned long long key = ((unsigned long long)ub << 12) | (unsigned)(s * 64 + lane);
    bool lt1 = key < m1;
    unsigned long long k2 = lt1 ? m1 : key;
    m1 = lt1 ? key : m1;
    m2 = (k2 < m2) ? k2 : m2;
  }
  for (int pass = 0; pass < 16; ++pass) {
    unsigned long long w = m1;
#pragma unroll
    for (int mv = 1; mv < 64; mv <<= 1) {
      unsigned long long o = __shfl_xor(w, mv);
      w = (o < w) ? o : w;
    }
    if (lane == pass) idx[(p << 4) + pass] = (int)(w & 0xFFFu);
    if (m1 == w) { m1 = m2; m2 = ~0ull; }
    if (__any(m1 == ~0ull)) {
      if (m1 == ~0ull) {
        m1 = ~0ull; m2 = ~0ull;
#pragma unroll
        for (int s = 0; s < 64; ++s) {
          unsigned long long key = ((unsigned long long)u[s] << 12) | (unsigned)(s * 64 + lane);
          key = (key > w) ? key : ~0ull;
          bool lt1 = key < m1;
          unsigned long long k2 = lt1 ? m1 : key;
          m1 = lt1 ? key : m1;
          m2 = (k2 < m2) ? k2 : m2;
        }
      }
    }
  }
}

// ---------------------------------------------------------------------------
// fc: y = data @ W_fc + b_fc (K=9, C=64) + column stats.
// ---------------------------------------------------------------------------
__global__ __launch_bounds__(256) void fc_kernel(const float* __restrict__ data,
                                                 const float* __restrict__ W,
                                                 const float* __restrict__ bias,
                                                 float* __restrict__ y,
                                                 float* __restrict__ stats) {
  const int t = blockIdx.x * 256 + threadIdx.x;
  const int r = t >> 6, c = t & 63;
  const float* dr = data + (size_t)r * 9;
  float acc = bias[c];
#pragma unroll
  for (int k = 0; k < 9; ++k) acc = fmaf(dr[k], W[k * 64 + c], acc);
  y[t] = acc;
  __shared__ float red[256];
  red[threadIdx.x] = acc;
  __syncthreads();
  if (threadIdx.x < 64) {
    float s = red[threadIdx.x] + red[threadIdx.x + 64] + red[threadIdx.x + 128] + red[threadIdx.x + 192];
    atomicAdd(&stats[threadIdx.x], s);
  }
  __syncthreads();
  red[threadIdx.x] = acc * acc;
  __syncthreads();
  if (threadIdx.x < 64) {
    float s = red[threadIdx.x] + red[threadIdx.x + 64] + red[threadIdx.x + 128] + red[threadIdx.x + 192];
    atomicAdd(&stats[64 + threadIdx.x], s);
  }
}

// ---------------------------------------------------------------------------
// BN(+ReLU) normalize in place.
// ---------------------------------------------------------------------------
__global__ void bn_norm_kernel(float* __restrict__ buf, const float* __restrict__ stats,
                               int cmask, int C, float inv_cnt, int total) {
  int t = blockIdx.x * 256 + threadIdx.x;
  if (t >= total) return;
  int c = t & cmask;
  float m = stats[c] * inv_cnt;
  float v = fmaxf(stats[C + c] * inv_cnt - m * m, 0.0f);
  float rs = rsqrtf(v + EPSBN);
  float x = (buf[t] - m) * rs;
  buf[t] = fmaxf(x, 0.0f);
}

// ---------------------------------------------------------------------------
// Edge conv via MFMA with bf16 hi/lo split (fp32-grade precision):
// nb.Wmid ~ ah.bh + ah.bl + al.bh  (lo.lo term ~2^-18, dropped).
// base = c.(Wtop-Wmid) precomputed fp32; dp.Wbot fp32 epilogue.
// Wave = 16-col tile x 16 points. D layout: col=lane&15, row=(lane>>4)*4+reg.
// ---------------------------------------------------------------------------
template <bool HAS_PTS>
__global__ __launch_bounds__(256) void edge_mfma_kernel(
    const unsigned short* __restrict__ Xh, const unsigned short* __restrict__ Xl,
    const int* __restrict__ idx,
    const float4* __restrict__ pack,
    const unsigned short* __restrict__ Wmh, const unsigned short* __restrict__ Wml,
    const float4* __restrict__ Wbt, const float* __restrict__ basemat,
    float* __restrict__ out, float* __restrict__ stats) {
  const int wave = threadIdx.x >> 6;
  const int lane = threadIdx.x & 63;
  const int pg   = blockIdx.x >> 2;                 // 0..1023
  const int ct   = ((blockIdx.x & 3) << 2) | wave;  // 0..15
  const int c    = (ct << 4) + (lane & 15);
  const int kg   = (lane >> 4) << 3;
  short8 b0h, b1h, b0l, b1l;
  { const unsigned short* wp = Wmh + (size_t)c * 64 + kg;
    b0h = *(const short8*)wp; b1h = *(const short8*)(wp + 32); }
  { const unsigned short* wp = Wml + (size_t)c * 64 + kg;
    b0l = *(const short8*)wp; b1l = *(const short8*)(wp + 32); }
  float4 wb = make_float4(0.f, 0.f, 0.f, 0.f);
  if (HAS_PTS) wb = Wbt[c];
  float rs1 = 0.f, rs2 = 0.f;
  for (int pp = 0; pp < 16; ++pp) {
    const int p = (pg << 4) | pp;
    const int b = p >> 12;
    const int j = idx[(p << 4) + (lane & 15)];
    const size_t rowoff = ((size_t)((b << 12) | j) << 6) + kg;
    short8 a0h = *(const short8*)(Xh + rowoff);
    short8 a1h = *(const short8*)(Xh + rowoff + 32);
    short8 a0l = *(const short8*)(Xl + rowoff);
    short8 a1l = *(const short8*)(Xl + rowoff + 32);
    f32x4 acc = {0.f, 0.f, 0.f, 0.f};
    acc = __builtin_amdgcn_mfma_f32_16x16x32_bf16(a0l, b0h, acc, 0, 0, 0);
    acc = __builtin_amdgcn_mfma_f32_16x16x32_bf16(a1l, b1h, acc, 0, 0, 0);
    acc = __builtin_amdgcn_mfma_f32_16x16x32_bf16(a0h, b0l, acc, 0, 0, 0);
    acc = __builtin_amdgcn_mfma_f32_16x16x32_bf16(a1h, b1l, acc, 0, 0, 0);
    acc = __builtin_amdgcn_mfma_f32_16x16x32_bf16(a0h, b0h, acc, 0, 0, 0);
    acc = __builtin_amdgcn_mfma_f32_16x16x32_bf16(a1h, b1h, acc, 0, 0, 0);
    if (HAS_PTS) {
      const int4 j4 = *(const int4*)(idx + (p << 4) + ((lane >> 4) << 2));
      const float4 pc = pack[p];
      const float4 q0 = pack[(b << 12) | j4.x];
      const float4 q1 = pack[(b << 12) | j4.y];
      const float4 q2 = pack[(b << 12) | j4.z];
      const float4 q3 = pack[(b << 12) | j4.w];
      acc.x += (q0.x - pc.x) * wb.x + (q0.y - pc.y) * wb.y + (q0.z - pc.z) * wb.z;
      acc.y += (q1.x - pc.x) * wb.x + (q1.y - pc.y) * wb.y + (q1.z - pc.z) * wb.z;
      acc.z += (q2.x - pc.x) * wb.x + (q2.y - pc.y) * wb.y + (q2.z - pc.z) * wb.z;
      acc.w += (q3.x - pc.x) * wb.x + (q3.y - pc.y) * wb.y + (q3.z - pc.z) * wb.z;
    }
    float s1 = acc.x + acc.y + acc.z + acc.w;
    float s2 = acc.x * acc.x + acc.y * acc.y + acc.z * acc.z + acc.w * acc.w;
    float mx = fmaxf(fmaxf(acc.x, acc.y), fmaxf(acc.z, acc.w));
    s1 += __shfl_xor(s1, 16); s1 += __shfl_xor(s1, 32);
    s2 += __shfl_xor(s2, 16); s2 += __shfl_xor(s2, 32);
    mx = fmaxf(mx, __shfl_xor(mx, 16)); mx = fmaxf(mx, __shfl_xor(mx, 32));
    float bb = basemat[(size_t)p * 256 + c];
    if (lane < 16) out[(size_t)p * 256 + c] = mx + bb;
    rs1 += s1 + 16.f * bb;
    rs2 += s2 + 2.f * bb * s1 + 16.f * bb * bb;
  }
  if (lane < 16) {
    atomicAdd(&stats[c], rs1);
    atomicAdd(&stats[256 + c], rs2);
  }
}

// ---------------------------------------------------------------------------
// agg[r,c] = max over 16 neighbors, float4 per thread. lg = log2(C/4).
// ---------------------------------------------------------------------------
__global__ void agg_kernel(const float* __restrict__ X, const int* __restrict__ idx,
                           float* __restrict__ out, int lg) {
  const int c4 = 1 << lg;
  int t = blockIdx.x * 256 + threadIdx.x;
  int total = RN * c4;
  if (t >= total) return;
  int r = t >> lg, cq = t & (c4 - 1);
  int base = (r >> 12) << 12;
  const int* ip = idx + (size_t)r * KSN;
  float4 mx = make_float4(-FLT_MAX, -FLT_MAX, -FLT_MAX, -FLT_MAX);
  const int C = c4 * 4;
#pragma unroll
  for (int k = 0; k < KSN; ++k) {
    int j = ip[k];
    const float4 v = *reinterpret_cast<const float4*>(X + (size_t)(base + j) * C + cq * 4);
    mx.x = fmaxf(mx.x, v.x); mx.y = fmaxf(mx.y, v.y);
    mx.z = fmaxf(mx.z, v.z); mx.w = fmaxf(mx.w, v.w);
  }
  *reinterpret_cast<float4*>(out + (size_t)r * C + cq * 4) = mx;
}

// ---------------------------------------------------------------------------
// Tiled fp32 GEMM Y = A @ W + stats. MODE 0: A buffer; 2: [x1|x2]; 3: [g|x1|x2].
// DOMAX: per-row-tile column max to pmax instead of Y.
// ---------------------------------------------------------------------------
template <int MODE, bool DOMAX>
__global__ __launch_bounds__(256) void gemm_kernel(const float* __restrict__ A,
                                                   const float* __restrict__ px1,
                                                   const float* __restrict__ px2,
                                                   const float* __restrict__ pg,
                                                   const float* __restrict__ W,
                                                   float* __restrict__ Y,
                                                   float* __restrict__ pmax,
                                                   float* __restrict__ stats,
                                                   int K, int C) {
  __shared__ float a_lds[16][65];
  __shared__ float b_lds[16][64];
  __shared__ float red[64 * 17];
  const int t  = threadIdx.x;
  const int r0 = blockIdx.x * 64, c0 = blockIdx.y * 64;
  const int tr = t >> 4, tc = t & 15;
  float acc[4][4] = {{0.f}};
  for (int k0 = 0; k0 < K; k0 += 16) {
#pragma unroll
    for (int i = 0; i < 4; ++i) {
      int e = t + i * 256;
      int ar = e >> 4, ak = e & 15;
      int rr = r0 + ar, kk = k0 + ak;
      float v;
      if (MODE == 0) {
        v = A[(size_t)rr * K + kk];
      } else if (MODE == 2) {
        v = (kk < 64) ? px1[(size_t)rr * 64 + kk] : px2[(size_t)rr * 64 + kk - 64];
      } else {
        int b = rr >> 12;
        v = (kk < 1024) ? pg[b * 1024 + kk]
            : (kk < 1088 ? px1[(size_t)rr * 64 + kk - 1024]
                         : px2[(size_t)rr * 64 + kk - 1088]);
      }
      a_lds[ak][ar] = v;
    }
#pragma unroll
    for (int i = 0; i < 4; ++i) {
      int e = t + i * 256;
      int bk = e >> 6, bc = e & 63;
      b_lds[bk][bc] = W[(size_t)(k0 + bk) * C + c0 + bc];
    }
    __syncthreads();
#pragma unroll
    for (int k = 0; k < 16; ++k) {
      float av[4], bv[4];
#pragma unroll
      for (int i = 0; i < 4; ++i) av[i] = a_lds[k][tr * 4 + i];
#pragma unroll
      for (int j = 0; j < 4; ++j) bv[j] = b_lds[k][tc * 4 + j];
#pragma unroll
      for (int i = 0; i < 4; ++i)
#pragma unroll
        for (int j = 0; j < 4; ++j) acc[i][j] = fmaf(av[i], bv[j], acc[i][j]);
    }
    __syncthreads();
  }
  if (!DOMAX) {
#pragma unroll
    for (int i = 0; i < 4; ++i) {
      int rr = r0 + tr * 4 + i;
#pragma unroll
      for (int j = 0; j < 4; ++j) Y[(size_t)rr * C + c0 + tc * 4 + j] = acc[i][j];
    }
  }
  float s1[4] = {0.f, 0.f, 0.f, 0.f}, s2[4] = {0.f, 0.f, 0.f, 0.f};
#pragma unroll
  for (int i = 0; i < 4; ++i)
#pragma unroll
    for (int j = 0; j < 4; ++j) {
      s1[j] += acc[i][j];
      s2[j] = fmaf(acc[i][j], acc[i][j], s2[j]);
    }
#pragma unroll
  for (int j = 0; j < 4; ++j) red[(tc * 4 + j) * 17 + tr] = s1[j];
  __syncthreads();
  if (t < 64) {
    float s = 0.f;
    for (int q = 0; q < 16; ++q) s += red[t * 17 + q];
    atomicAdd(&stats[c0 + t], s);
  }
  __syncthreads();
#pragma unroll
  for (int j = 0; j < 4; ++j) red[(tc * 4 + j) * 17 + tr] = s2[j];
  __syncthreads();
  if (t < 64) {
    float s = 0.f;
    for (int q = 0; q < 16; ++q) s += red[t * 17 + q];
    atomicAdd(&stats[C + c0 + t], s);
  }
  if (DOMAX) {
    __syncthreads();
    float m[4];
#pragma unroll
    for (int j = 0; j < 4; ++j) {
      m[j] = fmaxf(fmaxf(acc[0][j], acc[1][j]), fmaxf(acc[2][j], acc[3][j]));
      red[(tc * 4 + j) * 17 + tr] = m[j];
    }
    __syncthreads();
    if (t < 64) {
      float mm = -FLT_MAX;
      for (int q = 0; q < 16; ++q) mm = fmaxf(mm, red[t * 17 + q]);
      pmax[(size_t)blockIdx.x * C + c0 + t] = mm;
    }
  }
}

__global__ void fin_g_kernel(const float* __restrict__ pmax, const float* __restrict__ stats,
                             float* __restrict__ g) {
  int t = blockIdx.x * 256 + threadIdx.x;
  int b = t >> 10, c = t & 1023;
  const float inv = 1.0f / 16384.0f;
  float m = stats[c] * inv;
  float v = fmaxf(stats[1024 + c] * inv - m * m, 0.0f);
  float rs = rsqrtf(v + EPSBN);
  float mx = -FLT_MAX;
  for (int s = 0; s < 64; ++s) mx = fmaxf(mx, pmax[(size_t)(b * 64 + s) * 1024 + c]);
  g[t] = fmaxf((mx - m) * rs, 0.0f);
}

__global__ void final13_kernel(const float* __restrict__ h, const float* __restrict__ W,
                               float* __restrict__ out) {
  int t = blockIdx.x * 256 + threadIdx.x;
  if (t >= RN * 13) return;
  int r = t / 13, c = t - r * 13;
  float acc = 0.0f;
  for (int k = 0; k < 256; ++k) acc = fmaf(h[(size_t)r * 256 + k], W[k * 13 + c], acc);
  int b = r >> 12, n = r & 4095;
  out[(size_t)b * 13 * NN + (size_t)c * NN + n] = acc;
}

// ---------------------------------------------------------------------------
extern "C" void kernel_launch(void* const* d_in, const int* in_sizes, int n_in,
                              void* d_out, int out_size, void* d_ws, size_t ws_size,
                              hipStream_t stream) {
  (void)in_sizes; (void)n_in; (void)out_size; (void)ws_size;
  const float* data = (const float*)d_in[0];
  const float* W_fc = (const float*)d_in[1];
  const float* b_fc = (const float*)d_in[2];
  const float* W1   = (const float*)d_in[3];
  const float* W2   = (const float*)d_in[4];
  const float* W3   = (const float*)d_in[5];
  const float* W4   = (const float*)d_in[6];
  const float* W5   = (const float*)d_in[7];
  const float* W6   = (const float*)d_in[8];
  const float* W10  = (const float*)d_in[9];
  const float* W11  = (const float*)d_in[10];
  const float* W12  = (const float*)d_in[11];
  const float* W13  = (const float*)d_in[12];
  float* out = (float*)d_out;

  float* ws  = (float*)d_ws;
  int*   idx = (int*)d_ws;
  size_t o = 262144;
  float* x0   = ws + o; o += (size_t)RN * 64;
  float* x1v  = ws + o; o += (size_t)RN * 64;
  float* x2v  = ws + o; o += (size_t)RN * 64;
  float* bufA = ws + o; o += (size_t)RN * 256;
  float* bufB = ws + o; o += (size_t)RN * 256;
  float* bufC = ws + o; o += (size_t)RN * 64;
  float* gbuf = ws + o; o += 4096;
  float* pmax = ws + o; o += (size_t)256 * 1024;
  float* h11  = ws + o; o += (size_t)RN * 512;
  float* h12  = ws + o; o += (size_t)RN * 256;
  float* stats = ws + o; o += 8192;
  float4* pack = (float4*)(ws + o); o += (size_t)RN * 4;
  unsigned short* xbh = (unsigned short*)(ws + o); o += (size_t)RN * 32;
  unsigned short* xbl = (unsigned short*)(ws + o); o += (size_t)RN * 32;
  float* W1p = ws + o; o += 16384;
  float* W4p = ws + o; o += 16384;
  unsigned short* W1mh = (unsigned short*)(ws + o); o += 8192;
  unsigned short* W1ml = (unsigned short*)(ws + o); o += 8192;
  unsigned short* W4mh = (unsigned short*)(ws + o); o += 8192;
  unsigned short* W4ml = (unsigned short*)(ws + o); o += 8192;
  float4* W1bt = (float4*)(ws + o); o += 1024;

  float* S0 = stats;          // 64 (fc)
  float* S1 = stats + 128;    // 256 (edge1)
  float* S2 = stats + 640;    // 64  (W2)
  float* S3 = stats + 768;    // 64  (W3)
  float* S4 = stats + 896;    // 256 (edge2)
  float* S5 = stats + 1408;   // 64  (W5)
  float* S6 = stats + 1536;   // 64  (W6)
  float* S7 = stats + 1664;   // 1024 (W10)
  float* S8 = stats + 3712;   // 512 (W11)
  float* S9 = stats + 4736;   // 256 (W12)
  float* Sd = stats + 5248;   // dummy (512)

  hipMemsetAsync(stats, 0, 8192 * sizeof(float), stream);

  prep_kernel<<<RN / 256, 256, 0, stream>>>(data, pack);
  knn_kernel<<<RN / 4, 256, 0, stream>>>(pack, idx);
  prep_w_kernel<<<64, 256, 0, stream>>>(W1, W4, W1p, W1mh, W1ml, W1bt, W4p, W4mh, W4ml);

  fc_kernel<<<RN * 64 / 256, 256, 0, stream>>>(data, W_fc, b_fc, x0, S0);
  bn_norm_kernel<<<RN * 64 / 256, 256, 0, stream>>>(x0, S0, 63, 64, 1.0f / RN, RN * 64);

  // edge conv 1: base = x0 @ (W1top - W1mid); MFMA hi/lo gather for nb part
  tobf2_kernel<<<RN * 64 / 256, 256, 0, stream>>>(x0, xbh, xbl, RN * 64);
  gemm_kernel<0, false><<<dim3(256, 4), 256, 0, stream>>>(x0, nullptr, nullptr, nullptr, W1p, bufB, nullptr, Sd, 64, 256);
  edge_mfma_kernel<true><<<4096, 256, 0, stream>>>(xbh, xbl, idx, pack, W1mh, W1ml, W1bt, bufB, bufA, S1);
  bn_norm_kernel<<<RN * 256 / 256, 256, 0, stream>>>(bufA, S1, 255, 256, 1.0f / (RN * 16), RN * 256);

  agg_kernel<<<RN * 64 / 256, 256, 0, stream>>>(bufA, idx, bufB, 6);
  gemm_kernel<0, false><<<dim3(256, 1), 256, 0, stream>>>(bufB, nullptr, nullptr, nullptr, W2, bufC, nullptr, S2, 256, 64);
  bn_norm_kernel<<<RN * 64 / 256, 256, 0, stream>>>(bufC, S2, 63, 64, 1.0f / RN, RN * 64);

  agg_kernel<<<RN * 16 / 256, 256, 0, stream>>>(bufC, idx, bufB, 4);
  gemm_kernel<0, false><<<dim3(256, 1), 256, 0, stream>>>(bufB, nullptr, nullptr, nullptr, W3, x1v, nullptr, S3, 64, 64);
  bn_norm_kernel<<<RN * 64 / 256, 256, 0, stream>>>(x1v, S3, 63, 64, 1.0f / RN, RN * 64);

  // edge conv 2 (no pts)
  tobf2_kernel<<<RN * 64 / 256, 256, 0, stream>>>(x1v, xbh, xbl, RN * 64);
  gemm_kernel<0, false><<<dim3(256, 4), 256, 0, stream>>>(x1v, nullptr, nullptr, nullptr, W4p, bufB, nullptr, Sd, 64, 256);
  edge_mfma_kernel<false><<<4096, 256, 0, stream>>>(xbh, xbl, idx, pack, W4mh, W4ml, nullptr, bufB, bufA, S4);
  bn_norm_kernel<<<RN * 256 / 256, 256, 0, stream>>>(bufA, S4, 255, 256, 1.0f / (RN * 16), RN * 256);

  agg_kernel<<<RN * 64 / 256, 256, 0, stream>>>(bufA, idx, bufB, 6);
  gemm_kernel<0, false><<<dim3(256, 1), 256, 0, stream>>>(bufB, nullptr, nullptr, nullptr, W5, bufC, nullptr, S5, 256, 64);
  bn_norm_kernel<<<RN * 64 / 256, 256, 0, stream>>>(bufC, S5, 63, 64, 1.0f / RN, RN * 64);

  agg_kernel<<<RN * 16 / 256, 256, 0, stream>>>(bufC, idx, bufB, 4);
  gemm_kernel<0, false><<<dim3(256, 1), 256, 0, stream>>>(bufB, nullptr, nullptr, nullptr, W6, x2v, nullptr, S6, 64, 64);
  bn_norm_kernel<<<RN * 64 / 256, 256, 0, stream>>>(x2v, S6, 63, 64, 1.0f / RN, RN * 64);

  gemm_kernel<2, true><<<dim3(256, 16), 256, 0, stream>>>(nullptr, x1v, x2v, nullptr, W10, nullptr, pmax, S7, 128, 1024);
  fin_g_kernel<<<16, 256, 0, stream>>>(pmax, S7, gbuf);

  gemm_kernel<3, false><<<dim3(256, 8), 256, 0, stream>>>(nullptr, x1v, x2v, gbuf, W11, h11, nullptr, S8, 1152, 512);
  bn_norm_kernel<<<RN * 512 / 256, 256, 0, stream>>>(h11, S8, 511, 512, 1.0f / RN, RN * 512);

  gemm_kernel<0, false><<<dim3(256, 4), 256, 0, stream>>>(h11, nullptr, nullptr, nullptr, W12, h12, nullptr, S9, 512, 256);
  bn_norm_kernel<<<RN * 256 / 256, 256, 0, stream>>>(h12, S9, 255, 256, 1.0f / RN, RN * 256);

  final13_kernel<<<(RN * 13 + 255) / 256, 256, 0, stream>>>(h12, W13, out);
}

// Round 5
// 987.348 us; speedup vs baseline: 2.4570x; 1.4618x over previous
//
#include <hip/hip_runtime.h>
#include <hip/hip_bf16.h>
#include <float.h>

static constexpr int BB  = 4;
static constexpr int NN  = 4096;
static constexpr int KSN = 16;
static constexpr int RN  = BB * NN;     // 16384 rows (b,n)
#define EPSBN 1e-5f

typedef __attribute__((ext_vector_type(8))) short short8;
typedef __attribute__((ext_vector_type(4))) float f32x4;

__device__ inline unsigned short f2bf(float f) {
  union { float f; unsigned u; } v; v.f = f;
  unsigned r = v.u + 0x7FFF + ((v.u >> 16) & 1);
  return (unsigned short)(r >> 16);
}
__device__ inline float bf2f(unsigned short h) {
  union { unsigned u; float f; } v; v.u = ((unsigned)h) << 16; return v.f;
}

// ---------------------------------------------------------------------------
// Prep: pack (x,y,z,|p|^2) as float4 per point.
// ---------------------------------------------------------------------------
__global__ void prep_kernel(const float* __restrict__ data, float4* __restrict__ pack) {
  int t = blockIdx.x * 256 + threadIdx.x;
  if (t >= RN) return;
  const float* dr = data + (size_t)t * 9;
  float x = dr[0], y = dr[1], z = dr[2];
  pack[t] = make_float4(x, y, z, fmaf(z, z, fmaf(y, y, x * x)));
}

// ---------------------------------------------------------------------------
// Weight prep for edge convs (unchanged from round 4).
// ---------------------------------------------------------------------------
__global__ void prep_w_kernel(const float* __restrict__ W1, const float* __restrict__ W4,
                              float* __restrict__ W1p,
                              unsigned short* __restrict__ W1mh, unsigned short* __restrict__ W1ml,
                              float4* __restrict__ W1bt,
                              float* __restrict__ W4p,
                              unsigned short* __restrict__ W4mh, unsigned short* __restrict__ W4ml) {
  int t = blockIdx.x * 256 + threadIdx.x;   // 16384
  int k = t >> 8, cc = t & 255;
  float w1top = W1[k * 256 + cc], w1mid = W1[(64 + k) * 256 + cc];
  W1p[t] = w1top - w1mid;
  unsigned short h1 = f2bf(w1mid);
  W1mh[cc * 64 + k] = h1;
  W1ml[cc * 64 + k] = f2bf(w1mid - bf2f(h1));
  float w4top = W4[k * 256 + cc], w4mid = W4[(64 + k) * 256 + cc];
  W4p[t] = w4top - w4mid;
  unsigned short h4 = f2bf(w4mid);
  W4mh[cc * 64 + k] = h4;
  W4ml[cc * 64 + k] = f2bf(w4mid - bf2f(h4));
  if (t < 256) W1bt[t] = make_float4(W1[128 * 256 + t], W1[129 * 256 + t], W1[130 * 256 + t], 0.f);
}

// W -> fragment-major hi/lo pack: dst[ct][ks][lane][8]
__global__ void prep_wpack_kernel(const float* __restrict__ W,
                                  unsigned short* __restrict__ wh, unsigned short* __restrict__ wl,
                                  int lgC, int total, int NK) {
  int t = blockIdx.x * 256 + threadIdx.x;
  if (t >= total) return;
  int k = t >> lgC, c = t & ((1 << lgC) - 1);
  float v = W[t];
  int ct = c >> 4, cl = c & 15, ks = k >> 5, kl = k & 31;
  int dst = ((ct * NK + ks) * 64 + (((kl >> 3) << 4) | cl)) * 8 + (kl & 7);
  unsigned short h = f2bf(v);
  wh[dst] = h; wl[dst] = f2bf(v - bf2f(h));
}

// x -> bf16 hi/lo pair (row-major, for edge gather)
__global__ void tobf2_kernel(const float* __restrict__ x, unsigned short* __restrict__ hi,
                             unsigned short* __restrict__ lo, int n) {
  int t = blockIdx.x * 256 + threadIdx.x;
  if (t < n) {
    float v = x[t];
    unsigned short h = f2bf(v);
    hi[t] = h;
    lo[t] = f2bf(v - bf2f(h));
  }
}

// [x1|x2] -> fragment-major hi/lo pack (K=128)
__global__ void pack_x12_kernel(const float* __restrict__ x1, const float* __restrict__ x2,
                                unsigned short* __restrict__ ph, unsigned short* __restrict__ pl) {
  int t = blockIdx.x * 256 + threadIdx.x;   // RN*128
  int r = t >> 7, k = t & 127;
  float v = (k < 64) ? x1[(size_t)r * 64 + k] : x2[(size_t)r * 64 + k - 64];
  int rt = r >> 4, rl = r & 15, ks = k >> 5, kl = k & 31;
  int dst = ((rt * 4 + ks) * 64 + (((kl >> 3) << 4) | rl)) * 8 + (kl & 7);
  unsigned short h = f2bf(v);
  ph[dst] = h; pl[dst] = f2bf(v - bf2f(h));
}

// BN+ReLU on h11 (C=512) fused with fragment-major hi/lo pack (no fp32 writeback)
__global__ void bn_pack_kernel(const float* __restrict__ buf, const float* __restrict__ stats,
                               unsigned short* __restrict__ ph, unsigned short* __restrict__ pl) {
  int t = blockIdx.x * 256 + threadIdx.x;   // RN*512
  int c = t & 511, r = t >> 9;
  const float inv = 1.0f / RN;
  float m = stats[c] * inv;
  float v = fmaxf(stats[512 + c] * inv - m * m, 0.0f);
  float x = fmaxf((buf[t] - m) * rsqrtf(v + EPSBN), 0.0f);
  int rt = r >> 4, rl = r & 15, ks = c >> 5, kl = c & 31;
  int dst = ((rt * 16 + ks) * 64 + (((kl >> 3) << 4) | rl)) * 8 + (kl & 7);
  unsigned short h = f2bf(x);
  ph[dst] = h; pl[dst] = f2bf(x - bf2f(h));
}

// ---------------------------------------------------------------------------
// KNN v3: one wave per point, branchless sorted top-4 per lane, no register
// distance cache (VGPR ~48 -> high occupancy). 16 extraction passes of
// 64-bit shfl min-reduce. A lane rescans (reload from L2, filter key>w) only
// if >=5 of the top-16 landed in it (~3e-4 per point). Keys unique:
// (ordered_dist<<12)|j  -> exact index tie-break.
// ---------------------------------------------------------------------------
__global__ __launch_bounds__(256) void knn_kernel(const float4* __restrict__ pack,
                                                  int* __restrict__ idx) {
  const int lane = threadIdx.x & 63;
  const int p = blockIdx.x * 4 + (threadIdx.x >> 6);
  const int b = p >> 12;
  const float4* __restrict__ pb = pack + ((size_t)b << 12);
  const float4 me = pack[p];
  unsigned long long m0 = ~0ull, m1 = ~0ull, m2 = ~0ull, m3 = ~0ull;
#pragma unroll 8
  for (int s = 0; s < 64; ++s) {
    const float4 q = pb[s * 64 + lane];
    float d = me.w + q.w - 2.0f * fmaf(me.x, q.x, fmaf(me.y, q.y, me.z * q.z));
    unsigned ub = __float_as_uint(d);
    ub = (ub & 0x80000000u) ? ~ub : (ub | 0x80000000u);
    unsigned long long k = ((unsigned long long)ub << 12) | (unsigned)(s * 64 + lane);
    if (k < m3) {
      bool l0 = k < m0;  unsigned long long t0 = l0 ? m0 : k;  m0 = l0 ? k : m0;
      bool l1 = t0 < m1; unsigned long long t1 = l1 ? m1 : t0; m1 = l1 ? t0 : m1;
      bool l2 = t1 < m2; unsigned long long t2 = l2 ? m2 : t1; m2 = l2 ? t1 : m2;
      m3 = (t2 < m3) ? t2 : m3;
    }
  }
  for (int pass = 0; pass < 16; ++pass) {
    unsigned long long w = m0;
#pragma unroll
    for (int mv = 1; mv < 64; mv <<= 1) {
      unsigned long long o = __shfl_xor(w, mv);
      w = (o < w) ? o : w;
    }
    if (lane == pass) idx[(p << 4) + pass] = (int)(w & 0xFFFull);
    if (m0 == w) { m0 = m1; m1 = m2; m2 = m3; m3 = ~0ull; }
    if (pass < 15 && __any(m0 == ~0ull)) {
      if (m0 == ~0ull) {                    // rare: rebuild from global
        m1 = ~0ull; m2 = ~0ull; m3 = ~0ull;
#pragma unroll 8
        for (int s = 0; s < 64; ++s) {
          const float4 q = pb[s * 64 + lane];
          float d = me.w + q.w - 2.0f * fmaf(me.x, q.x, fmaf(me.y, q.y, me.z * q.z));
          unsigned ub = __float_as_uint(d);
          ub = (ub & 0x80000000u) ? ~ub : (ub | 0x80000000u);
          unsigned long long k = ((unsigned long long)ub << 12) | (unsigned)(s * 64 + lane);
          k = (k > w) ? k : ~0ull;
          bool l0 = k < m0;  unsigned long long t0 = l0 ? m0 : k;  m0 = l0 ? k : m0;
          bool l1 = t0 < m1; unsigned long long t1 = l1 ? m1 : t0; m1 = l1 ? t0 : m1;
          bool l2 = t1 < m2; unsigned long long t2 = l2 ? m2 : t1; m2 = l2 ? t1 : m2;
          m3 = (t2 < m3) ? t2 : m3;
        }
      }
    }
  }
}

// ---------------------------------------------------------------------------
// fc: y = data @ W_fc + b_fc (K=9, C=64) + column stats.
// ---------------------------------------------------------------------------
__global__ __launch_bounds__(256) void fc_kernel(const float* __restrict__ data,
                                                 const float* __restrict__ W,
                                                 const float* __restrict__ bias,
                                                 float* __restrict__ y,
                                                 float* __restrict__ stats) {
  const int t = blockIdx.x * 256 + threadIdx.x;
  const int r = t >> 6, c = t & 63;
  const float* dr = data + (size_t)r * 9;
  float acc = bias[c];
#pragma unroll
  for (int k = 0; k < 9; ++k) acc = fmaf(dr[k], W[k * 64 + c], acc);
  y[t] = acc;
  __shared__ float red[256];
  red[threadIdx.x] = acc;
  __syncthreads();
  if (threadIdx.x < 64) {
    float s = red[threadIdx.x] + red[threadIdx.x + 64] + red[threadIdx.x + 128] + red[threadIdx.x + 192];
    atomicAdd(&stats[threadIdx.x], s);
  }
  __syncthreads();
  red[threadIdx.x] = acc * acc;
  __syncthreads();
  if (threadIdx.x < 64) {
    float s = red[threadIdx.x] + red[threadIdx.x + 64] + red[threadIdx.x + 128] + red[threadIdx.x + 192];
    atomicAdd(&stats[64 + threadIdx.x], s);
  }
}

// ---------------------------------------------------------------------------
// BN(+ReLU) normalize in place.
// ---------------------------------------------------------------------------
__global__ void bn_norm_kernel(float* __restrict__ buf, const float* __restrict__ stats,
                               int cmask, int C, float inv_cnt, int total) {
  int t = blockIdx.x * 256 + threadIdx.x;
  if (t >= total) return;
  int c = t & cmask;
  float m = stats[c] * inv_cnt;
  float v = fmaxf(stats[C + c] * inv_cnt - m * m, 0.0f);
  float rs = rsqrtf(v + EPSBN);
  float x = (buf[t] - m) * rs;
  buf[t] = fmaxf(x, 0.0f);
}

// ---------------------------------------------------------------------------
// Edge conv via MFMA with bf16 hi/lo split (validated round 4).
// ---------------------------------------------------------------------------
template <bool HAS_PTS>
__global__ __launch_bounds__(256) void edge_mfma_kernel(
    const unsigned short* __restrict__ Xh, const unsigned short* __restrict__ Xl,
    const int* __restrict__ idx,
    const float4* __restrict__ pack,
    const unsigned short* __restrict__ Wmh, const unsigned short* __restrict__ Wml,
    const float4* __restrict__ Wbt, const float* __restrict__ basemat,
    float* __restrict__ out, float* __restrict__ stats) {
  const int wave = threadIdx.x >> 6;
  const int lane = threadIdx.x & 63;
  const int pg   = blockIdx.x >> 2;
  const int ct   = ((blockIdx.x & 3) << 2) | wave;
  const int c    = (ct << 4) + (lane & 15);
  const int kg   = (lane >> 4) << 3;
  short8 b0h, b1h, b0l, b1l;
  { const unsigned short* wp = Wmh + (size_t)c * 64 + kg;
    b0h = *(const short8*)wp; b1h = *(const short8*)(wp + 32); }
  { const unsigned short* wp = Wml + (size_t)c * 64 + kg;
    b0l = *(const short8*)wp; b1l = *(const short8*)(wp + 32); }
  float4 wb = make_float4(0.f, 0.f, 0.f, 0.f);
  if (HAS_PTS) wb = Wbt[c];
  float rs1 = 0.f, rs2 = 0.f;
  for (int pp = 0; pp < 16; ++pp) {
    const int p = (pg << 4) | pp;
    const int b = p >> 12;
    const int j = idx[(p << 4) + (lane & 15)];
    const size_t rowoff = ((size_t)((b << 12) | j) << 6) + kg;
    short8 a0h = *(const short8*)(Xh + rowoff);
    short8 a1h = *(const short8*)(Xh + rowoff + 32);
    short8 a0l = *(const short8*)(Xl + rowoff);
    short8 a1l = *(const short8*)(Xl + rowoff + 32);
    f32x4 acc = {0.f, 0.f, 0.f, 0.f};
    acc = __builtin_amdgcn_mfma_f32_16x16x32_bf16(a0l, b0h, acc, 0, 0, 0);
    acc = __builtin_amdgcn_mfma_f32_16x16x32_bf16(a1l, b1h, acc, 0, 0, 0);
    acc = __builtin_amdgcn_mfma_f32_16x16x32_bf16(a0h, b0l, acc, 0, 0, 0);
    acc = __builtin_amdgcn_mfma_f32_16x16x32_bf16(a1h, b1l, acc, 0, 0, 0);
    acc = __builtin_amdgcn_mfma_f32_16x16x32_bf16(a0h, b0h, acc, 0, 0, 0);
    acc = __builtin_amdgcn_mfma_f32_16x16x32_bf16(a1h, b1h, acc, 0, 0, 0);
    if (HAS_PTS) {
      const int4 j4 = *(const int4*)(idx + (p << 4) + ((lane >> 4) << 2));
      const float4 pc = pack[p];
      const float4 q0 = pack[(b << 12) | j4.x];
      const float4 q1 = pack[(b << 12) | j4.y];
      const float4 q2 = pack[(b << 12) | j4.z];
      const float4 q3 = pack[(b << 12) | j4.w];
      acc.x += (q0.x - pc.x) * wb.x + (q0.y - pc.y) * wb.y + (q0.z - pc.z) * wb.z;
      acc.y += (q1.x - pc.x) * wb.x + (q1.y - pc.y) * wb.y + (q1.z - pc.z) * wb.z;
      acc.z += (q2.x - pc.x) * wb.x + (q2.y - pc.y) * wb.y + (q2.z - pc.z) * wb.z;
      acc.w += (q3.x - pc.x) * wb.x + (q3.y - pc.y) * wb.y + (q3.z - pc.z) * wb.z;
    }
    float s1 = acc.x + acc.y + acc.z + acc.w;
    float s2 = acc.x * acc.x + acc.y * acc.y + acc.z * acc.z + acc.w * acc.w;
    float mx = fmaxf(fmaxf(acc.x, acc.y), fmaxf(acc.z, acc.w));
    s1 += __shfl_xor(s1, 16); s1 += __shfl_xor(s1, 32);
    s2 += __shfl_xor(s2, 16); s2 += __shfl_xor(s2, 32);
    mx = fmaxf(mx, __shfl_xor(mx, 16)); mx = fmaxf(mx, __shfl_xor(mx, 32));
    float bb = basemat[(size_t)p * 256 + c];
    if (lane < 16) out[(size_t)p * 256 + c] = mx + bb;
    rs1 += s1 + 16.f * bb;
    rs2 += s2 + 2.f * bb * s1 + 16.f * bb * bb;
  }
  if (lane < 16) {
    atomicAdd(&stats[c], rs1);
    atomicAdd(&stats[256 + c], rs2);
  }
}

// ---------------------------------------------------------------------------
// agg[r,c] = max over 16 neighbors, float4 per thread. lg = log2(C/4).
// ---------------------------------------------------------------------------
__global__ void agg_kernel(const float* __restrict__ X, const int* __restrict__ idx,
                           float* __restrict__ out, int lg) {
  const int c4 = 1 << lg;
  int t = blockIdx.x * 256 + threadIdx.x;
  int total = RN * c4;
  if (t >= total) return;
  int r = t >> lg, cq = t & (c4 - 1);
  int base = (r >> 12) << 12;
  const int* ip = idx + (size_t)r * KSN;
  float4 mx = make_float4(-FLT_MAX, -FLT_MAX, -FLT_MAX, -FLT_MAX);
  const int C = c4 * 4;
#pragma unroll
  for (int k = 0; k < KSN; ++k) {
    int j = ip[k];
    const float4 v = *reinterpret_cast<const float4*>(X + (size_t)(base + j) * C + cq * 4);
    mx.x = fmaxf(mx.x, v.x); mx.y = fmaxf(mx.y, v.y);
    mx.z = fmaxf(mx.z, v.z); mx.w = fmaxf(mx.w, v.w);
  }
  *reinterpret_cast<float4*>(out + (size_t)r * C + cq * 4) = mx;
}

// ---------------------------------------------------------------------------
// fp32 GEMM for small layers (MODE 0 only now).
// ---------------------------------------------------------------------------
template <int MODE, bool DOMAX>
__global__ __launch_bounds__(256) void gemm_kernel(const float* __restrict__ A,
                                                   const float* __restrict__ W,
                                                   float* __restrict__ Y,
                                                   float* __restrict__ stats,
                                                   int K, int C) {
  __shared__ float a_lds[16][65];
  __shared__ float b_lds[16][64];
  __shared__ float red[64 * 17];
  const int t  = threadIdx.x;
  const int r0 = blockIdx.x * 64, c0 = blockIdx.y * 64;
  const int tr = t >> 4, tc = t & 15;
  float acc[4][4] = {{0.f}};
  for (int k0 = 0; k0 < K; k0 += 16) {
#pragma unroll
    for (int i = 0; i < 4; ++i) {
      int e = t + i * 256;
      int ar = e >> 4, ak = e & 15;
      a_lds[ak][ar] = A[(size_t)(r0 + ar) * K + k0 + ak];
    }
#pragma unroll
    for (int i = 0; i < 4; ++i) {
      int e = t + i * 256;
      int bk = e >> 6, bc = e & 63;
      b_lds[bk][bc] = W[(size_t)(k0 + bk) * C + c0 + bc];
    }
    __syncthreads();
#pragma unroll
    for (int k = 0; k < 16; ++k) {
      float av[4], bv[4];
#pragma unroll
      for (int i = 0; i < 4; ++i) av[i] = a_lds[k][tr * 4 + i];
#pragma unroll
      for (int j = 0; j < 4; ++j) bv[j] = b_lds[k][tc * 4 + j];
#pragma unroll
      for (int i = 0; i < 4; ++i)
#pragma unroll
        for (int j = 0; j < 4; ++j) acc[i][j] = fmaf(av[i], bv[j], acc[i][j]);
    }
    __syncthreads();
  }
#pragma unroll
  for (int i = 0; i < 4; ++i) {
    int rr = r0 + tr * 4 + i;
#pragma unroll
    for (int j = 0; j < 4; ++j) Y[(size_t)rr * C + c0 + tc * 4 + j] = acc[i][j];
  }
  float s1[4] = {0.f, 0.f, 0.f, 0.f}, s2[4] = {0.f, 0.f, 0.f, 0.f};
#pragma unroll
  for (int i = 0; i < 4; ++i)
#pragma unroll
    for (int j = 0; j < 4; ++j) {
      s1[j] += acc[i][j];
      s2[j] = fmaf(acc[i][j], acc[i][j], s2[j]);
    }
#pragma unroll
  for (int j = 0; j < 4; ++j) red[(tc * 4 + j) * 17 + tr] = s1[j];
  __syncthreads();
  if (t < 64) {
    float s = 0.f;
    for (int q = 0; q < 16; ++q) s += red[t * 17 + q];
    atomicAdd(&stats[c0 + t], s);
  }
  __syncthreads();
#pragma unroll
  for (int j = 0; j < 4; ++j) red[(tc * 4 + j) * 17 + tr] = s2[j];
  __syncthreads();
  if (t < 64) {
    float s = 0.f;
    for (int q = 0; q < 16; ++q) s += red[t * 17 + q];
    atomicAdd(&stats[C + c0 + t], s);
  }
}

// ---------------------------------------------------------------------------
// MFMA GEMM Y = A@W with hi/lo bf16 (fp32-grade). A and W pre-packed
// fragment-major. Block = 4 waves, tile 64x64, BK=32; wave owns a 16-row
// strip x 4 col-tiles. AMODE 0: packed A only. AMODE 3: first 1024 k from
// per-batch broadcast g (row-major), last 128 from packed x12.
// DOMAX: skip Y, emit per-block column max to pmax. Stats always.
// ---------------------------------------------------------------------------
template <int AMODE, bool DOMAX>
__global__ __launch_bounds__(256) void gemm_mfma_kernel(
    const unsigned short* __restrict__ Ah, const unsigned short* __restrict__ Al,
    const unsigned short* __restrict__ gh, const unsigned short* __restrict__ gl,
    const unsigned short* __restrict__ Wh, const unsigned short* __restrict__ Wl,
    float* __restrict__ Y, float* __restrict__ pmax, float* __restrict__ stats,
    int K, int C) {
  __shared__ float red1[4][64], red2[4][64], redm[4][64];
  const int wave = threadIdx.x >> 6, lane = threadIdx.x & 63;
  const int rt  = blockIdx.x * 4 + wave;     // global 16-row tile
  const int c0  = blockIdx.y * 64;
  const int ct0 = blockIdx.y * 4;
  const int NK  = K >> 5;
  const int KP  = (AMODE == 3) ? 4 : NK;     // packed-A k-tiles
  f32x4 acc[4] = {{0.f,0.f,0.f,0.f},{0.f,0.f,0.f,0.f},{0.f,0.f,0.f,0.f},{0.f,0.f,0.f,0.f}};
  const int lhalf = (lane >> 4) << 3;
  for (int ks = 0; ks < NK; ++ks) {
    short8 ah, al;
    if (AMODE == 3 && ks < 32) {
      const int b = rt >> 8;                 // 256 row-tiles per batch
      const int go = b * 1024 + ks * 32 + lhalf;
      ah = *(const short8*)(gh + go);
      al = *(const short8*)(gl + go);
    } else {
      const int ksp = (AMODE == 3) ? ks - 32 : ks;
      const size_t aoff = (((size_t)rt * KP + ksp) * 64 + lane) * 8;
      ah = *(const short8*)(Ah + aoff);
      al = *(const short8*)(Al + aoff);
    }
#pragma unroll
    for (int cc = 0; cc < 4; ++cc) {
      const size_t woff = (((size_t)(ct0 + cc) * NK + ks) * 64 + lane) * 8;
      short8 bh = *(const short8*)(Wh + woff);
      short8 bl = *(const short8*)(Wl + woff);
      acc[cc] = __builtin_amdgcn_mfma_f32_16x16x32_bf16(al, bh, acc[cc], 0, 0, 0);
      acc[cc] = __builtin_amdgcn_mfma_f32_16x16x32_bf16(ah, bl, acc[cc], 0, 0, 0);
      acc[cc] = __builtin_amdgcn_mfma_f32_16x16x32_bf16(ah, bh, acc[cc], 0, 0, 0);
    }
  }
  // Y write: col = c0+cc*16+(lane&15), row = rt*16+(lane>>4)*4+i
#pragma unroll
  for (int cc = 0; cc < 4; ++cc) {
    if (!DOMAX) {
#pragma unroll
      for (int i = 0; i < 4; ++i)
        Y[(size_t)(rt * 16 + ((lane >> 4) << 2) + i) * C + c0 + cc * 16 + (lane & 15)] = acc[cc][i];
    }
    float s1 = acc[cc][0] + acc[cc][1] + acc[cc][2] + acc[cc][3];
    float s2 = acc[cc][0]*acc[cc][0] + acc[cc][1]*acc[cc][1] + acc[cc][2]*acc[cc][2] + acc[cc][3]*acc[cc][3];
    float mm = fmaxf(fmaxf(acc[cc][0], acc[cc][1]), fmaxf(acc[cc][2], acc[cc][3]));
    s1 += __shfl_xor(s1, 16); s1 += __shfl_xor(s1, 32);
    s2 += __shfl_xor(s2, 16); s2 += __shfl_xor(s2, 32);
    mm = fmaxf(mm, __shfl_xor(mm, 16)); mm = fmaxf(mm, __shfl_xor(mm, 32));
    if (lane < 16) {
      red1[wave][cc * 16 + lane] = s1;
      red2[wave][cc * 16 + lane] = s2;
      if (DOMAX) redm[wave][cc * 16 + lane] = mm;
    }
  }
  __syncthreads();
  if (threadIdx.x < 64) {
    const int t = threadIdx.x;
    float a = red1[0][t] + red1[1][t] + red1[2][t] + red1[3][t];
    float b = red2[0][t] + red2[1][t] + red2[2][t] + red2[3][t];
    atomicAdd(&stats[c0 + t], a);
    atomicAdd(&stats[C + c0 + t], b);
    if (DOMAX) {
      float mm = fmaxf(fmaxf(redm[0][t], redm[1][t]), fmaxf(redm[2][t], redm[3][t]));
      pmax[(size_t)blockIdx.x * C + c0 + t] = mm;
    }
  }
}

// g[b,c] = relu(bn(max over 64 row-tiles)) -> bf16 hi/lo
__global__ void fin_g_kernel(const float* __restrict__ pmax, const float* __restrict__ stats,
                             unsigned short* __restrict__ gh, unsigned short* __restrict__ gl) {
  int t = blockIdx.x * 256 + threadIdx.x;   // 4096
  int b = t >> 10, c = t & 1023;
  const float inv = 1.0f / 16384.0f;
  float m = stats[c] * inv;
  float v = fmaxf(stats[1024 + c] * inv - m * m, 0.0f);
  float rs = rsqrtf(v + EPSBN);
  float mx = -FLT_MAX;
  for (int s = 0; s < 64; ++s) mx = fmaxf(mx, pmax[(size_t)(b * 64 + s) * 1024 + c]);
  float val = fmaxf((mx - m) * rs, 0.0f);
  unsigned short h = f2bf(val);
  gh[t] = h; gl[t] = f2bf(val - bf2f(h));
}

__global__ void final13_kernel(const float* __restrict__ h, const float* __restrict__ W,
                               float* __restrict__ out) {
  int t = blockIdx.x * 256 + threadIdx.x;
  if (t >= RN * 13) return;
  int r = t / 13, c = t - r * 13;
  float acc = 0.0f;
  for (int k = 0; k < 256; ++k) acc = fmaf(h[(size_t)r * 256 + k], W[k * 13 + c], acc);
  int b = r >> 12, n = r & 4095;
  out[(size_t)b * 13 * NN + (size_t)c * NN + n] = acc;
}

// ---------------------------------------------------------------------------
extern "C" void kernel_launch(void* const* d_in, const int* in_sizes, int n_in,
                              void* d_out, int out_size, void* d_ws, size_t ws_size,
                              hipStream_t stream) {
  (void)in_sizes; (void)n_in; (void)out_size; (void)ws_size;
  const float* data = (const float*)d_in[0];
  const float* W_fc = (const float*)d_in[1];
  const float* b_fc = (const float*)d_in[2];
  const float* W1   = (const float*)d_in[3];
  const float* W2   = (const float*)d_in[4];
  const float* W3   = (const float*)d_in[5];
  const float* W4   = (const float*)d_in[6];
  const float* W5   = (const float*)d_in[7];
  const float* W6   = (const float*)d_in[8];
  const float* W10  = (const float*)d_in[9];
  const float* W11  = (const float*)d_in[10];
  const float* W12  = (const float*)d_in[11];
  const float* W13  = (const float*)d_in[12];
  float* out = (float*)d_out;

  float* ws  = (float*)d_ws;
  int*   idx = (int*)d_ws;
  size_t o = 262144;
  float* x0   = ws + o; o += (size_t)RN * 64;
  float* x1v  = ws + o; o += (size_t)RN * 64;
  float* x2v  = ws + o; o += (size_t)RN * 64;
  float* bufA = ws + o; o += (size_t)RN * 256;
  float* bufB = ws + o; o += (size_t)RN * 256;
  float* bufC = ws + o; o += (size_t)RN * 64;
  float* pmax = ws + o; o += (size_t)256 * 1024;
  float* h11  = ws + o; o += (size_t)RN * 512;
  float* h12  = ws + o; o += (size_t)RN * 256;
  float* stats = ws + o; o += 8192;
  float4* pack = (float4*)(ws + o); o += (size_t)RN * 4;
  unsigned short* xbh = (unsigned short*)(ws + o); o += (size_t)RN * 32;
  unsigned short* xbl = (unsigned short*)(ws + o); o += (size_t)RN * 32;
  float* W1p = ws + o; o += 16384;
  float* W4p = ws + o; o += 16384;
  unsigned short* W1mh = (unsigned short*)(ws + o); o += 8192;
  unsigned short* W1ml = (unsigned short*)(ws + o); o += 8192;
  unsigned short* W4mh = (unsigned short*)(ws + o); o += 8192;
  unsigned short* W4ml = (unsigned short*)(ws + o); o += 8192;
  float4* W1bt = (float4*)(ws + o); o += 1024;
  unsigned short* W10h = (unsigned short*)(ws + o); o += 65536;
  unsigned short* W10l = (unsigned short*)(ws + o); o += 65536;
  unsigned short* W11h = (unsigned short*)(ws + o); o += 294912;
  unsigned short* W11l = (unsigned short*)(ws + o); o += 294912;
  unsigned short* W12h = (unsigned short*)(ws + o); o += 65536;
  unsigned short* W12l = (unsigned short*)(ws + o); o += 65536;
  unsigned short* gh   = (unsigned short*)(ws + o); o += 2048;
  unsigned short* gl   = (unsigned short*)(ws + o); o += 2048;
  // overlays on dead buffers:
  unsigned short* x12h = (unsigned short*)bufC;   // RN*128 ushorts = RN*64 floats
  unsigned short* x12l = (unsigned short*)x0;
  unsigned short* h11h = (unsigned short*)bufA;   // RN*512 ushorts = 16MB
  unsigned short* h11l = (unsigned short*)bufB;

  float* S0 = stats;          // 64 (fc)
  float* S1 = stats + 128;    // 256 (edge1)
  float* S2 = stats + 640;    // 64  (W2)
  float* S3 = stats + 768;    // 64  (W3)
  float* S4 = stats + 896;    // 256 (edge2)
  float* S5 = stats + 1408;   // 64  (W5)
  float* S6 = stats + 1536;   // 64  (W6)
  float* S7 = stats + 1664;   // 1024 (W10)
  float* S8 = stats + 3712;   // 512 (W11)
  float* S9 = stats + 4736;   // 256 (W12)
  float* Sd = stats + 5248;   // dummy (512)

  hipMemsetAsync(stats, 0, 8192 * sizeof(float), stream);

  prep_kernel<<<RN / 256, 256, 0, stream>>>(data, pack);
  knn_kernel<<<RN / 4, 256, 0, stream>>>(pack, idx);
  prep_w_kernel<<<64, 256, 0, stream>>>(W1, W4, W1p, W1mh, W1ml, W1bt, W4p, W4mh, W4ml);
  prep_wpack_kernel<<<512, 256, 0, stream>>>(W10, W10h, W10l, 10, 131072, 4);
  prep_wpack_kernel<<<2304, 256, 0, stream>>>(W11, W11h, W11l, 9, 589824, 36);
  prep_wpack_kernel<<<512, 256, 0, stream>>>(W12, W12h, W12l, 8, 131072, 16);

  fc_kernel<<<RN * 64 / 256, 256, 0, stream>>>(data, W_fc, b_fc, x0, S0);
  bn_norm_kernel<<<RN * 64 / 256, 256, 0, stream>>>(x0, S0, 63, 64, 1.0f / RN, RN * 64);

  // edge conv 1
  tobf2_kernel<<<RN * 64 / 256, 256, 0, stream>>>(x0, xbh, xbl, RN * 64);
  gemm_kernel<0, false><<<dim3(256, 4), 256, 0, stream>>>(x0, W1p, bufB, Sd, 64, 256);
  edge_mfma_kernel<true><<<4096, 256, 0, stream>>>(xbh, xbl, idx, pack, W1mh, W1ml, W1bt, bufB, bufA, S1);
  bn_norm_kernel<<<RN * 256 / 256, 256, 0, stream>>>(bufA, S1, 255, 256, 1.0f / (RN * 16), RN * 256);

  agg_kernel<<<RN * 64 / 256, 256, 0, stream>>>(bufA, idx, bufB, 6);
  gemm_kernel<0, false><<<dim3(256, 1), 256, 0, stream>>>(bufB, W2, bufC, S2, 256, 64);
  bn_norm_kernel<<<RN * 64 / 256, 256, 0, stream>>>(bufC, S2, 63, 64, 1.0f / RN, RN * 64);

  agg_kernel<<<RN * 16 / 256, 256, 0, stream>>>(bufC, idx, bufB, 4);
  gemm_kernel<0, false><<<dim3(256, 1), 256, 0, stream>>>(bufB, W3, x1v, S3, 64, 64);
  bn_norm_kernel<<<RN * 64 / 256, 256, 0, stream>>>(x1v, S3, 63, 64, 1.0f / RN, RN * 64);

  // edge conv 2 (no pts)
  tobf2_kernel<<<RN * 64 / 256, 256, 0, stream>>>(x1v, xbh, xbl, RN * 64);
  gemm_kernel<0, false><<<dim3(256, 4), 256, 0, stream>>>(x1v, W4p, bufB, Sd, 64, 256);
  edge_mfma_kernel<false><<<4096, 256, 0, stream>>>(xbh, xbl, idx, pack, W4mh, W4ml, nullptr, bufB, bufA, S4);
  bn_norm_kernel<<<RN * 256 / 256, 256, 0, stream>>>(bufA, S4, 255, 256, 1.0f / (RN * 16), RN * 256);

  agg_kernel<<<RN * 64 / 256, 256, 0, stream>>>(bufA, idx, bufB, 6);
  gemm_kernel<0, false><<<dim3(256, 1), 256, 0, stream>>>(bufB, W5, bufC, S5, 256, 64);
  bn_norm_kernel<<<RN * 64 / 256, 256, 0, stream>>>(bufC, S5, 63, 64, 1.0f / RN, RN * 64);

  agg_kernel<<<RN * 16 / 256, 256, 0, stream>>>(bufC, idx, bufB, 4);
  gemm_kernel<0, false><<<dim3(256, 1), 256, 0, stream>>>(bufB, W6, x2v, S6, 64, 64);
  bn_norm_kernel<<<RN * 64 / 256, 256, 0, stream>>>(x2v, S6, 63, 64, 1.0f / RN, RN * 64);

  // pack [x1|x2] (bufC and x0 are dead now; overlay)
  pack_x12_kernel<<<RN * 128 / 256, 256, 0, stream>>>(x1v, x2v, x12h, x12l);

  // W10 path: MFMA, stats + per-row-tile col max only
  gemm_mfma_kernel<0, true><<<dim3(256, 16), 256, 0, stream>>>(
      x12h, x12l, nullptr, nullptr, W10h, W10l, nullptr, pmax, S7, 128, 1024);
  fin_g_kernel<<<16, 256, 0, stream>>>(pmax, S7, gh, gl);

  // W11: [g | x12] @ W11 -> h11
  gemm_mfma_kernel<3, false><<<dim3(256, 8), 256, 0, stream>>>(
      x12h, x12l, gh, gl, W11h, W11l, h11, nullptr, S8, 1152, 512);
  bn_pack_kernel<<<RN * 512 / 256, 256, 0, stream>>>(h11, S8, h11h, h11l);

  // W12: h11 @ W12 -> h12
  gemm_mfma_kernel<0, false><<<dim3(256, 4), 256, 0, stream>>>(
      h11h, h11l, nullptr, nullptr, W12h, W12l, h12, nullptr, S9, 512, 256);
  bn_norm_kernel<<<RN * 256 / 256, 256, 0, stream>>>(h12, S9, 255, 256, 1.0f / RN, RN * 256);

  final13_kernel<<<(RN * 13 + 255) / 256, 256, 0, stream>>>(h12, W13, out);
}

// Round 6
// 860.254 us; speedup vs baseline: 2.8200x; 1.1477x over previous
//
#include <hip/hip_runtime.h>
#include <hip/hip_bf16.h>
#include <float.h>

static constexpr int BB  = 4;
static constexpr int NN  = 4096;
static constexpr int KSN = 16;
static constexpr int RN  = BB * NN;     // 16384 rows (b,n)
#define EPSBN 1e-5f

typedef __attribute__((ext_vector_type(8))) short short8;
typedef __attribute__((ext_vector_type(4))) float f32x4;

__device__ inline unsigned short f2bf(float f) {
  union { float f; unsigned u; } v; v.f = f;
  unsigned r = v.u + 0x7FFF + ((v.u >> 16) & 1);
  return (unsigned short)(r >> 16);
}
__device__ inline float bf2f(unsigned short h) {
  union { unsigned u; float f; } v; v.u = ((unsigned)h) << 16; return v.f;
}

// ---------------------------------------------------------------------------
// Prep: pack (x,y,z,|p|^2) as float4 per point.
// ---------------------------------------------------------------------------
__global__ void prep_kernel(const float* __restrict__ data, float4* __restrict__ pack) {
  int t = blockIdx.x * 256 + threadIdx.x;
  if (t >= RN) return;
  const float* dr = data + (size_t)t * 9;
  float x = dr[0], y = dr[1], z = dr[2];
  pack[t] = make_float4(x, y, z, fmaf(z, z, fmaf(y, y, x * x)));
}

// ---------------------------------------------------------------------------
// Weight prep for edge convs.
// ---------------------------------------------------------------------------
__global__ void prep_w_kernel(const float* __restrict__ W1, const float* __restrict__ W4,
                              float* __restrict__ W1p,
                              unsigned short* __restrict__ W1mh, unsigned short* __restrict__ W1ml,
                              float4* __restrict__ W1bt,
                              float* __restrict__ W4p,
                              unsigned short* __restrict__ W4mh, unsigned short* __restrict__ W4ml) {
  int t = blockIdx.x * 256 + threadIdx.x;   // 16384
  int k = t >> 8, cc = t & 255;
  float w1top = W1[k * 256 + cc], w1mid = W1[(64 + k) * 256 + cc];
  W1p[t] = w1top - w1mid;
  unsigned short h1 = f2bf(w1mid);
  W1mh[cc * 64 + k] = h1;
  W1ml[cc * 64 + k] = f2bf(w1mid - bf2f(h1));
  float w4top = W4[k * 256 + cc], w4mid = W4[(64 + k) * 256 + cc];
  W4p[t] = w4top - w4mid;
  unsigned short h4 = f2bf(w4mid);
  W4mh[cc * 64 + k] = h4;
  W4ml[cc * 64 + k] = f2bf(w4mid - bf2f(h4));
  if (t < 256) W1bt[t] = make_float4(W1[128 * 256 + t], W1[129 * 256 + t], W1[130 * 256 + t], 0.f);
}

// W -> fragment-major hi/lo pack: dst[ct][ks][lane][8]
__global__ void prep_wpack_kernel(const float* __restrict__ W,
                                  unsigned short* __restrict__ wh, unsigned short* __restrict__ wl,
                                  int lgC, int total, int NK) {
  int t = blockIdx.x * 256 + threadIdx.x;
  if (t >= total) return;
  int k = t >> lgC, c = t & ((1 << lgC) - 1);
  float v = W[t];
  int ct = c >> 4, cl = c & 15, ks = k >> 5, kl = k & 31;
  int dst = ((ct * NK + ks) * 64 + (((kl >> 3) << 4) | cl)) * 8 + (kl & 7);
  unsigned short h = f2bf(v);
  wh[dst] = h; wl[dst] = f2bf(v - bf2f(h));
}

// [x1|x2] -> fragment-major hi/lo pack (K=128)
__global__ void pack_x12_kernel(const float* __restrict__ x1, const float* __restrict__ x2,
                                unsigned short* __restrict__ ph, unsigned short* __restrict__ pl) {
  int t = blockIdx.x * 256 + threadIdx.x;   // RN*128
  int r = t >> 7, k = t & 127;
  float v = (k < 64) ? x1[(size_t)r * 64 + k] : x2[(size_t)r * 64 + k - 64];
  int rt = r >> 4, rl = r & 15, ks = k >> 5, kl = k & 31;
  int dst = ((rt * 4 + ks) * 64 + (((kl >> 3) << 4) | rl)) * 8 + (kl & 7);
  unsigned short h = f2bf(v);
  ph[dst] = h; pl[dst] = f2bf(v - bf2f(h));
}

// BN+ReLU on h11 (C=512) fused with fragment-major hi/lo pack
__global__ void bn_pack_kernel(const float* __restrict__ buf, const float* __restrict__ stats,
                               unsigned short* __restrict__ ph, unsigned short* __restrict__ pl) {
  int t = blockIdx.x * 256 + threadIdx.x;   // RN*512
  int c = t & 511, r = t >> 9;
  const float inv = 1.0f / RN;
  float m = stats[c] * inv;
  float v = fmaxf(stats[512 + c] * inv - m * m, 0.0f);
  float x = fmaxf((buf[t] - m) * rsqrtf(v + EPSBN), 0.0f);
  int rt = r >> 4, rl = r & 15, ks = c >> 5, kl = c & 31;
  int dst = ((rt * 16 + ks) * 64 + (((kl >> 3) << 4) | rl)) * 8 + (kl & 7);
  unsigned short h = f2bf(x);
  ph[dst] = h; pl[dst] = f2bf(x - bf2f(h));
}

// BN+ReLU in place (C=64) fused with row-major hi/lo write (edge-conv input)
__global__ void bn_normpack_kernel(float* __restrict__ buf, const float* __restrict__ stats,
                                   unsigned short* __restrict__ hi, unsigned short* __restrict__ lo) {
  int t = blockIdx.x * 256 + threadIdx.x;   // RN*64
  int c = t & 63;
  const float inv = 1.0f / RN;
  float m = stats[c] * inv;
  float v = fmaxf(stats[64 + c] * inv - m * m, 0.0f);
  float x = fmaxf((buf[t] - m) * rsqrtf(v + EPSBN), 0.0f);
  buf[t] = x;
  unsigned short h = f2bf(x);
  hi[t] = h; lo[t] = f2bf(x - bf2f(h));
}

// ---------------------------------------------------------------------------
// KNN: one wave per point, branchless sorted top-4 per lane (validated r5).
// ---------------------------------------------------------------------------
__global__ __launch_bounds__(256) void knn_kernel(const float4* __restrict__ pack,
                                                  int* __restrict__ idx) {
  const int lane = threadIdx.x & 63;
  const int p = blockIdx.x * 4 + (threadIdx.x >> 6);
  const int b = p >> 12;
  const float4* __restrict__ pb = pack + ((size_t)b << 12);
  const float4 me = pack[p];
  unsigned long long m0 = ~0ull, m1 = ~0ull, m2 = ~0ull, m3 = ~0ull;
#pragma unroll 8
  for (int s = 0; s < 64; ++s) {
    const float4 q = pb[s * 64 + lane];
    float d = me.w + q.w - 2.0f * fmaf(me.x, q.x, fmaf(me.y, q.y, me.z * q.z));
    unsigned ub = __float_as_uint(d);
    ub = (ub & 0x80000000u) ? ~ub : (ub | 0x80000000u);
    unsigned long long k = ((unsigned long long)ub << 12) | (unsigned)(s * 64 + lane);
    if (k < m3) {
      bool l0 = k < m0;  unsigned long long t0 = l0 ? m0 : k;  m0 = l0 ? k : m0;
      bool l1 = t0 < m1; unsigned long long t1 = l1 ? m1 : t0; m1 = l1 ? t0 : m1;
      bool l2 = t1 < m2; unsigned long long t2 = l2 ? m2 : t1; m2 = l2 ? t1 : m2;
      m3 = (t2 < m3) ? t2 : m3;
    }
  }
  for (int pass = 0; pass < 16; ++pass) {
    unsigned long long w = m0;
#pragma unroll
    for (int mv = 1; mv < 64; mv <<= 1) {
      unsigned long long o = __shfl_xor(w, mv);
      w = (o < w) ? o : w;
    }
    if (lane == pass) idx[(p << 4) + pass] = (int)(w & 0xFFFull);
    if (m0 == w) { m0 = m1; m1 = m2; m2 = m3; m3 = ~0ull; }
    if (pass < 15 && __any(m0 == ~0ull)) {
      if (m0 == ~0ull) {
        m1 = ~0ull; m2 = ~0ull; m3 = ~0ull;
#pragma unroll 8
        for (int s = 0; s < 64; ++s) {
          const float4 q = pb[s * 64 + lane];
          float d = me.w + q.w - 2.0f * fmaf(me.x, q.x, fmaf(me.y, q.y, me.z * q.z));
          unsigned ub = __float_as_uint(d);
          ub = (ub & 0x80000000u) ? ~ub : (ub | 0x80000000u);
          unsigned long long k = ((unsigned long long)ub << 12) | (unsigned)(s * 64 + lane);
          k = (k > w) ? k : ~0ull;
          bool l0 = k < m0;  unsigned long long t0 = l0 ? m0 : k;  m0 = l0 ? k : m0;
          bool l1 = t0 < m1; unsigned long long t1 = l1 ? m1 : t0; m1 = l1 ? t0 : m1;
          bool l2 = t1 < m2; unsigned long long t2 = l2 ? m2 : t1; m2 = l2 ? t1 : m2;
          m3 = (t2 < m3) ? t2 : m3;
        }
      }
    }
  }
}

// ---------------------------------------------------------------------------
// fc: y = data @ W_fc + b_fc (K=9, C=64) + column stats.
// ---------------------------------------------------------------------------
__global__ __launch_bounds__(256) void fc_kernel(const float* __restrict__ data,
                                                 const float* __restrict__ W,
                                                 const float* __restrict__ bias,
                                                 float* __restrict__ y,
                                                 float* __restrict__ stats) {
  const int t = blockIdx.x * 256 + threadIdx.x;
  const int r = t >> 6, c = t & 63;
  const float* dr = data + (size_t)r * 9;
  float acc = bias[c];
#pragma unroll
  for (int k = 0; k < 9; ++k) acc = fmaf(dr[k], W[k * 64 + c], acc);
  y[t] = acc;
  __shared__ float red[256];
  red[threadIdx.x] = acc;
  __syncthreads();
  if (threadIdx.x < 64) {
    float s = red[threadIdx.x] + red[threadIdx.x + 64] + red[threadIdx.x + 128] + red[threadIdx.x + 192];
    atomicAdd(&stats[threadIdx.x], s);
  }
  __syncthreads();
  red[threadIdx.x] = acc * acc;
  __syncthreads();
  if (threadIdx.x < 64) {
    float s = red[threadIdx.x] + red[threadIdx.x + 64] + red[threadIdx.x + 128] + red[threadIdx.x + 192];
    atomicAdd(&stats[64 + threadIdx.x], s);
  }
}

// ---------------------------------------------------------------------------
// BN(+ReLU) normalize in place.
// ---------------------------------------------------------------------------
__global__ void bn_norm_kernel(float* __restrict__ buf, const float* __restrict__ stats,
                               int cmask, int C, float inv_cnt, int total) {
  int t = blockIdx.x * 256 + threadIdx.x;
  if (t >= total) return;
  int c = t & cmask;
  float m = stats[c] * inv_cnt;
  float v = fmaxf(stats[C + c] * inv_cnt - m * m, 0.0f);
  float rs = rsqrtf(v + EPSBN);
  float x = (buf[t] - m) * rs;
  buf[t] = fmaxf(x, 0.0f);
}

// ---------------------------------------------------------------------------
// Edge conv via MFMA, v2: wave = 16 points x 64 cols (4 col-tiles). All 16
// B-fragments (hi/lo) live in registers; per point 4 gathered A loads feed
// 24 MFMAs. Software-pipelined: idx prefetched 2 points ahead, A-frags 1
// point ahead (named regs, all-static indices). hi/lo split = fp32-grade.
// ---------------------------------------------------------------------------
template <bool HAS_PTS>
__global__ __launch_bounds__(256) void edge_mfma_kernel(
    const unsigned short* __restrict__ Xh, const unsigned short* __restrict__ Xl,
    const int* __restrict__ idx,
    const float4* __restrict__ pack,
    const unsigned short* __restrict__ Wmh, const unsigned short* __restrict__ Wml,
    const float4* __restrict__ Wbt, const float* __restrict__ basemat,
    float* __restrict__ out, float* __restrict__ stats) {
  const int wave = threadIdx.x >> 6;
  const int lane = threadIdx.x & 63;
  const int pg   = blockIdx.x;            // 0..1023, 16 points each
  const int c0   = wave << 6;             // col quarter
  const int cl   = lane & 15;
  const int kg   = (lane >> 4) << 3;
  const int bat  = pg >> 8;               // batch (constant per block)
  const int pbase = bat << 12;
  const int ib   = pg << 8;               // idx base

  short8 bh[4][2], blo[4][2];
#pragma unroll
  for (int q = 0; q < 4; ++q) {
    const unsigned short* wp = Wmh + (size_t)(c0 + q * 16 + cl) * 64 + kg;
    bh[q][0] = *(const short8*)wp; bh[q][1] = *(const short8*)(wp + 32);
    const unsigned short* wq = Wml + (size_t)(c0 + q * 16 + cl) * 64 + kg;
    blo[q][0] = *(const short8*)wq; blo[q][1] = *(const short8*)(wq + 32);
  }
  float4 wb[4];
  if (HAS_PTS) {
#pragma unroll
    for (int q = 0; q < 4; ++q) wb[q] = Wbt[c0 + q * 16 + cl];
  }
  float rs1[4] = {0.f, 0.f, 0.f, 0.f}, rs2[4] = {0.f, 0.f, 0.f, 0.f};

  // pipeline prologue: idx for p0,p1; frags for p0
  int jn = idx[ib + 16 + cl];
  {
  }
  int j0 = idx[ib + cl];
  size_t ro = ((size_t)(pbase | j0) << 6) + kg;
  short8 a0h = *(const short8*)(Xh + ro);
  short8 a1h = *(const short8*)(Xh + ro + 32);
  short8 a0l = *(const short8*)(Xl + ro);
  short8 a1l = *(const short8*)(Xl + ro + 32);

  for (int pp = 0; pp < 16; ++pp) {
    const int p = (pg << 4) | pp;
    // prefetch idx two ahead
    int jf = 0;
    if (pp < 14) jf = idx[ib + ((pp + 2) << 4) + cl];
    // prefetch next point's A frags
    short8 n0h, n1h, n0l, n1l;
    if (pp < 15) {
      size_t rn = ((size_t)(pbase | jn) << 6) + kg;
      n0h = *(const short8*)(Xh + rn);
      n1h = *(const short8*)(Xh + rn + 32);
      n0l = *(const short8*)(Xl + rn);
      n1l = *(const short8*)(Xl + rn + 32);
    }
    // HAS_PTS loads (independent)
    float dx0, dy0, dz0, dx1, dy1, dz1, dx2, dy2, dz2, dx3, dy3, dz3;
    if (HAS_PTS) {
      const int4 j4 = *(const int4*)(idx + (p << 4) + ((lane >> 4) << 2));
      const float4 pc = pack[p];
      const float4 q0 = pack[pbase | j4.x];
      const float4 q1 = pack[pbase | j4.y];
      const float4 q2 = pack[pbase | j4.z];
      const float4 q3 = pack[pbase | j4.w];
      dx0 = q0.x - pc.x; dy0 = q0.y - pc.y; dz0 = q0.z - pc.z;
      dx1 = q1.x - pc.x; dy1 = q1.y - pc.y; dz1 = q1.z - pc.z;
      dx2 = q2.x - pc.x; dy2 = q2.y - pc.y; dz2 = q2.z - pc.z;
      dx3 = q3.x - pc.x; dy3 = q3.y - pc.y; dz3 = q3.z - pc.z;
    }
    f32x4 acc[4];
#pragma unroll
    for (int q = 0; q < 4; ++q) {
      acc[q][0] = 0.f; acc[q][1] = 0.f; acc[q][2] = 0.f; acc[q][3] = 0.f;
    }
#pragma unroll
    for (int q = 0; q < 4; ++q) {
      acc[q] = __builtin_amdgcn_mfma_f32_16x16x32_bf16(a0l, bh[q][0], acc[q], 0, 0, 0);
      acc[q] = __builtin_amdgcn_mfma_f32_16x16x32_bf16(a1l, bh[q][1], acc[q], 0, 0, 0);
      acc[q] = __builtin_amdgcn_mfma_f32_16x16x32_bf16(a0h, blo[q][0], acc[q], 0, 0, 0);
      acc[q] = __builtin_amdgcn_mfma_f32_16x16x32_bf16(a1h, blo[q][1], acc[q], 0, 0, 0);
      acc[q] = __builtin_amdgcn_mfma_f32_16x16x32_bf16(a0h, bh[q][0], acc[q], 0, 0, 0);
      acc[q] = __builtin_amdgcn_mfma_f32_16x16x32_bf16(a1h, bh[q][1], acc[q], 0, 0, 0);
    }
    if (HAS_PTS) {
#pragma unroll
      for (int q = 0; q < 4; ++q) {
        acc[q][0] += dx0 * wb[q].x + dy0 * wb[q].y + dz0 * wb[q].z;
        acc[q][1] += dx1 * wb[q].x + dy1 * wb[q].y + dz1 * wb[q].z;
        acc[q][2] += dx2 * wb[q].x + dy2 * wb[q].y + dz2 * wb[q].z;
        acc[q][3] += dx3 * wb[q].x + dy3 * wb[q].y + dz3 * wb[q].z;
      }
    }
#pragma unroll
    for (int q = 0; q < 4; ++q) {
      float s1 = acc[q][0] + acc[q][1] + acc[q][2] + acc[q][3];
      float s2 = acc[q][0] * acc[q][0] + acc[q][1] * acc[q][1]
               + acc[q][2] * acc[q][2] + acc[q][3] * acc[q][3];
      float mx = fmaxf(fmaxf(acc[q][0], acc[q][1]), fmaxf(acc[q][2], acc[q][3]));
      s1 += __shfl_xor(s1, 16); s1 += __shfl_xor(s1, 32);
      s2 += __shfl_xor(s2, 16); s2 += __shfl_xor(s2, 32);
      mx = fmaxf(mx, __shfl_xor(mx, 16)); mx = fmaxf(mx, __shfl_xor(mx, 32));
      float bb = basemat[(size_t)p * 256 + c0 + q * 16 + cl];
      if (lane < 16) out[(size_t)p * 256 + c0 + q * 16 + cl] = mx + bb;
      rs1[q] += s1 + 16.f * bb;
      rs2[q] += s2 + 2.f * bb * s1 + 16.f * bb * bb;
    }
    a0h = n0h; a1h = n1h; a0l = n0l; a1l = n1l;
    jn = jf;
  }
  if (lane < 16) {
#pragma unroll
    for (int q = 0; q < 4; ++q) {
      atomicAdd(&stats[c0 + q * 16 + lane], rs1[q]);
      atomicAdd(&stats[256 + c0 + q * 16 + lane], rs2[q]);
    }
  }
}

// ---------------------------------------------------------------------------
// agg[r,c] = max over 16 neighbors, float4 per thread. lg = log2(C/4).
// ---------------------------------------------------------------------------
__global__ void agg_kernel(const float* __restrict__ X, const int* __restrict__ idx,
                           float* __restrict__ out, int lg) {
  const int c4 = 1 << lg;
  int t = blockIdx.x * 256 + threadIdx.x;
  int total = RN * c4;
  if (t >= total) return;
  int r = t >> lg, cq = t & (c4 - 1);
  int base = (r >> 12) << 12;
  const int* ip = idx + (size_t)r * KSN;
  float4 mx = make_float4(-FLT_MAX, -FLT_MAX, -FLT_MAX, -FLT_MAX);
  const int C = c4 * 4;
#pragma unroll
  for (int k = 0; k < KSN; ++k) {
    int j = ip[k];
    const float4 v = *reinterpret_cast<const float4*>(X + (size_t)(base + j) * C + cq * 4);
    mx.x = fmaxf(mx.x, v.x); mx.y = fmaxf(mx.y, v.y);
    mx.z = fmaxf(mx.z, v.z); mx.w = fmaxf(mx.w, v.w);
  }
  *reinterpret_cast<float4*>(out + (size_t)r * C + cq * 4) = mx;
}

// ---------------------------------------------------------------------------
// fp32 GEMM for small layers.
// ---------------------------------------------------------------------------
template <int MODE, bool DOMAX>
__global__ __launch_bounds__(256) void gemm_kernel(const float* __restrict__ A,
                                                   const float* __restrict__ W,
                                                   float* __restrict__ Y,
                                                   float* __restrict__ stats,
                                                   int K, int C) {
  __shared__ float a_lds[16][65];
  __shared__ float b_lds[16][64];
  __shared__ float red[64 * 17];
  const int t  = threadIdx.x;
  const int r0 = blockIdx.x * 64, c0 = blockIdx.y * 64;
  const int tr = t >> 4, tc = t & 15;
  float acc[4][4] = {{0.f}};
  for (int k0 = 0; k0 < K; k0 += 16) {
#pragma unroll
    for (int i = 0; i < 4; ++i) {
      int e = t + i * 256;
      int ar = e >> 4, ak = e & 15;
      a_lds[ak][ar] = A[(size_t)(r0 + ar) * K + k0 + ak];
    }
#pragma unroll
    for (int i = 0; i < 4; ++i) {
      int e = t + i * 256;
      int bk = e >> 6, bc = e & 63;
      b_lds[bk][bc] = W[(size_t)(k0 + bk) * C + c0 + bc];
    }
    __syncthreads();
#pragma unroll
    for (int k = 0; k < 16; ++k) {
      float av[4], bv[4];
#pragma unroll
      for (int i = 0; i < 4; ++i) av[i] = a_lds[k][tr * 4 + i];
#pragma unroll
      for (int j = 0; j < 4; ++j) bv[j] = b_lds[k][tc * 4 + j];
#pragma unroll
      for (int i = 0; i < 4; ++i)
#pragma unroll
        for (int j = 0; j < 4; ++j) acc[i][j] = fmaf(av[i], bv[j], acc[i][j]);
    }
    __syncthreads();
  }
#pragma unroll
  for (int i = 0; i < 4; ++i) {
    int rr = r0 + tr * 4 + i;
#pragma unroll
    for (int j = 0; j < 4; ++j) Y[(size_t)rr * C + c0 + tc * 4 + j] = acc[i][j];
  }
  float s1[4] = {0.f, 0.f, 0.f, 0.f}, s2[4] = {0.f, 0.f, 0.f, 0.f};
#pragma unroll
  for (int i = 0; i < 4; ++i)
#pragma unroll
    for (int j = 0; j < 4; ++j) {
      s1[j] += acc[i][j];
      s2[j] = fmaf(acc[i][j], acc[i][j], s2[j]);
    }
#pragma unroll
  for (int j = 0; j < 4; ++j) red[(tc * 4 + j) * 17 + tr] = s1[j];
  __syncthreads();
  if (t < 64) {
    float s = 0.f;
    for (int q = 0; q < 16; ++q) s += red[t * 17 + q];
    atomicAdd(&stats[c0 + t], s);
  }
  __syncthreads();
#pragma unroll
  for (int j = 0; j < 4; ++j) red[(tc * 4 + j) * 17 + tr] = s2[j];
  __syncthreads();
  if (t < 64) {
    float s = 0.f;
    for (int q = 0; q < 16; ++q) s += red[t * 17 + q];
    atomicAdd(&stats[C + c0 + t], s);
  }
}

// ---------------------------------------------------------------------------
// MFMA GEMM Y = A@W with hi/lo bf16 (validated round 5).
// ---------------------------------------------------------------------------
template <int AMODE, bool DOMAX>
__global__ __launch_bounds__(256) void gemm_mfma_kernel(
    const unsigned short* __restrict__ Ah, const unsigned short* __restrict__ Al,
    const unsigned short* __restrict__ gh, const unsigned short* __restrict__ gl,
    const unsigned short* __restrict__ Wh, const unsigned short* __restrict__ Wl,
    float* __restrict__ Y, float* __restrict__ pmax, float* __restrict__ stats,
    int K, int C) {
  __shared__ float red1[4][64], red2[4][64], redm[4][64];
  const int wave = threadIdx.x >> 6, lane = threadIdx.x & 63;
  const int rt  = blockIdx.x * 4 + wave;
  const int c0  = blockIdx.y * 64;
  const int ct0 = blockIdx.y * 4;
  const int NK  = K >> 5;
  const int KP  = (AMODE == 3) ? 4 : NK;
  f32x4 acc[4] = {{0.f,0.f,0.f,0.f},{0.f,0.f,0.f,0.f},{0.f,0.f,0.f,0.f},{0.f,0.f,0.f,0.f}};
  const int lhalf = (lane >> 4) << 3;
  for (int ks = 0; ks < NK; ++ks) {
    short8 ah, al;
    if (AMODE == 3 && ks < 32) {
      const int b = rt >> 8;
      const int go = b * 1024 + ks * 32 + lhalf;
      ah = *(const short8*)(gh + go);
      al = *(const short8*)(gl + go);
    } else {
      const int ksp = (AMODE == 3) ? ks - 32 : ks;
      const size_t aoff = (((size_t)rt * KP + ksp) * 64 + lane) * 8;
      ah = *(const short8*)(Ah + aoff);
      al = *(const short8*)(Al + aoff);
    }
#pragma unroll
    for (int cc = 0; cc < 4; ++cc) {
      const size_t woff = (((size_t)(ct0 + cc) * NK + ks) * 64 + lane) * 8;
      short8 bh = *(const short8*)(Wh + woff);
      short8 bl = *(const short8*)(Wl + woff);
      acc[cc] = __builtin_amdgcn_mfma_f32_16x16x32_bf16(al, bh, acc[cc], 0, 0, 0);
      acc[cc] = __builtin_amdgcn_mfma_f32_16x16x32_bf16(ah, bl, acc[cc], 0, 0, 0);
      acc[cc] = __builtin_amdgcn_mfma_f32_16x16x32_bf16(ah, bh, acc[cc], 0, 0, 0);
    }
  }
#pragma unroll
  for (int cc = 0; cc < 4; ++cc) {
    if (!DOMAX) {
#pragma unroll
      for (int i = 0; i < 4; ++i)
        Y[(size_t)(rt * 16 + ((lane >> 4) << 2) + i) * C + c0 + cc * 16 + (lane & 15)] = acc[cc][i];
    }
    float s1 = acc[cc][0] + acc[cc][1] + acc[cc][2] + acc[cc][3];
    float s2 = acc[cc][0]*acc[cc][0] + acc[cc][1]*acc[cc][1] + acc[cc][2]*acc[cc][2] + acc[cc][3]*acc[cc][3];
    float mm = fmaxf(fmaxf(acc[cc][0], acc[cc][1]), fmaxf(acc[cc][2], acc[cc][3]));
    s1 += __shfl_xor(s1, 16); s1 += __shfl_xor(s1, 32);
    s2 += __shfl_xor(s2, 16); s2 += __shfl_xor(s2, 32);
    mm = fmaxf(mm, __shfl_xor(mm, 16)); mm = fmaxf(mm, __shfl_xor(mm, 32));
    if (lane < 16) {
      red1[wave][cc * 16 + lane] = s1;
      red2[wave][cc * 16 + lane] = s2;
      if (DOMAX) redm[wave][cc * 16 + lane] = mm;
    }
  }
  __syncthreads();
  if (threadIdx.x < 64) {
    const int t = threadIdx.x;
    float a = red1[0][t] + red1[1][t] + red1[2][t] + red1[3][t];
    float b = red2[0][t] + red2[1][t] + red2[2][t] + red2[3][t];
    atomicAdd(&stats[c0 + t], a);
    atomicAdd(&stats[C + c0 + t], b);
    if (DOMAX) {
      float mm = fmaxf(fmaxf(redm[0][t], redm[1][t]), fmaxf(redm[2][t], redm[3][t]));
      pmax[(size_t)blockIdx.x * C + c0 + t] = mm;
    }
  }
}

// g[b,c] = relu(bn(max over 64 row-tiles)) -> bf16 hi/lo
__global__ void fin_g_kernel(const float* __restrict__ pmax, const float* __restrict__ stats,
                             unsigned short* __restrict__ gh, unsigned short* __restrict__ gl) {
  int t = blockIdx.x * 256 + threadIdx.x;   // 4096
  int b = t >> 10, c = t & 1023;
  const float inv = 1.0f / 16384.0f;
  float m = stats[c] * inv;
  float v = fmaxf(stats[1024 + c] * inv - m * m, 0.0f);
  float rs = rsqrtf(v + EPSBN);
  float mx = -FLT_MAX;
  for (int s = 0; s < 64; ++s) mx = fmaxf(mx, pmax[(size_t)(b * 64 + s) * 1024 + c]);
  float val = fmaxf((mx - m) * rs, 0.0f);
  unsigned short h = f2bf(val);
  gh[t] = h; gl[t] = f2bf(val - bf2f(h));
}

__global__ void final13_kernel(const float* __restrict__ h, const float* __restrict__ W,
                               float* __restrict__ out) {
  int t = blockIdx.x * 256 + threadIdx.x;
  if (t >= RN * 13) return;
  int r = t / 13, c = t - r * 13;
  float acc = 0.0f;
  for (int k = 0; k < 256; ++k) acc = fmaf(h[(size_t)r * 256 + k], W[k * 13 + c], acc);
  int b = r >> 12, n = r & 4095;
  out[(size_t)b * 13 * NN + (size_t)c * NN + n] = acc;
}

// ---------------------------------------------------------------------------
extern "C" void kernel_launch(void* const* d_in, const int* in_sizes, int n_in,
                              void* d_out, int out_size, void* d_ws, size_t ws_size,
                              hipStream_t stream) {
  (void)in_sizes; (void)n_in; (void)out_size; (void)ws_size;
  const float* data = (const float*)d_in[0];
  const float* W_fc = (const float*)d_in[1];
  const float* b_fc = (const float*)d_in[2];
  const float* W1   = (const float*)d_in[3];
  const float* W2   = (const float*)d_in[4];
  const float* W3   = (const float*)d_in[5];
  const float* W4   = (const float*)d_in[6];
  const float* W5   = (const float*)d_in[7];
  const float* W6   = (const float*)d_in[8];
  const float* W10  = (const float*)d_in[9];
  const float* W11  = (const float*)d_in[10];
  const float* W12  = (const float*)d_in[11];
  const float* W13  = (const float*)d_in[12];
  float* out = (float*)d_out;

  float* ws  = (float*)d_ws;
  int*   idx = (int*)d_ws;
  size_t o = 262144;
  float* x0   = ws + o; o += (size_t)RN * 64;
  float* x1v  = ws + o; o += (size_t)RN * 64;
  float* x2v  = ws + o; o += (size_t)RN * 64;
  float* bufA = ws + o; o += (size_t)RN * 256;
  float* bufB = ws + o; o += (size_t)RN * 256;
  float* bufC = ws + o; o += (size_t)RN * 64;
  float* pmax = ws + o; o += (size_t)256 * 1024;
  float* h11  = ws + o; o += (size_t)RN * 512;
  float* h12  = ws + o; o += (size_t)RN * 256;
  float* stats = ws + o; o += 8192;
  float4* pack = (float4*)(ws + o); o += (size_t)RN * 4;
  unsigned short* xbh = (unsigned short*)(ws + o); o += (size_t)RN * 32;
  unsigned short* xbl = (unsigned short*)(ws + o); o += (size_t)RN * 32;
  float* W1p = ws + o; o += 16384;
  float* W4p = ws + o; o += 16384;
  unsigned short* W1mh = (unsigned short*)(ws + o); o += 8192;
  unsigned short* W1ml = (unsigned short*)(ws + o); o += 8192;
  unsigned short* W4mh = (unsigned short*)(ws + o); o += 8192;
  unsigned short* W4ml = (unsigned short*)(ws + o); o += 8192;
  float4* W1bt = (float4*)(ws + o); o += 1024;
  unsigned short* W10h = (unsigned short*)(ws + o); o += 65536;
  unsigned short* W10l = (unsigned short*)(ws + o); o += 65536;
  unsigned short* W11h = (unsigned short*)(ws + o); o += 294912;
  unsigned short* W11l = (unsigned short*)(ws + o); o += 294912;
  unsigned short* W12h = (unsigned short*)(ws + o); o += 65536;
  unsigned short* W12l = (unsigned short*)(ws + o); o += 65536;
  unsigned short* gh   = (unsigned short*)(ws + o); o += 2048;
  unsigned short* gl   = (unsigned short*)(ws + o); o += 2048;
  // overlays on dead buffers:
  unsigned short* x12h = (unsigned short*)bufC;
  unsigned short* x12l = (unsigned short*)x0;
  unsigned short* h11h = (unsigned short*)bufA;
  unsigned short* h11l = (unsigned short*)bufB;

  float* S0 = stats;          // 64 (fc)
  float* S1 = stats + 128;    // 256 (edge1)
  float* S2 = stats + 640;    // 64  (W2)
  float* S3 = stats + 768;    // 64  (W3)
  float* S4 = stats + 896;    // 256 (edge2)
  float* S5 = stats + 1408;   // 64  (W5)
  float* S6 = stats + 1536;   // 64  (W6)
  float* S7 = stats + 1664;   // 1024 (W10)
  float* S8 = stats + 3712;   // 512 (W11)
  float* S9 = stats + 4736;   // 256 (W12)
  float* Sd = stats + 5248;   // dummy (512)

  hipMemsetAsync(stats, 0, 8192 * sizeof(float), stream);

  prep_kernel<<<RN / 256, 256, 0, stream>>>(data, pack);
  knn_kernel<<<RN / 4, 256, 0, stream>>>(pack, idx);
  prep_w_kernel<<<64, 256, 0, stream>>>(W1, W4, W1p, W1mh, W1ml, W1bt, W4p, W4mh, W4ml);
  prep_wpack_kernel<<<512, 256, 0, stream>>>(W10, W10h, W10l, 10, 131072, 4);
  prep_wpack_kernel<<<2304, 256, 0, stream>>>(W11, W11h, W11l, 9, 589824, 36);
  prep_wpack_kernel<<<512, 256, 0, stream>>>(W12, W12h, W12l, 8, 131072, 16);

  fc_kernel<<<RN * 64 / 256, 256, 0, stream>>>(data, W_fc, b_fc, x0, S0);
  bn_normpack_kernel<<<RN * 64 / 256, 256, 0, stream>>>(x0, S0, xbh, xbl);

  // edge conv 1
  gemm_kernel<0, false><<<dim3(256, 4), 256, 0, stream>>>(x0, W1p, bufB, Sd, 64, 256);
  edge_mfma_kernel<true><<<1024, 256, 0, stream>>>(xbh, xbl, idx, pack, W1mh, W1ml, W1bt, bufB, bufA, S1);
  bn_norm_kernel<<<RN * 256 / 256, 256, 0, stream>>>(bufA, S1, 255, 256, 1.0f / (RN * 16), RN * 256);

  agg_kernel<<<RN * 64 / 256, 256, 0, stream>>>(bufA, idx, bufB, 6);
  gemm_kernel<0, false><<<dim3(256, 1), 256, 0, stream>>>(bufB, W2, bufC, S2, 256, 64);
  bn_norm_kernel<<<RN * 64 / 256, 256, 0, stream>>>(bufC, S2, 63, 64, 1.0f / RN, RN * 64);

  agg_kernel<<<RN * 16 / 256, 256, 0, stream>>>(bufC, idx, bufB, 4);
  gemm_kernel<0, false><<<dim3(256, 1), 256, 0, stream>>>(bufB, W3, x1v, S3, 64, 64);
  bn_normpack_kernel<<<RN * 64 / 256, 256, 0, stream>>>(x1v, S3, xbh, xbl);

  // edge conv 2 (no pts)
  gemm_kernel<0, false><<<dim3(256, 4), 256, 0, stream>>>(x1v, W4p, bufB, Sd, 64, 256);
  edge_mfma_kernel<false><<<1024, 256, 0, stream>>>(xbh, xbl, idx, pack, W4mh, W4ml, nullptr, bufB, bufA, S4);
  bn_norm_kernel<<<RN * 256 / 256, 256, 0, stream>>>(bufA, S4, 255, 256, 1.0f / (RN * 16), RN * 256);

  agg_kernel<<<RN * 64 / 256, 256, 0, stream>>>(bufA, idx, bufB, 6);
  gemm_kernel<0, false><<<dim3(256, 1), 256, 0, stream>>>(bufB, W5, bufC, S5, 256, 64);
  bn_norm_kernel<<<RN * 64 / 256, 256, 0, stream>>>(bufC, S5, 63, 64, 1.0f / RN, RN * 64);

  agg_kernel<<<RN * 16 / 256, 256, 0, stream>>>(bufC, idx, bufB, 4);
  gemm_kernel<0, false><<<dim3(256, 1), 256, 0, stream>>>(bufB, W6, x2v, S6, 64, 64);
  bn_norm_kernel<<<RN * 64 / 256, 256, 0, stream>>>(x2v, S6, 63, 64, 1.0f / RN, RN * 64);

  // pack [x1|x2] (bufC and x0 are dead now; overlay)
  pack_x12_kernel<<<RN * 128 / 256, 256, 0, stream>>>(x1v, x2v, x12h, x12l);

  // W10 path: MFMA, stats + per-row-tile col max only
  gemm_mfma_kernel<0, true><<<dim3(256, 16), 256, 0, stream>>>(
      x12h, x12l, nullptr, nullptr, W10h, W10l, nullptr, pmax, S7, 128, 1024);
  fin_g_kernel<<<16, 256, 0, stream>>>(pmax, S7, gh, gl);

  // W11: [g | x12] @ W11 -> h11
  gemm_mfma_kernel<3, false><<<dim3(256, 8), 256, 0, stream>>>(
      x12h, x12l, gh, gl, W11h, W11l, h11, nullptr, S8, 1152, 512);
  bn_pack_kernel<<<RN * 512 / 256, 256, 0, stream>>>(h11, S8, h11h, h11l);

  // W12: h11 @ W12 -> h12
  gemm_mfma_kernel<0, false><<<dim3(256, 4), 256, 0, stream>>>(
      h11h, h11l, nullptr, nullptr, W12h, W12l, h12, nullptr, S9, 512, 256);
  bn_norm_kernel<<<RN * 256 / 256, 256, 0, stream>>>(h12, S9, 255, 256, 1.0f / RN, RN * 256);

  final13_kernel<<<(RN * 13 + 255) / 256, 256, 0, stream>>>(h12, W13, out);
}

// Round 7
// 805.758 us; speedup vs baseline: 3.0107x; 1.0676x over previous
//
#include <hip/hip_runtime.h>
#include <hip/hip_bf16.h>
#include <float.h>

static constexpr int BB  = 4;
static constexpr int NN  = 4096;
static constexpr int KSN = 16;
static constexpr int RN  = BB * NN;     // 16384 rows (b,n)
#define EPSBN 1e-5f

typedef __attribute__((ext_vector_type(8))) short short8;
typedef __attribute__((ext_vector_type(4))) float f32x4;

__device__ inline unsigned short f2bf(float f) {
  union { float f; unsigned u; } v; v.f = f;
  unsigned r = v.u + 0x7FFF + ((v.u >> 16) & 1);
  return (unsigned short)(r >> 16);
}
__device__ inline float bf2f(unsigned short h) {
  union { unsigned u; float f; } v; v.u = ((unsigned)h) << 16; return v.f;
}

// ---------------------------------------------------------------------------
// Prep: pack (x,y,z,|p|^2) as float4 per point.
// ---------------------------------------------------------------------------
__global__ void prep_kernel(const float* __restrict__ data, float4* __restrict__ pack) {
  int t = blockIdx.x * 256 + threadIdx.x;
  if (t >= RN) return;
  const float* dr = data + (size_t)t * 9;
  float x = dr[0], y = dr[1], z = dr[2];
  pack[t] = make_float4(x, y, z, fmaf(z, z, fmaf(y, y, x * x)));
}

// ---------------------------------------------------------------------------
// Weight prep for edge convs.
// ---------------------------------------------------------------------------
__global__ void prep_w_kernel(const float* __restrict__ W1, const float* __restrict__ W4,
                              float* __restrict__ W1p,
                              unsigned short* __restrict__ W1mh, unsigned short* __restrict__ W1ml,
                              float4* __restrict__ W1bt,
                              float* __restrict__ W4p,
                              unsigned short* __restrict__ W4mh, unsigned short* __restrict__ W4ml) {
  int t = blockIdx.x * 256 + threadIdx.x;   // 16384
  int k = t >> 8, cc = t & 255;
  float w1top = W1[k * 256 + cc], w1mid = W1[(64 + k) * 256 + cc];
  W1p[t] = w1top - w1mid;
  unsigned short h1 = f2bf(w1mid);
  W1mh[cc * 64 + k] = h1;
  W1ml[cc * 64 + k] = f2bf(w1mid - bf2f(h1));
  float w4top = W4[k * 256 + cc], w4mid = W4[(64 + k) * 256 + cc];
  W4p[t] = w4top - w4mid;
  unsigned short h4 = f2bf(w4mid);
  W4mh[cc * 64 + k] = h4;
  W4ml[cc * 64 + k] = f2bf(w4mid - bf2f(h4));
  if (t < 256) W1bt[t] = make_float4(W1[128 * 256 + t], W1[129 * 256 + t], W1[130 * 256 + t], 0.f);
}

// W -> fragment-major hi/lo pack: dst[ct][ks][lane][8]
__global__ void prep_wpack_kernel(const float* __restrict__ W,
                                  unsigned short* __restrict__ wh, unsigned short* __restrict__ wl,
                                  int lgC, int total, int NK) {
  int t = blockIdx.x * 256 + threadIdx.x;
  if (t >= total) return;
  int k = t >> lgC, c = t & ((1 << lgC) - 1);
  float v = W[t];
  int ct = c >> 4, cl = c & 15, ks = k >> 5, kl = k & 31;
  int dst = ((ct * NK + ks) * 64 + (((kl >> 3) << 4) | cl)) * 8 + (kl & 7);
  unsigned short h = f2bf(v);
  wh[dst] = h; wl[dst] = f2bf(v - bf2f(h));
}

// [x1|x2] -> fragment-major hi/lo pack (K=128)
__global__ void pack_x12_kernel(const float* __restrict__ x1, const float* __restrict__ x2,
                                unsigned short* __restrict__ ph, unsigned short* __restrict__ pl) {
  int t = blockIdx.x * 256 + threadIdx.x;   // RN*128
  int r = t >> 7, k = t & 127;
  float v = (k < 64) ? x1[(size_t)r * 64 + k] : x2[(size_t)r * 64 + k - 64];
  int rt = r >> 4, rl = r & 15, ks = k >> 5, kl = k & 31;
  int dst = ((rt * 4 + ks) * 64 + (((kl >> 3) << 4) | rl)) * 8 + (kl & 7);
  unsigned short h = f2bf(v);
  ph[dst] = h; pl[dst] = f2bf(v - bf2f(h));
}

// BN+ReLU on h11 (C=512) fused with fragment-major hi/lo pack
__global__ void bn_pack_kernel(const float* __restrict__ buf, const float* __restrict__ stats,
                               unsigned short* __restrict__ ph, unsigned short* __restrict__ pl) {
  int t = blockIdx.x * 256 + threadIdx.x;   // RN*512
  int c = t & 511, r = t >> 9;
  const float inv = 1.0f / RN;
  float m = stats[c] * inv;
  float v = fmaxf(stats[512 + c] * inv - m * m, 0.0f);
  float x = fmaxf((buf[t] - m) * rsqrtf(v + EPSBN), 0.0f);
  int rt = r >> 4, rl = r & 15, ks = c >> 5, kl = c & 31;
  int dst = ((rt * 16 + ks) * 64 + (((kl >> 3) << 4) | rl)) * 8 + (kl & 7);
  unsigned short h = f2bf(x);
  ph[dst] = h; pl[dst] = f2bf(x - bf2f(h));
}

// BN+ReLU in place (C=64) fused with row-major hi/lo write (edge-conv input)
__global__ void bn_normpack_kernel(float* __restrict__ buf, const float* __restrict__ stats,
                                   unsigned short* __restrict__ hi, unsigned short* __restrict__ lo) {
  int t = blockIdx.x * 256 + threadIdx.x;   // RN*64
  int c = t & 63;
  const float inv = 1.0f / RN;
  float m = stats[c] * inv;
  float v = fmaxf(stats[64 + c] * inv - m * m, 0.0f);
  float x = fmaxf((buf[t] - m) * rsqrtf(v + EPSBN), 0.0f);
  buf[t] = x;
  unsigned short h = f2bf(x);
  hi[t] = h; lo[t] = f2bf(x - bf2f(h));
}

// ---------------------------------------------------------------------------
// KNN: one wave per point, branchless sorted top-4 per lane (validated r5).
// ---------------------------------------------------------------------------
__global__ __launch_bounds__(256) void knn_kernel(const float4* __restrict__ pack,
                                                  int* __restrict__ idx) {
  const int lane = threadIdx.x & 63;
  const int p = blockIdx.x * 4 + (threadIdx.x >> 6);
  const int b = p >> 12;
  const float4* __restrict__ pb = pack + ((size_t)b << 12);
  const float4 me = pack[p];
  unsigned long long m0 = ~0ull, m1 = ~0ull, m2 = ~0ull, m3 = ~0ull;
#pragma unroll 8
  for (int s = 0; s < 64; ++s) {
    const float4 q = pb[s * 64 + lane];
    float d = me.w + q.w - 2.0f * fmaf(me.x, q.x, fmaf(me.y, q.y, me.z * q.z));
    unsigned ub = __float_as_uint(d);
    ub = (ub & 0x80000000u) ? ~ub : (ub | 0x80000000u);
    unsigned long long k = ((unsigned long long)ub << 12) | (unsigned)(s * 64 + lane);
    if (k < m3) {
      bool l0 = k < m0;  unsigned long long t0 = l0 ? m0 : k;  m0 = l0 ? k : m0;
      bool l1 = t0 < m1; unsigned long long t1 = l1 ? m1 : t0; m1 = l1 ? t0 : m1;
      bool l2 = t1 < m2; unsigned long long t2 = l2 ? m2 : t1; m2 = l2 ? t1 : m2;
      m3 = (t2 < m3) ? t2 : m3;
    }
  }
  for (int pass = 0; pass < 16; ++pass) {
    unsigned long long w = m0;
#pragma unroll
    for (int mv = 1; mv < 64; mv <<= 1) {
      unsigned long long o = __shfl_xor(w, mv);
      w = (o < w) ? o : w;
    }
    if (lane == pass) idx[(p << 4) + pass] = (int)(w & 0xFFFull);
    if (m0 == w) { m0 = m1; m1 = m2; m2 = m3; m3 = ~0ull; }
    if (pass < 15 && __any(m0 == ~0ull)) {
      if (m0 == ~0ull) {
        m1 = ~0ull; m2 = ~0ull; m3 = ~0ull;
#pragma unroll 8
        for (int s = 0; s < 64; ++s) {
          const float4 q = pb[s * 64 + lane];
          float d = me.w + q.w - 2.0f * fmaf(me.x, q.x, fmaf(me.y, q.y, me.z * q.z));
          unsigned ub = __float_as_uint(d);
          ub = (ub & 0x80000000u) ? ~ub : (ub | 0x80000000u);
          unsigned long long k = ((unsigned long long)ub << 12) | (unsigned)(s * 64 + lane);
          k = (k > w) ? k : ~0ull;
          bool l0 = k < m0;  unsigned long long t0 = l0 ? m0 : k;  m0 = l0 ? k : m0;
          bool l1 = t0 < m1; unsigned long long t1 = l1 ? m1 : t0; m1 = l1 ? t0 : m1;
          bool l2 = t1 < m2; unsigned long long t2 = l2 ? m2 : t1; m2 = l2 ? t1 : m2;
          m3 = (t2 < m3) ? t2 : m3;
        }
      }
    }
  }
}

// ---------------------------------------------------------------------------
// fc: y = data @ W_fc + b_fc (K=9, C=64) + column stats.
// ---------------------------------------------------------------------------
__global__ __launch_bounds__(256) void fc_kernel(const float* __restrict__ data,
                                                 const float* __restrict__ W,
                                                 const float* __restrict__ bias,
                                                 float* __restrict__ y,
                                                 float* __restrict__ stats) {
  const int t = blockIdx.x * 256 + threadIdx.x;
  const int r = t >> 6, c = t & 63;
  const float* dr = data + (size_t)r * 9;
  float acc = bias[c];
#pragma unroll
  for (int k = 0; k < 9; ++k) acc = fmaf(dr[k], W[k * 64 + c], acc);
  y[t] = acc;
  __shared__ float red[256];
  red[threadIdx.x] = acc;
  __syncthreads();
  if (threadIdx.x < 64) {
    float s = red[threadIdx.x] + red[threadIdx.x + 64] + red[threadIdx.x + 128] + red[threadIdx.x + 192];
    atomicAdd(&stats[threadIdx.x], s);
  }
  __syncthreads();
  red[threadIdx.x] = acc * acc;
  __syncthreads();
  if (threadIdx.x < 64) {
    float s = red[threadIdx.x] + red[threadIdx.x + 64] + red[threadIdx.x + 128] + red[threadIdx.x + 192];
    atomicAdd(&stats[64 + threadIdx.x], s);
  }
}

// ---------------------------------------------------------------------------
// BN(+ReLU) normalize in place.
// ---------------------------------------------------------------------------
__global__ void bn_norm_kernel(float* __restrict__ buf, const float* __restrict__ stats,
                               int cmask, int C, float inv_cnt, int total) {
  int t = blockIdx.x * 256 + threadIdx.x;
  if (t >= total) return;
  int c = t & cmask;
  float m = stats[c] * inv_cnt;
  float v = fmaxf(stats[C + c] * inv_cnt - m * m, 0.0f);
  float rs = rsqrtf(v + EPSBN);
  float x = (buf[t] - m) * rs;
  buf[t] = fmaxf(x, 0.0f);
}

// ---------------------------------------------------------------------------
// Edge conv via MFMA, v2 (validated round 6): wave = 16 points x 64 cols,
// B-frags in regs, idx/A prefetch pipeline.
// ---------------------------------------------------------------------------
template <bool HAS_PTS>
__global__ __launch_bounds__(256) void edge_mfma_kernel(
    const unsigned short* __restrict__ Xh, const unsigned short* __restrict__ Xl,
    const int* __restrict__ idx,
    const float4* __restrict__ pack,
    const unsigned short* __restrict__ Wmh, const unsigned short* __restrict__ Wml,
    const float4* __restrict__ Wbt, const float* __restrict__ basemat,
    float* __restrict__ out, float* __restrict__ stats) {
  const int wave = threadIdx.x >> 6;
  const int lane = threadIdx.x & 63;
  const int pg   = blockIdx.x;
  const int c0   = wave << 6;
  const int cl   = lane & 15;
  const int kg   = (lane >> 4) << 3;
  const int bat  = pg >> 8;
  const int pbase = bat << 12;
  const int ib   = pg << 8;

  short8 bh[4][2], blo[4][2];
#pragma unroll
  for (int q = 0; q < 4; ++q) {
    const unsigned short* wp = Wmh + (size_t)(c0 + q * 16 + cl) * 64 + kg;
    bh[q][0] = *(const short8*)wp; bh[q][1] = *(const short8*)(wp + 32);
    const unsigned short* wq = Wml + (size_t)(c0 + q * 16 + cl) * 64 + kg;
    blo[q][0] = *(const short8*)wq; blo[q][1] = *(const short8*)(wq + 32);
  }
  float4 wb[4];
  if (HAS_PTS) {
#pragma unroll
    for (int q = 0; q < 4; ++q) wb[q] = Wbt[c0 + q * 16 + cl];
  }
  float rs1[4] = {0.f, 0.f, 0.f, 0.f}, rs2[4] = {0.f, 0.f, 0.f, 0.f};

  int jn = idx[ib + 16 + cl];
  int j0 = idx[ib + cl];
  size_t ro = ((size_t)(pbase | j0) << 6) + kg;
  short8 a0h = *(const short8*)(Xh + ro);
  short8 a1h = *(const short8*)(Xh + ro + 32);
  short8 a0l = *(const short8*)(Xl + ro);
  short8 a1l = *(const short8*)(Xl + ro + 32);

  for (int pp = 0; pp < 16; ++pp) {
    const int p = (pg << 4) | pp;
    int jf = 0;
    if (pp < 14) jf = idx[ib + ((pp + 2) << 4) + cl];
    short8 n0h, n1h, n0l, n1l;
    if (pp < 15) {
      size_t rn = ((size_t)(pbase | jn) << 6) + kg;
      n0h = *(const short8*)(Xh + rn);
      n1h = *(const short8*)(Xh + rn + 32);
      n0l = *(const short8*)(Xl + rn);
      n1l = *(const short8*)(Xl + rn + 32);
    }
    float dx0, dy0, dz0, dx1, dy1, dz1, dx2, dy2, dz2, dx3, dy3, dz3;
    if (HAS_PTS) {
      const int4 j4 = *(const int4*)(idx + (p << 4) + ((lane >> 4) << 2));
      const float4 pc = pack[p];
      const float4 q0 = pack[pbase | j4.x];
      const float4 q1 = pack[pbase | j4.y];
      const float4 q2 = pack[pbase | j4.z];
      const float4 q3 = pack[pbase | j4.w];
      dx0 = q0.x - pc.x; dy0 = q0.y - pc.y; dz0 = q0.z - pc.z;
      dx1 = q1.x - pc.x; dy1 = q1.y - pc.y; dz1 = q1.z - pc.z;
      dx2 = q2.x - pc.x; dy2 = q2.y - pc.y; dz2 = q2.z - pc.z;
      dx3 = q3.x - pc.x; dy3 = q3.y - pc.y; dz3 = q3.z - pc.z;
    }
    f32x4 acc[4];
#pragma unroll
    for (int q = 0; q < 4; ++q) {
      acc[q][0] = 0.f; acc[q][1] = 0.f; acc[q][2] = 0.f; acc[q][3] = 0.f;
    }
#pragma unroll
    for (int q = 0; q < 4; ++q) {
      acc[q] = __builtin_amdgcn_mfma_f32_16x16x32_bf16(a0l, bh[q][0], acc[q], 0, 0, 0);
      acc[q] = __builtin_amdgcn_mfma_f32_16x16x32_bf16(a1l, bh[q][1], acc[q], 0, 0, 0);
      acc[q] = __builtin_amdgcn_mfma_f32_16x16x32_bf16(a0h, blo[q][0], acc[q], 0, 0, 0);
      acc[q] = __builtin_amdgcn_mfma_f32_16x16x32_bf16(a1h, blo[q][1], acc[q], 0, 0, 0);
      acc[q] = __builtin_amdgcn_mfma_f32_16x16x32_bf16(a0h, bh[q][0], acc[q], 0, 0, 0);
      acc[q] = __builtin_amdgcn_mfma_f32_16x16x32_bf16(a1h, bh[q][1], acc[q], 0, 0, 0);
    }
    if (HAS_PTS) {
#pragma unroll
      for (int q = 0; q < 4; ++q) {
        acc[q][0] += dx0 * wb[q].x + dy0 * wb[q].y + dz0 * wb[q].z;
        acc[q][1] += dx1 * wb[q].x + dy1 * wb[q].y + dz1 * wb[q].z;
        acc[q][2] += dx2 * wb[q].x + dy2 * wb[q].y + dz2 * wb[q].z;
        acc[q][3] += dx3 * wb[q].x + dy3 * wb[q].y + dz3 * wb[q].z;
      }
    }
#pragma unroll
    for (int q = 0; q < 4; ++q) {
      float s1 = acc[q][0] + acc[q][1] + acc[q][2] + acc[q][3];
      float s2 = acc[q][0] * acc[q][0] + acc[q][1] * acc[q][1]
               + acc[q][2] * acc[q][2] + acc[q][3] * acc[q][3];
      float mx = fmaxf(fmaxf(acc[q][0], acc[q][1]), fmaxf(acc[q][2], acc[q][3]));
      s1 += __shfl_xor(s1, 16); s1 += __shfl_xor(s1, 32);
      s2 += __shfl_xor(s2, 16); s2 += __shfl_xor(s2, 32);
      mx = fmaxf(mx, __shfl_xor(mx, 16)); mx = fmaxf(mx, __shfl_xor(mx, 32));
      float bb = basemat[(size_t)p * 256 + c0 + q * 16 + cl];
      if (lane < 16) out[(size_t)p * 256 + c0 + q * 16 + cl] = mx + bb;
      rs1[q] += s1 + 16.f * bb;
      rs2[q] += s2 + 2.f * bb * s1 + 16.f * bb * bb;
    }
    a0h = n0h; a1h = n1h; a0l = n0l; a1l = n1l;
    jn = jf;
  }
  if (lane < 16) {
#pragma unroll
    for (int q = 0; q < 4; ++q) {
      atomicAdd(&stats[c0 + q * 16 + lane], rs1[q]);
      atomicAdd(&stats[256 + c0 + q * 16 + lane], rs2[q]);
    }
  }
}

// ---------------------------------------------------------------------------
// agg[r,c] = max over 16 neighbors, float4 per thread. lg = log2(C/4).
// ---------------------------------------------------------------------------
__global__ void agg_kernel(const float* __restrict__ X, const int* __restrict__ idx,
                           float* __restrict__ out, int lg) {
  const int c4 = 1 << lg;
  int t = blockIdx.x * 256 + threadIdx.x;
  int total = RN * c4;
  if (t >= total) return;
  int r = t >> lg, cq = t & (c4 - 1);
  int base = (r >> 12) << 12;
  const int* ip = idx + (size_t)r * KSN;
  float4 mx = make_float4(-FLT_MAX, -FLT_MAX, -FLT_MAX, -FLT_MAX);
  const int C = c4 * 4;
#pragma unroll
  for (int k = 0; k < KSN; ++k) {
    int j = ip[k];
    const float4 v = *reinterpret_cast<const float4*>(X + (size_t)(base + j) * C + cq * 4);
    mx.x = fmaxf(mx.x, v.x); mx.y = fmaxf(mx.y, v.y);
    mx.z = fmaxf(mx.z, v.z); mx.w = fmaxf(mx.w, v.w);
  }
  *reinterpret_cast<float4*>(out + (size_t)r * C + cq * 4) = mx;
}

// ---------------------------------------------------------------------------
// fp32 GEMM for small layers.
// ---------------------------------------------------------------------------
template <int MODE, bool DOMAX>
__global__ __launch_bounds__(256) void gemm_kernel(const float* __restrict__ A,
                                                   const float* __restrict__ W,
                                                   float* __restrict__ Y,
                                                   float* __restrict__ stats,
                                                   int K, int C) {
  __shared__ float a_lds[16][65];
  __shared__ float b_lds[16][64];
  __shared__ float red[64 * 17];
  const int t  = threadIdx.x;
  const int r0 = blockIdx.x * 64, c0 = blockIdx.y * 64;
  const int tr = t >> 4, tc = t & 15;
  float acc[4][4] = {{0.f}};
  for (int k0 = 0; k0 < K; k0 += 16) {
#pragma unroll
    for (int i = 0; i < 4; ++i) {
      int e = t + i * 256;
      int ar = e >> 4, ak = e & 15;
      a_lds[ak][ar] = A[(size_t)(r0 + ar) * K + k0 + ak];
    }
#pragma unroll
    for (int i = 0; i < 4; ++i) {
      int e = t + i * 256;
      int bk = e >> 6, bc = e & 63;
      b_lds[bk][bc] = W[(size_t)(k0 + bk) * C + c0 + bc];
    }
    __syncthreads();
#pragma unroll
    for (int k = 0; k < 16; ++k) {
      float av[4], bv[4];
#pragma unroll
      for (int i = 0; i < 4; ++i) av[i] = a_lds[k][tr * 4 + i];
#pragma unroll
      for (int j = 0; j < 4; ++j) bv[j] = b_lds[k][tc * 4 + j];
#pragma unroll
      for (int i = 0; i < 4; ++i)
#pragma unroll
        for (int j = 0; j < 4; ++j) acc[i][j] = fmaf(av[i], bv[j], acc[i][j]);
    }
    __syncthreads();
  }
#pragma unroll
  for (int i = 0; i < 4; ++i) {
    int rr = r0 + tr * 4 + i;
#pragma unroll
    for (int j = 0; j < 4; ++j) Y[(size_t)rr * C + c0 + tc * 4 + j] = acc[i][j];
  }
  float s1[4] = {0.f, 0.f, 0.f, 0.f}, s2[4] = {0.f, 0.f, 0.f, 0.f};
#pragma unroll
  for (int i = 0; i < 4; ++i)
#pragma unroll
    for (int j = 0; j < 4; ++j) {
      s1[j] += acc[i][j];
      s2[j] = fmaf(acc[i][j], acc[i][j], s2[j]);
    }
#pragma unroll
  for (int j = 0; j < 4; ++j) red[(tc * 4 + j) * 17 + tr] = s1[j];
  __syncthreads();
  if (t < 64) {
    float s = 0.f;
    for (int q = 0; q < 16; ++q) s += red[t * 17 + q];
    atomicAdd(&stats[c0 + t], s);
  }
  __syncthreads();
#pragma unroll
  for (int j = 0; j < 4; ++j) red[(tc * 4 + j) * 17 + tr] = s2[j];
  __syncthreads();
  if (t < 64) {
    float s = 0.f;
    for (int q = 0; q < 16; ++q) s += red[t * 17 + q];
    atomicAdd(&stats[C + c0 + t], s);
  }
}

// ---------------------------------------------------------------------------
// MFMA GEMM v2: wave = 64 rows (4 row-tiles) x 64 cols (4 col-tiles),
// acc[4][4]; block = 4 waves = 256 rows x 64 cols. 48 MFMAs per K-step per
// wave vs 16 loads -> MFMA-issue-bound, W L2 traffic 4x lower than v1.
// AMODE 3: ks<32 A-frag is batch-broadcast g (single load serves 4 rt).
// DOMAX: per-block (256-row) column max to pmax.
// ---------------------------------------------------------------------------
template <int AMODE, bool DOMAX>
__global__ __launch_bounds__(256) void gemm_mfma_kernel(
    const unsigned short* __restrict__ Ah, const unsigned short* __restrict__ Al,
    const unsigned short* __restrict__ gh, const unsigned short* __restrict__ gl,
    const unsigned short* __restrict__ Wh, const unsigned short* __restrict__ Wl,
    float* __restrict__ Y, float* __restrict__ pmax, float* __restrict__ stats,
    int K, int C) {
  __shared__ float red1[4][64], red2[4][64], redm[4][64];
  const int wave = threadIdx.x >> 6, lane = threadIdx.x & 63;
  const int rtb = blockIdx.x * 16 + wave * 4;   // first of 4 row-tiles
  const int c0  = blockIdx.y * 64;
  const int ct0 = blockIdx.y * 4;
  const int NK  = K >> 5;
  const int KP  = (AMODE == 3) ? 4 : NK;
  const int bat = blockIdx.x >> 4;              // batch (AMODE 3; 16 blocks/batch)
  f32x4 acc[4][4];
#pragma unroll
  for (int r = 0; r < 4; ++r)
#pragma unroll
    for (int cc = 0; cc < 4; ++cc) {
      acc[r][cc][0] = 0.f; acc[r][cc][1] = 0.f; acc[r][cc][2] = 0.f; acc[r][cc][3] = 0.f;
    }
  const int lhalf = (lane >> 4) << 3;
  for (int ks = 0; ks < NK; ++ks) {
    short8 ah[4], al[4];
    if (AMODE == 3 && ks < 32) {
      const int go = bat * 1024 + ks * 32 + lhalf;
      short8 gav = *(const short8*)(gh + go);
      short8 galv = *(const short8*)(gl + go);
#pragma unroll
      for (int r = 0; r < 4; ++r) { ah[r] = gav; al[r] = galv; }
    } else {
      const int ksp = (AMODE == 3) ? ks - 32 : ks;
#pragma unroll
      for (int r = 0; r < 4; ++r) {
        const size_t aoff = (((size_t)(rtb + r) * KP + ksp) * 64 + lane) * 8;
        ah[r] = *(const short8*)(Ah + aoff);
        al[r] = *(const short8*)(Al + aoff);
      }
    }
#pragma unroll
    for (int cc = 0; cc < 4; ++cc) {
      const size_t woff = (((size_t)(ct0 + cc) * NK + ks) * 64 + lane) * 8;
      short8 bh = *(const short8*)(Wh + woff);
      short8 bl = *(const short8*)(Wl + woff);
#pragma unroll
      for (int r = 0; r < 4; ++r) {
        acc[r][cc] = __builtin_amdgcn_mfma_f32_16x16x32_bf16(al[r], bh, acc[r][cc], 0, 0, 0);
        acc[r][cc] = __builtin_amdgcn_mfma_f32_16x16x32_bf16(ah[r], bl, acc[r][cc], 0, 0, 0);
        acc[r][cc] = __builtin_amdgcn_mfma_f32_16x16x32_bf16(ah[r], bh, acc[r][cc], 0, 0, 0);
      }
    }
  }
#pragma unroll
  for (int cc = 0; cc < 4; ++cc) {
    float s1 = 0.f, s2 = 0.f, mm = -FLT_MAX;
#pragma unroll
    for (int r = 0; r < 4; ++r) {
      if (!DOMAX) {
#pragma unroll
        for (int i = 0; i < 4; ++i)
          Y[(size_t)((rtb + r) * 16 + ((lane >> 4) << 2) + i) * C + c0 + cc * 16 + (lane & 15)] = acc[r][cc][i];
      }
#pragma unroll
      for (int i = 0; i < 4; ++i) {
        float v = acc[r][cc][i];
        s1 += v; s2 = fmaf(v, v, s2); mm = fmaxf(mm, v);
      }
    }
    s1 += __shfl_xor(s1, 16); s1 += __shfl_xor(s1, 32);
    s2 += __shfl_xor(s2, 16); s2 += __shfl_xor(s2, 32);
    mm = fmaxf(mm, __shfl_xor(mm, 16)); mm = fmaxf(mm, __shfl_xor(mm, 32));
    if (lane < 16) {
      red1[wave][cc * 16 + lane] = s1;
      red2[wave][cc * 16 + lane] = s2;
      if (DOMAX) redm[wave][cc * 16 + lane] = mm;
    }
  }
  __syncthreads();
  if (threadIdx.x < 64) {
    const int t = threadIdx.x;
    float a = red1[0][t] + red1[1][t] + red1[2][t] + red1[3][t];
    float b = red2[0][t] + red2[1][t] + red2[2][t] + red2[3][t];
    atomicAdd(&stats[c0 + t], a);
    atomicAdd(&stats[C + c0 + t], b);
    if (DOMAX) {
      float mm = fmaxf(fmaxf(redm[0][t], redm[1][t]), fmaxf(redm[2][t], redm[3][t]));
      pmax[(size_t)blockIdx.x * C + c0 + t] = mm;
    }
  }
}

// g[b,c] = relu(bn(max over 16 row-blocks)) -> bf16 hi/lo
__global__ void fin_g_kernel(const float* __restrict__ pmax, const float* __restrict__ stats,
                             unsigned short* __restrict__ gh, unsigned short* __restrict__ gl) {
  int t = blockIdx.x * 256 + threadIdx.x;   // 4096
  int b = t >> 10, c = t & 1023;
  const float inv = 1.0f / 16384.0f;
  float m = stats[c] * inv;
  float v = fmaxf(stats[1024 + c] * inv - m * m, 0.0f);
  float rs = rsqrtf(v + EPSBN);
  float mx = -FLT_MAX;
  for (int s = 0; s < 16; ++s) mx = fmaxf(mx, pmax[(size_t)(b * 16 + s) * 1024 + c]);
  float val = fmaxf((mx - m) * rs, 0.0f);
  unsigned short h = f2bf(val);
  gh[t] = h; gl[t] = f2bf(val - bf2f(h));
}

__global__ void final13_kernel(const float* __restrict__ h, const float* __restrict__ W,
                               float* __restrict__ out) {
  int t = blockIdx.x * 256 + threadIdx.x;
  if (t >= RN * 13) return;
  int r = t / 13, c = t - r * 13;
  float acc = 0.0f;
  for (int k = 0; k < 256; ++k) acc = fmaf(h[(size_t)r * 256 + k], W[k * 13 + c], acc);
  int b = r >> 12, n = r & 4095;
  out[(size_t)b * 13 * NN + (size_t)c * NN + n] = acc;
}

// ---------------------------------------------------------------------------
extern "C" void kernel_launch(void* const* d_in, const int* in_sizes, int n_in,
                              void* d_out, int out_size, void* d_ws, size_t ws_size,
                              hipStream_t stream) {
  (void)in_sizes; (void)n_in; (void)out_size; (void)ws_size;
  const float* data = (const float*)d_in[0];
  const float* W_fc = (const float*)d_in[1];
  const float* b_fc = (const float*)d_in[2];
  const float* W1   = (const float*)d_in[3];
  const float* W2   = (const float*)d_in[4];
  const float* W3   = (const float*)d_in[5];
  const float* W4   = (const float*)d_in[6];
  const float* W5   = (const float*)d_in[7];
  const float* W6   = (const float*)d_in[8];
  const float* W10  = (const float*)d_in[9];
  const float* W11  = (const float*)d_in[10];
  const float* W12  = (const float*)d_in[11];
  const float* W13  = (const float*)d_in[12];
  float* out = (float*)d_out;

  float* ws  = (float*)d_ws;
  int*   idx = (int*)d_ws;
  size_t o = 262144;
  float* x0   = ws + o; o += (size_t)RN * 64;
  float* x1v  = ws + o; o += (size_t)RN * 64;
  float* x2v  = ws + o; o += (size_t)RN * 64;
  float* bufA = ws + o; o += (size_t)RN * 256;
  float* bufB = ws + o; o += (size_t)RN * 256;
  float* bufC = ws + o; o += (size_t)RN * 64;
  float* pmax = ws + o; o += (size_t)64 * 1024;
  float* h11  = ws + o; o += (size_t)RN * 512;
  float* h12  = ws + o; o += (size_t)RN * 256;
  float* stats = ws + o; o += 8192;
  float4* pack = (float4*)(ws + o); o += (size_t)RN * 4;
  unsigned short* xbh = (unsigned short*)(ws + o); o += (size_t)RN * 32;
  unsigned short* xbl = (unsigned short*)(ws + o); o += (size_t)RN * 32;
  float* W1p = ws + o; o += 16384;
  float* W4p = ws + o; o += 16384;
  unsigned short* W1mh = (unsigned short*)(ws + o); o += 8192;
  unsigned short* W1ml = (unsigned short*)(ws + o); o += 8192;
  unsigned short* W4mh = (unsigned short*)(ws + o); o += 8192;
  unsigned short* W4ml = (unsigned short*)(ws + o); o += 8192;
  float4* W1bt = (float4*)(ws + o); o += 1024;
  unsigned short* W10h = (unsigned short*)(ws + o); o += 65536;
  unsigned short* W10l = (unsigned short*)(ws + o); o += 65536;
  unsigned short* W11h = (unsigned short*)(ws + o); o += 294912;
  unsigned short* W11l = (unsigned short*)(ws + o); o += 294912;
  unsigned short* W12h = (unsigned short*)(ws + o); o += 65536;
  unsigned short* W12l = (unsigned short*)(ws + o); o += 65536;
  unsigned short* gh   = (unsigned short*)(ws + o); o += 2048;
  unsigned short* gl   = (unsigned short*)(ws + o); o += 2048;
  // overlays on dead buffers:
  unsigned short* x12h = (unsigned short*)bufC;
  unsigned short* x12l = (unsigned short*)x0;
  unsigned short* h11h = (unsigned short*)bufA;
  unsigned short* h11l = (unsigned short*)bufB;

  float* S0 = stats;          // 64 (fc)
  float* S1 = stats + 128;    // 256 (edge1)
  float* S2 = stats + 640;    // 64  (W2)
  float* S3 = stats + 768;    // 64  (W3)
  float* S4 = stats + 896;    // 256 (edge2)
  float* S5 = stats + 1408;   // 64  (W5)
  float* S6 = stats + 1536;   // 64  (W6)
  float* S7 = stats + 1664;   // 1024 (W10)
  float* S8 = stats + 3712;   // 512 (W11)
  float* S9 = stats + 4736;   // 256 (W12)
  float* Sd = stats + 5248;   // dummy (512)

  hipMemsetAsync(stats, 0, 8192 * sizeof(float), stream);

  prep_kernel<<<RN / 256, 256, 0, stream>>>(data, pack);
  knn_kernel<<<RN / 4, 256, 0, stream>>>(pack, idx);
  prep_w_kernel<<<64, 256, 0, stream>>>(W1, W4, W1p, W1mh, W1ml, W1bt, W4p, W4mh, W4ml);
  prep_wpack_kernel<<<512, 256, 0, stream>>>(W10, W10h, W10l, 10, 131072, 4);
  prep_wpack_kernel<<<2304, 256, 0, stream>>>(W11, W11h, W11l, 9, 589824, 36);
  prep_wpack_kernel<<<512, 256, 0, stream>>>(W12, W12h, W12l, 8, 131072, 16);

  fc_kernel<<<RN * 64 / 256, 256, 0, stream>>>(data, W_fc, b_fc, x0, S0);
  bn_normpack_kernel<<<RN * 64 / 256, 256, 0, stream>>>(x0, S0, xbh, xbl);

  // edge conv 1
  gemm_kernel<0, false><<<dim3(256, 4), 256, 0, stream>>>(x0, W1p, bufB, Sd, 64, 256);
  edge_mfma_kernel<true><<<1024, 256, 0, stream>>>(xbh, xbl, idx, pack, W1mh, W1ml, W1bt, bufB, bufA, S1);
  bn_norm_kernel<<<RN * 256 / 256, 256, 0, stream>>>(bufA, S1, 255, 256, 1.0f / (RN * 16), RN * 256);

  agg_kernel<<<RN * 64 / 256, 256, 0, stream>>>(bufA, idx, bufB, 6);
  gemm_kernel<0, false><<<dim3(256, 1), 256, 0, stream>>>(bufB, W2, bufC, S2, 256, 64);
  bn_norm_kernel<<<RN * 64 / 256, 256, 0, stream>>>(bufC, S2, 63, 64, 1.0f / RN, RN * 64);

  agg_kernel<<<RN * 16 / 256, 256, 0, stream>>>(bufC, idx, bufB, 4);
  gemm_kernel<0, false><<<dim3(256, 1), 256, 0, stream>>>(bufB, W3, x1v, S3, 64, 64);
  bn_normpack_kernel<<<RN * 64 / 256, 256, 0, stream>>>(x1v, S3, xbh, xbl);

  // edge conv 2 (no pts)
  gemm_kernel<0, false><<<dim3(256, 4), 256, 0, stream>>>(x1v, W4p, bufB, Sd, 64, 256);
  edge_mfma_kernel<false><<<1024, 256, 0, stream>>>(xbh, xbl, idx, pack, W4mh, W4ml, nullptr, bufB, bufA, S4);
  bn_norm_kernel<<<RN * 256 / 256, 256, 0, stream>>>(bufA, S4, 255, 256, 1.0f / (RN * 16), RN * 256);

  agg_kernel<<<RN * 64 / 256, 256, 0, stream>>>(bufA, idx, bufB, 6);
  gemm_kernel<0, false><<<dim3(256, 1), 256, 0, stream>>>(bufB, W5, bufC, S5, 256, 64);
  bn_norm_kernel<<<RN * 64 / 256, 256, 0, stream>>>(bufC, S5, 63, 64, 1.0f / RN, RN * 64);

  agg_kernel<<<RN * 16 / 256, 256, 0, stream>>>(bufC, idx, bufB, 4);
  gemm_kernel<0, false><<<dim3(256, 1), 256, 0, stream>>>(bufB, W6, x2v, S6, 64, 64);
  bn_norm_kernel<<<RN * 64 / 256, 256, 0, stream>>>(x2v, S6, 63, 64, 1.0f / RN, RN * 64);

  // pack [x1|x2] (bufC and x0 are dead now; overlay)
  pack_x12_kernel<<<RN * 128 / 256, 256, 0, stream>>>(x1v, x2v, x12h, x12l);

  // W10 path: MFMA, stats + per-block col max only
  gemm_mfma_kernel<0, true><<<dim3(64, 16), 256, 0, stream>>>(
      x12h, x12l, nullptr, nullptr, W10h, W10l, nullptr, pmax, S7, 128, 1024);
  fin_g_kernel<<<16, 256, 0, stream>>>(pmax, S7, gh, gl);

  // W11: [g | x12] @ W11 -> h11
  gemm_mfma_kernel<3, false><<<dim3(64, 8), 256, 0, stream>>>(
      x12h, x12l, gh, gl, W11h, W11l, h11, nullptr, S8, 1152, 512);
  bn_pack_kernel<<<RN * 512 / 256, 256, 0, stream>>>(h11, S8, h11h, h11l);

  // W12: h11 @ W12 -> h12
  gemm_mfma_kernel<0, false><<<dim3(64, 4), 256, 0, stream>>>(
      h11h, h11l, nullptr, nullptr, W12h, W12l, h12, nullptr, S9, 512, 256);
  bn_norm_kernel<<<RN * 256 / 256, 256, 0, stream>>>(h12, S9, 255, 256, 1.0f / RN, RN * 256);

  final13_kernel<<<(RN * 13 + 255) / 256, 256, 0, stream>>>(h12, W13, out);
}

// Round 8
// 753.432 us; speedup vs baseline: 3.2198x; 1.0694x over previous
//
#include <hip/hip_runtime.h>
#include <hip/hip_bf16.h>
#include <float.h>

static constexpr int BB  = 4;
static constexpr int NN  = 4096;
static constexpr int KSN = 16;
static constexpr int RN  = BB * NN;     // 16384 rows (b,n)
#define EPSBN 1e-5f

typedef __attribute__((ext_vector_type(8))) short short8;
typedef __attribute__((ext_vector_type(4))) short short4v;
typedef __attribute__((ext_vector_type(4))) float f32x4;

__device__ inline unsigned short f2bf(float f) {
  union { float f; unsigned u; } v; v.f = f;
  unsigned r = v.u + 0x7FFF + ((v.u >> 16) & 1);
  return (unsigned short)(r >> 16);
}
__device__ inline float bf2f(unsigned short h) {
  union { unsigned u; float f; } v; v.u = ((unsigned)h) << 16; return v.f;
}

// ---------------------------------------------------------------------------
// Prep: pack (x,y,z,|p|^2) as float4 per point.
// ---------------------------------------------------------------------------
__global__ void prep_kernel(const float* __restrict__ data, float4* __restrict__ pack) {
  int t = blockIdx.x * 256 + threadIdx.x;
  if (t >= RN) return;
  const float* dr = data + (size_t)t * 9;
  float x = dr[0], y = dr[1], z = dr[2];
  pack[t] = make_float4(x, y, z, fmaf(z, z, fmaf(y, y, x * x)));
}

// ---------------------------------------------------------------------------
// Weight prep for edge convs.
// ---------------------------------------------------------------------------
__global__ void prep_w_kernel(const float* __restrict__ W1, const float* __restrict__ W4,
                              float* __restrict__ W1p,
                              unsigned short* __restrict__ W1mh, unsigned short* __restrict__ W1ml,
                              float4* __restrict__ W1bt,
                              float* __restrict__ W4p,
                              unsigned short* __restrict__ W4mh, unsigned short* __restrict__ W4ml) {
  int t = blockIdx.x * 256 + threadIdx.x;   // 16384
  int k = t >> 8, cc = t & 255;
  float w1top = W1[k * 256 + cc], w1mid = W1[(64 + k) * 256 + cc];
  W1p[t] = w1top - w1mid;
  unsigned short h1 = f2bf(w1mid);
  W1mh[cc * 64 + k] = h1;
  W1ml[cc * 64 + k] = f2bf(w1mid - bf2f(h1));
  float w4top = W4[k * 256 + cc], w4mid = W4[(64 + k) * 256 + cc];
  W4p[t] = w4top - w4mid;
  unsigned short h4 = f2bf(w4mid);
  W4mh[cc * 64 + k] = h4;
  W4ml[cc * 64 + k] = f2bf(w4mid - bf2f(h4));
  if (t < 256) W1bt[t] = make_float4(W1[128 * 256 + t], W1[129 * 256 + t], W1[130 * 256 + t], 0.f);
}

// W (row-major [K][C] fp32) -> fragment-major hi/lo pack: dst[ct][ks][lane][8]
__global__ void prep_wpack_kernel(const float* __restrict__ W,
                                  unsigned short* __restrict__ wh, unsigned short* __restrict__ wl,
                                  int lgC, int total, int NK) {
  int t = blockIdx.x * 256 + threadIdx.x;
  if (t >= total) return;
  int k = t >> lgC, c = t & ((1 << lgC) - 1);
  float v = W[t];
  int ct = c >> 4, cl = c & 15, ks = k >> 5, kl = k & 31;
  int dst = ((ct * NK + ks) * 64 + (((kl >> 3) << 4) | cl)) * 8 + (kl & 7);
  unsigned short h = f2bf(v);
  wh[dst] = h; wl[dst] = f2bf(v - bf2f(h));
}

// [x1|x2] -> fragment-major hi/lo pack (K=128)
__global__ void pack_x12_kernel(const float* __restrict__ x1, const float* __restrict__ x2,
                                unsigned short* __restrict__ ph, unsigned short* __restrict__ pl) {
  int t = blockIdx.x * 256 + threadIdx.x;   // RN*128
  int r = t >> 7, k = t & 127;
  float v = (k < 64) ? x1[(size_t)r * 64 + k] : x2[(size_t)r * 64 + k - 64];
  int rt = r >> 4, rl = r & 15, ks = k >> 5, kl = k & 31;
  int dst = ((rt * 4 + ks) * 64 + (((kl >> 3) << 4) | rl)) * 8 + (kl & 7);
  unsigned short h = f2bf(v);
  ph[dst] = h; pl[dst] = f2bf(v - bf2f(h));
}

// BN+ReLU on h11 (C=512) fused with fragment-major hi/lo pack
__global__ void bn_pack_kernel(const float* __restrict__ buf, const float* __restrict__ stats,
                               unsigned short* __restrict__ ph, unsigned short* __restrict__ pl) {
  int t = blockIdx.x * 256 + threadIdx.x;   // RN*512
  int c = t & 511, r = t >> 9;
  const float inv = 1.0f / RN;
  float m = stats[c] * inv;
  float v = fmaxf(stats[512 + c] * inv - m * m, 0.0f);
  float x = fmaxf((buf[t] - m) * rsqrtf(v + EPSBN), 0.0f);
  int rt = r >> 4, rl = r & 15, ks = c >> 5, kl = c & 31;
  int dst = ((rt * 16 + ks) * 64 + (((kl >> 3) << 4) | rl)) * 8 + (kl & 7);
  unsigned short h = f2bf(x);
  ph[dst] = h; pl[dst] = f2bf(x - bf2f(h));
}

// BN+ReLU in place (C=64) fused with row-major hi/lo write (edge-conv input)
__global__ void bn_normpack_kernel(float* __restrict__ buf, const float* __restrict__ stats,
                                   unsigned short* __restrict__ hi, unsigned short* __restrict__ lo) {
  int t = blockIdx.x * 256 + threadIdx.x;   // RN*64
  int c = t & 63;
  const float inv = 1.0f / RN;
  float m = stats[c] * inv;
  float v = fmaxf(stats[64 + c] * inv - m * m, 0.0f);
  float x = fmaxf((buf[t] - m) * rsqrtf(v + EPSBN), 0.0f);
  buf[t] = x;
  unsigned short h = f2bf(x);
  hi[t] = h; lo[t] = f2bf(x - bf2f(h));
}

// ---------------------------------------------------------------------------
// KNN: one wave per point, branchless sorted top-4 per lane (validated r5-7).
// ---------------------------------------------------------------------------
__global__ __launch_bounds__(256) void knn_kernel(const float4* __restrict__ pack,
                                                  int* __restrict__ idx) {
  const int lane = threadIdx.x & 63;
  const int p = blockIdx.x * 4 + (threadIdx.x >> 6);
  const int b = p >> 12;
  const float4* __restrict__ pb = pack + ((size_t)b << 12);
  const float4 me = pack[p];
  unsigned long long m0 = ~0ull, m1 = ~0ull, m2 = ~0ull, m3 = ~0ull;
#pragma unroll 8
  for (int s = 0; s < 64; ++s) {
    const float4 q = pb[s * 64 + lane];
    float d = me.w + q.w - 2.0f * fmaf(me.x, q.x, fmaf(me.y, q.y, me.z * q.z));
    unsigned ub = __float_as_uint(d);
    ub = (ub & 0x80000000u) ? ~ub : (ub | 0x80000000u);
    unsigned long long k = ((unsigned long long)ub << 12) | (unsigned)(s * 64 + lane);
    if (k < m3) {
      bool l0 = k < m0;  unsigned long long t0 = l0 ? m0 : k;  m0 = l0 ? k : m0;
      bool l1 = t0 < m1; unsigned long long t1 = l1 ? m1 : t0; m1 = l1 ? t0 : m1;
      bool l2 = t1 < m2; unsigned long long t2 = l2 ? m2 : t1; m2 = l2 ? t1 : m2;
      m3 = (t2 < m3) ? t2 : m3;
    }
  }
  for (int pass = 0; pass < 16; ++pass) {
    unsigned long long w = m0;
#pragma unroll
    for (int mv = 1; mv < 64; mv <<= 1) {
      unsigned long long o = __shfl_xor(w, mv);
      w = (o < w) ? o : w;
    }
    if (lane == pass) idx[(p << 4) + pass] = (int)(w & 0xFFFull);
    if (m0 == w) { m0 = m1; m1 = m2; m2 = m3; m3 = ~0ull; }
    if (pass < 15 && __any(m0 == ~0ull)) {
      if (m0 == ~0ull) {
        m1 = ~0ull; m2 = ~0ull; m3 = ~0ull;
#pragma unroll 8
        for (int s = 0; s < 64; ++s) {
          const float4 q = pb[s * 64 + lane];
          float d = me.w + q.w - 2.0f * fmaf(me.x, q.x, fmaf(me.y, q.y, me.z * q.z));
          unsigned ub = __float_as_uint(d);
          ub = (ub & 0x80000000u) ? ~ub : (ub | 0x80000000u);
          unsigned long long k = ((unsigned long long)ub << 12) | (unsigned)(s * 64 + lane);
          k = (k > w) ? k : ~0ull;
          bool l0 = k < m0;  unsigned long long t0 = l0 ? m0 : k;  m0 = l0 ? k : m0;
          bool l1 = t0 < m1; unsigned long long t1 = l1 ? m1 : t0; m1 = l1 ? t0 : m1;
          bool l2 = t1 < m2; unsigned long long t2 = l2 ? m2 : t1; m2 = l2 ? t1 : m2;
          m3 = (t2 < m3) ? t2 : m3;
        }
      }
    }
  }
}

// ---------------------------------------------------------------------------
// fc: y = data @ W_fc + b_fc (K=9, C=64) + column stats.
// ---------------------------------------------------------------------------
__global__ __launch_bounds__(256) void fc_kernel(const float* __restrict__ data,
                                                 const float* __restrict__ W,
                                                 const float* __restrict__ bias,
                                                 float* __restrict__ y,
                                                 float* __restrict__ stats) {
  const int t = blockIdx.x * 256 + threadIdx.x;
  const int r = t >> 6, c = t & 63;
  const float* dr = data + (size_t)r * 9;
  float acc = bias[c];
#pragma unroll
  for (int k = 0; k < 9; ++k) acc = fmaf(dr[k], W[k * 64 + c], acc);
  y[t] = acc;
  __shared__ float red[256];
  red[threadIdx.x] = acc;
  __syncthreads();
  if (threadIdx.x < 64) {
    float s = red[threadIdx.x] + red[threadIdx.x + 64] + red[threadIdx.x + 128] + red[threadIdx.x + 192];
    atomicAdd(&stats[threadIdx.x], s);
  }
  __syncthreads();
  red[threadIdx.x] = acc * acc;
  __syncthreads();
  if (threadIdx.x < 64) {
    float s = red[threadIdx.x] + red[threadIdx.x + 64] + red[threadIdx.x + 128] + red[threadIdx.x + 192];
    atomicAdd(&stats[64 + threadIdx.x], s);
  }
}

// ---------------------------------------------------------------------------
// BN(+ReLU) normalize in place (x2v, h12).
// ---------------------------------------------------------------------------
__global__ void bn_norm_kernel(float* __restrict__ buf, const float* __restrict__ stats,
                               int cmask, int C, float inv_cnt, int total) {
  int t = blockIdx.x * 256 + threadIdx.x;
  if (t >= total) return;
  int c = t & cmask;
  float m = stats[c] * inv_cnt;
  float v = fmaxf(stats[C + c] * inv_cnt - m * m, 0.0f);
  float rs = rsqrtf(v + EPSBN);
  float x = (buf[t] - m) * rs;
  buf[t] = fmaxf(x, 0.0f);
}

// ---------------------------------------------------------------------------
// Edge conv via MFMA (validated round 6/7): wave = 16 points x 64 cols,
// B-frags in regs, idx/A prefetch pipeline.
// ---------------------------------------------------------------------------
template <bool HAS_PTS>
__global__ __launch_bounds__(256) void edge_mfma_kernel(
    const unsigned short* __restrict__ Xh, const unsigned short* __restrict__ Xl,
    const int* __restrict__ idx,
    const float4* __restrict__ pack,
    const unsigned short* __restrict__ Wmh, const unsigned short* __restrict__ Wml,
    const float4* __restrict__ Wbt, const float* __restrict__ basemat,
    float* __restrict__ out, float* __restrict__ stats) {
  const int wave = threadIdx.x >> 6;
  const int lane = threadIdx.x & 63;
  const int pg   = blockIdx.x;
  const int c0   = wave << 6;
  const int cl   = lane & 15;
  const int kg   = (lane >> 4) << 3;
  const int bat  = pg >> 8;
  const int pbase = bat << 12;
  const int ib   = pg << 8;

  short8 bh[4][2], blo[4][2];
#pragma unroll
  for (int q = 0; q < 4; ++q) {
    const unsigned short* wp = Wmh + (size_t)(c0 + q * 16 + cl) * 64 + kg;
    bh[q][0] = *(const short8*)wp; bh[q][1] = *(const short8*)(wp + 32);
    const unsigned short* wq = Wml + (size_t)(c0 + q * 16 + cl) * 64 + kg;
    blo[q][0] = *(const short8*)wq; blo[q][1] = *(const short8*)(wq + 32);
  }
  float4 wb[4];
  if (HAS_PTS) {
#pragma unroll
    for (int q = 0; q < 4; ++q) wb[q] = Wbt[c0 + q * 16 + cl];
  }
  float rs1[4] = {0.f, 0.f, 0.f, 0.f}, rs2[4] = {0.f, 0.f, 0.f, 0.f};

  int jn = idx[ib + 16 + cl];
  int j0 = idx[ib + cl];
  size_t ro = ((size_t)(pbase | j0) << 6) + kg;
  short8 a0h = *(const short8*)(Xh + ro);
  short8 a1h = *(const short8*)(Xh + ro + 32);
  short8 a0l = *(const short8*)(Xl + ro);
  short8 a1l = *(const short8*)(Xl + ro + 32);

  for (int pp = 0; pp < 16; ++pp) {
    const int p = (pg << 4) | pp;
    int jf = 0;
    if (pp < 14) jf = idx[ib + ((pp + 2) << 4) + cl];
    short8 n0h, n1h, n0l, n1l;
    if (pp < 15) {
      size_t rn = ((size_t)(pbase | jn) << 6) + kg;
      n0h = *(const short8*)(Xh + rn);
      n1h = *(const short8*)(Xh + rn + 32);
      n0l = *(const short8*)(Xl + rn);
      n1l = *(const short8*)(Xl + rn + 32);
    }
    float dx0, dy0, dz0, dx1, dy1, dz1, dx2, dy2, dz2, dx3, dy3, dz3;
    if (HAS_PTS) {
      const int4 j4 = *(const int4*)(idx + (p << 4) + ((lane >> 4) << 2));
      const float4 pc = pack[p];
      const float4 q0 = pack[pbase | j4.x];
      const float4 q1 = pack[pbase | j4.y];
      const float4 q2 = pack[pbase | j4.z];
      const float4 q3 = pack[pbase | j4.w];
      dx0 = q0.x - pc.x; dy0 = q0.y - pc.y; dz0 = q0.z - pc.z;
      dx1 = q1.x - pc.x; dy1 = q1.y - pc.y; dz1 = q1.z - pc.z;
      dx2 = q2.x - pc.x; dy2 = q2.y - pc.y; dz2 = q2.z - pc.z;
      dx3 = q3.x - pc.x; dy3 = q3.y - pc.y; dz3 = q3.z - pc.z;
    }
    f32x4 acc[4];
#pragma unroll
    for (int q = 0; q < 4; ++q) {
      acc[q][0] = 0.f; acc[q][1] = 0.f; acc[q][2] = 0.f; acc[q][3] = 0.f;
    }
#pragma unroll
    for (int q = 0; q < 4; ++q) {
      acc[q] = __builtin_amdgcn_mfma_f32_16x16x32_bf16(a0l, bh[q][0], acc[q], 0, 0, 0);
      acc[q] = __builtin_amdgcn_mfma_f32_16x16x32_bf16(a1l, bh[q][1], acc[q], 0, 0, 0);
      acc[q] = __builtin_amdgcn_mfma_f32_16x16x32_bf16(a0h, blo[q][0], acc[q], 0, 0, 0);
      acc[q] = __builtin_amdgcn_mfma_f32_16x16x32_bf16(a1h, blo[q][1], acc[q], 0, 0, 0);
      acc[q] = __builtin_amdgcn_mfma_f32_16x16x32_bf16(a0h, bh[q][0], acc[q], 0, 0, 0);
      acc[q] = __builtin_amdgcn_mfma_f32_16x16x32_bf16(a1h, bh[q][1], acc[q], 0, 0, 0);
    }
    if (HAS_PTS) {
#pragma unroll
      for (int q = 0; q < 4; ++q) {
        acc[q][0] += dx0 * wb[q].x + dy0 * wb[q].y + dz0 * wb[q].z;
        acc[q][1] += dx1 * wb[q].x + dy1 * wb[q].y + dz1 * wb[q].z;
        acc[q][2] += dx2 * wb[q].x + dy2 * wb[q].y + dz2 * wb[q].z;
        acc[q][3] += dx3 * wb[q].x + dy3 * wb[q].y + dz3 * wb[q].z;
      }
    }
#pragma unroll
    for (int q = 0; q < 4; ++q) {
      float s1 = acc[q][0] + acc[q][1] + acc[q][2] + acc[q][3];
      float s2 = acc[q][0] * acc[q][0] + acc[q][1] * acc[q][1]
               + acc[q][2] * acc[q][2] + acc[q][3] * acc[q][3];
      float mx = fmaxf(fmaxf(acc[q][0], acc[q][1]), fmaxf(acc[q][2], acc[q][3]));
      s1 += __shfl_xor(s1, 16); s1 += __shfl_xor(s1, 32);
      s2 += __shfl_xor(s2, 16); s2 += __shfl_xor(s2, 32);
      mx = fmaxf(mx, __shfl_xor(mx, 16)); mx = fmaxf(mx, __shfl_xor(mx, 32));
      float bb = basemat[(size_t)p * 256 + c0 + q * 16 + cl];
      if (lane < 16) out[(size_t)p * 256 + c0 + q * 16 + cl] = mx + bb;
      rs1[q] += s1 + 16.f * bb;
      rs2[q] += s2 + 2.f * bb * s1 + 16.f * bb * bb;
    }
    a0h = n0h; a1h = n1h; a0l = n0l; a1l = n1l;
    jn = jf;
  }
  if (lane < 16) {
#pragma unroll
    for (int q = 0; q < 4; ++q) {
      atomicAdd(&stats[c0 + q * 16 + lane], rs1[q]);
      atomicAdd(&stats[256 + c0 + q * 16 + lane], rs2[q]);
    }
  }
}

// ---------------------------------------------------------------------------
// agg_pack: out[r,c] = bn_relu(max over 16 neighbors of X[(b,j),c]), emitted
// as fragment-major hi/lo bf16 (feeds gemm_mfma directly). BN fused: bn_relu
// is monotone per channel, so bn_relu(max) == max(bn_relu).
// ---------------------------------------------------------------------------
template <int LGC>
__global__ __launch_bounds__(256) void agg_pack_kernel(
    const float* __restrict__ X, const int* __restrict__ idx,
    const float* __restrict__ stats, float inv_cnt,
    unsigned short* __restrict__ ph, unsigned short* __restrict__ pl) {
  const int C = 1 << LGC;
  const int t = blockIdx.x * 256 + threadIdx.x;
  const int r = t >> (LGC - 2), cq = t & ((C >> 2) - 1);
  const int base = (r >> 12) << 12;
  const int* ip = idx + (size_t)r * KSN;
  float4 mx = make_float4(-FLT_MAX, -FLT_MAX, -FLT_MAX, -FLT_MAX);
#pragma unroll
  for (int k = 0; k < KSN; ++k) {
    int j = ip[k];
    const float4 v = *reinterpret_cast<const float4*>(X + (size_t)(base + j) * C + cq * 4);
    mx.x = fmaxf(mx.x, v.x); mx.y = fmaxf(mx.y, v.y);
    mx.z = fmaxf(mx.z, v.z); mx.w = fmaxf(mx.w, v.w);
  }
  const int c = cq * 4;
  const float4 sa = *reinterpret_cast<const float4*>(stats + c);
  const float4 sb = *reinterpret_cast<const float4*>(stats + C + c);
  float m0 = sa.x * inv_cnt, m1 = sa.y * inv_cnt, m2 = sa.z * inv_cnt, m3 = sa.w * inv_cnt;
  float o0 = fmaxf((mx.x - m0) * rsqrtf(fmaxf(sb.x * inv_cnt - m0 * m0, 0.f) + EPSBN), 0.f);
  float o1 = fmaxf((mx.y - m1) * rsqrtf(fmaxf(sb.y * inv_cnt - m1 * m1, 0.f) + EPSBN), 0.f);
  float o2 = fmaxf((mx.z - m2) * rsqrtf(fmaxf(sb.z * inv_cnt - m2 * m2, 0.f) + EPSBN), 0.f);
  float o3 = fmaxf((mx.w - m3) * rsqrtf(fmaxf(sb.w * inv_cnt - m3 * m3, 0.f) + EPSBN), 0.f);
  short4v H, L;
  H.x = (short)f2bf(o0); L.x = (short)f2bf(o0 - bf2f((unsigned short)H.x));
  H.y = (short)f2bf(o1); L.y = (short)f2bf(o1 - bf2f((unsigned short)H.y));
  H.z = (short)f2bf(o2); L.z = (short)f2bf(o2 - bf2f((unsigned short)H.z));
  H.w = (short)f2bf(o3); L.w = (short)f2bf(o3 - bf2f((unsigned short)H.w));
  const int NK = C >> 5;
  const int rt = r >> 4, rl = r & 15, ks = c >> 5, kl = c & 31;
  const size_t dst = (((size_t)rt * NK + ks) * 64 + (((kl >> 3) << 4) | rl)) * 8 + (kl & 7);
  *(short4v*)(ph + dst) = H;
  *(short4v*)(pl + dst) = L;
}

// ---------------------------------------------------------------------------
// MFMA GEMM (validated round 7): wave = 64 rows x 64 cols, acc[4][4].
// AMODE 0: packed A. AMODE 1: row-major ushort hi/lo A, row stride 64 (K=64).
// AMODE 3: ks<32 batch-broadcast g + packed x12 tail.
// ---------------------------------------------------------------------------
template <int AMODE, bool DOMAX>
__global__ __launch_bounds__(256) void gemm_mfma_kernel(
    const unsigned short* __restrict__ Ah, const unsigned short* __restrict__ Al,
    const unsigned short* __restrict__ gh, const unsigned short* __restrict__ gl,
    const unsigned short* __restrict__ Wh, const unsigned short* __restrict__ Wl,
    float* __restrict__ Y, float* __restrict__ pmax, float* __restrict__ stats,
    int K, int C) {
  __shared__ float red1[4][64], red2[4][64], redm[4][64];
  const int wave = threadIdx.x >> 6, lane = threadIdx.x & 63;
  const int rtb = blockIdx.x * 16 + wave * 4;
  const int c0  = blockIdx.y * 64;
  const int ct0 = blockIdx.y * 4;
  const int NK  = K >> 5;
  const int KP  = (AMODE == 3) ? 4 : NK;
  const int bat = blockIdx.x >> 4;
  f32x4 acc[4][4];
#pragma unroll
  for (int r = 0; r < 4; ++r)
#pragma unroll
    for (int cc = 0; cc < 4; ++cc) {
      acc[r][cc][0] = 0.f; acc[r][cc][1] = 0.f; acc[r][cc][2] = 0.f; acc[r][cc][3] = 0.f;
    }
  const int lhalf = (lane >> 4) << 3;
  for (int ks = 0; ks < NK; ++ks) {
    short8 ah[4], al[4];
    if (AMODE == 3 && ks < 32) {
      const int go = bat * 1024 + ks * 32 + lhalf;
      short8 gav = *(const short8*)(gh + go);
      short8 galv = *(const short8*)(gl + go);
#pragma unroll
      for (int r = 0; r < 4; ++r) { ah[r] = gav; al[r] = galv; }
    } else if (AMODE == 1) {
#pragma unroll
      for (int r = 0; r < 4; ++r) {
        const size_t aoff = ((size_t)((rtb + r) * 16 + (lane & 15))) * 64 + ks * 32 + lhalf;
        ah[r] = *(const short8*)(Ah + aoff);
        al[r] = *(const short8*)(Al + aoff);
      }
    } else {
      const int ksp = (AMODE == 3) ? ks - 32 : ks;
#pragma unroll
      for (int r = 0; r < 4; ++r) {
        const size_t aoff = (((size_t)(rtb + r) * KP + ksp) * 64 + lane) * 8;
        ah[r] = *(const short8*)(Ah + aoff);
        al[r] = *(const short8*)(Al + aoff);
      }
    }
#pragma unroll
    for (int cc = 0; cc < 4; ++cc) {
      const size_t woff = (((size_t)(ct0 + cc) * NK + ks) * 64 + lane) * 8;
      short8 bh = *(const short8*)(Wh + woff);
      short8 bl = *(const short8*)(Wl + woff);
#pragma unroll
      for (int r = 0; r < 4; ++r) {
        acc[r][cc] = __builtin_amdgcn_mfma_f32_16x16x32_bf16(al[r], bh, acc[r][cc], 0, 0, 0);
        acc[r][cc] = __builtin_amdgcn_mfma_f32_16x16x32_bf16(ah[r], bl, acc[r][cc], 0, 0, 0);
        acc[r][cc] = __builtin_amdgcn_mfma_f32_16x16x32_bf16(ah[r], bh, acc[r][cc], 0, 0, 0);
      }
    }
  }
#pragma unroll
  for (int cc = 0; cc < 4; ++cc) {
    float s1 = 0.f, s2 = 0.f, mm = -FLT_MAX;
#pragma unroll
    for (int r = 0; r < 4; ++r) {
      if (!DOMAX) {
#pragma unroll
        for (int i = 0; i < 4; ++i)
          Y[(size_t)((rtb + r) * 16 + ((lane >> 4) << 2) + i) * C + c0 + cc * 16 + (lane & 15)] = acc[r][cc][i];
      }
#pragma unroll
      for (int i = 0; i < 4; ++i) {
        float v = acc[r][cc][i];
        s1 += v; s2 = fmaf(v, v, s2); mm = fmaxf(mm, v);
      }
    }
    s1 += __shfl_xor(s1, 16); s1 += __shfl_xor(s1, 32);
    s2 += __shfl_xor(s2, 16); s2 += __shfl_xor(s2, 32);
    mm = fmaxf(mm, __shfl_xor(mm, 16)); mm = fmaxf(mm, __shfl_xor(mm, 32));
    if (lane < 16) {
      red1[wave][cc * 16 + lane] = s1;
      red2[wave][cc * 16 + lane] = s2;
      if (DOMAX) redm[wave][cc * 16 + lane] = mm;
    }
  }
  __syncthreads();
  if (threadIdx.x < 64) {
    const int t = threadIdx.x;
    float a = red1[0][t] + red1[1][t] + red1[2][t] + red1[3][t];
    float b = red2[0][t] + red2[1][t] + red2[2][t] + red2[3][t];
    atomicAdd(&stats[c0 + t], a);
    atomicAdd(&stats[C + c0 + t], b);
    if (DOMAX) {
      float mm = fmaxf(fmaxf(redm[0][t], redm[1][t]), fmaxf(redm[2][t], redm[3][t]));
      pmax[(size_t)blockIdx.x * C + c0 + t] = mm;
    }
  }
}

// g[b,c] = relu(bn(max over 16 row-blocks)) -> bf16 hi/lo
__global__ void fin_g_kernel(const float* __restrict__ pmax, const float* __restrict__ stats,
                             unsigned short* __restrict__ gh, unsigned short* __restrict__ gl) {
  int t = blockIdx.x * 256 + threadIdx.x;   // 4096
  int b = t >> 10, c = t & 1023;
  const float inv = 1.0f / 16384.0f;
  float m = stats[c] * inv;
  float v = fmaxf(stats[1024 + c] * inv - m * m, 0.0f);
  float rs = rsqrtf(v + EPSBN);
  float mx = -FLT_MAX;
  for (int s = 0; s < 16; ++s) mx = fmaxf(mx, pmax[(size_t)(b * 16 + s) * 1024 + c]);
  float val = fmaxf((mx - m) * rs, 0.0f);
  unsigned short h = f2bf(val);
  gh[t] = h; gl[t] = f2bf(val - bf2f(h));
}

__global__ void final13_kernel(const float* __restrict__ h, const float* __restrict__ W,
                               float* __restrict__ out) {
  int t = blockIdx.x * 256 + threadIdx.x;
  if (t >= RN * 13) return;
  int r = t / 13, c = t - r * 13;
  float acc = 0.0f;
  for (int k = 0; k < 256; ++k) acc = fmaf(h[(size_t)r * 256 + k], W[k * 13 + c], acc);
  int b = r >> 12, n = r & 4095;
  out[(size_t)b * 13 * NN + (size_t)c * NN + n] = acc;
}

// ---------------------------------------------------------------------------
extern "C" void kernel_launch(void* const* d_in, const int* in_sizes, int n_in,
                              void* d_out, int out_size, void* d_ws, size_t ws_size,
                              hipStream_t stream) {
  (void)in_sizes; (void)n_in; (void)out_size; (void)ws_size;
  const float* data = (const float*)d_in[0];
  const float* W_fc = (const float*)d_in[1];
  const float* b_fc = (const float*)d_in[2];
  const float* W1   = (const float*)d_in[3];
  const float* W2   = (const float*)d_in[4];
  const float* W3   = (const float*)d_in[5];
  const float* W4   = (const float*)d_in[6];
  const float* W5   = (const float*)d_in[7];
  const float* W6   = (const float*)d_in[8];
  const float* W10  = (const float*)d_in[9];
  const float* W11  = (const float*)d_in[10];
  const float* W12  = (const float*)d_in[11];
  const float* W13  = (const float*)d_in[12];
  float* out = (float*)d_out;

  float* ws  = (float*)d_ws;
  int*   idx = (int*)d_ws;
  size_t o = 262144;
  float* x0   = ws + o; o += (size_t)RN * 64;
  float* x1v  = ws + o; o += (size_t)RN * 64;
  float* x2v  = ws + o; o += (size_t)RN * 64;
  float* bufA = ws + o; o += (size_t)RN * 256;
  float* bufB = ws + o; o += (size_t)RN * 256;
  float* bufC = ws + o; o += (size_t)RN * 64;
  float* pmax = ws + o; o += (size_t)64 * 1024;
  float* h11  = ws + o; o += (size_t)RN * 512;
  float* h12  = ws + o; o += (size_t)RN * 256;
  float* stats = ws + o; o += 8192;
  float4* pack = (float4*)(ws + o); o += (size_t)RN * 4;
  unsigned short* xbh = (unsigned short*)(ws + o); o += (size_t)RN * 32;
  unsigned short* xbl = (unsigned short*)(ws + o); o += (size_t)RN * 32;
  float* W1p = ws + o; o += 16384;
  float* W4p = ws + o; o += 16384;
  unsigned short* W1mh = (unsigned short*)(ws + o); o += 8192;
  unsigned short* W1ml = (unsigned short*)(ws + o); o += 8192;
  unsigned short* W4mh = (unsigned short*)(ws + o); o += 8192;
  unsigned short* W4ml = (unsigned short*)(ws + o); o += 8192;
  float4* W1bt = (float4*)(ws + o); o += 1024;
  unsigned short* W10h = (unsigned short*)(ws + o); o += 65536;
  unsigned short* W10l = (unsigned short*)(ws + o); o += 65536;
  unsigned short* W11h = (unsigned short*)(ws + o); o += 294912;
  unsigned short* W11l = (unsigned short*)(ws + o); o += 294912;
  unsigned short* W12h = (unsigned short*)(ws + o); o += 65536;
  unsigned short* W12l = (unsigned short*)(ws + o); o += 65536;
  unsigned short* gh   = (unsigned short*)(ws + o); o += 2048;
  unsigned short* gl   = (unsigned short*)(ws + o); o += 2048;
  unsigned short* W1ph = (unsigned short*)(ws + o); o += 8192;
  unsigned short* W1pl = (unsigned short*)(ws + o); o += 8192;
  unsigned short* W4ph = (unsigned short*)(ws + o); o += 8192;
  unsigned short* W4pl = (unsigned short*)(ws + o); o += 8192;
  unsigned short* W2h  = (unsigned short*)(ws + o); o += 8192;
  unsigned short* W2l  = (unsigned short*)(ws + o); o += 8192;
  unsigned short* W3h  = (unsigned short*)(ws + o); o += 2048;
  unsigned short* W3l  = (unsigned short*)(ws + o); o += 2048;
  unsigned short* W5h  = (unsigned short*)(ws + o); o += 8192;
  unsigned short* W5l  = (unsigned short*)(ws + o); o += 8192;
  unsigned short* W6h  = (unsigned short*)(ws + o); o += 2048;
  unsigned short* W6l  = (unsigned short*)(ws + o); o += 2048;
  // overlays on dead buffers:
  unsigned short* x12h = (unsigned short*)bufC;              // RN*128 us
  unsigned short* x12l = (unsigned short*)x0;                // RN*128 us
  unsigned short* h11h = (unsigned short*)bufA;              // RN*512 us
  unsigned short* h11l = (unsigned short*)bufB;              // RN*512 us
  unsigned short* aggh = (unsigned short*)h11;               // RN*256 us
  unsigned short* aggl = (unsigned short*)h11 + (size_t)RN * 256;

  float* S0 = stats;          // 64 (fc)
  float* S1 = stats + 128;    // 256 (edge1)
  float* S2 = stats + 640;    // 64  (W2)
  float* S3 = stats + 768;    // 64  (W3)
  float* S4 = stats + 896;    // 256 (edge2)
  float* S5 = stats + 1408;   // 64  (W5)
  float* S6 = stats + 1536;   // 64  (W6)
  float* S7 = stats + 1664;   // 1024 (W10)
  float* S8 = stats + 3712;   // 512 (W11)
  float* S9 = stats + 4736;   // 256 (W12)
  float* Sd = stats + 5248;   // dummy sink (512)

  hipMemsetAsync(stats, 0, 8192 * sizeof(float), stream);

  prep_kernel<<<RN / 256, 256, 0, stream>>>(data, pack);
  knn_kernel<<<RN / 4, 256, 0, stream>>>(pack, idx);
  prep_w_kernel<<<64, 256, 0, stream>>>(W1, W4, W1p, W1mh, W1ml, W1bt, W4p, W4mh, W4ml);
  prep_wpack_kernel<<<64, 256, 0, stream>>>(W1p, W1ph, W1pl, 8, 16384, 2);
  prep_wpack_kernel<<<64, 256, 0, stream>>>(W4p, W4ph, W4pl, 8, 16384, 2);
  prep_wpack_kernel<<<64, 256, 0, stream>>>(W2, W2h, W2l, 6, 16384, 8);
  prep_wpack_kernel<<<16, 256, 0, stream>>>(W3, W3h, W3l, 6, 4096, 2);
  prep_wpack_kernel<<<64, 256, 0, stream>>>(W5, W5h, W5l, 6, 16384, 8);
  prep_wpack_kernel<<<16, 256, 0, stream>>>(W6, W6h, W6l, 6, 4096, 2);
  prep_wpack_kernel<<<512, 256, 0, stream>>>(W10, W10h, W10l, 10, 131072, 4);
  prep_wpack_kernel<<<2304, 256, 0, stream>>>(W11, W11h, W11l, 9, 589824, 36);
  prep_wpack_kernel<<<512, 256, 0, stream>>>(W12, W12h, W12l, 8, 131072, 16);

  fc_kernel<<<RN * 64 / 256, 256, 0, stream>>>(data, W_fc, b_fc, x0, S0);
  bn_normpack_kernel<<<RN * 64 / 256, 256, 0, stream>>>(x0, S0, xbh, xbl);

  // edge conv 1: basemat = x0 @ W1p (MFMA, row-major bf16 A)
  gemm_mfma_kernel<1, false><<<dim3(64, 4), 256, 0, stream>>>(
      xbh, xbl, nullptr, nullptr, W1ph, W1pl, bufB, nullptr, Sd, 64, 256);
  edge_mfma_kernel<true><<<1024, 256, 0, stream>>>(xbh, xbl, idx, pack, W1mh, W1ml, W1bt, bufB, bufA, S1);

  // graph conv 1: agg(+bn fused) -> packed, then MFMA W2
  agg_pack_kernel<8><<<4096, 256, 0, stream>>>(bufA, idx, S1, 1.0f / (RN * 16), aggh, aggl);
  gemm_mfma_kernel<0, false><<<dim3(64, 1), 256, 0, stream>>>(
      aggh, aggl, nullptr, nullptr, W2h, W2l, bufC, nullptr, S2, 256, 64);

  // graph conv 2
  agg_pack_kernel<6><<<1024, 256, 0, stream>>>(bufC, idx, S2, 1.0f / RN, aggh, aggl);
  gemm_mfma_kernel<0, false><<<dim3(64, 1), 256, 0, stream>>>(
      aggh, aggl, nullptr, nullptr, W3h, W3l, x1v, nullptr, S3, 64, 64);
  bn_normpack_kernel<<<RN * 64 / 256, 256, 0, stream>>>(x1v, S3, xbh, xbl);

  // edge conv 2 (no pts)
  gemm_mfma_kernel<1, false><<<dim3(64, 4), 256, 0, stream>>>(
      xbh, xbl, nullptr, nullptr, W4ph, W4pl, bufB, nullptr, Sd, 64, 256);
  edge_mfma_kernel<false><<<1024, 256, 0, stream>>>(xbh, xbl, idx, pack, W4mh, W4ml, nullptr, bufB, bufA, S4);

  // graph conv 3
  agg_pack_kernel<8><<<4096, 256, 0, stream>>>(bufA, idx, S4, 1.0f / (RN * 16), aggh, aggl);
  gemm_mfma_kernel<0, false><<<dim3(64, 1), 256, 0, stream>>>(
      aggh, aggl, nullptr, nullptr, W5h, W5l, bufC, nullptr, S5, 256, 64);

  // graph conv 4
  agg_pack_kernel<6><<<1024, 256, 0, stream>>>(bufC, idx, S5, 1.0f / RN, aggh, aggl);
  gemm_mfma_kernel<0, false><<<dim3(64, 1), 256, 0, stream>>>(
      aggh, aggl, nullptr, nullptr, W6h, W6l, x2v, nullptr, S6, 64, 64);
  bn_norm_kernel<<<RN * 64 / 256, 256, 0, stream>>>(x2v, S6, 63, 64, 1.0f / RN, RN * 64);

  // pack [x1|x2] (bufC and x0 dead now; overlay)
  pack_x12_kernel<<<RN * 128 / 256, 256, 0, stream>>>(x1v, x2v, x12h, x12l);

  // W10 path: MFMA, stats + per-block col max only
  gemm_mfma_kernel<0, true><<<dim3(64, 16), 256, 0, stream>>>(
      x12h, x12l, nullptr, nullptr, W10h, W10l, nullptr, pmax, S7, 128, 1024);
  fin_g_kernel<<<16, 256, 0, stream>>>(pmax, S7, gh, gl);

  // W11: [g | x12] @ W11 -> h11
  gemm_mfma_kernel<3, false><<<dim3(64, 8), 256, 0, stream>>>(
      x12h, x12l, gh, gl, W11h, W11l, h11, nullptr, S8, 1152, 512);
  bn_pack_kernel<<<RN * 512 / 256, 256, 0, stream>>>(h11, S8, h11h, h11l);

  // W12: h11 @ W12 -> h12
  gemm_mfma_kernel<0, false><<<dim3(64, 4), 256, 0, stream>>>(
      h11h, h11l, nullptr, nullptr, W12h, W12l, h12, nullptr, S9, 512, 256);
  bn_norm_kernel<<<RN * 256 / 256, 256, 0, stream>>>(h12, S9, 255, 256, 1.0f / RN, RN * 256);

  final13_kernel<<<(RN * 13 + 255) / 256, 256, 0, stream>>>(h12, W13, out);
}

// Round 9
// 667.468 us; speedup vs baseline: 3.6344x; 1.1288x over previous
//
#include <hip/hip_runtime.h>
#include <hip/hip_bf16.h>
#include <float.h>

static constexpr int BB  = 4;
static constexpr int NN  = 4096;
static constexpr int KSN = 16;
static constexpr int RN  = BB * NN;     // 16384 rows (b,n)
#define EPSBN 1e-5f

typedef __attribute__((ext_vector_type(8))) short short8;
typedef __attribute__((ext_vector_type(4))) short short4v;
typedef __attribute__((ext_vector_type(4))) float f32x4;

__device__ inline unsigned short f2bf(float f) {
  union { float f; unsigned u; } v; v.f = f;
  unsigned r = v.u + 0x7FFF + ((v.u >> 16) & 1);
  return (unsigned short)(r >> 16);
}
__device__ inline float bf2f(unsigned short h) {
  union { unsigned u; float f; } v; v.u = ((unsigned)h) << 16; return v.f;
}

// ---------------------------------------------------------------------------
// Prep: pack (x,y,z,|p|^2) as float4 per point.
// ---------------------------------------------------------------------------
__global__ void prep_kernel(const float* __restrict__ data, float4* __restrict__ pack) {
  int t = blockIdx.x * 256 + threadIdx.x;
  if (t >= RN) return;
  const float* dr = data + (size_t)t * 9;
  float x = dr[0], y = dr[1], z = dr[2];
  pack[t] = make_float4(x, y, z, fmaf(z, z, fmaf(y, y, x * x)));
}

// ---------------------------------------------------------------------------
// Weight prep for edge convs.
// ---------------------------------------------------------------------------
__global__ void prep_w_kernel(const float* __restrict__ W1, const float* __restrict__ W4,
                              float* __restrict__ W1p,
                              unsigned short* __restrict__ W1mh, unsigned short* __restrict__ W1ml,
                              float4* __restrict__ W1bt,
                              float* __restrict__ W4p,
                              unsigned short* __restrict__ W4mh, unsigned short* __restrict__ W4ml) {
  int t = blockIdx.x * 256 + threadIdx.x;   // 16384
  int k = t >> 8, cc = t & 255;
  float w1top = W1[k * 256 + cc], w1mid = W1[(64 + k) * 256 + cc];
  W1p[t] = w1top - w1mid;
  unsigned short h1 = f2bf(w1mid);
  W1mh[cc * 64 + k] = h1;
  W1ml[cc * 64 + k] = f2bf(w1mid - bf2f(h1));
  float w4top = W4[k * 256 + cc], w4mid = W4[(64 + k) * 256 + cc];
  W4p[t] = w4top - w4mid;
  unsigned short h4 = f2bf(w4mid);
  W4mh[cc * 64 + k] = h4;
  W4ml[cc * 64 + k] = f2bf(w4mid - bf2f(h4));
  if (t < 256) W1bt[t] = make_float4(W1[128 * 256 + t], W1[129 * 256 + t], W1[130 * 256 + t], 0.f);
}

// W (row-major [K][C] fp32) -> fragment-major hi/lo pack: dst[ct][ks][lane][8]
__global__ void prep_wpack_kernel(const float* __restrict__ W,
                                  unsigned short* __restrict__ wh, unsigned short* __restrict__ wl,
                                  int lgC, int total, int NK) {
  int t = blockIdx.x * 256 + threadIdx.x;
  if (t >= total) return;
  int k = t >> lgC, c = t & ((1 << lgC) - 1);
  float v = W[t];
  int ct = c >> 4, cl = c & 15, ks = k >> 5, kl = k & 31;
  int dst = ((ct * NK + ks) * 64 + (((kl >> 3) << 4) | cl)) * 8 + (kl & 7);
  unsigned short h = f2bf(v);
  wh[dst] = h; wl[dst] = f2bf(v - bf2f(h));
}

// [x1|x2] -> fragment-major hi/lo pack (K=128)
__global__ void pack_x12_kernel(const float* __restrict__ x1, const float* __restrict__ x2,
                                unsigned short* __restrict__ ph, unsigned short* __restrict__ pl) {
  int t = blockIdx.x * 256 + threadIdx.x;   // RN*128
  int r = t >> 7, k = t & 127;
  float v = (k < 64) ? x1[(size_t)r * 64 + k] : x2[(size_t)r * 64 + k - 64];
  int rt = r >> 4, rl = r & 15, ks = k >> 5, kl = k & 31;
  int dst = ((rt * 4 + ks) * 64 + (((kl >> 3) << 4) | rl)) * 8 + (kl & 7);
  unsigned short h = f2bf(v);
  ph[dst] = h; pl[dst] = f2bf(v - bf2f(h));
}

// BN+ReLU on h11 (C=512) fused with fragment-major hi/lo pack
__global__ void bn_pack_kernel(const float* __restrict__ buf, const float* __restrict__ stats,
                               unsigned short* __restrict__ ph, unsigned short* __restrict__ pl) {
  int t = blockIdx.x * 256 + threadIdx.x;   // RN*512
  int c = t & 511, r = t >> 9;
  const float inv = 1.0f / RN;
  float m = stats[c] * inv;
  float v = fmaxf(stats[512 + c] * inv - m * m, 0.0f);
  float x = fmaxf((buf[t] - m) * rsqrtf(v + EPSBN), 0.0f);
  int rt = r >> 4, rl = r & 15, ks = c >> 5, kl = c & 31;
  int dst = ((rt * 16 + ks) * 64 + (((kl >> 3) << 4) | rl)) * 8 + (kl & 7);
  unsigned short h = f2bf(x);
  ph[dst] = h; pl[dst] = f2bf(x - bf2f(h));
}

// BN+ReLU in place (C=64) fused with row-major hi/lo write (x1v: fp32 kept)
__global__ void bn_normpack_kernel(float* __restrict__ buf, const float* __restrict__ stats,
                                   unsigned short* __restrict__ hi, unsigned short* __restrict__ lo) {
  int t = blockIdx.x * 256 + threadIdx.x;   // RN*64
  int c = t & 63;
  const float inv = 1.0f / RN;
  float m = stats[c] * inv;
  float v = fmaxf(stats[64 + c] * inv - m * m, 0.0f);
  float x = fmaxf((buf[t] - m) * rsqrtf(v + EPSBN), 0.0f);
  buf[t] = x;
  unsigned short h = f2bf(x);
  hi[t] = h; lo[t] = f2bf(x - bf2f(h));
}

// ---------------------------------------------------------------------------
// fc stats via 9x9 Gram: x0 = data@W+b is linear, so column stats are a
// quadratic form of G = sum_r d d^T (45 upper-tri) + sumd (9). Zero atomics.
// ---------------------------------------------------------------------------
__global__ __launch_bounds__(256) void gram_kernel(const float* __restrict__ data,
                                                   float* __restrict__ partials) {
  const int r = blockIdx.x * 256 + threadIdx.x;   // RN = 64 blocks x 256
  const int lane = threadIdx.x & 63, wave = threadIdx.x >> 6;
  __shared__ float red[4][54];
  float d[9];
#pragma unroll
  for (int k = 0; k < 9; ++k) d[k] = data[(size_t)r * 9 + k];
  int p = 0;
#pragma unroll
  for (int i = 0; i < 9; ++i) {
    float v = d[i];
#pragma unroll
    for (int mv = 1; mv < 64; mv <<= 1) v += __shfl_xor(v, mv);
    if (lane == 0) red[wave][p] = v;
    ++p;
  }
#pragma unroll
  for (int i = 0; i < 9; ++i)
#pragma unroll
    for (int j = i; j < 9; ++j) {
      float v = d[i] * d[j];
#pragma unroll
      for (int mv = 1; mv < 64; mv <<= 1) v += __shfl_xor(v, mv);
      if (lane == 0) red[wave][p] = v;
      ++p;
    }
  __syncthreads();
  if (threadIdx.x < 54)
    partials[blockIdx.x * 54 + threadIdx.x] =
        red[0][threadIdx.x] + red[1][threadIdx.x] + red[2][threadIdx.x] + red[3][threadIdx.x];
}

__global__ void fcstats_kernel(const float* __restrict__ partials,
                               const float* __restrict__ W, const float* __restrict__ bias,
                               float* __restrict__ S0) {
  __shared__ float g[54];
  const int t = threadIdx.x;   // 64 threads
  if (t < 54) {
    float s = 0.f;
    for (int b = 0; b < 64; ++b) s += partials[b * 54 + t];
    g[t] = s;
  }
  __syncthreads();
  float w[9];
#pragma unroll
  for (int k = 0; k < 9; ++k) w[k] = W[k * 64 + t];
  float b = bias[t];
  float dotw = 0.f;
#pragma unroll
  for (int k = 0; k < 9; ++k) dotw = fmaf(g[k], w[k], dotw);
  float s2 = 0.f;
  int p = 9;
#pragma unroll
  for (int i = 0; i < 9; ++i)
#pragma unroll
    for (int j = i; j < 9; ++j) {
      float gij = g[p++];
      s2 = fmaf(gij * ((i == j) ? 1.f : 2.f), w[i] * w[j], s2);
    }
  s2 += 2.f * b * dotw + (float)RN * b * b;
  S0[t] = dotw + (float)RN * b;
  S0[64 + t] = s2;
}

// fused fc + BN + ReLU + hi/lo pack (no fp32 writeback, no stats)
__global__ __launch_bounds__(256) void fc_bnpack_kernel(
    const float* __restrict__ data, const float* __restrict__ W,
    const float* __restrict__ bias, const float* __restrict__ stats,
    unsigned short* __restrict__ hi, unsigned short* __restrict__ lo) {
  const int t = blockIdx.x * 256 + threadIdx.x;   // RN*64
  const int r = t >> 6, c = t & 63;
  const float* dr = data + (size_t)r * 9;
  float acc = bias[c];
#pragma unroll
  for (int k = 0; k < 9; ++k) acc = fmaf(dr[k], W[k * 64 + c], acc);
  const float inv = 1.0f / RN;
  float m = stats[c] * inv;
  float v = fmaxf(stats[64 + c] * inv - m * m, 0.0f);
  float x = fmaxf((acc - m) * rsqrtf(v + EPSBN), 0.0f);
  unsigned short h = f2bf(x);
  hi[t] = h; lo[t] = f2bf(x - bf2f(h));
}

// ---------------------------------------------------------------------------
// KNN: one wave per point, branchless sorted top-4 per lane (validated r5-8).
// ---------------------------------------------------------------------------
__global__ __launch_bounds__(256) void knn_kernel(const float4* __restrict__ pack,
                                                  int* __restrict__ idx) {
  const int lane = threadIdx.x & 63;
  const int p = blockIdx.x * 4 + (threadIdx.x >> 6);
  const int b = p >> 12;
  const float4* __restrict__ pb = pack + ((size_t)b << 12);
  const float4 me = pack[p];
  unsigned long long m0 = ~0ull, m1 = ~0ull, m2 = ~0ull, m3 = ~0ull;
#pragma unroll 8
  for (int s = 0; s < 64; ++s) {
    const float4 q = pb[s * 64 + lane];
    float d = me.w + q.w - 2.0f * fmaf(me.x, q.x, fmaf(me.y, q.y, me.z * q.z));
    unsigned ub = __float_as_uint(d);
    ub = (ub & 0x80000000u) ? ~ub : (ub | 0x80000000u);
    unsigned long long k = ((unsigned long long)ub << 12) | (unsigned)(s * 64 + lane);
    if (k < m3) {
      bool l0 = k < m0;  unsigned long long t0 = l0 ? m0 : k;  m0 = l0 ? k : m0;
      bool l1 = t0 < m1; unsigned long long t1 = l1 ? m1 : t0; m1 = l1 ? t0 : m1;
      bool l2 = t1 < m2; unsigned long long t2 = l2 ? m2 : t1; m2 = l2 ? t1 : m2;
      m3 = (t2 < m3) ? t2 : m3;
    }
  }
  for (int pass = 0; pass < 16; ++pass) {
    unsigned long long w = m0;
#pragma unroll
    for (int mv = 1; mv < 64; mv <<= 1) {
      unsigned long long o = __shfl_xor(w, mv);
      w = (o < w) ? o : w;
    }
    if (lane == pass) idx[(p << 4) + pass] = (int)(w & 0xFFFull);
    if (m0 == w) { m0 = m1; m1 = m2; m2 = m3; m3 = ~0ull; }
    if (pass < 15 && __any(m0 == ~0ull)) {
      if (m0 == ~0ull) {
        m1 = ~0ull; m2 = ~0ull; m3 = ~0ull;
#pragma unroll 8
        for (int s = 0; s < 64; ++s) {
          const float4 q = pb[s * 64 + lane];
          float d = me.w + q.w - 2.0f * fmaf(me.x, q.x, fmaf(me.y, q.y, me.z * q.z));
          unsigned ub = __float_as_uint(d);
          ub = (ub & 0x80000000u) ? ~ub : (ub | 0x80000000u);
          unsigned long long k = ((unsigned long long)ub << 12) | (unsigned)(s * 64 + lane);
          k = (k > w) ? k : ~0ull;
          bool l0 = k < m0;  unsigned long long t0 = l0 ? m0 : k;  m0 = l0 ? k : m0;
          bool l1 = t0 < m1; unsigned long long t1 = l1 ? m1 : t0; m1 = l1 ? t0 : m1;
          bool l2 = t1 < m2; unsigned long long t2 = l2 ? m2 : t1; m2 = l2 ? t1 : m2;
          m3 = (t2 < m3) ? t2 : m3;
        }
      }
    }
  }
}

// ---------------------------------------------------------------------------
// BN(+ReLU) normalize in place (x2v, h12).
// ---------------------------------------------------------------------------
__global__ void bn_norm_kernel(float* __restrict__ buf, const float* __restrict__ stats,
                               int cmask, int C, float inv_cnt, int total) {
  int t = blockIdx.x * 256 + threadIdx.x;
  if (t >= total) return;
  int c = t & cmask;
  float m = stats[c] * inv_cnt;
  float v = fmaxf(stats[C + c] * inv_cnt - m * m, 0.0f);
  float rs = rsqrtf(v + EPSBN);
  float x = (buf[t] - m) * rs;
  buf[t] = fmaxf(x, 0.0f);
}

// ---------------------------------------------------------------------------
// Edge conv via MFMA (validated round 6/7): wave = 16 points x 64 cols,
// B-frags in regs, idx/A prefetch pipeline.
// ---------------------------------------------------------------------------
template <bool HAS_PTS>
__global__ __launch_bounds__(256) void edge_mfma_kernel(
    const unsigned short* __restrict__ Xh, const unsigned short* __restrict__ Xl,
    const int* __restrict__ idx,
    const float4* __restrict__ pack,
    const unsigned short* __restrict__ Wmh, const unsigned short* __restrict__ Wml,
    const float4* __restrict__ Wbt, const float* __restrict__ basemat,
    float* __restrict__ out, float* __restrict__ stats) {
  const int wave = threadIdx.x >> 6;
  const int lane = threadIdx.x & 63;
  const int pg   = blockIdx.x;
  const int c0   = wave << 6;
  const int cl   = lane & 15;
  const int kg   = (lane >> 4) << 3;
  const int bat  = pg >> 8;
  const int pbase = bat << 12;
  const int ib   = pg << 8;

  short8 bh[4][2], blo[4][2];
#pragma unroll
  for (int q = 0; q < 4; ++q) {
    const unsigned short* wp = Wmh + (size_t)(c0 + q * 16 + cl) * 64 + kg;
    bh[q][0] = *(const short8*)wp; bh[q][1] = *(const short8*)(wp + 32);
    const unsigned short* wq = Wml + (size_t)(c0 + q * 16 + cl) * 64 + kg;
    blo[q][0] = *(const short8*)wq; blo[q][1] = *(const short8*)(wq + 32);
  }
  float4 wb[4];
  if (HAS_PTS) {
#pragma unroll
    for (int q = 0; q < 4; ++q) wb[q] = Wbt[c0 + q * 16 + cl];
  }
  float rs1[4] = {0.f, 0.f, 0.f, 0.f}, rs2[4] = {0.f, 0.f, 0.f, 0.f};

  int jn = idx[ib + 16 + cl];
  int j0 = idx[ib + cl];
  size_t ro = ((size_t)(pbase | j0) << 6) + kg;
  short8 a0h = *(const short8*)(Xh + ro);
  short8 a1h = *(const short8*)(Xh + ro + 32);
  short8 a0l = *(const short8*)(Xl + ro);
  short8 a1l = *(const short8*)(Xl + ro + 32);

  for (int pp = 0; pp < 16; ++pp) {
    const int p = (pg << 4) | pp;
    int jf = 0;
    if (pp < 14) jf = idx[ib + ((pp + 2) << 4) + cl];
    short8 n0h, n1h, n0l, n1l;
    if (pp < 15) {
      size_t rn = ((size_t)(pbase | jn) << 6) + kg;
      n0h = *(const short8*)(Xh + rn);
      n1h = *(const short8*)(Xh + rn + 32);
      n0l = *(const short8*)(Xl + rn);
      n1l = *(const short8*)(Xl + rn + 32);
    }
    float dx0, dy0, dz0, dx1, dy1, dz1, dx2, dy2, dz2, dx3, dy3, dz3;
    if (HAS_PTS) {
      const int4 j4 = *(const int4*)(idx + (p << 4) + ((lane >> 4) << 2));
      const float4 pc = pack[p];
      const float4 q0 = pack[pbase | j4.x];
      const float4 q1 = pack[pbase | j4.y];
      const float4 q2 = pack[pbase | j4.z];
      const float4 q3 = pack[pbase | j4.w];
      dx0 = q0.x - pc.x; dy0 = q0.y - pc.y; dz0 = q0.z - pc.z;
      dx1 = q1.x - pc.x; dy1 = q1.y - pc.y; dz1 = q1.z - pc.z;
      dx2 = q2.x - pc.x; dy2 = q2.y - pc.y; dz2 = q2.z - pc.z;
      dx3 = q3.x - pc.x; dy3 = q3.y - pc.y; dz3 = q3.z - pc.z;
    }
    f32x4 acc[4];
#pragma unroll
    for (int q = 0; q < 4; ++q) {
      acc[q][0] = 0.f; acc[q][1] = 0.f; acc[q][2] = 0.f; acc[q][3] = 0.f;
    }
#pragma unroll
    for (int q = 0; q < 4; ++q) {
      acc[q] = __builtin_amdgcn_mfma_f32_16x16x32_bf16(a0l, bh[q][0], acc[q], 0, 0, 0);
      acc[q] = __builtin_amdgcn_mfma_f32_16x16x32_bf16(a1l, bh[q][1], acc[q], 0, 0, 0);
      acc[q] = __builtin_amdgcn_mfma_f32_16x16x32_bf16(a0h, blo[q][0], acc[q], 0, 0, 0);
      acc[q] = __builtin_amdgcn_mfma_f32_16x16x32_bf16(a1h, blo[q][1], acc[q], 0, 0, 0);
      acc[q] = __builtin_amdgcn_mfma_f32_16x16x32_bf16(a0h, bh[q][0], acc[q], 0, 0, 0);
      acc[q] = __builtin_amdgcn_mfma_f32_16x16x32_bf16(a1h, bh[q][1], acc[q], 0, 0, 0);
    }
    if (HAS_PTS) {
#pragma unroll
      for (int q = 0; q < 4; ++q) {
        acc[q][0] += dx0 * wb[q].x + dy0 * wb[q].y + dz0 * wb[q].z;
        acc[q][1] += dx1 * wb[q].x + dy1 * wb[q].y + dz1 * wb[q].z;
        acc[q][2] += dx2 * wb[q].x + dy2 * wb[q].y + dz2 * wb[q].z;
        acc[q][3] += dx3 * wb[q].x + dy3 * wb[q].y + dz3 * wb[q].z;
      }
    }
#pragma unroll
    for (int q = 0; q < 4; ++q) {
      float s1 = acc[q][0] + acc[q][1] + acc[q][2] + acc[q][3];
      float s2 = acc[q][0] * acc[q][0] + acc[q][1] * acc[q][1]
               + acc[q][2] * acc[q][2] + acc[q][3] * acc[q][3];
      float mx = fmaxf(fmaxf(acc[q][0], acc[q][1]), fmaxf(acc[q][2], acc[q][3]));
      s1 += __shfl_xor(s1, 16); s1 += __shfl_xor(s1, 32);
      s2 += __shfl_xor(s2, 16); s2 += __shfl_xor(s2, 32);
      mx = fmaxf(mx, __shfl_xor(mx, 16)); mx = fmaxf(mx, __shfl_xor(mx, 32));
      float bb = basemat[(size_t)p * 256 + c0 + q * 16 + cl];
      if (lane < 16) out[(size_t)p * 256 + c0 + q * 16 + cl] = mx + bb;
      rs1[q] += s1 + 16.f * bb;
      rs2[q] += s2 + 2.f * bb * s1 + 16.f * bb * bb;
    }
    a0h = n0h; a1h = n1h; a0l = n0l; a1l = n1l;
    jn = jf;
  }
  if (lane < 16) {
#pragma unroll
    for (int q = 0; q < 4; ++q) {
      atomicAdd(&stats[c0 + q * 16 + lane], rs1[q]);
      atomicAdd(&stats[256 + c0 + q * 16 + lane], rs2[q]);
    }
  }
}

// ---------------------------------------------------------------------------
// agg_pack: out[r,c] = bn_relu(max over 16 neighbors of X[(b,j),c]), emitted
// as fragment-major hi/lo bf16 (feeds gemm_mfma directly).
// ---------------------------------------------------------------------------
template <int LGC>
__global__ __launch_bounds__(256) void agg_pack_kernel(
    const float* __restrict__ X, const int* __restrict__ idx,
    const float* __restrict__ stats, float inv_cnt,
    unsigned short* __restrict__ ph, unsigned short* __restrict__ pl) {
  const int C = 1 << LGC;
  const int t = blockIdx.x * 256 + threadIdx.x;
  const int r = t >> (LGC - 2), cq = t & ((C >> 2) - 1);
  const int base = (r >> 12) << 12;
  const int* ip = idx + (size_t)r * KSN;
  float4 mx = make_float4(-FLT_MAX, -FLT_MAX, -FLT_MAX, -FLT_MAX);
#pragma unroll
  for (int k = 0; k < KSN; ++k) {
    int j = ip[k];
    const float4 v = *reinterpret_cast<const float4*>(X + (size_t)(base + j) * C + cq * 4);
    mx.x = fmaxf(mx.x, v.x); mx.y = fmaxf(mx.y, v.y);
    mx.z = fmaxf(mx.z, v.z); mx.w = fmaxf(mx.w, v.w);
  }
  const int c = cq * 4;
  const float4 sa = *reinterpret_cast<const float4*>(stats + c);
  const float4 sb = *reinterpret_cast<const float4*>(stats + C + c);
  float m0 = sa.x * inv_cnt, m1 = sa.y * inv_cnt, m2 = sa.z * inv_cnt, m3 = sa.w * inv_cnt;
  float o0 = fmaxf((mx.x - m0) * rsqrtf(fmaxf(sb.x * inv_cnt - m0 * m0, 0.f) + EPSBN), 0.f);
  float o1 = fmaxf((mx.y - m1) * rsqrtf(fmaxf(sb.y * inv_cnt - m1 * m1, 0.f) + EPSBN), 0.f);
  float o2 = fmaxf((mx.z - m2) * rsqrtf(fmaxf(sb.z * inv_cnt - m2 * m2, 0.f) + EPSBN), 0.f);
  float o3 = fmaxf((mx.w - m3) * rsqrtf(fmaxf(sb.w * inv_cnt - m3 * m3, 0.f) + EPSBN), 0.f);
  short4v H, L;
  H.x = (short)f2bf(o0); L.x = (short)f2bf(o0 - bf2f((unsigned short)H.x));
  H.y = (short)f2bf(o1); L.y = (short)f2bf(o1 - bf2f((unsigned short)H.y));
  H.z = (short)f2bf(o2); L.z = (short)f2bf(o2 - bf2f((unsigned short)H.z));
  H.w = (short)f2bf(o3); L.w = (short)f2bf(o3 - bf2f((unsigned short)H.w));
  const int NK = C >> 5;
  const int rt = r >> 4, rl = r & 15, ks = c >> 5, kl = c & 31;
  const size_t dst = (((size_t)rt * NK + ks) * 64 + (((kl >> 3) << 4) | rl)) * 8 + (kl & 7);
  *(short4v*)(ph + dst) = H;
  *(short4v*)(pl + dst) = L;
}

// ---------------------------------------------------------------------------
// MFMA GEMM (validated round 7/8): wave = 64 rows x 64 cols, acc[4][4].
// AMODE 0: packed A. AMODE 1: row-major ushort hi/lo A (K=64).
// AMODE 3: ks<32 batch-broadcast g + packed x12 tail.
// ---------------------------------------------------------------------------
template <int AMODE, bool DOMAX>
__global__ __launch_bounds__(256) void gemm_mfma_kernel(
    const unsigned short* __restrict__ Ah, const unsigned short* __restrict__ Al,
    const unsigned short* __restrict__ gh, const unsigned short* __restrict__ gl,
    const unsigned short* __restrict__ Wh, const unsigned short* __restrict__ Wl,
    float* __restrict__ Y, float* __restrict__ pmax, float* __restrict__ stats,
    int K, int C) {
  __shared__ float red1[4][64], red2[4][64], redm[4][64];
  const int wave = threadIdx.x >> 6, lane = threadIdx.x & 63;
  const int rtb = blockIdx.x * 16 + wave * 4;
  const int c0  = blockIdx.y * 64;
  const int ct0 = blockIdx.y * 4;
  const int NK  = K >> 5;
  const int KP  = (AMODE == 3) ? 4 : NK;
  const int bat = blockIdx.x >> 4;
  f32x4 acc[4][4];
#pragma unroll
  for (int r = 0; r < 4; ++r)
#pragma unroll
    for (int cc = 0; cc < 4; ++cc) {
      acc[r][cc][0] = 0.f; acc[r][cc][1] = 0.f; acc[r][cc][2] = 0.f; acc[r][cc][3] = 0.f;
    }
  const int lhalf = (lane >> 4) << 3;
  for (int ks = 0; ks < NK; ++ks) {
    short8 ah[4], al[4];
    if (AMODE == 3 && ks < 32) {
      const int go = bat * 1024 + ks * 32 + lhalf;
      short8 gav = *(const short8*)(gh + go);
      short8 galv = *(const short8*)(gl + go);
#pragma unroll
      for (int r = 0; r < 4; ++r) { ah[r] = gav; al[r] = galv; }
    } else if (AMODE == 1) {
#pragma unroll
      for (int r = 0; r < 4; ++r) {
        const size_t aoff = ((size_t)((rtb + r) * 16 + (lane & 15))) * 64 + ks * 32 + lhalf;
        ah[r] = *(const short8*)(Ah + aoff);
        al[r] = *(const short8*)(Al + aoff);
      }
    } else {
      const int ksp = (AMODE == 3) ? ks - 32 : ks;
#pragma unroll
      for (int r = 0; r < 4; ++r) {
        const size_t aoff = (((size_t)(rtb + r) * KP + ksp) * 64 + lane) * 8;
        ah[r] = *(const short8*)(Ah + aoff);
        al[r] = *(const short8*)(Al + aoff);
      }
    }
#pragma unroll
    for (int cc = 0; cc < 4; ++cc) {
      const size_t woff = (((size_t)(ct0 + cc) * NK + ks) * 64 + lane) * 8;
      short8 bh = *(const short8*)(Wh + woff);
      short8 bl = *(const short8*)(Wl + woff);
#pragma unroll
      for (int r = 0; r < 4; ++r) {
        acc[r][cc] = __builtin_amdgcn_mfma_f32_16x16x32_bf16(al[r], bh, acc[r][cc], 0, 0, 0);
        acc[r][cc] = __builtin_amdgcn_mfma_f32_16x16x32_bf16(ah[r], bl, acc[r][cc], 0, 0, 0);
        acc[r][cc] = __builtin_amdgcn_mfma_f32_16x16x32_bf16(ah[r], bh, acc[r][cc], 0, 0, 0);
      }
    }
  }
#pragma unroll
  for (int cc = 0; cc < 4; ++cc) {
    float s1 = 0.f, s2 = 0.f, mm = -FLT_MAX;
#pragma unroll
    for (int r = 0; r < 4; ++r) {
      if (!DOMAX) {
#pragma unroll
        for (int i = 0; i < 4; ++i)
          Y[(size_t)((rtb + r) * 16 + ((lane >> 4) << 2) + i) * C + c0 + cc * 16 + (lane & 15)] = acc[r][cc][i];
      }
#pragma unroll
      for (int i = 0; i < 4; ++i) {
        float v = acc[r][cc][i];
        s1 += v; s2 = fmaf(v, v, s2); mm = fmaxf(mm, v);
      }
    }
    s1 += __shfl_xor(s1, 16); s1 += __shfl_xor(s1, 32);
    s2 += __shfl_xor(s2, 16); s2 += __shfl_xor(s2, 32);
    mm = fmaxf(mm, __shfl_xor(mm, 16)); mm = fmaxf(mm, __shfl_xor(mm, 32));
    if (lane < 16) {
      red1[wave][cc * 16 + lane] = s1;
      red2[wave][cc * 16 + lane] = s2;
      if (DOMAX) redm[wave][cc * 16 + lane] = mm;
    }
  }
  __syncthreads();
  if (threadIdx.x < 64) {
    const int t = threadIdx.x;
    float a = red1[0][t] + red1[1][t] + red1[2][t] + red1[3][t];
    float b = red2[0][t] + red2[1][t] + red2[2][t] + red2[3][t];
    atomicAdd(&stats[c0 + t], a);
    atomicAdd(&stats[C + c0 + t], b);
    if (DOMAX) {
      float mm = fmaxf(fmaxf(redm[0][t], redm[1][t]), fmaxf(redm[2][t], redm[3][t]));
      pmax[(size_t)blockIdx.x * C + c0 + t] = mm;
    }
  }
}

// g[b,c] = relu(bn(max over 16 row-blocks)) -> bf16 hi/lo
__global__ void fin_g_kernel(const float* __restrict__ pmax, const float* __restrict__ stats,
                             unsigned short* __restrict__ gh, unsigned short* __restrict__ gl) {
  int t = blockIdx.x * 256 + threadIdx.x;   // 4096
  int b = t >> 10, c = t & 1023;
  const float inv = 1.0f / 16384.0f;
  float m = stats[c] * inv;
  float v = fmaxf(stats[1024 + c] * inv - m * m, 0.0f);
  float rs = rsqrtf(v + EPSBN);
  float mx = -FLT_MAX;
  for (int s = 0; s < 16; ++s) mx = fmaxf(mx, pmax[(size_t)(b * 16 + s) * 1024 + c]);
  float val = fmaxf((mx - m) * rs, 0.0f);
  unsigned short h = f2bf(val);
  gh[t] = h; gl[t] = f2bf(val - bf2f(h));
}

__global__ void final13_kernel(const float* __restrict__ h, const float* __restrict__ W,
                               float* __restrict__ out) {
  int t = blockIdx.x * 256 + threadIdx.x;
  if (t >= RN * 13) return;
  int r = t / 13, c = t - r * 13;
  float acc = 0.0f;
  for (int k = 0; k < 256; ++k) acc = fmaf(h[(size_t)r * 256 + k], W[k * 13 + c], acc);
  int b = r >> 12, n = r & 4095;
  out[(size_t)b * 13 * NN + (size_t)c * NN + n] = acc;
}

// ---------------------------------------------------------------------------
extern "C" void kernel_launch(void* const* d_in, const int* in_sizes, int n_in,
                              void* d_out, int out_size, void* d_ws, size_t ws_size,
                              hipStream_t stream) {
  (void)in_sizes; (void)n_in; (void)out_size; (void)ws_size;
  const float* data = (const float*)d_in[0];
  const float* W_fc = (const float*)d_in[1];
  const float* b_fc = (const float*)d_in[2];
  const float* W1   = (const float*)d_in[3];
  const float* W2   = (const float*)d_in[4];
  const float* W3   = (const float*)d_in[5];
  const float* W4   = (const float*)d_in[6];
  const float* W5   = (const float*)d_in[7];
  const float* W6   = (const float*)d_in[8];
  const float* W10  = (const float*)d_in[9];
  const float* W11  = (const float*)d_in[10];
  const float* W12  = (const float*)d_in[11];
  const float* W13  = (const float*)d_in[12];
  float* out = (float*)d_out;

  float* ws  = (float*)d_ws;
  int*   idx = (int*)d_ws;
  size_t o = 262144;
  float* x0   = ws + o; o += (size_t)RN * 64;
  float* x1v  = ws + o; o += (size_t)RN * 64;
  float* x2v  = ws + o; o += (size_t)RN * 64;
  float* bufA = ws + o; o += (size_t)RN * 256;
  float* bufB = ws + o; o += (size_t)RN * 256;
  float* bufC = ws + o; o += (size_t)RN * 64;
  float* pmax = ws + o; o += (size_t)64 * 1024;
  float* h11  = ws + o; o += (size_t)RN * 512;
  float* h12  = ws + o; o += (size_t)RN * 256;
  float* stats = ws + o; o += 8192;
  float4* pack = (float4*)(ws + o); o += (size_t)RN * 4;
  unsigned short* xbh = (unsigned short*)(ws + o); o += (size_t)RN * 32;
  unsigned short* xbl = (unsigned short*)(ws + o); o += (size_t)RN * 32;
  float* W1p = ws + o; o += 16384;
  float* W4p = ws + o; o += 16384;
  unsigned short* W1mh = (unsigned short*)(ws + o); o += 8192;
  unsigned short* W1ml = (unsigned short*)(ws + o); o += 8192;
  unsigned short* W4mh = (unsigned short*)(ws + o); o += 8192;
  unsigned short* W4ml = (unsigned short*)(ws + o); o += 8192;
  float4* W1bt = (float4*)(ws + o); o += 1024;
  unsigned short* W10h = (unsigned short*)(ws + o); o += 65536;
  unsigned short* W10l = (unsigned short*)(ws + o); o += 65536;
  unsigned short* W11h = (unsigned short*)(ws + o); o += 294912;
  unsigned short* W11l = (unsigned short*)(ws + o); o += 294912;
  unsigned short* W12h = (unsigned short*)(ws + o); o += 65536;
  unsigned short* W12l = (unsigned short*)(ws + o); o += 65536;
  unsigned short* gh   = (unsigned short*)(ws + o); o += 2048;
  unsigned short* gl   = (unsigned short*)(ws + o); o += 2048;
  unsigned short* W1ph = (unsigned short*)(ws + o); o += 8192;
  unsigned short* W1pl = (unsigned short*)(ws + o); o += 8192;
  unsigned short* W4ph = (unsigned short*)(ws + o); o += 8192;
  unsigned short* W4pl = (unsigned short*)(ws + o); o += 8192;
  unsigned short* W2h  = (unsigned short*)(ws + o); o += 8192;
  unsigned short* W2l  = (unsigned short*)(ws + o); o += 8192;
  unsigned short* W3h  = (unsigned short*)(ws + o); o += 2048;
  unsigned short* W3l  = (unsigned short*)(ws + o); o += 2048;
  unsigned short* W5h  = (unsigned short*)(ws + o); o += 8192;
  unsigned short* W5l  = (unsigned short*)(ws + o); o += 8192;
  unsigned short* W6h  = (unsigned short*)(ws + o); o += 2048;
  unsigned short* W6l  = (unsigned short*)(ws + o); o += 2048;
  float* gpart = ws + o; o += 64 * 54;
  // overlays on dead buffers:
  unsigned short* x12h = (unsigned short*)bufC;              // RN*128 us
  unsigned short* x12l = (unsigned short*)x0;                // RN*128 us
  unsigned short* h11h = (unsigned short*)bufA;              // RN*512 us
  unsigned short* h11l = (unsigned short*)bufB;              // RN*512 us
  unsigned short* aggh = (unsigned short*)h11;               // RN*256 us
  unsigned short* aggl = (unsigned short*)h11 + (size_t)RN * 256;

  float* S0 = stats;          // 64 (fc)
  float* S1 = stats + 128;    // 256 (edge1)
  float* S2 = stats + 640;    // 64  (W2)
  float* S3 = stats + 768;    // 64  (W3)
  float* S4 = stats + 896;    // 256 (edge2)
  float* S5 = stats + 1408;   // 64  (W5)
  float* S6 = stats + 1536;   // 64  (W6)
  float* S7 = stats + 1664;   // 1024 (W10)
  float* S8 = stats + 3712;   // 512 (W11)
  float* S9 = stats + 4736;   // 256 (W12)
  float* Sd = stats + 5248;   // dummy sink (512)

  hipMemsetAsync(stats, 0, 8192 * sizeof(float), stream);

  prep_kernel<<<RN / 256, 256, 0, stream>>>(data, pack);
  knn_kernel<<<RN / 4, 256, 0, stream>>>(pack, idx);
  prep_w_kernel<<<64, 256, 0, stream>>>(W1, W4, W1p, W1mh, W1ml, W1bt, W4p, W4mh, W4ml);
  prep_wpack_kernel<<<64, 256, 0, stream>>>(W1p, W1ph, W1pl, 8, 16384, 2);
  prep_wpack_kernel<<<64, 256, 0, stream>>>(W4p, W4ph, W4pl, 8, 16384, 2);
  prep_wpack_kernel<<<64, 256, 0, stream>>>(W2, W2h, W2l, 6, 16384, 8);
  prep_wpack_kernel<<<16, 256, 0, stream>>>(W3, W3h, W3l, 6, 4096, 2);
  prep_wpack_kernel<<<64, 256, 0, stream>>>(W5, W5h, W5l, 6, 16384, 8);
  prep_wpack_kernel<<<16, 256, 0, stream>>>(W6, W6h, W6l, 6, 4096, 2);
  prep_wpack_kernel<<<512, 256, 0, stream>>>(W10, W10h, W10l, 10, 131072, 4);
  prep_wpack_kernel<<<2304, 256, 0, stream>>>(W11, W11h, W11l, 9, 589824, 36);
  prep_wpack_kernel<<<512, 256, 0, stream>>>(W12, W12h, W12l, 8, 131072, 16);

  // fc path: Gram-based stats (no atomics), fused fc+bn+pack
  gram_kernel<<<64, 256, 0, stream>>>(data, gpart);
  fcstats_kernel<<<1, 64, 0, stream>>>(gpart, W_fc, b_fc, S0);
  fc_bnpack_kernel<<<RN * 64 / 256, 256, 0, stream>>>(data, W_fc, b_fc, S0, xbh, xbl);

  // edge conv 1: basemat = x0 @ W1p (MFMA, row-major bf16 A)
  gemm_mfma_kernel<1, false><<<dim3(64, 4), 256, 0, stream>>>(
      xbh, xbl, nullptr, nullptr, W1ph, W1pl, bufB, nullptr, Sd, 64, 256);
  edge_mfma_kernel<true><<<1024, 256, 0, stream>>>(xbh, xbl, idx, pack, W1mh, W1ml, W1bt, bufB, bufA, S1);

  // graph conv 1: agg(+bn fused) -> packed, then MFMA W2
  agg_pack_kernel<8><<<4096, 256, 0, stream>>>(bufA, idx, S1, 1.0f / (RN * 16), aggh, aggl);
  gemm_mfma_kernel<0, false><<<dim3(64, 1), 256, 0, stream>>>(
      aggh, aggl, nullptr, nullptr, W2h, W2l, bufC, nullptr, S2, 256, 64);

  // graph conv 2
  agg_pack_kernel<6><<<1024, 256, 0, stream>>>(bufC, idx, S2, 1.0f / RN, aggh, aggl);
  gemm_mfma_kernel<0, false><<<dim3(64, 1), 256, 0, stream>>>(
      aggh, aggl, nullptr, nullptr, W3h, W3l, x1v, nullptr, S3, 64, 64);
  bn_normpack_kernel<<<RN * 64 / 256, 256, 0, stream>>>(x1v, S3, xbh, xbl);

  // edge conv 2 (no pts)
  gemm_mfma_kernel<1, false><<<dim3(64, 4), 256, 0, stream>>>(
      xbh, xbl, nullptr, nullptr, W4ph, W4pl, bufB, nullptr, Sd, 64, 256);
  edge_mfma_kernel<false><<<1024, 256, 0, stream>>>(xbh, xbl, idx, pack, W4mh, W4ml, nullptr, bufB, bufA, S4);

  // graph conv 3
  agg_pack_kernel<8><<<4096, 256, 0, stream>>>(bufA, idx, S4, 1.0f / (RN * 16), aggh, aggl);
  gemm_mfma_kernel<0, false><<<dim3(64, 1), 256, 0, stream>>>(
      aggh, aggl, nullptr, nullptr, W5h, W5l, bufC, nullptr, S5, 256, 64);

  // graph conv 4
  agg_pack_kernel<6><<<1024, 256, 0, stream>>>(bufC, idx, S5, 1.0f / RN, aggh, aggl);
  gemm_mfma_kernel<0, false><<<dim3(64, 1), 256, 0, stream>>>(
      aggh, aggl, nullptr, nullptr, W6h, W6l, x2v, nullptr, S6, 64, 64);
  bn_norm_kernel<<<RN * 64 / 256, 256, 0, stream>>>(x2v, S6, 63, 64, 1.0f / RN, RN * 64);

  // pack [x1|x2] (bufC and x0 dead now; overlay)
  pack_x12_kernel<<<RN * 128 / 256, 256, 0, stream>>>(x1v, x2v, x12h, x12l);

  // W10 path: MFMA, stats + per-block col max only
  gemm_mfma_kernel<0, true><<<dim3(64, 16), 256, 0, stream>>>(
      x12h, x12l, nullptr, nullptr, W10h, W10l, nullptr, pmax, S7, 128, 1024);
  fin_g_kernel<<<16, 256, 0, stream>>>(pmax, S7, gh, gl);

  // W11: [g | x12] @ W11 -> h11
  gemm_mfma_kernel<3, false><<<dim3(64, 8), 256, 0, stream>>>(
      x12h, x12l, gh, gl, W11h, W11l, h11, nullptr, S8, 1152, 512);
  bn_pack_kernel<<<RN * 512 / 256, 256, 0, stream>>>(h11, S8, h11h, h11l);

  // W12: h11 @ W12 -> h12
  gemm_mfma_kernel<0, false><<<dim3(64, 4), 256, 0, stream>>>(
      h11h, h11l, nullptr, nullptr, W12h, W12l, h12, nullptr, S9, 512, 256);
  bn_norm_kernel<<<RN * 256 / 256, 256, 0, stream>>>(h12, S9, 255, 256, 1.0f / RN, RN * 256);

  final13_kernel<<<(RN * 13 + 255) / 256, 256, 0, stream>>>(h12, W13, out);
}

// Round 10
// 613.949 us; speedup vs baseline: 3.9513x; 1.0872x over previous
//
#include <hip/hip_runtime.h>
#include <hip/hip_bf16.h>
#include <float.h>

static constexpr int BB  = 4;
static constexpr int NN  = 4096;
static constexpr int KSN = 16;
static constexpr int RN  = BB * NN;     // 16384 rows (b,n)
#define EPSBN 1e-5f

typedef __attribute__((ext_vector_type(8))) short short8;
typedef __attribute__((ext_vector_type(4))) short short4v;
typedef __attribute__((ext_vector_type(4))) float f32x4;

__device__ inline unsigned short f2bf(float f) {
  union { float f; unsigned u; } v; v.f = f;
  unsigned r = v.u + 0x7FFF + ((v.u >> 16) & 1);
  return (unsigned short)(r >> 16);
}
__device__ inline float bf2f(unsigned short h) {
  union { unsigned u; float f; } v; v.u = ((unsigned)h) << 16; return v.f;
}

// ---------------------------------------------------------------------------
// prep + gram fused: pack (x,y,z,|p|^2); 9-sum + 45-uppertri Gram partials
// per block (shfl-reduced, no atomics).
// ---------------------------------------------------------------------------
__global__ __launch_bounds__(256) void prepgram_kernel(const float* __restrict__ data,
                                                       float4* __restrict__ pack,
                                                       float* __restrict__ partials) {
  const int t = blockIdx.x * 256 + threadIdx.x;   // RN
  const int lane = threadIdx.x & 63, wave = threadIdx.x >> 6;
  __shared__ float red[4][54];
  float d[9];
#pragma unroll
  for (int k = 0; k < 9; ++k) d[k] = data[(size_t)t * 9 + k];
  pack[t] = make_float4(d[0], d[1], d[2], fmaf(d[2], d[2], fmaf(d[1], d[1], d[0] * d[0])));
  int p = 0;
#pragma unroll
  for (int i = 0; i < 9; ++i) {
    float v = d[i];
#pragma unroll
    for (int mv = 1; mv < 64; mv <<= 1) v += __shfl_xor(v, mv);
    if (lane == 0) red[wave][p] = v;
    ++p;
  }
#pragma unroll
  for (int i = 0; i < 9; ++i)
#pragma unroll
    for (int j = i; j < 9; ++j) {
      float v = d[i] * d[j];
#pragma unroll
      for (int mv = 1; mv < 64; mv <<= 1) v += __shfl_xor(v, mv);
      if (lane == 0) red[wave][p] = v;
      ++p;
    }
  __syncthreads();
  if (threadIdx.x < 54)
    partials[blockIdx.x * 54 + threadIdx.x] =
        red[0][threadIdx.x] + red[1][threadIdx.x] + red[2][threadIdx.x] + red[3][threadIdx.x];
}

__global__ void fcstats_kernel(const float* __restrict__ partials,
                               const float* __restrict__ W, const float* __restrict__ bias,
                               float* __restrict__ S0) {
  __shared__ float g[54];
  const int t = threadIdx.x;   // 64 threads
  if (t < 54) {
    float s = 0.f;
    for (int b = 0; b < 64; ++b) s += partials[b * 54 + t];
    g[t] = s;
  }
  __syncthreads();
  float w[9];
#pragma unroll
  for (int k = 0; k < 9; ++k) w[k] = W[k * 64 + t];
  float b = bias[t];
  float dotw = 0.f;
#pragma unroll
  for (int k = 0; k < 9; ++k) dotw = fmaf(g[k], w[k], dotw);
  float s2 = 0.f;
  int p = 9;
#pragma unroll
  for (int i = 0; i < 9; ++i)
#pragma unroll
    for (int j = i; j < 9; ++j) {
      float gij = g[p++];
      s2 = fmaf(gij * ((i == j) ? 1.f : 2.f), w[i] * w[j], s2);
    }
  s2 += 2.f * b * dotw + (float)RN * b * b;
  S0[t] = dotw + (float)RN * b;
  S0[64 + t] = s2;
}

// fused fc + BN + ReLU + hi/lo pack
__global__ __launch_bounds__(256) void fc_bnpack_kernel(
    const float* __restrict__ data, const float* __restrict__ W,
    const float* __restrict__ bias, const float* __restrict__ stats,
    unsigned short* __restrict__ hi, unsigned short* __restrict__ lo) {
  const int t = blockIdx.x * 256 + threadIdx.x;   // RN*64
  const int r = t >> 6, c = t & 63;
  const float* dr = data + (size_t)r * 9;
  float acc = bias[c];
#pragma unroll
  for (int k = 0; k < 9; ++k) acc = fmaf(dr[k], W[k * 64 + c], acc);
  const float inv = 1.0f / RN;
  float m = stats[c] * inv;
  float v = fmaxf(stats[64 + c] * inv - m * m, 0.0f);
  float x = fmaxf((acc - m) * rsqrtf(v + EPSBN), 0.0f);
  unsigned short h = f2bf(x);
  hi[t] = h; lo[t] = f2bf(x - bf2f(h));
}

// ---------------------------------------------------------------------------
// megaprep: all weight transforms in one launch (block-range dispatch).
// ---------------------------------------------------------------------------
__device__ inline void wpack_one(const float* __restrict__ W, unsigned short* __restrict__ wh,
                                 unsigned short* __restrict__ wl, int t, int lgC, int NK) {
  int k = t >> lgC, c = t & ((1 << lgC) - 1);
  float v = W[t];
  int ct = c >> 4, cl = c & 15, ks = k >> 5, kl = k & 31;
  int dst = ((ct * NK + ks) * 64 + (((kl >> 3) << 4) | cl)) * 8 + (kl & 7);
  unsigned short h = f2bf(v);
  wh[dst] = h; wl[dst] = f2bf(v - bf2f(h));
}
__device__ inline void diffpack_one(const float* __restrict__ W, unsigned short* __restrict__ wh,
                                    unsigned short* __restrict__ wl, int t) {
  int k = t >> 8, cc = t & 255;
  float v = W[k * 256 + cc] - W[(64 + k) * 256 + cc];  // Wtop - Wmid
  int ct = cc >> 4, cl = cc & 15, ks = k >> 5, kl = k & 31;
  int dst = ((ct * 2 + ks) * 64 + (((kl >> 3) << 4) | cl)) * 8 + (kl & 7);
  unsigned short h = f2bf(v);
  wh[dst] = h; wl[dst] = f2bf(v - bf2f(h));
}

__global__ __launch_bounds__(256) void megaprep_kernel(
    const float* __restrict__ W1, const float* __restrict__ W4,
    const float* __restrict__ W2, const float* __restrict__ W3,
    const float* __restrict__ W5, const float* __restrict__ W6,
    const float* __restrict__ W10, const float* __restrict__ W11, const float* __restrict__ W12,
    unsigned short* __restrict__ W1mh, unsigned short* __restrict__ W1ml, float4* __restrict__ W1bt,
    unsigned short* __restrict__ W4mh, unsigned short* __restrict__ W4ml,
    unsigned short* __restrict__ W1ph, unsigned short* __restrict__ W1pl,
    unsigned short* __restrict__ W4ph, unsigned short* __restrict__ W4pl,
    unsigned short* __restrict__ W2h, unsigned short* __restrict__ W2l,
    unsigned short* __restrict__ W3h, unsigned short* __restrict__ W3l,
    unsigned short* __restrict__ W5h, unsigned short* __restrict__ W5l,
    unsigned short* __restrict__ W6h, unsigned short* __restrict__ W6l,
    unsigned short* __restrict__ W10h, unsigned short* __restrict__ W10l,
    unsigned short* __restrict__ W11h, unsigned short* __restrict__ W11l,
    unsigned short* __restrict__ W12h, unsigned short* __restrict__ W12l) {
  const int blk = blockIdx.x;
  if (blk < 64) {                       // edge mid weights (transposed hi/lo) + W1bt
    int t = blk * 256 + threadIdx.x;
    int k = t >> 8, cc = t & 255;
    float w1mid = W1[(64 + k) * 256 + cc];
    unsigned short h1 = f2bf(w1mid);
    W1mh[cc * 64 + k] = h1;
    W1ml[cc * 64 + k] = f2bf(w1mid - bf2f(h1));
    float w4mid = W4[(64 + k) * 256 + cc];
    unsigned short h4 = f2bf(w4mid);
    W4mh[cc * 64 + k] = h4;
    W4ml[cc * 64 + k] = f2bf(w4mid - bf2f(h4));
    if (t < 256) W1bt[t] = make_float4(W1[128 * 256 + t], W1[129 * 256 + t], W1[130 * 256 + t], 0.f);
  } else if (blk < 128) {
    diffpack_one(W1, W1ph, W1pl, (blk - 64) * 256 + threadIdx.x);
  } else if (blk < 192) {
    diffpack_one(W4, W4ph, W4pl, (blk - 128) * 256 + threadIdx.x);
  } else if (blk < 256) {
    wpack_one(W2, W2h, W2l, (blk - 192) * 256 + threadIdx.x, 6, 8);
  } else if (blk < 272) {
    wpack_one(W3, W3h, W3l, (blk - 256) * 256 + threadIdx.x, 6, 2);
  } else if (blk < 336) {
    wpack_one(W5, W5h, W5l, (blk - 272) * 256 + threadIdx.x, 6, 8);
  } else if (blk < 352) {
    wpack_one(W6, W6h, W6l, (blk - 336) * 256 + threadIdx.x, 6, 2);
  } else if (blk < 864) {
    wpack_one(W10, W10h, W10l, (blk - 352) * 256 + threadIdx.x, 10, 4);
  } else if (blk < 3168) {
    wpack_one(W11, W11h, W11l, (blk - 864) * 256 + threadIdx.x, 9, 36);
  } else {
    wpack_one(W12, W12h, W12l, (blk - 3168) * 256 + threadIdx.x, 8, 16);
  }
}

// [x1|x2] -> fragment-major hi/lo pack (K=128); BN of x2 fused (S6 stats).
__global__ void pack_x12_kernel(const float* __restrict__ x1, const float* __restrict__ x2,
                                const float* __restrict__ S6,
                                unsigned short* __restrict__ ph, unsigned short* __restrict__ pl) {
  int t = blockIdx.x * 256 + threadIdx.x;   // RN*128
  int r = t >> 7, k = t & 127;
  float v;
  if (k < 64) {
    v = x1[(size_t)r * 64 + k];
  } else {
    int c = k - 64;
    const float inv = 1.0f / RN;
    float m = S6[c] * inv;
    float var = fmaxf(S6[64 + c] * inv - m * m, 0.f);
    v = fmaxf((x2[(size_t)r * 64 + c] - m) * rsqrtf(var + EPSBN), 0.f);
  }
  int rt = r >> 4, rl = r & 15, ks = k >> 5, kl = k & 31;
  int dst = ((rt * 4 + ks) * 64 + (((kl >> 3) << 4) | rl)) * 8 + (kl & 7);
  unsigned short h = f2bf(v);
  ph[dst] = h; pl[dst] = f2bf(v - bf2f(h));
}

// BN+ReLU on h11 (C=512) fused with fragment-major hi/lo pack
__global__ void bn_pack_kernel(const float* __restrict__ buf, const float* __restrict__ stats,
                               unsigned short* __restrict__ ph, unsigned short* __restrict__ pl) {
  int t = blockIdx.x * 256 + threadIdx.x;   // RN*512
  int c = t & 511, r = t >> 9;
  const float inv = 1.0f / RN;
  float m = stats[c] * inv;
  float v = fmaxf(stats[512 + c] * inv - m * m, 0.0f);
  float x = fmaxf((buf[t] - m) * rsqrtf(v + EPSBN), 0.0f);
  int rt = r >> 4, rl = r & 15, ks = c >> 5, kl = c & 31;
  int dst = ((rt * 16 + ks) * 64 + (((kl >> 3) << 4) | rl)) * 8 + (kl & 7);
  unsigned short h = f2bf(x);
  ph[dst] = h; pl[dst] = f2bf(x - bf2f(h));
}

// BN+ReLU in place (C=64) fused with row-major hi/lo write (x1v)
__global__ void bn_normpack_kernel(float* __restrict__ buf, const float* __restrict__ stats,
                                   unsigned short* __restrict__ hi, unsigned short* __restrict__ lo) {
  int t = blockIdx.x * 256 + threadIdx.x;   // RN*64
  int c = t & 63;
  const float inv = 1.0f / RN;
  float m = stats[c] * inv;
  float v = fmaxf(stats[64 + c] * inv - m * m, 0.0f);
  float x = fmaxf((buf[t] - m) * rsqrtf(v + EPSBN), 0.0f);
  buf[t] = x;
  unsigned short h = f2bf(x);
  hi[t] = h; lo[t] = f2bf(x - bf2f(h));
}

// ---------------------------------------------------------------------------
// KNN: one wave per point, top-4/lane, float-gate (NaN-open, equal-admitted)
// skips key-packing for ~75% of candidates. Exact 64-bit keys on insert.
// ---------------------------------------------------------------------------
__global__ __launch_bounds__(256) void knn_kernel(const float4* __restrict__ pack,
                                                  int* __restrict__ idx) {
  const int lane = threadIdx.x & 63;
  const int p = blockIdx.x * 4 + (threadIdx.x >> 6);
  const int b = p >> 12;
  const float4* __restrict__ pb = pack + ((size_t)b << 12);
  const float4 me = pack[p];
  unsigned long long m0 = ~0ull, m1 = ~0ull, m2 = ~0ull, m3 = ~0ull;
  float f3 = __uint_as_float(0x7FFFFFFFu);   // NaN => gate open
#pragma unroll 8
  for (int s = 0; s < 64; ++s) {
    const float4 q = pb[s * 64 + lane];
    float d = me.w + q.w - 2.0f * fmaf(me.x, q.x, fmaf(me.y, q.y, me.z * q.z));
    if (!(d > f3)) {
      unsigned ub = __float_as_uint(d);
      ub = (ub & 0x80000000u) ? ~ub : (ub | 0x80000000u);
      unsigned long long k = ((unsigned long long)ub << 12) | (unsigned)(s * 64 + lane);
      if (k < m3) {
        bool l0 = k < m0;  unsigned long long t0 = l0 ? m0 : k;  m0 = l0 ? k : m0;
        bool l1 = t0 < m1; unsigned long long t1 = l1 ? m1 : t0; m1 = l1 ? t0 : m1;
        bool l2 = t1 < m2; unsigned long long t2 = l2 ? m2 : t1; m2 = l2 ? t1 : m2;
        m3 = (t2 < m3) ? t2 : m3;
        unsigned u3 = (unsigned)(m3 >> 12);
        u3 = (u3 & 0x80000000u) ? (u3 & 0x7FFFFFFFu) : ~u3;
        f3 = __uint_as_float(u3);
      }
    }
  }
  for (int pass = 0; pass < 16; ++pass) {
    unsigned long long w = m0;
#pragma unroll
    for (int mv = 1; mv < 64; mv <<= 1) {
      unsigned long long o = __shfl_xor(w, mv);
      w = (o < w) ? o : w;
    }
    if (lane == pass) idx[(p << 4) + pass] = (int)(w & 0xFFFull);
    if (m0 == w) { m0 = m1; m1 = m2; m2 = m3; m3 = ~0ull; }
    if (pass < 15 && __any(m0 == ~0ull)) {
      if (m0 == ~0ull) {
        m1 = ~0ull; m2 = ~0ull; m3 = ~0ull;
        float g3 = __uint_as_float(0x7FFFFFFFu);
#pragma unroll 8
        for (int s = 0; s < 64; ++s) {
          const float4 q = pb[s * 64 + lane];
          float d = me.w + q.w - 2.0f * fmaf(me.x, q.x, fmaf(me.y, q.y, me.z * q.z));
          if (!(d > g3)) {
            unsigned ub = __float_as_uint(d);
            ub = (ub & 0x80000000u) ? ~ub : (ub | 0x80000000u);
            unsigned long long k = ((unsigned long long)ub << 12) | (unsigned)(s * 64 + lane);
            k = (k > w) ? k : ~0ull;                  // exclude consumed
            if (k < m3) {
              bool l0 = k < m0;  unsigned long long t0 = l0 ? m0 : k;  m0 = l0 ? k : m0;
              bool l1 = t0 < m1; unsigned long long t1 = l1 ? m1 : t0; m1 = l1 ? t0 : m1;
              bool l2 = t1 < m2; unsigned long long t2 = l2 ? m2 : t1; m2 = l2 ? t1 : m2;
              m3 = (t2 < m3) ? t2 : m3;
              unsigned u3 = (unsigned)(m3 >> 12);
              u3 = (u3 & 0x80000000u) ? (u3 & 0x7FFFFFFFu) : ~u3;
              g3 = __uint_as_float(u3);
            }
          }
        }
      }
    }
  }
}

// ---------------------------------------------------------------------------
// Edge conv via MFMA, deferred-stats epilogue: per-lane partials P1/P2/PC/
// PB1/PB2 accumulated over all 16 points, shfl-reduced ONCE at the end.
// S1 = P1r + 16*PB1; S2 = P2r + 2*PCr + 16*PB2 (cross-term linear in lanes).
// ---------------------------------------------------------------------------
template <bool HAS_PTS>
__global__ __launch_bounds__(256) void edge_mfma_kernel(
    const unsigned short* __restrict__ Xh, const unsigned short* __restrict__ Xl,
    const int* __restrict__ idx,
    const float4* __restrict__ pack,
    const unsigned short* __restrict__ Wmh, const unsigned short* __restrict__ Wml,
    const float4* __restrict__ Wbt, const float* __restrict__ basemat,
    float* __restrict__ out, float* __restrict__ stats) {
  const int wave = threadIdx.x >> 6;
  const int lane = threadIdx.x & 63;
  const int pg   = blockIdx.x;
  const int c0   = wave << 6;
  const int cl   = lane & 15;
  const int kg   = (lane >> 4) << 3;
  const int bat  = pg >> 8;
  const int pbase = bat << 12;
  const int ib   = pg << 8;

  short8 bh[4][2], blo[4][2];
#pragma unroll
  for (int q = 0; q < 4; ++q) {
    const unsigned short* wp = Wmh + (size_t)(c0 + q * 16 + cl) * 64 + kg;
    bh[q][0] = *(const short8*)wp; bh[q][1] = *(const short8*)(wp + 32);
    const unsigned short* wq = Wml + (size_t)(c0 + q * 16 + cl) * 64 + kg;
    blo[q][0] = *(const short8*)wq; blo[q][1] = *(const short8*)(wq + 32);
  }
  float4 wb[4];
  if (HAS_PTS) {
#pragma unroll
    for (int q = 0; q < 4; ++q) wb[q] = Wbt[c0 + q * 16 + cl];
  }
  float P1[4] = {0.f, 0.f, 0.f, 0.f}, P2[4] = {0.f, 0.f, 0.f, 0.f};
  float PCx[4] = {0.f, 0.f, 0.f, 0.f};
  float PB1[4] = {0.f, 0.f, 0.f, 0.f}, PB2[4] = {0.f, 0.f, 0.f, 0.f};

  int jn = idx[ib + 16 + cl];
  int j0 = idx[ib + cl];
  size_t ro = ((size_t)(pbase | j0) << 6) + kg;
  short8 a0h = *(const short8*)(Xh + ro);
  short8 a1h = *(const short8*)(Xh + ro + 32);
  short8 a0l = *(const short8*)(Xl + ro);
  short8 a1l = *(const short8*)(Xl + ro + 32);

  for (int pp = 0; pp < 16; ++pp) {
    const int p = (pg << 4) | pp;
    int jf = 0;
    if (pp < 14) jf = idx[ib + ((pp + 2) << 4) + cl];
    short8 n0h, n1h, n0l, n1l;
    if (pp < 15) {
      size_t rn = ((size_t)(pbase | jn) << 6) + kg;
      n0h = *(const short8*)(Xh + rn);
      n1h = *(const short8*)(Xh + rn + 32);
      n0l = *(const short8*)(Xl + rn);
      n1l = *(const short8*)(Xl + rn + 32);
    }
    float dx0, dy0, dz0, dx1, dy1, dz1, dx2, dy2, dz2, dx3, dy3, dz3;
    if (HAS_PTS) {
      const int4 j4 = *(const int4*)(idx + (p << 4) + ((lane >> 4) << 2));
      const float4 pc = pack[p];
      const float4 q0 = pack[pbase | j4.x];
      const float4 q1 = pack[pbase | j4.y];
      const float4 q2 = pack[pbase | j4.z];
      const float4 q3 = pack[pbase | j4.w];
      dx0 = q0.x - pc.x; dy0 = q0.y - pc.y; dz0 = q0.z - pc.z;
      dx1 = q1.x - pc.x; dy1 = q1.y - pc.y; dz1 = q1.z - pc.z;
      dx2 = q2.x - pc.x; dy2 = q2.y - pc.y; dz2 = q2.z - pc.z;
      dx3 = q3.x - pc.x; dy3 = q3.y - pc.y; dz3 = q3.z - pc.z;
    }
    f32x4 acc[4];
#pragma unroll
    for (int q = 0; q < 4; ++q) {
      acc[q][0] = 0.f; acc[q][1] = 0.f; acc[q][2] = 0.f; acc[q][3] = 0.f;
    }
#pragma unroll
    for (int q = 0; q < 4; ++q) {
      acc[q] = __builtin_amdgcn_mfma_f32_16x16x32_bf16(a0l, bh[q][0], acc[q], 0, 0, 0);
      acc[q] = __builtin_amdgcn_mfma_f32_16x16x32_bf16(a1l, bh[q][1], acc[q], 0, 0, 0);
      acc[q] = __builtin_amdgcn_mfma_f32_16x16x32_bf16(a0h, blo[q][0], acc[q], 0, 0, 0);
      acc[q] = __builtin_amdgcn_mfma_f32_16x16x32_bf16(a1h, blo[q][1], acc[q], 0, 0, 0);
      acc[q] = __builtin_amdgcn_mfma_f32_16x16x32_bf16(a0h, bh[q][0], acc[q], 0, 0, 0);
      acc[q] = __builtin_amdgcn_mfma_f32_16x16x32_bf16(a1h, bh[q][1], acc[q], 0, 0, 0);
    }
    if (HAS_PTS) {
#pragma unroll
      for (int q = 0; q < 4; ++q) {
        acc[q][0] += dx0 * wb[q].x + dy0 * wb[q].y + dz0 * wb[q].z;
        acc[q][1] += dx1 * wb[q].x + dy1 * wb[q].y + dz1 * wb[q].z;
        acc[q][2] += dx2 * wb[q].x + dy2 * wb[q].y + dz2 * wb[q].z;
        acc[q][3] += dx3 * wb[q].x + dy3 * wb[q].y + dz3 * wb[q].z;
      }
    }
#pragma unroll
    for (int q = 0; q < 4; ++q) {
      float s1p = acc[q][0] + acc[q][1] + acc[q][2] + acc[q][3];
      float s2p = acc[q][0] * acc[q][0] + acc[q][1] * acc[q][1]
                + acc[q][2] * acc[q][2] + acc[q][3] * acc[q][3];
      float mx = fmaxf(fmaxf(acc[q][0], acc[q][1]), fmaxf(acc[q][2], acc[q][3]));
      mx = fmaxf(mx, __shfl_xor(mx, 16));
      mx = fmaxf(mx, __shfl_xor(mx, 32));
      float bb = basemat[(size_t)p * 256 + c0 + q * 16 + cl];
      if (lane < 16) out[(size_t)p * 256 + c0 + q * 16 + cl] = mx + bb;
      P1[q] += s1p;
      P2[q] += s2p;
      PCx[q] = fmaf(bb, s1p, PCx[q]);
      PB1[q] += bb;
      PB2[q] = fmaf(bb, bb, PB2[q]);
    }
    a0h = n0h; a1h = n1h; a0l = n0l; a1l = n1l;
    jn = jf;
  }
#pragma unroll
  for (int q = 0; q < 4; ++q) {
    float p1 = P1[q]; p1 += __shfl_xor(p1, 16); p1 += __shfl_xor(p1, 32);
    float p2 = P2[q]; p2 += __shfl_xor(p2, 16); p2 += __shfl_xor(p2, 32);
    float pc = PCx[q]; pc += __shfl_xor(pc, 16); pc += __shfl_xor(pc, 32);
    if (lane < 16) {
      atomicAdd(&stats[c0 + q * 16 + lane], p1 + 16.f * PB1[q]);
      atomicAdd(&stats[256 + c0 + q * 16 + lane], p2 + 2.f * pc + 16.f * PB2[q]);
    }
  }
}

// ---------------------------------------------------------------------------
// agg_pack: bn_relu(max over 16 neighbors) -> fragment-major hi/lo bf16.
// XCD-swizzled block mapping: each batch's source slice owned by 2 XCDs
// (L2-resident gathers instead of L3).
// ---------------------------------------------------------------------------
template <int LGC>
__global__ __launch_bounds__(256) void agg_pack_kernel(
    const float* __restrict__ X, const int* __restrict__ idx,
    const float* __restrict__ stats, float inv_cnt,
    unsigned short* __restrict__ ph, unsigned short* __restrict__ pl) {
  const int C = 1 << LGC;
  const int xcd = blockIdx.x & 7, bat = xcd >> 1;
  const int j = ((blockIdx.x >> 3) << 1) | (xcd & 1);
  const int rows_per_block = 256 >> (LGC - 2);
  const int r = bat * 4096 + j * rows_per_block + (threadIdx.x >> (LGC - 2));
  const int cq = threadIdx.x & ((C >> 2) - 1);
  const int base = bat << 12;
  const int* ip = idx + (size_t)r * KSN;
  float4 mx = make_float4(-FLT_MAX, -FLT_MAX, -FLT_MAX, -FLT_MAX);
#pragma unroll
  for (int k = 0; k < KSN; ++k) {
    int jj = ip[k];
    const float4 v = *reinterpret_cast<const float4*>(X + (size_t)(base + jj) * C + cq * 4);
    mx.x = fmaxf(mx.x, v.x); mx.y = fmaxf(mx.y, v.y);
    mx.z = fmaxf(mx.z, v.z); mx.w = fmaxf(mx.w, v.w);
  }
  const int c = cq * 4;
  const float4 sa = *reinterpret_cast<const float4*>(stats + c);
  const float4 sb = *reinterpret_cast<const float4*>(stats + C + c);
  float m0 = sa.x * inv_cnt, m1 = sa.y * inv_cnt, m2 = sa.z * inv_cnt, m3 = sa.w * inv_cnt;
  float o0 = fmaxf((mx.x - m0) * rsqrtf(fmaxf(sb.x * inv_cnt - m0 * m0, 0.f) + EPSBN), 0.f);
  float o1 = fmaxf((mx.y - m1) * rsqrtf(fmaxf(sb.y * inv_cnt - m1 * m1, 0.f) + EPSBN), 0.f);
  float o2 = fmaxf((mx.z - m2) * rsqrtf(fmaxf(sb.z * inv_cnt - m2 * m2, 0.f) + EPSBN), 0.f);
  float o3 = fmaxf((mx.w - m3) * rsqrtf(fmaxf(sb.w * inv_cnt - m3 * m3, 0.f) + EPSBN), 0.f);
  short4v H, L;
  H.x = (short)f2bf(o0); L.x = (short)f2bf(o0 - bf2f((unsigned short)H.x));
  H.y = (short)f2bf(o1); L.y = (short)f2bf(o1 - bf2f((unsigned short)H.y));
  H.z = (short)f2bf(o2); L.z = (short)f2bf(o2 - bf2f((unsigned short)H.z));
  H.w = (short)f2bf(o3); L.w = (short)f2bf(o3 - bf2f((unsigned short)H.w));
  const int NK = C >> 5;
  const int rt = r >> 4, rl = r & 15, ks = c >> 5, kl = c & 31;
  const size_t dst = (((size_t)rt * NK + ks) * 64 + (((kl >> 3) << 4) | rl)) * 8 + (kl & 7);
  *(short4v*)(ph + dst) = H;
  *(short4v*)(pl + dst) = L;
}

// ---------------------------------------------------------------------------
// MFMA GEMM (validated r7-9): wave = 64 rows x 64 cols, acc[4][4].
// AMODE 0: packed A. AMODE 1: row-major ushort hi/lo A (K=64).
// AMODE 3: ks<32 batch-broadcast g + packed x12 tail.
// ---------------------------------------------------------------------------
template <int AMODE, bool DOMAX>
__global__ __launch_bounds__(256) void gemm_mfma_kernel(
    const unsigned short* __restrict__ Ah, const unsigned short* __restrict__ Al,
    const unsigned short* __restrict__ gh, const unsigned short* __restrict__ gl,
    const unsigned short* __restrict__ Wh, const unsigned short* __restrict__ Wl,
    float* __restrict__ Y, float* __restrict__ pmax, float* __restrict__ stats,
    int K, int C) {
  __shared__ float red1[4][64], red2[4][64], redm[4][64];
  const int wave = threadIdx.x >> 6, lane = threadIdx.x & 63;
  const int rtb = blockIdx.x * 16 + wave * 4;
  const int c0  = blockIdx.y * 64;
  const int ct0 = blockIdx.y * 4;
  const int NK  = K >> 5;
  const int KP  = (AMODE == 3) ? 4 : NK;
  const int bat = blockIdx.x >> 4;
  f32x4 acc[4][4];
#pragma unroll
  for (int r = 0; r < 4; ++r)
#pragma unroll
    for (int cc = 0; cc < 4; ++cc) {
      acc[r][cc][0] = 0.f; acc[r][cc][1] = 0.f; acc[r][cc][2] = 0.f; acc[r][cc][3] = 0.f;
    }
  const int lhalf = (lane >> 4) << 3;
  for (int ks = 0; ks < NK; ++ks) {
    short8 ah[4], al[4];
    if (AMODE == 3 && ks < 32) {
      const int go = bat * 1024 + ks * 32 + lhalf;
      short8 gav = *(const short8*)(gh + go);
      short8 galv = *(const short8*)(gl + go);
#pragma unroll
      for (int r = 0; r < 4; ++r) { ah[r] = gav; al[r] = galv; }
    } else if (AMODE == 1) {
#pragma unroll
      for (int r = 0; r < 4; ++r) {
        const size_t aoff = ((size_t)((rtb + r) * 16 + (lane & 15))) * 64 + ks * 32 + lhalf;
        ah[r] = *(const short8*)(Ah + aoff);
        al[r] = *(const short8*)(Al + aoff);
      }
    } else {
      const int ksp = (AMODE == 3) ? ks - 32 : ks;
#pragma unroll
      for (int r = 0; r < 4; ++r) {
        const size_t aoff = (((size_t)(rtb + r) * KP + ksp) * 64 + lane) * 8;
        ah[r] = *(const short8*)(Ah + aoff);
        al[r] = *(const short8*)(Al + aoff);
      }
    }
#pragma unroll
    for (int cc = 0; cc < 4; ++cc) {
      const size_t woff = (((size_t)(ct0 + cc) * NK + ks) * 64 + lane) * 8;
      short8 bh = *(const short8*)(Wh + woff);
      short8 bl = *(const short8*)(Wl + woff);
#pragma unroll
      for (int r = 0; r < 4; ++r) {
        acc[r][cc] = __builtin_amdgcn_mfma_f32_16x16x32_bf16(al[r], bh, acc[r][cc], 0, 0, 0);
        acc[r][cc] = __builtin_amdgcn_mfma_f32_16x16x32_bf16(ah[r], bl, acc[r][cc], 0, 0, 0);
        acc[r][cc] = __builtin_amdgcn_mfma_f32_16x16x32_bf16(ah[r], bh, acc[r][cc], 0, 0, 0);
      }
    }
  }
#pragma unroll
  for (int cc = 0; cc < 4; ++cc) {
    float s1 = 0.f, s2 = 0.f, mm = -FLT_MAX;
#pragma unroll
    for (int r = 0; r < 4; ++r) {
      if (!DOMAX) {
#pragma unroll
        for (int i = 0; i < 4; ++i)
          Y[(size_t)((rtb + r) * 16 + ((lane >> 4) << 2) + i) * C + c0 + cc * 16 + (lane & 15)] = acc[r][cc][i];
      }
#pragma unroll
      for (int i = 0; i < 4; ++i) {
        float v = acc[r][cc][i];
        s1 += v; s2 = fmaf(v, v, s2); mm = fmaxf(mm, v);
      }
    }
    s1 += __shfl_xor(s1, 16); s1 += __shfl_xor(s1, 32);
    s2 += __shfl_xor(s2, 16); s2 += __shfl_xor(s2, 32);
    mm = fmaxf(mm, __shfl_xor(mm, 16)); mm = fmaxf(mm, __shfl_xor(mm, 32));
    if (lane < 16) {
      red1[wave][cc * 16 + lane] = s1;
      red2[wave][cc * 16 + lane] = s2;
      if (DOMAX) redm[wave][cc * 16 + lane] = mm;
    }
  }
  __syncthreads();
  if (threadIdx.x < 64) {
    const int t = threadIdx.x;
    float a = red1[0][t] + red1[1][t] + red1[2][t] + red1[3][t];
    float b = red2[0][t] + red2[1][t] + red2[2][t] + red2[3][t];
    atomicAdd(&stats[c0 + t], a);
    atomicAdd(&stats[C + c0 + t], b);
    if (DOMAX) {
      float mm = fmaxf(fmaxf(redm[0][t], redm[1][t]), fmaxf(redm[2][t], redm[3][t]));
      pmax[(size_t)blockIdx.x * C + c0 + t] = mm;
    }
  }
}

// g[b,c] = relu(bn(max over 16 row-blocks)) -> bf16 hi/lo
__global__ void fin_g_kernel(const float* __restrict__ pmax, const float* __restrict__ stats,
                             unsigned short* __restrict__ gh, unsigned short* __restrict__ gl) {
  int t = blockIdx.x * 256 + threadIdx.x;   // 4096
  int b = t >> 10, c = t & 1023;
  const float inv = 1.0f / 16384.0f;
  float m = stats[c] * inv;
  float v = fmaxf(stats[1024 + c] * inv - m * m, 0.0f);
  float rs = rsqrtf(v + EPSBN);
  float mx = -FLT_MAX;
  for (int s = 0; s < 16; ++s) mx = fmaxf(mx, pmax[(size_t)(b * 16 + s) * 1024 + c]);
  float val = fmaxf((mx - m) * rs, 0.0f);
  unsigned short h = f2bf(val);
  gh[t] = h; gl[t] = f2bf(val - bf2f(h));
}

// final13 with fused BN(h12): out[b,c,n] = sum_k bn_relu(h12)[r,k] * W13[k,c]
__global__ __launch_bounds__(256) void final13_kernel(const float* __restrict__ h,
                                                      const float* __restrict__ S9,
                                                      const float* __restrict__ W,
                                                      float* __restrict__ out) {
  __shared__ float wl[256 * 13];
  __shared__ float ms[256], rs[256];
  const int t = threadIdx.x;
  {
    const float inv = 1.0f / RN;
    float m = S9[t] * inv;
    float v = fmaxf(S9[256 + t] * inv - m * m, 0.0f);
    ms[t] = m; rs[t] = rsqrtf(v + EPSBN);
#pragma unroll
    for (int i = 0; i < 13; ++i) wl[t * 13 + i] = W[t * 13 + i];
  }
  __syncthreads();
  const int r = blockIdx.x * 16 + (t >> 4);
  const int c = t & 15;
  const int ci = (c < 13) ? c : 0;
  const float* hr = h + (size_t)r * 256;
  float acc = 0.0f;
  for (int k = 0; k < 256; ++k) {
    float x = fmaxf((hr[k] - ms[k]) * rs[k], 0.0f);
    acc = fmaf(x, wl[k * 13 + ci], acc);
  }
  if (c < 13) {
    int b = r >> 12, n = r & 4095;
    out[(size_t)b * 13 * NN + (size_t)c * NN + n] = acc;
  }
}

// ---------------------------------------------------------------------------
extern "C" void kernel_launch(void* const* d_in, const int* in_sizes, int n_in,
                              void* d_out, int out_size, void* d_ws, size_t ws_size,
                              hipStream_t stream) {
  (void)in_sizes; (void)n_in; (void)out_size; (void)ws_size;
  const float* data = (const float*)d_in[0];
  const float* W_fc = (const float*)d_in[1];
  const float* b_fc = (const float*)d_in[2];
  const float* W1   = (const float*)d_in[3];
  const float* W2   = (const float*)d_in[4];
  const float* W3   = (const float*)d_in[5];
  const float* W4   = (const float*)d_in[6];
  const float* W5   = (const float*)d_in[7];
  const float* W6   = (const float*)d_in[8];
  const float* W10  = (const float*)d_in[9];
  const float* W11  = (const float*)d_in[10];
  const float* W12  = (const float*)d_in[11];
  const float* W13  = (const float*)d_in[12];
  float* out = (float*)d_out;

  float* ws  = (float*)d_ws;
  int*   idx = (int*)d_ws;
  size_t o = 262144;
  float* x0   = ws + o; o += (size_t)RN * 64;
  float* x1v  = ws + o; o += (size_t)RN * 64;
  float* x2v  = ws + o; o += (size_t)RN * 64;
  float* bufA = ws + o; o += (size_t)RN * 256;
  float* bufB = ws + o; o += (size_t)RN * 256;
  float* bufC = ws + o; o += (size_t)RN * 64;
  float* pmax = ws + o; o += (size_t)64 * 1024;
  float* h11  = ws + o; o += (size_t)RN * 512;
  float* h12  = ws + o; o += (size_t)RN * 256;
  float* stats = ws + o; o += 8192;
  float4* pack = (float4*)(ws + o); o += (size_t)RN * 4;
  unsigned short* xbh = (unsigned short*)(ws + o); o += (size_t)RN * 32;
  unsigned short* xbl = (unsigned short*)(ws + o); o += (size_t)RN * 32;
  unsigned short* W1mh = (unsigned short*)(ws + o); o += 8192;
  unsigned short* W1ml = (unsigned short*)(ws + o); o += 8192;
  unsigned short* W4mh = (unsigned short*)(ws + o); o += 8192;
  unsigned short* W4ml = (unsigned short*)(ws + o); o += 8192;
  float4* W1bt = (float4*)(ws + o); o += 1024;
  unsigned short* W10h = (unsigned short*)(ws + o); o += 65536;
  unsigned short* W10l = (unsigned short*)(ws + o); o += 65536;
  unsigned short* W11h = (unsigned short*)(ws + o); o += 294912;
  unsigned short* W11l = (unsigned short*)(ws + o); o += 294912;
  unsigned short* W12h = (unsigned short*)(ws + o); o += 65536;
  unsigned short* W12l = (unsigned short*)(ws + o); o += 65536;
  unsigned short* gh   = (unsigned short*)(ws + o); o += 2048;
  unsigned short* gl   = (unsigned short*)(ws + o); o += 2048;
  unsigned short* W1ph = (unsigned short*)(ws + o); o += 8192;
  unsigned short* W1pl = (unsigned short*)(ws + o); o += 8192;
  unsigned short* W4ph = (unsigned short*)(ws + o); o += 8192;
  unsigned short* W4pl = (unsigned short*)(ws + o); o += 8192;
  unsigned short* W2h  = (unsigned short*)(ws + o); o += 8192;
  unsigned short* W2l  = (unsigned short*)(ws + o); o += 8192;
  unsigned short* W3h  = (unsigned short*)(ws + o); o += 2048;
  unsigned short* W3l  = (unsigned short*)(ws + o); o += 2048;
  unsigned short* W5h  = (unsigned short*)(ws + o); o += 8192;
  unsigned short* W5l  = (unsigned short*)(ws + o); o += 8192;
  unsigned short* W6h  = (unsigned short*)(ws + o); o += 2048;
  unsigned short* W6l  = (unsigned short*)(ws + o); o += 2048;
  float* gpart = ws + o; o += 64 * 54;
  // overlays on dead buffers:
  unsigned short* x12h = (unsigned short*)bufC;
  unsigned short* x12l = (unsigned short*)x0;
  unsigned short* h11h = (unsigned short*)bufA;
  unsigned short* h11l = (unsigned short*)bufB;
  unsigned short* aggh = (unsigned short*)h11;
  unsigned short* aggl = (unsigned short*)h11 + (size_t)RN * 256;

  float* S0 = stats;          // 64 (fc)
  float* S1 = stats + 128;    // 256 (edge1)
  float* S2 = stats + 640;    // 64  (W2)
  float* S3 = stats + 768;    // 64  (W3)
  float* S4 = stats + 896;    // 256 (edge2)
  float* S5 = stats + 1408;   // 64  (W5)
  float* S6 = stats + 1536;   // 64  (W6)
  float* S7 = stats + 1664;   // 1024 (W10)
  float* S8 = stats + 3712;   // 512 (W11)
  float* S9 = stats + 4736;   // 256 (W12)
  float* Sd = stats + 5248;   // dummy sink (512)

  hipMemsetAsync(stats, 0, 8192 * sizeof(float), stream);

  prepgram_kernel<<<64, 256, 0, stream>>>(data, pack, gpart);
  megaprep_kernel<<<3680, 256, 0, stream>>>(
      W1, W4, W2, W3, W5, W6, W10, W11, W12,
      W1mh, W1ml, W1bt, W4mh, W4ml,
      W1ph, W1pl, W4ph, W4pl, W2h, W2l, W3h, W3l, W5h, W5l, W6h, W6l,
      W10h, W10l, W11h, W11l, W12h, W12l);
  knn_kernel<<<RN / 4, 256, 0, stream>>>(pack, idx);
  fcstats_kernel<<<1, 64, 0, stream>>>(gpart, W_fc, b_fc, S0);
  fc_bnpack_kernel<<<RN * 64 / 256, 256, 0, stream>>>(data, W_fc, b_fc, S0, xbh, xbl);

  // edge conv 1: basemat = x0 @ (W1top-W1mid) via MFMA (row-major bf16 A)
  gemm_mfma_kernel<1, false><<<dim3(64, 4), 256, 0, stream>>>(
      xbh, xbl, nullptr, nullptr, W1ph, W1pl, bufB, nullptr, Sd, 64, 256);
  edge_mfma_kernel<true><<<1024, 256, 0, stream>>>(xbh, xbl, idx, pack, W1mh, W1ml, W1bt, bufB, bufA, S1);

  // graph conv 1
  agg_pack_kernel<8><<<4096, 256, 0, stream>>>(bufA, idx, S1, 1.0f / (RN * 16), aggh, aggl);
  gemm_mfma_kernel<0, false><<<dim3(64, 1), 256, 0, stream>>>(
      aggh, aggl, nullptr, nullptr, W2h, W2l, bufC, nullptr, S2, 256, 64);

  // graph conv 2
  agg_pack_kernel<6><<<1024, 256, 0, stream>>>(bufC, idx, S2, 1.0f / RN, aggh, aggl);
  gemm_mfma_kernel<0, false><<<dim3(64, 1), 256, 0, stream>>>(
      aggh, aggl, nullptr, nullptr, W3h, W3l, x1v, nullptr, S3, 64, 64);
  bn_normpack_kernel<<<RN * 64 / 256, 256, 0, stream>>>(x1v, S3, xbh, xbl);

  // edge conv 2 (no pts)
  gemm_mfma_kernel<1, false><<<dim3(64, 4), 256, 0, stream>>>(
      xbh, xbl, nullptr, nullptr, W4ph, W4pl, bufB, nullptr, Sd, 64, 256);
  edge_mfma_kernel<false><<<1024, 256, 0, stream>>>(xbh, xbl, idx, pack, W4mh, W4ml, nullptr, bufB, bufA, S4);

  // graph conv 3
  agg_pack_kernel<8><<<4096, 256, 0, stream>>>(bufA, idx, S4, 1.0f / (RN * 16), aggh, aggl);
  gemm_mfma_kernel<0, false><<<dim3(64, 1), 256, 0, stream>>>(
      aggh, aggl, nullptr, nullptr, W5h, W5l, bufC, nullptr, S5, 256, 64);

  // graph conv 4 -> x2v raw (+S6); bn fused into pack_x12
  agg_pack_kernel<6><<<1024, 256, 0, stream>>>(bufC, idx, S5, 1.0f / RN, aggh, aggl);
  gemm_mfma_kernel<0, false><<<dim3(64, 1), 256, 0, stream>>>(
      aggh, aggl, nullptr, nullptr, W6h, W6l, x2v, nullptr, S6, 64, 64);

  // pack [x1|bn(x2)]
  pack_x12_kernel<<<RN * 128 / 256, 256, 0, stream>>>(x1v, x2v, S6, x12h, x12l);

  // W10 path
  gemm_mfma_kernel<0, true><<<dim3(64, 16), 256, 0, stream>>>(
      x12h, x12l, nullptr, nullptr, W10h, W10l, nullptr, pmax, S7, 128, 1024);
  fin_g_kernel<<<16, 256, 0, stream>>>(pmax, S7, gh, gl);

  // W11
  gemm_mfma_kernel<3, false><<<dim3(64, 8), 256, 0, stream>>>(
      x12h, x12l, gh, gl, W11h, W11l, h11, nullptr, S8, 1152, 512);
  bn_pack_kernel<<<RN * 512 / 256, 256, 0, stream>>>(h11, S8, h11h, h11l);

  // W12 -> h12 raw (+S9); bn fused into final13
  gemm_mfma_kernel<0, false><<<dim3(64, 4), 256, 0, stream>>>(
      h11h, h11l, nullptr, nullptr, W12h, W12l, h12, nullptr, S9, 512, 256);

  final13_kernel<<<RN / 16, 256, 0, stream>>>(h12, S9, W13, out);
}

// Round 11
// 598.153 us; speedup vs baseline: 4.0556x; 1.0264x over previous
//
#include <hip/hip_runtime.h>
#include <hip/hip_bf16.h>
#include <float.h>

static constexpr int BB  = 4;
static constexpr int NN  = 4096;
static constexpr int KSN = 16;
static constexpr int RN  = BB * NN;     // 16384 rows (b,n)
#define EPSBN 1e-5f

typedef __attribute__((ext_vector_type(8))) short short8;
typedef __attribute__((ext_vector_type(4))) short short4v;
typedef __attribute__((ext_vector_type(4))) float f32x4;

__device__ inline unsigned short f2bf(float f) {
  union { float f; unsigned u; } v; v.f = f;
  unsigned r = v.u + 0x7FFF + ((v.u >> 16) & 1);
  return (unsigned short)(r >> 16);
}
__device__ inline float bf2f(unsigned short h) {
  union { unsigned u; float f; } v; v.u = ((unsigned)h) << 16; return v.f;
}

// ---------------------------------------------------------------------------
// prep + gram fused (validated r10).
// ---------------------------------------------------------------------------
__global__ __launch_bounds__(256) void prepgram_kernel(const float* __restrict__ data,
                                                       float4* __restrict__ pack,
                                                       float* __restrict__ partials) {
  const int t = blockIdx.x * 256 + threadIdx.x;   // RN
  const int lane = threadIdx.x & 63, wave = threadIdx.x >> 6;
  __shared__ float red[4][54];
  float d[9];
#pragma unroll
  for (int k = 0; k < 9; ++k) d[k] = data[(size_t)t * 9 + k];
  pack[t] = make_float4(d[0], d[1], d[2], fmaf(d[2], d[2], fmaf(d[1], d[1], d[0] * d[0])));
  int p = 0;
#pragma unroll
  for (int i = 0; i < 9; ++i) {
    float v = d[i];
#pragma unroll
    for (int mv = 1; mv < 64; mv <<= 1) v += __shfl_xor(v, mv);
    if (lane == 0) red[wave][p] = v;
    ++p;
  }
#pragma unroll
  for (int i = 0; i < 9; ++i)
#pragma unroll
    for (int j = i; j < 9; ++j) {
      float v = d[i] * d[j];
#pragma unroll
      for (int mv = 1; mv < 64; mv <<= 1) v += __shfl_xor(v, mv);
      if (lane == 0) red[wave][p] = v;
      ++p;
    }
  __syncthreads();
  if (threadIdx.x < 54)
    partials[blockIdx.x * 54 + threadIdx.x] =
        red[0][threadIdx.x] + red[1][threadIdx.x] + red[2][threadIdx.x] + red[3][threadIdx.x];
}

__global__ void fcstats_kernel(const float* __restrict__ partials,
                               const float* __restrict__ W, const float* __restrict__ bias,
                               float* __restrict__ S0) {
  __shared__ float g[54];
  const int t = threadIdx.x;   // 64 threads
  if (t < 54) {
    float s = 0.f;
    for (int b = 0; b < 64; ++b) s += partials[b * 54 + t];
    g[t] = s;
  }
  __syncthreads();
  float w[9];
#pragma unroll
  for (int k = 0; k < 9; ++k) w[k] = W[k * 64 + t];
  float b = bias[t];
  float dotw = 0.f;
#pragma unroll
  for (int k = 0; k < 9; ++k) dotw = fmaf(g[k], w[k], dotw);
  float s2 = 0.f;
  int p = 9;
#pragma unroll
  for (int i = 0; i < 9; ++i)
#pragma unroll
    for (int j = i; j < 9; ++j) {
      float gij = g[p++];
      s2 = fmaf(gij * ((i == j) ? 1.f : 2.f), w[i] * w[j], s2);
    }
  s2 += 2.f * b * dotw + (float)RN * b * b;
  S0[t] = dotw + (float)RN * b;
  S0[64 + t] = s2;
}

// ---------------------------------------------------------------------------
// weight-pack helpers (megaprep body).
// ---------------------------------------------------------------------------
__device__ inline void wpack_one(const float* __restrict__ W, unsigned short* __restrict__ wh,
                                 unsigned short* __restrict__ wl, int t, int lgC, int NK) {
  int k = t >> lgC, c = t & ((1 << lgC) - 1);
  float v = W[t];
  int ct = c >> 4, cl = c & 15, ks = k >> 5, kl = k & 31;
  int dst = ((ct * NK + ks) * 64 + (((kl >> 3) << 4) | cl)) * 8 + (kl & 7);
  unsigned short h = f2bf(v);
  wh[dst] = h; wl[dst] = f2bf(v - bf2f(h));
}
__device__ inline void diffpack_one(const float* __restrict__ W, unsigned short* __restrict__ wh,
                                    unsigned short* __restrict__ wl, int t) {
  int k = t >> 8, cc = t & 255;
  float v = W[k * 256 + cc] - W[(64 + k) * 256 + cc];  // Wtop - Wmid
  int ct = cc >> 4, cl = cc & 15, ks = k >> 5, kl = k & 31;
  int dst = ((ct * 2 + ks) * 64 + (((kl >> 3) << 4) | cl)) * 8 + (kl & 7);
  unsigned short h = f2bf(v);
  wh[dst] = h; wl[dst] = f2bf(v - bf2f(h));
}

// ---------------------------------------------------------------------------
// MEGA kernel: blocks [0,4096) knn; [4096,8192) fc+bn+pack; rest megaprep.
// All three are mutually independent (prepgram+fcstats ran before).
// knn: one wave/point, top-4/lane, 16 extraction passes with 32-bit dist
// min-reduce + ballot index resolve (exact; rare-tie path does idx reduce).
// ---------------------------------------------------------------------------
__global__ __launch_bounds__(256) void mega_kernel(
    const float4* __restrict__ pack, int* __restrict__ idx,
    const float* __restrict__ data, const float* __restrict__ W_fc,
    const float* __restrict__ b_fc, const float* __restrict__ S0,
    unsigned short* __restrict__ xbh, unsigned short* __restrict__ xbl,
    const float* __restrict__ W1, const float* __restrict__ W4,
    const float* __restrict__ W2, const float* __restrict__ W3,
    const float* __restrict__ W5, const float* __restrict__ W6,
    const float* __restrict__ W10, const float* __restrict__ W11, const float* __restrict__ W12,
    unsigned short* __restrict__ W1mh, unsigned short* __restrict__ W1ml, float4* __restrict__ W1bt,
    unsigned short* __restrict__ W4mh, unsigned short* __restrict__ W4ml,
    unsigned short* __restrict__ W1ph, unsigned short* __restrict__ W1pl,
    unsigned short* __restrict__ W4ph, unsigned short* __restrict__ W4pl,
    unsigned short* __restrict__ W2h, unsigned short* __restrict__ W2l,
    unsigned short* __restrict__ W3h, unsigned short* __restrict__ W3l,
    unsigned short* __restrict__ W5h, unsigned short* __restrict__ W5l,
    unsigned short* __restrict__ W6h, unsigned short* __restrict__ W6l,
    unsigned short* __restrict__ W10h, unsigned short* __restrict__ W10l,
    unsigned short* __restrict__ W11xh, unsigned short* __restrict__ W11xl,
    unsigned short* __restrict__ W12h, unsigned short* __restrict__ W12l) {
  const int blk = blockIdx.x;
  if (blk < 4096) {
    // ------------------------------ KNN ------------------------------
    const int lane = threadIdx.x & 63;
    const int p = blk * 4 + (threadIdx.x >> 6);
    const int b = p >> 12;
    const float4* __restrict__ pb = pack + ((size_t)b << 12);
    const float4 me = pack[p];
    unsigned long long m0 = ~0ull, m1 = ~0ull, m2 = ~0ull, m3 = ~0ull;
#pragma unroll 8
    for (int s = 0; s < 64; ++s) {
      const float4 q = pb[s * 64 + lane];
      float d = me.w + q.w - 2.0f * fmaf(me.x, q.x, fmaf(me.y, q.y, me.z * q.z));
      unsigned ub = __float_as_uint(d);
      ub = (ub & 0x80000000u) ? ~ub : (ub | 0x80000000u);
      unsigned long long k = ((unsigned long long)ub << 12) | (unsigned)(s * 64 + lane);
      if (k < m3) {
        bool l0 = k < m0;  unsigned long long t0 = l0 ? m0 : k;  m0 = l0 ? k : m0;
        bool l1 = t0 < m1; unsigned long long t1 = l1 ? m1 : t0; m1 = l1 ? t0 : m1;
        bool l2 = t1 < m2; unsigned long long t2 = l2 ? m2 : t1; m2 = l2 ? t1 : m2;
        m3 = (t2 < m3) ? t2 : m3;
      }
    }
    for (int pass = 0; pass < 16; ++pass) {
      unsigned d0 = (unsigned)(m0 >> 12);
      unsigned w32 = d0;
#pragma unroll
      for (int mv = 1; mv < 64; mv <<= 1) {
        unsigned o = __shfl_xor(w32, mv);
        w32 = (o < w32) ? o : w32;
      }
      unsigned long long ball = __ballot(d0 == w32);
      unsigned widx;
      if (__popcll(ball) == 1) {
        widx = __shfl((unsigned)(m0 & 0xFFFull), (int)(__ffsll((long long)ball) - 1));
      } else {
        unsigned cand = (d0 == w32) ? (unsigned)(m0 & 0xFFFull) : 0xFFFFFFFFu;
#pragma unroll
        for (int mv = 1; mv < 64; mv <<= 1) {
          unsigned o = __shfl_xor(cand, mv);
          cand = (o < cand) ? o : cand;
        }
        widx = cand;
      }
      const unsigned long long w = ((unsigned long long)w32 << 12) | widx;
      if (lane == pass) idx[(p << 4) + pass] = (int)widx;
      if (m0 == w) { m0 = m1; m1 = m2; m2 = m3; m3 = ~0ull; }
      if (pass < 15 && __any(m0 == ~0ull)) {
        if (m0 == ~0ull) {                    // rare: rebuild from global
          m1 = ~0ull; m2 = ~0ull; m3 = ~0ull;
#pragma unroll 8
          for (int s = 0; s < 64; ++s) {
            const float4 q = pb[s * 64 + lane];
            float d = me.w + q.w - 2.0f * fmaf(me.x, q.x, fmaf(me.y, q.y, me.z * q.z));
            unsigned ub = __float_as_uint(d);
            ub = (ub & 0x80000000u) ? ~ub : (ub | 0x80000000u);
            unsigned long long k = ((unsigned long long)ub << 12) | (unsigned)(s * 64 + lane);
            k = (k > w) ? k : ~0ull;          // exclude consumed
            if (k < m3) {
              bool l0 = k < m0;  unsigned long long t0 = l0 ? m0 : k;  m0 = l0 ? k : m0;
              bool l1 = t0 < m1; unsigned long long t1 = l1 ? m1 : t0; m1 = l1 ? t0 : m1;
              bool l2 = t1 < m2; unsigned long long t2 = l2 ? m2 : t1; m2 = l2 ? t1 : m2;
              m3 = (t2 < m3) ? t2 : m3;
            }
          }
        }
      }
    }
  } else if (blk < 8192) {
    // --------------------------- fc + BN + pack ---------------------------
    const int t = (blk - 4096) * 256 + threadIdx.x;   // RN*64
    const int r = t >> 6, c = t & 63;
    const float* dr = data + (size_t)r * 9;
    float acc = b_fc[c];
#pragma unroll
    for (int k = 0; k < 9; ++k) acc = fmaf(dr[k], W_fc[k * 64 + c], acc);
    const float inv = 1.0f / RN;
    float m = S0[c] * inv;
    float v = fmaxf(S0[64 + c] * inv - m * m, 0.0f);
    float x = fmaxf((acc - m) * rsqrtf(v + EPSBN), 0.0f);
    unsigned short h = f2bf(x);
    xbh[t] = h; xbl[t] = f2bf(x - bf2f(h));
  } else {
    // ------------------------------ megaprep ------------------------------
    const int mb = blk - 8192;
    if (mb < 64) {                       // edge mid weights (transposed hi/lo) + W1bt
      int t = mb * 256 + threadIdx.x;
      int k = t >> 8, cc = t & 255;
      float w1mid = W1[(64 + k) * 256 + cc];
      unsigned short h1 = f2bf(w1mid);
      W1mh[cc * 64 + k] = h1;
      W1ml[cc * 64 + k] = f2bf(w1mid - bf2f(h1));
      float w4mid = W4[(64 + k) * 256 + cc];
      unsigned short h4 = f2bf(w4mid);
      W4mh[cc * 64 + k] = h4;
      W4ml[cc * 64 + k] = f2bf(w4mid - bf2f(h4));
      if (t < 256) W1bt[t] = make_float4(W1[128 * 256 + t], W1[129 * 256 + t], W1[130 * 256 + t], 0.f);
    } else if (mb < 128) {
      diffpack_one(W1, W1ph, W1pl, (mb - 64) * 256 + threadIdx.x);
    } else if (mb < 192) {
      diffpack_one(W4, W4ph, W4pl, (mb - 128) * 256 + threadIdx.x);
    } else if (mb < 256) {
      wpack_one(W2, W2h, W2l, (mb - 192) * 256 + threadIdx.x, 6, 8);
    } else if (mb < 272) {
      wpack_one(W3, W3h, W3l, (mb - 256) * 256 + threadIdx.x, 6, 2);
    } else if (mb < 336) {
      wpack_one(W5, W5h, W5l, (mb - 272) * 256 + threadIdx.x, 6, 8);
    } else if (mb < 352) {
      wpack_one(W6, W6h, W6l, (mb - 336) * 256 + threadIdx.x, 6, 2);
    } else if (mb < 864) {
      wpack_one(W10, W10h, W10l, (mb - 352) * 256 + threadIdx.x, 10, 4);
    } else if (mb < 1120) {
      // last 128 rows of W11 (the x12 part), K=128 -> NK=4
      wpack_one(W11 + 1024 * 512, W11xh, W11xl, (mb - 864) * 256 + threadIdx.x, 9, 4);
    } else {
      wpack_one(W12, W12h, W12l, (mb - 1120) * 256 + threadIdx.x, 8, 16);
    }
  }
}

// [x1|bn(x2)] -> fragment-major hi/lo pack (K=128) (validated r10).
__global__ void pack_x12_kernel(const float* __restrict__ x1, const float* __restrict__ x2,
                                const float* __restrict__ S6,
                                unsigned short* __restrict__ ph, unsigned short* __restrict__ pl) {
  int t = blockIdx.x * 256 + threadIdx.x;   // RN*128
  int r = t >> 7, k = t & 127;
  float v;
  if (k < 64) {
    v = x1[(size_t)r * 64 + k];
  } else {
    int c = k - 64;
    const float inv = 1.0f / RN;
    float m = S6[c] * inv;
    float var = fmaxf(S6[64 + c] * inv - m * m, 0.f);
    v = fmaxf((x2[(size_t)r * 64 + c] - m) * rsqrtf(var + EPSBN), 0.f);
  }
  int rt = r >> 4, rl = r & 15, ks = k >> 5, kl = k & 31;
  int dst = ((rt * 4 + ks) * 64 + (((kl >> 3) << 4) | rl)) * 8 + (kl & 7);
  unsigned short h = f2bf(v);
  ph[dst] = h; pl[dst] = f2bf(v - bf2f(h));
}

// BN+ReLU on h11 (C=512) fused with fragment-major hi/lo pack
__global__ void bn_pack_kernel(const float* __restrict__ buf, const float* __restrict__ stats,
                               unsigned short* __restrict__ ph, unsigned short* __restrict__ pl) {
  int t = blockIdx.x * 256 + threadIdx.x;   // RN*512
  int c = t & 511, r = t >> 9;
  const float inv = 1.0f / RN;
  float m = stats[c] * inv;
  float v = fmaxf(stats[512 + c] * inv - m * m, 0.0f);
  float x = fmaxf((buf[t] - m) * rsqrtf(v + EPSBN), 0.0f);
  int rt = r >> 4, rl = r & 15, ks = c >> 5, kl = c & 31;
  int dst = ((rt * 16 + ks) * 64 + (((kl >> 3) << 4) | rl)) * 8 + (kl & 7);
  unsigned short h = f2bf(x);
  ph[dst] = h; pl[dst] = f2bf(x - bf2f(h));
}

// BN+ReLU in place (C=64) fused with row-major hi/lo write (x1v)
__global__ void bn_normpack_kernel(float* __restrict__ buf, const float* __restrict__ stats,
                                   unsigned short* __restrict__ hi, unsigned short* __restrict__ lo) {
  int t = blockIdx.x * 256 + threadIdx.x;   // RN*64
  int c = t & 63;
  const float inv = 1.0f / RN;
  float m = stats[c] * inv;
  float v = fmaxf(stats[64 + c] * inv - m * m, 0.0f);
  float x = fmaxf((buf[t] - m) * rsqrtf(v + EPSBN), 0.0f);
  buf[t] = x;
  unsigned short h = f2bf(x);
  hi[t] = h; lo[t] = f2bf(x - bf2f(h));
}

// ---------------------------------------------------------------------------
// Edge conv via MFMA, deferred-stats epilogue (validated r10).
// ---------------------------------------------------------------------------
template <bool HAS_PTS>
__global__ __launch_bounds__(256) void edge_mfma_kernel(
    const unsigned short* __restrict__ Xh, const unsigned short* __restrict__ Xl,
    const int* __restrict__ idx,
    const float4* __restrict__ pack,
    const unsigned short* __restrict__ Wmh, const unsigned short* __restrict__ Wml,
    const float4* __restrict__ Wbt, const float* __restrict__ basemat,
    float* __restrict__ out, float* __restrict__ stats) {
  const int wave = threadIdx.x >> 6;
  const int lane = threadIdx.x & 63;
  const int pg   = blockIdx.x;
  const int c0   = wave << 6;
  const int cl   = lane & 15;
  const int kg   = (lane >> 4) << 3;
  const int bat  = pg >> 8;
  const int pbase = bat << 12;
  const int ib   = pg << 8;

  short8 bh[4][2], blo[4][2];
#pragma unroll
  for (int q = 0; q < 4; ++q) {
    const unsigned short* wp = Wmh + (size_t)(c0 + q * 16 + cl) * 64 + kg;
    bh[q][0] = *(const short8*)wp; bh[q][1] = *(const short8*)(wp + 32);
    const unsigned short* wq = Wml + (size_t)(c0 + q * 16 + cl) * 64 + kg;
    blo[q][0] = *(const short8*)wq; blo[q][1] = *(const short8*)(wq + 32);
  }
  float4 wb[4];
  if (HAS_PTS) {
#pragma unroll
    for (int q = 0; q < 4; ++q) wb[q] = Wbt[c0 + q * 16 + cl];
  }
  float P1[4] = {0.f, 0.f, 0.f, 0.f}, P2[4] = {0.f, 0.f, 0.f, 0.f};
  float PCx[4] = {0.f, 0.f, 0.f, 0.f};
  float PB1[4] = {0.f, 0.f, 0.f, 0.f}, PB2[4] = {0.f, 0.f, 0.f, 0.f};

  int jn = idx[ib + 16 + cl];
  int j0 = idx[ib + cl];
  size_t ro = ((size_t)(pbase | j0) << 6) + kg;
  short8 a0h = *(const short8*)(Xh + ro);
  short8 a1h = *(const short8*)(Xh + ro + 32);
  short8 a0l = *(const short8*)(Xl + ro);
  short8 a1l = *(const short8*)(Xl + ro + 32);

  for (int pp = 0; pp < 16; ++pp) {
    const int p = (pg << 4) | pp;
    int jf = 0;
    if (pp < 14) jf = idx[ib + ((pp + 2) << 4) + cl];
    short8 n0h, n1h, n0l, n1l;
    if (pp < 15) {
      size_t rn = ((size_t)(pbase | jn) << 6) + kg;
      n0h = *(const short8*)(Xh + rn);
      n1h = *(const short8*)(Xh + rn + 32);
      n0l = *(const short8*)(Xl + rn);
      n1l = *(const short8*)(Xl + rn + 32);
    }
    float dx0, dy0, dz0, dx1, dy1, dz1, dx2, dy2, dz2, dx3, dy3, dz3;
    if (HAS_PTS) {
      const int4 j4 = *(const int4*)(idx + (p << 4) + ((lane >> 4) << 2));
      const float4 pc = pack[p];
      const float4 q0 = pack[pbase | j4.x];
      const float4 q1 = pack[pbase | j4.y];
      const float4 q2 = pack[pbase | j4.z];
      const float4 q3 = pack[pbase | j4.w];
      dx0 = q0.x - pc.x; dy0 = q0.y - pc.y; dz0 = q0.z - pc.z;
      dx1 = q1.x - pc.x; dy1 = q1.y - pc.y; dz1 = q1.z - pc.z;
      dx2 = q2.x - pc.x; dy2 = q2.y - pc.y; dz2 = q2.z - pc.z;
      dx3 = q3.x - pc.x; dy3 = q3.y - pc.y; dz3 = q3.z - pc.z;
    }
    f32x4 acc[4];
#pragma unroll
    for (int q = 0; q < 4; ++q) {
      acc[q][0] = 0.f; acc[q][1] = 0.f; acc[q][2] = 0.f; acc[q][3] = 0.f;
    }
#pragma unroll
    for (int q = 0; q < 4; ++q) {
      acc[q] = __builtin_amdgcn_mfma_f32_16x16x32_bf16(a0l, bh[q][0], acc[q], 0, 0, 0);
      acc[q] = __builtin_amdgcn_mfma_f32_16x16x32_bf16(a1l, bh[q][1], acc[q], 0, 0, 0);
      acc[q] = __builtin_amdgcn_mfma_f32_16x16x32_bf16(a0h, blo[q][0], acc[q], 0, 0, 0);
      acc[q] = __builtin_amdgcn_mfma_f32_16x16x32_bf16(a1h, blo[q][1], acc[q], 0, 0, 0);
      acc[q] = __builtin_amdgcn_mfma_f32_16x16x32_bf16(a0h, bh[q][0], acc[q], 0, 0, 0);
      acc[q] = __builtin_amdgcn_mfma_f32_16x16x32_bf16(a1h, bh[q][1], acc[q], 0, 0, 0);
    }
    if (HAS_PTS) {
#pragma unroll
      for (int q = 0; q < 4; ++q) {
        acc[q][0] += dx0 * wb[q].x + dy0 * wb[q].y + dz0 * wb[q].z;
        acc[q][1] += dx1 * wb[q].x + dy1 * wb[q].y + dz1 * wb[q].z;
        acc[q][2] += dx2 * wb[q].x + dy2 * wb[q].y + dz2 * wb[q].z;
        acc[q][3] += dx3 * wb[q].x + dy3 * wb[q].y + dz3 * wb[q].z;
      }
    }
#pragma unroll
    for (int q = 0; q < 4; ++q) {
      float s1p = acc[q][0] + acc[q][1] + acc[q][2] + acc[q][3];
      float s2p = acc[q][0] * acc[q][0] + acc[q][1] * acc[q][1]
                + acc[q][2] * acc[q][2] + acc[q][3] * acc[q][3];
      float mx = fmaxf(fmaxf(acc[q][0], acc[q][1]), fmaxf(acc[q][2], acc[q][3]));
      mx = fmaxf(mx, __shfl_xor(mx, 16));
      mx = fmaxf(mx, __shfl_xor(mx, 32));
      float bb = basemat[(size_t)p * 256 + c0 + q * 16 + cl];
      if (lane < 16) out[(size_t)p * 256 + c0 + q * 16 + cl] = mx + bb;
      P1[q] += s1p;
      P2[q] += s2p;
      PCx[q] = fmaf(bb, s1p, PCx[q]);
      PB1[q] += bb;
      PB2[q] = fmaf(bb, bb, PB2[q]);
    }
    a0h = n0h; a1h = n1h; a0l = n0l; a1l = n1l;
    jn = jf;
  }
#pragma unroll
  for (int q = 0; q < 4; ++q) {
    float p1 = P1[q]; p1 += __shfl_xor(p1, 16); p1 += __shfl_xor(p1, 32);
    float p2 = P2[q]; p2 += __shfl_xor(p2, 16); p2 += __shfl_xor(p2, 32);
    float pc = PCx[q]; pc += __shfl_xor(pc, 16); pc += __shfl_xor(pc, 32);
    if (lane < 16) {
      atomicAdd(&stats[c0 + q * 16 + lane], p1 + 16.f * PB1[q]);
      atomicAdd(&stats[256 + c0 + q * 16 + lane], p2 + 2.f * pc + 16.f * PB2[q]);
    }
  }
}

// ---------------------------------------------------------------------------
// agg_pack: bn_relu(max over 16 neighbors) -> fragment-major hi/lo bf16.
// XCD-swizzled (validated r10).
// ---------------------------------------------------------------------------
template <int LGC>
__global__ __launch_bounds__(256) void agg_pack_kernel(
    const float* __restrict__ X, const int* __restrict__ idx,
    const float* __restrict__ stats, float inv_cnt,
    unsigned short* __restrict__ ph, unsigned short* __restrict__ pl) {
  const int C = 1 << LGC;
  const int xcd = blockIdx.x & 7, bat = xcd >> 1;
  const int j = ((blockIdx.x >> 3) << 1) | (xcd & 1);
  const int rows_per_block = 256 >> (LGC - 2);
  const int r = bat * 4096 + j * rows_per_block + (threadIdx.x >> (LGC - 2));
  const int cq = threadIdx.x & ((C >> 2) - 1);
  const int base = bat << 12;
  const int* ip = idx + (size_t)r * KSN;
  float4 mx = make_float4(-FLT_MAX, -FLT_MAX, -FLT_MAX, -FLT_MAX);
#pragma unroll
  for (int k = 0; k < KSN; ++k) {
    int jj = ip[k];
    const float4 v = *reinterpret_cast<const float4*>(X + (size_t)(base + jj) * C + cq * 4);
    mx.x = fmaxf(mx.x, v.x); mx.y = fmaxf(mx.y, v.y);
    mx.z = fmaxf(mx.z, v.z); mx.w = fmaxf(mx.w, v.w);
  }
  const int c = cq * 4;
  const float4 sa = *reinterpret_cast<const float4*>(stats + c);
  const float4 sb = *reinterpret_cast<const float4*>(stats + C + c);
  float m0 = sa.x * inv_cnt, m1 = sa.y * inv_cnt, m2 = sa.z * inv_cnt, m3 = sa.w * inv_cnt;
  float o0 = fmaxf((mx.x - m0) * rsqrtf(fmaxf(sb.x * inv_cnt - m0 * m0, 0.f) + EPSBN), 0.f);
  float o1 = fmaxf((mx.y - m1) * rsqrtf(fmaxf(sb.y * inv_cnt - m1 * m1, 0.f) + EPSBN), 0.f);
  float o2 = fmaxf((mx.z - m2) * rsqrtf(fmaxf(sb.z * inv_cnt - m2 * m2, 0.f) + EPSBN), 0.f);
  float o3 = fmaxf((mx.w - m3) * rsqrtf(fmaxf(sb.w * inv_cnt - m3 * m3, 0.f) + EPSBN), 0.f);
  short4v H, L;
  H.x = (short)f2bf(o0); L.x = (short)f2bf(o0 - bf2f((unsigned short)H.x));
  H.y = (short)f2bf(o1); L.y = (short)f2bf(o1 - bf2f((unsigned short)H.y));
  H.z = (short)f2bf(o2); L.z = (short)f2bf(o2 - bf2f((unsigned short)H.z));
  H.w = (short)f2bf(o3); L.w = (short)f2bf(o3 - bf2f((unsigned short)H.w));
  const int NK = C >> 5;
  const int rt = r >> 4, rl = r & 15, ks = c >> 5, kl = c & 31;
  const size_t dst = (((size_t)rt * NK + ks) * 64 + (((kl >> 3) << 4) | rl)) * 8 + (kl & 7);
  *(short4v*)(ph + dst) = H;
  *(short4v*)(pl + dst) = L;
}

// ---------------------------------------------------------------------------
// MFMA GEMM (validated r7-10): wave = 64 rows x 64 cols, acc[4][4].
// AMODE 0: packed A. AMODE 1: row-major ushort hi/lo A (K=64).
// BIAS: add per-(batch,col) bias (gbias[bat*C+c]) before stats/write.
// ---------------------------------------------------------------------------
template <int AMODE, bool DOMAX, bool BIAS>
__global__ __launch_bounds__(256) void gemm_mfma_kernel(
    const unsigned short* __restrict__ Ah, const unsigned short* __restrict__ Al,
    const unsigned short* __restrict__ Wh, const unsigned short* __restrict__ Wl,
    float* __restrict__ Y, float* __restrict__ pmax, float* __restrict__ stats,
    const float* __restrict__ gbias,
    int K, int C) {
  __shared__ float red1[4][64], red2[4][64], redm[4][64];
  const int wave = threadIdx.x >> 6, lane = threadIdx.x & 63;
  const int rtb = blockIdx.x * 16 + wave * 4;
  const int c0  = blockIdx.y * 64;
  const int ct0 = blockIdx.y * 4;
  const int NK  = K >> 5;
  const int bat = blockIdx.x >> 4;
  f32x4 acc[4][4];
#pragma unroll
  for (int r = 0; r < 4; ++r)
#pragma unroll
    for (int cc = 0; cc < 4; ++cc) {
      acc[r][cc][0] = 0.f; acc[r][cc][1] = 0.f; acc[r][cc][2] = 0.f; acc[r][cc][3] = 0.f;
    }
  const int lhalf = (lane >> 4) << 3;
  for (int ks = 0; ks < NK; ++ks) {
    short8 ah[4], al[4];
    if (AMODE == 1) {
#pragma unroll
      for (int r = 0; r < 4; ++r) {
        const size_t aoff = ((size_t)((rtb + r) * 16 + (lane & 15))) * 64 + ks * 32 + lhalf;
        ah[r] = *(const short8*)(Ah + aoff);
        al[r] = *(const short8*)(Al + aoff);
      }
    } else {
#pragma unroll
      for (int r = 0; r < 4; ++r) {
        const size_t aoff = (((size_t)(rtb + r) * NK + ks) * 64 + lane) * 8;
        ah[r] = *(const short8*)(Ah + aoff);
        al[r] = *(const short8*)(Al + aoff);
      }
    }
#pragma unroll
    for (int cc = 0; cc < 4; ++cc) {
      const size_t woff = (((size_t)(ct0 + cc) * NK + ks) * 64 + lane) * 8;
      short8 bh = *(const short8*)(Wh + woff);
      short8 bl = *(const short8*)(Wl + woff);
#pragma unroll
      for (int r = 0; r < 4; ++r) {
        acc[r][cc] = __builtin_amdgcn_mfma_f32_16x16x32_bf16(al[r], bh, acc[r][cc], 0, 0, 0);
        acc[r][cc] = __builtin_amdgcn_mfma_f32_16x16x32_bf16(ah[r], bl, acc[r][cc], 0, 0, 0);
        acc[r][cc] = __builtin_amdgcn_mfma_f32_16x16x32_bf16(ah[r], bh, acc[r][cc], 0, 0, 0);
      }
    }
  }
#pragma unroll
  for (int cc = 0; cc < 4; ++cc) {
    float bv = 0.f;
    if (BIAS) bv = gbias[(size_t)bat * C + c0 + cc * 16 + (lane & 15)];
    float s1 = 0.f, s2 = 0.f, mm = -FLT_MAX;
#pragma unroll
    for (int r = 0; r < 4; ++r) {
#pragma unroll
      for (int i = 0; i < 4; ++i) {
        float v = acc[r][cc][i] + bv;
        if (!DOMAX)
          Y[(size_t)((rtb + r) * 16 + ((lane >> 4) << 2) + i) * C + c0 + cc * 16 + (lane & 15)] = v;
        s1 += v; s2 = fmaf(v, v, s2); mm = fmaxf(mm, v);
      }
    }
    s1 += __shfl_xor(s1, 16); s1 += __shfl_xor(s1, 32);
    s2 += __shfl_xor(s2, 16); s2 += __shfl_xor(s2, 32);
    mm = fmaxf(mm, __shfl_xor(mm, 16)); mm = fmaxf(mm, __shfl_xor(mm, 32));
    if (lane < 16) {
      red1[wave][cc * 16 + lane] = s1;
      red2[wave][cc * 16 + lane] = s2;
      if (DOMAX) redm[wave][cc * 16 + lane] = mm;
    }
  }
  __syncthreads();
  if (threadIdx.x < 64) {
    const int t = threadIdx.x;
    float a = red1[0][t] + red1[1][t] + red1[2][t] + red1[3][t];
    float b = red2[0][t] + red2[1][t] + red2[2][t] + red2[3][t];
    atomicAdd(&stats[c0 + t], a);
    atomicAdd(&stats[C + c0 + t], b);
    if (DOMAX) {
      float mm = fmaxf(fmaxf(redm[0][t], redm[1][t]), fmaxf(redm[2][t], redm[3][t]));
      pmax[(size_t)blockIdx.x * C + c0 + t] = mm;
    }
  }
}

// g[b,c] = relu(bn(max over 16 row-blocks)) -> fp32
__global__ void fin_g_kernel(const float* __restrict__ pmax, const float* __restrict__ stats,
                             float* __restrict__ gf) {
  int t = blockIdx.x * 256 + threadIdx.x;   // 4096
  int b = t >> 10, c = t & 1023;
  const float inv = 1.0f / 16384.0f;
  float m = stats[c] * inv;
  float v = fmaxf(stats[1024 + c] * inv - m * m, 0.0f);
  float rs = rsqrtf(v + EPSBN);
  float mx = -FLT_MAX;
  for (int s = 0; s < 16; ++s) mx = fmaxf(mx, pmax[(size_t)(b * 16 + s) * 1024 + c]);
  gf[t] = fmaxf((mx - m) * rs, 0.0f);
}

// gb[b,c] = g[b,:] @ W11[0:1024, c]  (per-batch bias row for W11 gemm)
__global__ __launch_bounds__(256) void gb11_kernel(const float* __restrict__ gf,
                                                   const float* __restrict__ W11,
                                                   float* __restrict__ gb) {
  int t = blockIdx.x * 256 + threadIdx.x;   // 2048
  int b = t >> 9, c = t & 511;
  const float* g = gf + b * 1024;
  float acc = 0.f;
#pragma unroll 8
  for (int k = 0; k < 1024; ++k) acc = fmaf(g[k], W11[(size_t)k * 512 + c], acc);
  gb[t] = acc;
}

// final13 with fused BN(h12) (validated r10)
__global__ __launch_bounds__(256) void final13_kernel(const float* __restrict__ h,
                                                      const float* __restrict__ S9,
                                                      const float* __restrict__ W,
                                                      float* __restrict__ out) {
  __shared__ float wl[256 * 13];
  __shared__ float ms[256], rs[256];
  const int t = threadIdx.x;
  {
    const float inv = 1.0f / RN;
    float m = S9[t] * inv;
    float v = fmaxf(S9[256 + t] * inv - m * m, 0.0f);
    ms[t] = m; rs[t] = rsqrtf(v + EPSBN);
#pragma unroll
    for (int i = 0; i < 13; ++i) wl[t * 13 + i] = W[t * 13 + i];
  }
  __syncthreads();
  const int r = blockIdx.x * 16 + (t >> 4);
  const int c = t & 15;
  const int ci = (c < 13) ? c : 0;
  const float* hr = h + (size_t)r * 256;
  float acc = 0.0f;
  for (int k = 0; k < 256; ++k) {
    float x = fmaxf((hr[k] - ms[k]) * rs[k], 0.0f);
    acc = fmaf(x, wl[k * 13 + ci], acc);
  }
  if (c < 13) {
    int b = r >> 12, n = r & 4095;
    out[(size_t)b * 13 * NN + (size_t)c * NN + n] = acc;
  }
}

// ---------------------------------------------------------------------------
extern "C" void kernel_launch(void* const* d_in, const int* in_sizes, int n_in,
                              void* d_out, int out_size, void* d_ws, size_t ws_size,
                              hipStream_t stream) {
  (void)in_sizes; (void)n_in; (void)out_size; (void)ws_size;
  const float* data = (const float*)d_in[0];
  const float* W_fc = (const float*)d_in[1];
  const float* b_fc = (const float*)d_in[2];
  const float* W1   = (const float*)d_in[3];
  const float* W2   = (const float*)d_in[4];
  const float* W3   = (const float*)d_in[5];
  const float* W4   = (const float*)d_in[6];
  const float* W5   = (const float*)d_in[7];
  const float* W6   = (const float*)d_in[8];
  const float* W10  = (const float*)d_in[9];
  const float* W11  = (const float*)d_in[10];
  const float* W12  = (const float*)d_in[11];
  const float* W13  = (const float*)d_in[12];
  float* out = (float*)d_out;

  float* ws  = (float*)d_ws;
  int*   idx = (int*)d_ws;
  size_t o = 262144;
  float* x0   = ws + o; o += (size_t)RN * 64;     // dead fp32; hosts x12l overlay
  float* x1v  = ws + o; o += (size_t)RN * 64;
  float* x2v  = ws + o; o += (size_t)RN * 64;
  float* bufA = ws + o; o += (size_t)RN * 256;
  float* bufB = ws + o; o += (size_t)RN * 256;
  float* bufC = ws + o; o += (size_t)RN * 64;
  float* pmax = ws + o; o += (size_t)64 * 1024;
  float* h11  = ws + o; o += (size_t)RN * 512;
  float* h12  = ws + o; o += (size_t)RN * 256;
  float* stats = ws + o; o += 8192;
  float4* pack = (float4*)(ws + o); o += (size_t)RN * 4;
  unsigned short* xbh = (unsigned short*)(ws + o); o += (size_t)RN * 32;
  unsigned short* xbl = (unsigned short*)(ws + o); o += (size_t)RN * 32;
  unsigned short* W1mh = (unsigned short*)(ws + o); o += 8192;
  unsigned short* W1ml = (unsigned short*)(ws + o); o += 8192;
  unsigned short* W4mh = (unsigned short*)(ws + o); o += 8192;
  unsigned short* W4ml = (unsigned short*)(ws + o); o += 8192;
  float4* W1bt = (float4*)(ws + o); o += 1024;
  unsigned short* W10h = (unsigned short*)(ws + o); o += 65536;
  unsigned short* W10l = (unsigned short*)(ws + o); o += 65536;
  unsigned short* W11xh = (unsigned short*)(ws + o); o += 32768;
  unsigned short* W11xl = (unsigned short*)(ws + o); o += 32768;
  unsigned short* W12h = (unsigned short*)(ws + o); o += 65536;
  unsigned short* W12l = (unsigned short*)(ws + o); o += 65536;
  float* gf = ws + o; o += 4096;
  float* gb = ws + o; o += 2048;
  unsigned short* W1ph = (unsigned short*)(ws + o); o += 8192;
  unsigned short* W1pl = (unsigned short*)(ws + o); o += 8192;
  unsigned short* W4ph = (unsigned short*)(ws + o); o += 8192;
  unsigned short* W4pl = (unsigned short*)(ws + o); o += 8192;
  unsigned short* W2h  = (unsigned short*)(ws + o); o += 8192;
  unsigned short* W2l  = (unsigned short*)(ws + o); o += 8192;
  unsigned short* W3h  = (unsigned short*)(ws + o); o += 2048;
  unsigned short* W3l  = (unsigned short*)(ws + o); o += 2048;
  unsigned short* W5h  = (unsigned short*)(ws + o); o += 8192;
  unsigned short* W5l  = (unsigned short*)(ws + o); o += 8192;
  unsigned short* W6h  = (unsigned short*)(ws + o); o += 2048;
  unsigned short* W6l  = (unsigned short*)(ws + o); o += 2048;
  float* gpart = ws + o; o += 64 * 54;
  // overlays on dead buffers:
  unsigned short* x12h = (unsigned short*)bufC;
  unsigned short* x12l = (unsigned short*)x0;
  unsigned short* h11h = (unsigned short*)bufA;
  unsigned short* h11l = (unsigned short*)bufB;
  unsigned short* aggh = (unsigned short*)h11;
  unsigned short* aggl = (unsigned short*)h11 + (size_t)RN * 256;

  float* S0 = stats;          // 64 (fc)
  float* S1 = stats + 128;    // 256 (edge1)
  float* S2 = stats + 640;    // 64  (W2)
  float* S3 = stats + 768;    // 64  (W3)
  float* S4 = stats + 896;    // 256 (edge2)
  float* S5 = stats + 1408;   // 64  (W5)
  float* S6 = stats + 1536;   // 64  (W6)
  float* S7 = stats + 1664;   // 1024 (W10)
  float* S8 = stats + 3712;   // 512 (W11)
  float* S9 = stats + 4736;   // 256 (W12)
  float* Sd = stats + 5248;   // dummy sink (512)

  hipMemsetAsync(stats, 0, 8192 * sizeof(float), stream);

  prepgram_kernel<<<64, 256, 0, stream>>>(data, pack, gpart);
  fcstats_kernel<<<1, 64, 0, stream>>>(gpart, W_fc, b_fc, S0);

  // MEGA: knn (4096 blocks) + fc_bnpack (4096) + megaprep (1632)
  mega_kernel<<<9824, 256, 0, stream>>>(
      pack, idx, data, W_fc, b_fc, S0, xbh, xbl,
      W1, W4, W2, W3, W5, W6, W10, W11, W12,
      W1mh, W1ml, W1bt, W4mh, W4ml,
      W1ph, W1pl, W4ph, W4pl, W2h, W2l, W3h, W3l, W5h, W5l, W6h, W6l,
      W10h, W10l, W11xh, W11xl, W12h, W12l);

  // edge conv 1: basemat = x0 @ (W1top-W1mid) via MFMA (row-major bf16 A)
  gemm_mfma_kernel<1, false, false><<<dim3(64, 4), 256, 0, stream>>>(
      xbh, xbl, W1ph, W1pl, bufB, nullptr, Sd, nullptr, 64, 256);
  edge_mfma_kernel<true><<<1024, 256, 0, stream>>>(xbh, xbl, idx, pack, W1mh, W1ml, W1bt, bufB, bufA, S1);

  // graph conv 1
  agg_pack_kernel<8><<<4096, 256, 0, stream>>>(bufA, idx, S1, 1.0f / (RN * 16), aggh, aggl);
  gemm_mfma_kernel<0, false, false><<<dim3(64, 1), 256, 0, stream>>>(
      aggh, aggl, W2h, W2l, bufC, nullptr, S2, nullptr, 256, 64);

  // graph conv 2
  agg_pack_kernel<6><<<1024, 256, 0, stream>>>(bufC, idx, S2, 1.0f / RN, aggh, aggl);
  gemm_mfma_kernel<0, false, false><<<dim3(64, 1), 256, 0, stream>>>(
      aggh, aggl, W3h, W3l, x1v, nullptr, S3, nullptr, 64, 64);
  bn_normpack_kernel<<<RN * 64 / 256, 256, 0, stream>>>(x1v, S3, xbh, xbl);

  // edge conv 2 (no pts)
  gemm_mfma_kernel<1, false, false><<<dim3(64, 4), 256, 0, stream>>>(
      xbh, xbl, W4ph, W4pl, bufB, nullptr, Sd, nullptr, 64, 256);
  edge_mfma_kernel<false><<<1024, 256, 0, stream>>>(xbh, xbl, idx, pack, W4mh, W4ml, nullptr, bufB, bufA, S4);

  // graph conv 3
  agg_pack_kernel<8><<<4096, 256, 0, stream>>>(bufA, idx, S4, 1.0f / (RN * 16), aggh, aggl);
  gemm_mfma_kernel<0, false, false><<<dim3(64, 1), 256, 0, stream>>>(
      aggh, aggl, W5h, W5l, bufC, nullptr, S5, nullptr, 256, 64);

  // graph conv 4 -> x2v raw (+S6); bn fused into pack_x12
  agg_pack_kernel<6><<<1024, 256, 0, stream>>>(bufC, idx, S5, 1.0f / RN, aggh, aggl);
  gemm_mfma_kernel<0, false, false><<<dim3(64, 1), 256, 0, stream>>>(
      aggh, aggl, W6h, W6l, x2v, nullptr, S6, nullptr, 64, 64);

  // pack [x1|bn(x2)]
  pack_x12_kernel<<<RN * 128 / 256, 256, 0, stream>>>(x1v, x2v, S6, x12h, x12l);

  // W10 path
  gemm_mfma_kernel<0, true, false><<<dim3(64, 16), 256, 0, stream>>>(
      x12h, x12l, W10h, W10l, nullptr, pmax, S7, nullptr, 128, 1024);
  fin_g_kernel<<<16, 256, 0, stream>>>(pmax, S7, gf);

  // W11 split: per-batch bias row (g @ W11[:1024]) + K=128 MFMA gemm
  gb11_kernel<<<8, 256, 0, stream>>>(gf, W11, gb);
  gemm_mfma_kernel<0, false, true><<<dim3(64, 8), 256, 0, stream>>>(
      x12h, x12l, W11xh, W11xl, h11, nullptr, S8, gb, 128, 512);
  bn_pack_kernel<<<RN * 512 / 256, 256, 0, stream>>>(h11, S8, h11h, h11l);

  // W12 -> h12 raw (+S9); bn fused into final13
  gemm_mfma_kernel<0, false, false><<<dim3(64, 4), 256, 0, stream>>>(
      h11h, h11l, W12h, W12l, h12, nullptr, S9, nullptr, 512, 256);

  final13_kernel<<<RN / 16, 256, 0, stream>>>(h12, S9, W13, out);
}

// Round 12
// 557.894 us; speedup vs baseline: 4.3483x; 1.0722x over previous
//
#include <hip/hip_runtime.h>
#include <hip/hip_bf16.h>
#include <float.h>

static constexpr int BB  = 4;
static constexpr int NN  = 4096;
static constexpr int KSN = 16;
static constexpr int RN  = BB * NN;     // 16384 rows (b,n)
#define EPSBN 1e-5f

typedef __attribute__((ext_vector_type(8))) short short8;
typedef __attribute__((ext_vector_type(4))) short short4v;
typedef __attribute__((ext_vector_type(4))) float f32x4;

__device__ inline unsigned short f2bf(float f) {
  union { float f; unsigned u; } v; v.f = f;
  unsigned r = v.u + 0x7FFF + ((v.u >> 16) & 1);
  return (unsigned short)(r >> 16);
}
__device__ inline float bf2f(unsigned short h) {
  union { unsigned u; float f; } v; v.u = ((unsigned)h) << 16; return v.f;
}

// ---------------------------------------------------------------------------
// prep + gram fused (validated r10/r11).
// ---------------------------------------------------------------------------
__global__ __launch_bounds__(256) void prepgram_kernel(const float* __restrict__ data,
                                                       float4* __restrict__ pack,
                                                       float* __restrict__ partials) {
  const int t = blockIdx.x * 256 + threadIdx.x;   // RN
  const int lane = threadIdx.x & 63, wave = threadIdx.x >> 6;
  __shared__ float red[4][54];
  float d[9];
#pragma unroll
  for (int k = 0; k < 9; ++k) d[k] = data[(size_t)t * 9 + k];
  pack[t] = make_float4(d[0], d[1], d[2], fmaf(d[2], d[2], fmaf(d[1], d[1], d[0] * d[0])));
  int p = 0;
#pragma unroll
  for (int i = 0; i < 9; ++i) {
    float v = d[i];
#pragma unroll
    for (int mv = 1; mv < 64; mv <<= 1) v += __shfl_xor(v, mv);
    if (lane == 0) red[wave][p] = v;
    ++p;
  }
#pragma unroll
  for (int i = 0; i < 9; ++i)
#pragma unroll
    for (int j = i; j < 9; ++j) {
      float v = d[i] * d[j];
#pragma unroll
      for (int mv = 1; mv < 64; mv <<= 1) v += __shfl_xor(v, mv);
      if (lane == 0) red[wave][p] = v;
      ++p;
    }
  __syncthreads();
  if (threadIdx.x < 54)
    partials[blockIdx.x * 54 + threadIdx.x] =
        red[0][threadIdx.x] + red[1][threadIdx.x] + red[2][threadIdx.x] + red[3][threadIdx.x];
}

__global__ void fcstats_kernel(const float* __restrict__ partials,
                               const float* __restrict__ W, const float* __restrict__ bias,
                               float* __restrict__ S0) {
  __shared__ float g[54];
  const int t = threadIdx.x;   // 64 threads
  if (t < 54) {
    float s = 0.f;
    for (int b = 0; b < 64; ++b) s += partials[b * 54 + t];
    g[t] = s;
  }
  __syncthreads();
  float w[9];
#pragma unroll
  for (int k = 0; k < 9; ++k) w[k] = W[k * 64 + t];
  float b = bias[t];
  float dotw = 0.f;
#pragma unroll
  for (int k = 0; k < 9; ++k) dotw = fmaf(g[k], w[k], dotw);
  float s2 = 0.f;
  int p = 9;
#pragma unroll
  for (int i = 0; i < 9; ++i)
#pragma unroll
    for (int j = i; j < 9; ++j) {
      float gij = g[p++];
      s2 = fmaf(gij * ((i == j) ? 1.f : 2.f), w[i] * w[j], s2);
    }
  s2 += 2.f * b * dotw + (float)RN * b * b;
  S0[t] = dotw + (float)RN * b;
  S0[64 + t] = s2;
}

// ---------------------------------------------------------------------------
// weight-pack helpers.
// ---------------------------------------------------------------------------
__device__ inline void wpack_one(const float* __restrict__ W, unsigned short* __restrict__ wh,
                                 unsigned short* __restrict__ wl, int t, int lgC, int NK) {
  int k = t >> lgC, c = t & ((1 << lgC) - 1);
  float v = W[t];
  int ct = c >> 4, cl = c & 15, ks = k >> 5, kl = k & 31;
  int dst = ((ct * NK + ks) * 64 + (((kl >> 3) << 4) | cl)) * 8 + (kl & 7);
  unsigned short h = f2bf(v);
  wh[dst] = h; wl[dst] = f2bf(v - bf2f(h));
}
__device__ inline void diffpack_one(const float* __restrict__ W, unsigned short* __restrict__ wh,
                                    unsigned short* __restrict__ wl, int t) {
  int k = t >> 8, cc = t & 255;
  float v = W[k * 256 + cc] - W[(64 + k) * 256 + cc];  // Wtop - Wmid
  int ct = cc >> 4, cl = cc & 15, ks = k >> 5, kl = k & 31;
  int dst = ((ct * 2 + ks) * 64 + (((kl >> 3) << 4) | cl)) * 8 + (kl & 7);
  unsigned short h = f2bf(v);
  wh[dst] = h; wl[dst] = f2bf(v - bf2f(h));
}

// ---------------------------------------------------------------------------
// MEGA kernel (validated r11): knn + fc_bnpack + megaprep.
// ---------------------------------------------------------------------------
__global__ __launch_bounds__(256) void mega_kernel(
    const float4* __restrict__ pack, int* __restrict__ idx,
    const float* __restrict__ data, const float* __restrict__ W_fc,
    const float* __restrict__ b_fc, const float* __restrict__ S0,
    unsigned short* __restrict__ xbh, unsigned short* __restrict__ xbl,
    const float* __restrict__ W1, const float* __restrict__ W4,
    const float* __restrict__ W2, const float* __restrict__ W3,
    const float* __restrict__ W5, const float* __restrict__ W6,
    const float* __restrict__ W10, const float* __restrict__ W11, const float* __restrict__ W12,
    unsigned short* __restrict__ W1mh, unsigned short* __restrict__ W1ml, float4* __restrict__ W1bt,
    unsigned short* __restrict__ W4mh, unsigned short* __restrict__ W4ml,
    unsigned short* __restrict__ W1ph, unsigned short* __restrict__ W1pl,
    unsigned short* __restrict__ W4ph, unsigned short* __restrict__ W4pl,
    unsigned short* __restrict__ W2h, unsigned short* __restrict__ W2l,
    unsigned short* __restrict__ W3h, unsigned short* __restrict__ W3l,
    unsigned short* __restrict__ W5h, unsigned short* __restrict__ W5l,
    unsigned short* __restrict__ W6h, unsigned short* __restrict__ W6l,
    unsigned short* __restrict__ W10h, unsigned short* __restrict__ W10l,
    unsigned short* __restrict__ W11xh, unsigned short* __restrict__ W11xl,
    unsigned short* __restrict__ W12h, unsigned short* __restrict__ W12l) {
  const int blk = blockIdx.x;
  if (blk < 4096) {
    // ------------------------------ KNN ------------------------------
    const int lane = threadIdx.x & 63;
    const int p = blk * 4 + (threadIdx.x >> 6);
    const int b = p >> 12;
    const float4* __restrict__ pb = pack + ((size_t)b << 12);
    const float4 me = pack[p];
    unsigned long long m0 = ~0ull, m1 = ~0ull, m2 = ~0ull, m3 = ~0ull;
#pragma unroll 8
    for (int s = 0; s < 64; ++s) {
      const float4 q = pb[s * 64 + lane];
      float d = me.w + q.w - 2.0f * fmaf(me.x, q.x, fmaf(me.y, q.y, me.z * q.z));
      unsigned ub = __float_as_uint(d);
      ub = (ub & 0x80000000u) ? ~ub : (ub | 0x80000000u);
      unsigned long long k = ((unsigned long long)ub << 12) | (unsigned)(s * 64 + lane);
      if (k < m3) {
        bool l0 = k < m0;  unsigned long long t0 = l0 ? m0 : k;  m0 = l0 ? k : m0;
        bool l1 = t0 < m1; unsigned long long t1 = l1 ? m1 : t0; m1 = l1 ? t0 : m1;
        bool l2 = t1 < m2; unsigned long long t2 = l2 ? m2 : t1; m2 = l2 ? t1 : m2;
        m3 = (t2 < m3) ? t2 : m3;
      }
    }
    for (int pass = 0; pass < 16; ++pass) {
      unsigned d0 = (unsigned)(m0 >> 12);
      unsigned w32 = d0;
#pragma unroll
      for (int mv = 1; mv < 64; mv <<= 1) {
        unsigned o = __shfl_xor(w32, mv);
        w32 = (o < w32) ? o : w32;
      }
      unsigned long long ball = __ballot(d0 == w32);
      unsigned widx;
      if (__popcll(ball) == 1) {
        widx = __shfl((unsigned)(m0 & 0xFFFull), (int)(__ffsll((long long)ball) - 1));
      } else {
        unsigned cand = (d0 == w32) ? (unsigned)(m0 & 0xFFFull) : 0xFFFFFFFFu;
#pragma unroll
        for (int mv = 1; mv < 64; mv <<= 1) {
          unsigned o = __shfl_xor(cand, mv);
          cand = (o < cand) ? o : cand;
        }
        widx = cand;
      }
      const unsigned long long w = ((unsigned long long)w32 << 12) | widx;
      if (lane == pass) idx[(p << 4) + pass] = (int)widx;
      if (m0 == w) { m0 = m1; m1 = m2; m2 = m3; m3 = ~0ull; }
      if (pass < 15 && __any(m0 == ~0ull)) {
        if (m0 == ~0ull) {                    // rare: rebuild from global
          m1 = ~0ull; m2 = ~0ull; m3 = ~0ull;
#pragma unroll 8
          for (int s = 0; s < 64; ++s) {
            const float4 q = pb[s * 64 + lane];
            float d = me.w + q.w - 2.0f * fmaf(me.x, q.x, fmaf(me.y, q.y, me.z * q.z));
            unsigned ub = __float_as_uint(d);
            ub = (ub & 0x80000000u) ? ~ub : (ub | 0x80000000u);
            unsigned long long k = ((unsigned long long)ub << 12) | (unsigned)(s * 64 + lane);
            k = (k > w) ? k : ~0ull;          // exclude consumed
            if (k < m3) {
              bool l0 = k < m0;  unsigned long long t0 = l0 ? m0 : k;  m0 = l0 ? k : m0;
              bool l1 = t0 < m1; unsigned long long t1 = l1 ? m1 : t0; m1 = l1 ? t0 : m1;
              bool l2 = t1 < m2; unsigned long long t2 = l2 ? m2 : t1; m2 = l2 ? t1 : m2;
              m3 = (t2 < m3) ? t2 : m3;
            }
          }
        }
      }
    }
  } else if (blk < 8192) {
    // --------------------------- fc + BN + pack ---------------------------
    const int t = (blk - 4096) * 256 + threadIdx.x;   // RN*64
    const int r = t >> 6, c = t & 63;
    const float* dr = data + (size_t)r * 9;
    float acc = b_fc[c];
#pragma unroll
    for (int k = 0; k < 9; ++k) acc = fmaf(dr[k], W_fc[k * 64 + c], acc);
    const float inv = 1.0f / RN;
    float m = S0[c] * inv;
    float v = fmaxf(S0[64 + c] * inv - m * m, 0.0f);
    float x = fmaxf((acc - m) * rsqrtf(v + EPSBN), 0.0f);
    unsigned short h = f2bf(x);
    xbh[t] = h; xbl[t] = f2bf(x - bf2f(h));
  } else {
    // ------------------------------ megaprep ------------------------------
    const int mb = blk - 8192;
    if (mb < 64) {
      int t = mb * 256 + threadIdx.x;
      int k = t >> 8, cc = t & 255;
      float w1mid = W1[(64 + k) * 256 + cc];
      unsigned short h1 = f2bf(w1mid);
      W1mh[cc * 64 + k] = h1;
      W1ml[cc * 64 + k] = f2bf(w1mid - bf2f(h1));
      float w4mid = W4[(64 + k) * 256 + cc];
      unsigned short h4 = f2bf(w4mid);
      W4mh[cc * 64 + k] = h4;
      W4ml[cc * 64 + k] = f2bf(w4mid - bf2f(h4));
      if (t < 256) W1bt[t] = make_float4(W1[128 * 256 + t], W1[129 * 256 + t], W1[130 * 256 + t], 0.f);
    } else if (mb < 128) {
      diffpack_one(W1, W1ph, W1pl, (mb - 64) * 256 + threadIdx.x);
    } else if (mb < 192) {
      diffpack_one(W4, W4ph, W4pl, (mb - 128) * 256 + threadIdx.x);
    } else if (mb < 256) {
      wpack_one(W2, W2h, W2l, (mb - 192) * 256 + threadIdx.x, 6, 8);
    } else if (mb < 272) {
      wpack_one(W3, W3h, W3l, (mb - 256) * 256 + threadIdx.x, 6, 2);
    } else if (mb < 336) {
      wpack_one(W5, W5h, W5l, (mb - 272) * 256 + threadIdx.x, 6, 8);
    } else if (mb < 352) {
      wpack_one(W6, W6h, W6l, (mb - 336) * 256 + threadIdx.x, 6, 2);
    } else if (mb < 864) {
      wpack_one(W10, W10h, W10l, (mb - 352) * 256 + threadIdx.x, 10, 4);
    } else if (mb < 1120) {
      wpack_one(W11 + 1024 * 512, W11xh, W11xl, (mb - 864) * 256 + threadIdx.x, 9, 4);
    } else {
      wpack_one(W12, W12h, W12l, (mb - 1120) * 256 + threadIdx.x, 8, 16);
    }
  }
}

// [x1|bn(x2)] -> fragment-major hi/lo pack (K=128) (validated r10/r11).
__global__ void pack_x12_kernel(const float* __restrict__ x1, const float* __restrict__ x2,
                                const float* __restrict__ S6,
                                unsigned short* __restrict__ ph, unsigned short* __restrict__ pl) {
  int t = blockIdx.x * 256 + threadIdx.x;   // RN*128
  int r = t >> 7, k = t & 127;
  float v;
  if (k < 64) {
    v = x1[(size_t)r * 64 + k];
  } else {
    int c = k - 64;
    const float inv = 1.0f / RN;
    float m = S6[c] * inv;
    float var = fmaxf(S6[64 + c] * inv - m * m, 0.f);
    v = fmaxf((x2[(size_t)r * 64 + c] - m) * rsqrtf(var + EPSBN), 0.f);
  }
  int rt = r >> 4, rl = r & 15, ks = k >> 5, kl = k & 31;
  int dst = ((rt * 4 + ks) * 64 + (((kl >> 3) << 4) | rl)) * 8 + (kl & 7);
  unsigned short h = f2bf(v);
  ph[dst] = h; pl[dst] = f2bf(v - bf2f(h));
}

// BN+ReLU on h11 (C=512) fused with fragment-major hi/lo pack
__global__ void bn_pack_kernel(const float* __restrict__ buf, const float* __restrict__ stats,
                               unsigned short* __restrict__ ph, unsigned short* __restrict__ pl) {
  int t = blockIdx.x * 256 + threadIdx.x;   // RN*512
  int c = t & 511, r = t >> 9;
  const float inv = 1.0f / RN;
  float m = stats[c] * inv;
  float v = fmaxf(stats[512 + c] * inv - m * m, 0.0f);
  float x = fmaxf((buf[t] - m) * rsqrtf(v + EPSBN), 0.0f);
  int rt = r >> 4, rl = r & 15, ks = c >> 5, kl = c & 31;
  int dst = ((rt * 16 + ks) * 64 + (((kl >> 3) << 4) | rl)) * 8 + (kl & 7);
  unsigned short h = f2bf(x);
  ph[dst] = h; pl[dst] = f2bf(x - bf2f(h));
}

// BN+ReLU in place (C=64) fused with row-major hi/lo write (x1v)
__global__ void bn_normpack_kernel(float* __restrict__ buf, const float* __restrict__ stats,
                                   unsigned short* __restrict__ hi, unsigned short* __restrict__ lo) {
  int t = blockIdx.x * 256 + threadIdx.x;   // RN*64
  int c = t & 63;
  const float inv = 1.0f / RN;
  float m = stats[c] * inv;
  float v = fmaxf(stats[64 + c] * inv - m * m, 0.0f);
  float x = fmaxf((buf[t] - m) * rsqrtf(v + EPSBN), 0.0f);
  buf[t] = x;
  unsigned short h = f2bf(x);
  hi[t] = h; lo[t] = f2bf(x - bf2f(h));
}

// ---------------------------------------------------------------------------
// Edge conv via MFMA, now with IN-KERNEL basemat: the wave computes its own
// 16x64 base tile base = x[p0..p15] @ Wp (24 MFMAs, K=64) from the same
// row-major xbh/xbl, then broadcasts bb per point via __shfl (static reg
// index: point loop split g x unrolled-i). Deferred-stats epilogue (r10).
// ---------------------------------------------------------------------------
template <bool HAS_PTS>
__global__ __launch_bounds__(256) void edge_mfma_kernel(
    const unsigned short* __restrict__ Xh, const unsigned short* __restrict__ Xl,
    const int* __restrict__ idx,
    const float4* __restrict__ pack,
    const unsigned short* __restrict__ Wmh, const unsigned short* __restrict__ Wml,
    const unsigned short* __restrict__ Wph, const unsigned short* __restrict__ Wpl,
    const float4* __restrict__ Wbt,
    float* __restrict__ out, float* __restrict__ stats) {
  const int wave = threadIdx.x >> 6;
  const int lane = threadIdx.x & 63;
  const int pg   = blockIdx.x;
  const int c0   = wave << 6;
  const int cl   = lane & 15;
  const int kg   = (lane >> 4) << 3;
  const int bat  = pg >> 8;
  const int pbase = bat << 12;
  const int ib   = pg << 8;

  short8 bh[4][2], blo[4][2];
#pragma unroll
  for (int q = 0; q < 4; ++q) {
    const unsigned short* wp = Wmh + (size_t)(c0 + q * 16 + cl) * 64 + kg;
    bh[q][0] = *(const short8*)wp; bh[q][1] = *(const short8*)(wp + 32);
    const unsigned short* wq = Wml + (size_t)(c0 + q * 16 + cl) * 64 + kg;
    blo[q][0] = *(const short8*)wq; blo[q][1] = *(const short8*)(wq + 32);
  }
  float4 wb[4];
  if (HAS_PTS) {
#pragma unroll
    for (int q = 0; q < 4; ++q) wb[q] = Wbt[c0 + q * 16 + cl];
  }

  // ---- in-kernel basemat: base[q] = x[p0+..] @ Wp quadrant q (K=64) ----
  f32x4 base[4];
  {
    const size_t xoff = ((size_t)((pg << 4) + cl)) * 64 + kg;   // row = own point
    short8 xa0h = *(const short8*)(Xh + xoff);
    short8 xa1h = *(const short8*)(Xh + xoff + 32);
    short8 xa0l = *(const short8*)(Xl + xoff);
    short8 xa1l = *(const short8*)(Xl + xoff + 32);
#pragma unroll
    for (int q = 0; q < 4; ++q) {
      base[q][0] = 0.f; base[q][1] = 0.f; base[q][2] = 0.f; base[q][3] = 0.f;
      const int ct = wave * 4 + q;
      const size_t w0 = (((size_t)ct * 2 + 0) * 64 + lane) * 8;
      const size_t w1 = (((size_t)ct * 2 + 1) * 64 + lane) * 8;
      short8 p0h = *(const short8*)(Wph + w0);
      short8 p0l = *(const short8*)(Wpl + w0);
      short8 p1h = *(const short8*)(Wph + w1);
      short8 p1l = *(const short8*)(Wpl + w1);
      base[q] = __builtin_amdgcn_mfma_f32_16x16x32_bf16(xa0l, p0h, base[q], 0, 0, 0);
      base[q] = __builtin_amdgcn_mfma_f32_16x16x32_bf16(xa0h, p0l, base[q], 0, 0, 0);
      base[q] = __builtin_amdgcn_mfma_f32_16x16x32_bf16(xa0h, p0h, base[q], 0, 0, 0);
      base[q] = __builtin_amdgcn_mfma_f32_16x16x32_bf16(xa1l, p1h, base[q], 0, 0, 0);
      base[q] = __builtin_amdgcn_mfma_f32_16x16x32_bf16(xa1h, p1l, base[q], 0, 0, 0);
      base[q] = __builtin_amdgcn_mfma_f32_16x16x32_bf16(xa1h, p1h, base[q], 0, 0, 0);
    }
  }

  float P1[4] = {0.f, 0.f, 0.f, 0.f}, P2[4] = {0.f, 0.f, 0.f, 0.f};
  float PCx[4] = {0.f, 0.f, 0.f, 0.f};
  float PB1[4] = {0.f, 0.f, 0.f, 0.f}, PB2[4] = {0.f, 0.f, 0.f, 0.f};

  int jn = idx[ib + 16 + cl];
  int j0 = idx[ib + cl];
  size_t ro = ((size_t)(pbase | j0) << 6) + kg;
  short8 a0h = *(const short8*)(Xh + ro);
  short8 a1h = *(const short8*)(Xh + ro + 32);
  short8 a0l = *(const short8*)(Xl + ro);
  short8 a1l = *(const short8*)(Xl + ro + 32);

  for (int g = 0; g < 4; ++g) {
#pragma unroll
    for (int i = 0; i < 4; ++i) {
      const int pp = g * 4 + i;
      const int p = (pg << 4) | pp;
      int jf = 0;
      if (pp < 14) jf = idx[ib + ((pp + 2) << 4) + cl];
      short8 n0h, n1h, n0l, n1l;
      if (pp < 15) {
        size_t rn = ((size_t)(pbase | jn) << 6) + kg;
        n0h = *(const short8*)(Xh + rn);
        n1h = *(const short8*)(Xh + rn + 32);
        n0l = *(const short8*)(Xl + rn);
        n1l = *(const short8*)(Xl + rn + 32);
      }
      float dx0, dy0, dz0, dx1, dy1, dz1, dx2, dy2, dz2, dx3, dy3, dz3;
      if (HAS_PTS) {
        const int4 j4 = *(const int4*)(idx + (p << 4) + ((lane >> 4) << 2));
        const float4 pc = pack[p];
        const float4 q0 = pack[pbase | j4.x];
        const float4 q1 = pack[pbase | j4.y];
        const float4 q2 = pack[pbase | j4.z];
        const float4 q3 = pack[pbase | j4.w];
        dx0 = q0.x - pc.x; dy0 = q0.y - pc.y; dz0 = q0.z - pc.z;
        dx1 = q1.x - pc.x; dy1 = q1.y - pc.y; dz1 = q1.z - pc.z;
        dx2 = q2.x - pc.x; dy2 = q2.y - pc.y; dz2 = q2.z - pc.z;
        dx3 = q3.x - pc.x; dy3 = q3.y - pc.y; dz3 = q3.z - pc.z;
      }
      f32x4 acc[4];
#pragma unroll
      for (int q = 0; q < 4; ++q) {
        acc[q][0] = 0.f; acc[q][1] = 0.f; acc[q][2] = 0.f; acc[q][3] = 0.f;
      }
#pragma unroll
      for (int q = 0; q < 4; ++q) {
        acc[q] = __builtin_amdgcn_mfma_f32_16x16x32_bf16(a0l, bh[q][0], acc[q], 0, 0, 0);
        acc[q] = __builtin_amdgcn_mfma_f32_16x16x32_bf16(a1l, bh[q][1], acc[q], 0, 0, 0);
        acc[q] = __builtin_amdgcn_mfma_f32_16x16x32_bf16(a0h, blo[q][0], acc[q], 0, 0, 0);
        acc[q] = __builtin_amdgcn_mfma_f32_16x16x32_bf16(a1h, blo[q][1], acc[q], 0, 0, 0);
        acc[q] = __builtin_amdgcn_mfma_f32_16x16x32_bf16(a0h, bh[q][0], acc[q], 0, 0, 0);
        acc[q] = __builtin_amdgcn_mfma_f32_16x16x32_bf16(a1h, bh[q][1], acc[q], 0, 0, 0);
      }
      if (HAS_PTS) {
#pragma unroll
        for (int q = 0; q < 4; ++q) {
          acc[q][0] += dx0 * wb[q].x + dy0 * wb[q].y + dz0 * wb[q].z;
          acc[q][1] += dx1 * wb[q].x + dy1 * wb[q].y + dz1 * wb[q].z;
          acc[q][2] += dx2 * wb[q].x + dy2 * wb[q].y + dz2 * wb[q].z;
          acc[q][3] += dx3 * wb[q].x + dy3 * wb[q].y + dz3 * wb[q].z;
        }
      }
#pragma unroll
      for (int q = 0; q < 4; ++q) {
        float s1p = acc[q][0] + acc[q][1] + acc[q][2] + acc[q][3];
        float s2p = acc[q][0] * acc[q][0] + acc[q][1] * acc[q][1]
                  + acc[q][2] * acc[q][2] + acc[q][3] * acc[q][3];
        float mx = fmaxf(fmaxf(acc[q][0], acc[q][1]), fmaxf(acc[q][2], acc[q][3]));
        mx = fmaxf(mx, __shfl_xor(mx, 16));
        mx = fmaxf(mx, __shfl_xor(mx, 32));
        // bb = base[pp][cl] lives in lane ((pp>>2)<<4)|cl, register i (static)
        float bb = __shfl(base[q][i], (g << 4) | cl);
        if (lane < 16) out[(size_t)p * 256 + c0 + q * 16 + cl] = mx + bb;
        P1[q] += s1p;
        P2[q] += s2p;
        PCx[q] = fmaf(bb, s1p, PCx[q]);
        PB1[q] += bb;
        PB2[q] = fmaf(bb, bb, PB2[q]);
      }
      a0h = n0h; a1h = n1h; a0l = n0l; a1l = n1l;
      jn = jf;
    }
  }
#pragma unroll
  for (int q = 0; q < 4; ++q) {
    float p1 = P1[q]; p1 += __shfl_xor(p1, 16); p1 += __shfl_xor(p1, 32);
    float p2 = P2[q]; p2 += __shfl_xor(p2, 16); p2 += __shfl_xor(p2, 32);
    float pc = PCx[q]; pc += __shfl_xor(pc, 16); pc += __shfl_xor(pc, 32);
    if (lane < 16) {
      atomicAdd(&stats[c0 + q * 16 + lane], p1 + 16.f * PB1[q]);
      atomicAdd(&stats[256 + c0 + q * 16 + lane], p2 + 2.f * pc + 16.f * PB2[q]);
    }
  }
}

// ---------------------------------------------------------------------------
// agg_pack (validated r10/r11): bn_relu(max over 16 nb) -> packed hi/lo.
// ---------------------------------------------------------------------------
template <int LGC>
__global__ __launch_bounds__(256) void agg_pack_kernel(
    const float* __restrict__ X, const int* __restrict__ idx,
    const float* __restrict__ stats, float inv_cnt,
    unsigned short* __restrict__ ph, unsigned short* __restrict__ pl) {
  const int C = 1 << LGC;
  const int xcd = blockIdx.x & 7, bat = xcd >> 1;
  const int j = ((blockIdx.x >> 3) << 1) | (xcd & 1);
  const int rows_per_block = 256 >> (LGC - 2);
  const int r = bat * 4096 + j * rows_per_block + (threadIdx.x >> (LGC - 2));
  const int cq = threadIdx.x & ((C >> 2) - 1);
  const int base = bat << 12;
  const int* ip = idx + (size_t)r * KSN;
  float4 mx = make_float4(-FLT_MAX, -FLT_MAX, -FLT_MAX, -FLT_MAX);
#pragma unroll
  for (int k = 0; k < KSN; ++k) {
    int jj = ip[k];
    const float4 v = *reinterpret_cast<const float4*>(X + (size_t)(base + jj) * C + cq * 4);
    mx.x = fmaxf(mx.x, v.x); mx.y = fmaxf(mx.y, v.y);
    mx.z = fmaxf(mx.z, v.z); mx.w = fmaxf(mx.w, v.w);
  }
  const int c = cq * 4;
  const float4 sa = *reinterpret_cast<const float4*>(stats + c);
  const float4 sb = *reinterpret_cast<const float4*>(stats + C + c);
  float m0 = sa.x * inv_cnt, m1 = sa.y * inv_cnt, m2 = sa.z * inv_cnt, m3 = sa.w * inv_cnt;
  float o0 = fmaxf((mx.x - m0) * rsqrtf(fmaxf(sb.x * inv_cnt - m0 * m0, 0.f) + EPSBN), 0.f);
  float o1 = fmaxf((mx.y - m1) * rsqrtf(fmaxf(sb.y * inv_cnt - m1 * m1, 0.f) + EPSBN), 0.f);
  float o2 = fmaxf((mx.z - m2) * rsqrtf(fmaxf(sb.z * inv_cnt - m2 * m2, 0.f) + EPSBN), 0.f);
  float o3 = fmaxf((mx.w - m3) * rsqrtf(fmaxf(sb.w * inv_cnt - m3 * m3, 0.f) + EPSBN), 0.f);
  short4v H, L;
  H.x = (short)f2bf(o0); L.x = (short)f2bf(o0 - bf2f((unsigned short)H.x));
  H.y = (short)f2bf(o1); L.y = (short)f2bf(o1 - bf2f((unsigned short)H.y));
  H.z = (short)f2bf(o2); L.z = (short)f2bf(o2 - bf2f((unsigned short)H.z));
  H.w = (short)f2bf(o3); L.w = (short)f2bf(o3 - bf2f((unsigned short)H.w));
  const int NK = C >> 5;
  const int rt = r >> 4, rl = r & 15, ks = c >> 5, kl = c & 31;
  const size_t dst = (((size_t)rt * NK + ks) * 64 + (((kl >> 3) << 4) | rl)) * 8 + (kl & 7);
  *(short4v*)(ph + dst) = H;
  *(short4v*)(pl + dst) = L;
}

// ---------------------------------------------------------------------------
// MFMA GEMM (validated r7-11): wave = 64 rows x 64 cols, acc[4][4].
// ---------------------------------------------------------------------------
template <int AMODE, bool DOMAX, bool BIAS>
__global__ __launch_bounds__(256) void gemm_mfma_kernel(
    const unsigned short* __restrict__ Ah, const unsigned short* __restrict__ Al,
    const unsigned short* __restrict__ Wh, const unsigned short* __restrict__ Wl,
    float* __restrict__ Y, float* __restrict__ pmax, float* __restrict__ stats,
    const float* __restrict__ gbias,
    int K, int C) {
  __shared__ float red1[4][64], red2[4][64], redm[4][64];
  const int wave = threadIdx.x >> 6, lane = threadIdx.x & 63;
  const int rtb = blockIdx.x * 16 + wave * 4;
  const int c0  = blockIdx.y * 64;
  const int ct0 = blockIdx.y * 4;
  const int NK  = K >> 5;
  const int bat = blockIdx.x >> 4;
  f32x4 acc[4][4];
#pragma unroll
  for (int r = 0; r < 4; ++r)
#pragma unroll
    for (int cc = 0; cc < 4; ++cc) {
      acc[r][cc][0] = 0.f; acc[r][cc][1] = 0.f; acc[r][cc][2] = 0.f; acc[r][cc][3] = 0.f;
    }
  const int lhalf = (lane >> 4) << 3;
  for (int ks = 0; ks < NK; ++ks) {
    short8 ah[4], al[4];
    if (AMODE == 1) {
#pragma unroll
      for (int r = 0; r < 4; ++r) {
        const size_t aoff = ((size_t)((rtb + r) * 16 + (lane & 15))) * 64 + ks * 32 + lhalf;
        ah[r] = *(const short8*)(Ah + aoff);
        al[r] = *(const short8*)(Al + aoff);
      }
    } else {
#pragma unroll
      for (int r = 0; r < 4; ++r) {
        const size_t aoff = (((size_t)(rtb + r) * NK + ks) * 64 + lane) * 8;
        ah[r] = *(const short8*)(Ah + aoff);
        al[r] = *(const short8*)(Al + aoff);
      }
    }
#pragma unroll
    for (int cc = 0; cc < 4; ++cc) {
      const size_t woff = (((size_t)(ct0 + cc) * NK + ks) * 64 + lane) * 8;
      short8 bh = *(const short8*)(Wh + woff);
      short8 bl = *(const short8*)(Wl + woff);
#pragma unroll
      for (int r = 0; r < 4; ++r) {
        acc[r][cc] = __builtin_amdgcn_mfma_f32_16x16x32_bf16(al[r], bh, acc[r][cc], 0, 0, 0);
        acc[r][cc] = __builtin_amdgcn_mfma_f32_16x16x32_bf16(ah[r], bl, acc[r][cc], 0, 0, 0);
        acc[r][cc] = __builtin_amdgcn_mfma_f32_16x16x32_bf16(ah[r], bh, acc[r][cc], 0, 0, 0);
      }
    }
  }
#pragma unroll
  for (int cc = 0; cc < 4; ++cc) {
    float bv = 0.f;
    if (BIAS) bv = gbias[(size_t)bat * C + c0 + cc * 16 + (lane & 15)];
    float s1 = 0.f, s2 = 0.f, mm = -FLT_MAX;
#pragma unroll
    for (int r = 0; r < 4; ++r) {
#pragma unroll
      for (int i = 0; i < 4; ++i) {
        float v = acc[r][cc][i] + bv;
        if (!DOMAX)
          Y[(size_t)((rtb + r) * 16 + ((lane >> 4) << 2) + i) * C + c0 + cc * 16 + (lane & 15)] = v;
        s1 += v; s2 = fmaf(v, v, s2); mm = fmaxf(mm, v);
      }
    }
    s1 += __shfl_xor(s1, 16); s1 += __shfl_xor(s1, 32);
    s2 += __shfl_xor(s2, 16); s2 += __shfl_xor(s2, 32);
    mm = fmaxf(mm, __shfl_xor(mm, 16)); mm = fmaxf(mm, __shfl_xor(mm, 32));
    if (lane < 16) {
      red1[wave][cc * 16 + lane] = s1;
      red2[wave][cc * 16 + lane] = s2;
      if (DOMAX) redm[wave][cc * 16 + lane] = mm;
    }
  }
  __syncthreads();
  if (threadIdx.x < 64) {
    const int t = threadIdx.x;
    float a = red1[0][t] + red1[1][t] + red1[2][t] + red1[3][t];
    float b = red2[0][t] + red2[1][t] + red2[2][t] + red2[3][t];
    atomicAdd(&stats[c0 + t], a);
    atomicAdd(&stats[C + c0 + t], b);
    if (DOMAX) {
      float mm = fmaxf(fmaxf(redm[0][t], redm[1][t]), fmaxf(redm[2][t], redm[3][t]));
      pmax[(size_t)blockIdx.x * C + c0 + t] = mm;
    }
  }
}

// ---------------------------------------------------------------------------
// fin_g + gb11 fused: 8 blocks (batch b = blk>>1, col-half ch = blk&1).
// Phase 1: g[b,0:1024] into LDS (bn_relu of 16-block pmax max).
// Phase 2: gb[b,c] = g . W11[0:1024, c] for 256 cols.
// ---------------------------------------------------------------------------
__global__ __launch_bounds__(256) void fing_gb_kernel(const float* __restrict__ pmax,
                                                      const float* __restrict__ S7,
                                                      const float* __restrict__ W11,
                                                      float* __restrict__ gb) {
  __shared__ float g_lds[1024];
  const int t = threadIdx.x;
  const int b = blockIdx.x >> 1, ch = blockIdx.x & 1;
  const float inv = 1.0f / 16384.0f;
#pragma unroll
  for (int kk = 0; kk < 4; ++kk) {
    int c = kk * 256 + t;
    float m = S7[c] * inv;
    float v = fmaxf(S7[1024 + c] * inv - m * m, 0.0f);
    float rs = rsqrtf(v + EPSBN);
    float mx = -FLT_MAX;
    for (int s = 0; s < 16; ++s) mx = fmaxf(mx, pmax[(size_t)(b * 16 + s) * 1024 + c]);
    g_lds[c] = fmaxf((mx - m) * rs, 0.0f);
  }
  __syncthreads();
  const int c_out = ch * 256 + t;
  float acc = 0.f;
#pragma unroll 8
  for (int k = 0; k < 1024; ++k) acc = fmaf(g_lds[k], W11[(size_t)k * 512 + c_out], acc);
  gb[b * 512 + c_out] = acc;
}

// final13 with fused BN(h12) (validated r10/r11)
__global__ __launch_bounds__(256) void final13_kernel(const float* __restrict__ h,
                                                      const float* __restrict__ S9,
                                                      const float* __restrict__ W,
                                                      float* __restrict__ out) {
  __shared__ float wl[256 * 13];
  __shared__ float ms[256], rs[256];
  const int t = threadIdx.x;
  {
    const float inv = 1.0f / RN;
    float m = S9[t] * inv;
    float v = fmaxf(S9[256 + t] * inv - m * m, 0.0f);
    ms[t] = m; rs[t] = rsqrtf(v + EPSBN);
#pragma unroll
    for (int i = 0; i < 13; ++i) wl[t * 13 + i] = W[t * 13 + i];
  }
  __syncthreads();
  const int r = blockIdx.x * 16 + (t >> 4);
  const int c = t & 15;
  const int ci = (c < 13) ? c : 0;
  const float* hr = h + (size_t)r * 256;
  float acc = 0.0f;
  for (int k = 0; k < 256; ++k) {
    float x = fmaxf((hr[k] - ms[k]) * rs[k], 0.0f);
    acc = fmaf(x, wl[k * 13 + ci], acc);
  }
  if (c < 13) {
    int b = r >> 12, n = r & 4095;
    out[(size_t)b * 13 * NN + (size_t)c * NN + n] = acc;
  }
}

// ---------------------------------------------------------------------------
extern "C" void kernel_launch(void* const* d_in, const int* in_sizes, int n_in,
                              void* d_out, int out_size, void* d_ws, size_t ws_size,
                              hipStream_t stream) {
  (void)in_sizes; (void)n_in; (void)out_size; (void)ws_size;
  const float* data = (const float*)d_in[0];
  const float* W_fc = (const float*)d_in[1];
  const float* b_fc = (const float*)d_in[2];
  const float* W1   = (const float*)d_in[3];
  const float* W2   = (const float*)d_in[4];
  const float* W3   = (const float*)d_in[5];
  const float* W4   = (const float*)d_in[6];
  const float* W5   = (const float*)d_in[7];
  const float* W6   = (const float*)d_in[8];
  const float* W10  = (const float*)d_in[9];
  const float* W11  = (const float*)d_in[10];
  const float* W12  = (const float*)d_in[11];
  const float* W13  = (const float*)d_in[12];
  float* out = (float*)d_out;

  float* ws  = (float*)d_ws;
  int*   idx = (int*)d_ws;
  size_t o = 262144;
  float* x0   = ws + o; o += (size_t)RN * 64;     // dead fp32; hosts x12l overlay
  float* x1v  = ws + o; o += (size_t)RN * 64;
  float* x2v  = ws + o; o += (size_t)RN * 64;
  float* bufA = ws + o; o += (size_t)RN * 256;
  float* bufB = ws + o; o += (size_t)RN * 256;    // hosts h11l overlay
  float* bufC = ws + o; o += (size_t)RN * 64;
  float* pmax = ws + o; o += (size_t)64 * 1024;
  float* h11  = ws + o; o += (size_t)RN * 512;
  float* h12  = ws + o; o += (size_t)RN * 256;
  float* stats = ws + o; o += 8192;
  float4* pack = (float4*)(ws + o); o += (size_t)RN * 4;
  unsigned short* xbh = (unsigned short*)(ws + o); o += (size_t)RN * 32;
  unsigned short* xbl = (unsigned short*)(ws + o); o += (size_t)RN * 32;
  unsigned short* W1mh = (unsigned short*)(ws + o); o += 8192;
  unsigned short* W1ml = (unsigned short*)(ws + o); o += 8192;
  unsigned short* W4mh = (unsigned short*)(ws + o); o += 8192;
  unsigned short* W4ml = (unsigned short*)(ws + o); o += 8192;
  float4* W1bt = (float4*)(ws + o); o += 1024;
  unsigned short* W10h = (unsigned short*)(ws + o); o += 65536;
  unsigned short* W10l = (unsigned short*)(ws + o); o += 65536;
  unsigned short* W11xh = (unsigned short*)(ws + o); o += 32768;
  unsigned short* W11xl = (unsigned short*)(ws + o); o += 32768;
  unsigned short* W12h = (unsigned short*)(ws + o); o += 65536;
  unsigned short* W12l = (unsigned short*)(ws + o); o += 65536;
  float* gb = ws + o; o += 2048;
  unsigned short* W1ph = (unsigned short*)(ws + o); o += 8192;
  unsigned short* W1pl = (unsigned short*)(ws + o); o += 8192;
  unsigned short* W4ph = (unsigned short*)(ws + o); o += 8192;
  unsigned short* W4pl = (unsigned short*)(ws + o); o += 8192;
  unsigned short* W2h  = (unsigned short*)(ws + o); o += 8192;
  unsigned short* W2l  = (unsigned short*)(ws + o); o += 8192;
  unsigned short* W3h  = (unsigned short*)(ws + o); o += 2048;
  unsigned short* W3l  = (unsigned short*)(ws + o); o += 2048;
  unsigned short* W5h  = (unsigned short*)(ws + o); o += 8192;
  unsigned short* W5l  = (unsigned short*)(ws + o); o += 8192;
  unsigned short* W6h  = (unsigned short*)(ws + o); o += 2048;
  unsigned short* W6l  = (unsigned short*)(ws + o); o += 2048;
  float* gpart = ws + o; o += 64 * 54;
  // overlays on dead buffers:
  unsigned short* x12h = (unsigned short*)bufC;
  unsigned short* x12l = (unsigned short*)x0;
  unsigned short* h11h = (unsigned short*)bufA;
  unsigned short* h11l = (unsigned short*)bufB;
  unsigned short* aggh = (unsigned short*)h11;
  unsigned short* aggl = (unsigned short*)h11 + (size_t)RN * 256;

  float* S0 = stats;          // 64 (fc)
  float* S1 = stats + 128;    // 256 (edge1)
  float* S2 = stats + 640;    // 64  (W2)
  float* S3 = stats + 768;    // 64  (W3)
  float* S4 = stats + 896;    // 256 (edge2)
  float* S5 = stats + 1408;   // 64  (W5)
  float* S6 = stats + 1536;   // 64  (W6)
  float* S7 = stats + 1664;   // 1024 (W10)
  float* S8 = stats + 3712;   // 512 (W11)
  float* S9 = stats + 4736;   // 256 (W12)

  hipMemsetAsync(stats, 0, 8192 * sizeof(float), stream);

  prepgram_kernel<<<64, 256, 0, stream>>>(data, pack, gpart);
  fcstats_kernel<<<1, 64, 0, stream>>>(gpart, W_fc, b_fc, S0);

  // MEGA: knn (4096 blocks) + fc_bnpack (4096) + megaprep (1632)
  mega_kernel<<<9824, 256, 0, stream>>>(
      pack, idx, data, W_fc, b_fc, S0, xbh, xbl,
      W1, W4, W2, W3, W5, W6, W10, W11, W12,
      W1mh, W1ml, W1bt, W4mh, W4ml,
      W1ph, W1pl, W4ph, W4pl, W2h, W2l, W3h, W3l, W5h, W5l, W6h, W6l,
      W10h, W10l, W11xh, W11xl, W12h, W12l);

  // edge conv 1 (basemat computed in-kernel from W1p packed)
  edge_mfma_kernel<true><<<1024, 256, 0, stream>>>(
      xbh, xbl, idx, pack, W1mh, W1ml, W1ph, W1pl, W1bt, bufA, S1);

  // graph conv 1
  agg_pack_kernel<8><<<4096, 256, 0, stream>>>(bufA, idx, S1, 1.0f / (RN * 16), aggh, aggl);
  gemm_mfma_kernel<0, false, false><<<dim3(64, 1), 256, 0, stream>>>(
      aggh, aggl, W2h, W2l, bufC, nullptr, S2, nullptr, 256, 64);

  // graph conv 2
  agg_pack_kernel<6><<<1024, 256, 0, stream>>>(bufC, idx, S2, 1.0f / RN, aggh, aggl);
  gemm_mfma_kernel<0, false, false><<<dim3(64, 1), 256, 0, stream>>>(
      aggh, aggl, W3h, W3l, x1v, nullptr, S3, nullptr, 64, 64);
  bn_normpack_kernel<<<RN * 64 / 256, 256, 0, stream>>>(x1v, S3, xbh, xbl);

  // edge conv 2 (no pts; basemat in-kernel from W4p packed)
  edge_mfma_kernel<false><<<1024, 256, 0, stream>>>(
      xbh, xbl, idx, pack, W4mh, W4ml, W4ph, W4pl, nullptr, bufA, S4);

  // graph conv 3
  agg_pack_kernel<8><<<4096, 256, 0, stream>>>(bufA, idx, S4, 1.0f / (RN * 16), aggh, aggl);
  gemm_mfma_kernel<0, false, false><<<dim3(64, 1), 256, 0, stream>>>(
      aggh, aggl, W5h, W5l, bufC, nullptr, S5, nullptr, 256, 64);

  // graph conv 4 -> x2v raw (+S6); bn fused into pack_x12
  agg_pack_kernel<6><<<1024, 256, 0, stream>>>(bufC, idx, S5, 1.0f / RN, aggh, aggl);
  gemm_mfma_kernel<0, false, false><<<dim3(64, 1), 256, 0, stream>>>(
      aggh, aggl, W6h, W6l, x2v, nullptr, S6, nullptr, 64, 64);

  // pack [x1|bn(x2)]
  pack_x12_kernel<<<RN * 128 / 256, 256, 0, stream>>>(x1v, x2v, S6, x12h, x12l);

  // W10 path
  gemm_mfma_kernel<0, true, false><<<dim3(64, 16), 256, 0, stream>>>(
      x12h, x12l, W10h, W10l, nullptr, pmax, S7, nullptr, 128, 1024);

  // fused fin_g + gb11
  fing_gb_kernel<<<8, 256, 0, stream>>>(pmax, S7, W11, gb);

  // W11: K=128 MFMA gemm + per-batch g-bias
  gemm_mfma_kernel<0, false, true><<<dim3(64, 8), 256, 0, stream>>>(
      x12h, x12l, W11xh, W11xl, h11, nullptr, S8, gb, 128, 512);
  bn_pack_kernel<<<RN * 512 / 256, 256, 0, stream>>>(h11, S8, h11h, h11l);

  // W12 -> h12 raw (+S9); bn fused into final13
  gemm_mfma_kernel<0, false, false><<<dim3(64, 4), 256, 0, stream>>>(
      h11h, h11l, W12h, W12l, h12, nullptr, S9, nullptr, 512, 256);

  final13_kernel<<<RN / 16, 256, 0, stream>>>(h12, S9, W13, out);
}